// Round 1
// baseline (3300.164 us; speedup 1.0000x reference)
//
#include <hip/hip_runtime.h>
#include <math.h>

#define NEG_SLOPE 0.2f

// ---------------- utility ----------------
__global__ void zero_i32(int* __restrict__ p, int n) {
    int i = blockIdx.x * blockDim.x + threadIdx.x;
    if (i < n) p[i] = 0;
}

// ---------------- CSR build ----------------
__global__ void count_edges(const int* __restrict__ dst, int* __restrict__ cnt, int E) {
    int i = blockIdx.x * blockDim.x + threadIdx.x;
    if (i < E) atomicAdd(&cnt[dst[i]], 1);
}

__global__ void scan_block(const int* __restrict__ cnt, int* __restrict__ rs, int N) {
    __shared__ int s[1024];
    int tid = threadIdx.x;
    int running = 0;
    for (int base = 0; base < N; base += 1024) {
        int v = (base + tid < N) ? cnt[base + tid] : 0;
        __syncthreads();
        s[tid] = v;
        __syncthreads();
        for (int off = 1; off < 1024; off <<= 1) {
            int t = (tid >= off) ? s[tid - off] : 0;
            __syncthreads();
            if (tid >= off) s[tid] += t;
            __syncthreads();
        }
        if (base + tid < N) rs[base + tid] = running + s[tid] - v;
        running += s[1023];
        // next loop iteration has a sync before writing s again
    }
    if (tid == 0) rs[N] = running;
}

__global__ void scatter_edges(const int* __restrict__ dst, const int* __restrict__ rs,
                              int* __restrict__ fill, int* __restrict__ eidx, int E) {
    int i = blockIdx.x * blockDim.x + threadIdx.x;
    if (i < E) {
        int d = dst[i];
        int pos = atomicAdd(&fill[d], 1);
        eidx[rs[d] + pos] = i;
    }
}

__global__ void graph_bounds(const int* __restrict__ nid, int* __restrict__ bounds, int N, int B) {
    int g = blockIdx.x * blockDim.x + threadIdx.x;
    if (g <= B) {
        int lo = 0, hi = N;
        while (lo < hi) { int mid = (lo + hi) >> 1; if (nid[mid] < g) lo = mid + 1; else hi = mid; }
        bounds[g] = lo;
    }
}

// ---------------- GEMM: C(MxN) = A(MxK) @ B(KxN), fp32, 64x64 tile ----------------
__global__ __launch_bounds__(256) void gemm64(const float* __restrict__ A,
                                              const float* __restrict__ Bw,
                                              float* __restrict__ C, int M, int K, int N) {
    __shared__ float As[16][64];
    __shared__ float Bs[16][64];
    int tid = threadIdx.x;
    int tx = tid & 15, ty = tid >> 4;
    int row0 = blockIdx.y << 6, col0 = blockIdx.x << 6;
    float acc[4][4] = {{0.f}};
    for (int k0 = 0; k0 < K; k0 += 16) {
        // A tile: 64 rows x 16 k, float4 along K
        {
            int ar = tid >> 2;
            int ac = (tid & 3) << 2;
            int r = row0 + ar, c = k0 + ac;
            float4 av;
            if (r < M && c + 3 < K) av = *(const float4*)&A[(size_t)r * K + c];
            else {
                av.x = (r < M && c + 0 < K) ? A[(size_t)r * K + c + 0] : 0.f;
                av.y = (r < M && c + 1 < K) ? A[(size_t)r * K + c + 1] : 0.f;
                av.z = (r < M && c + 2 < K) ? A[(size_t)r * K + c + 2] : 0.f;
                av.w = (r < M && c + 3 < K) ? A[(size_t)r * K + c + 3] : 0.f;
            }
            As[ac + 0][ar] = av.x; As[ac + 1][ar] = av.y;
            As[ac + 2][ar] = av.z; As[ac + 3][ar] = av.w;
        }
        // B tile: 16 k x 64 cols, float4 along N
        {
            int bk = tid >> 4;
            int bn = (tid & 15) << 2;
            int r = k0 + bk, c = col0 + bn;
            float4 bv;
            if (r < K && c + 3 < N) bv = *(const float4*)&Bw[(size_t)r * N + c];
            else {
                bv.x = (r < K && c + 0 < N) ? Bw[(size_t)r * N + c + 0] : 0.f;
                bv.y = (r < K && c + 1 < N) ? Bw[(size_t)r * N + c + 1] : 0.f;
                bv.z = (r < K && c + 2 < N) ? Bw[(size_t)r * N + c + 2] : 0.f;
                bv.w = (r < K && c + 3 < N) ? Bw[(size_t)r * N + c + 3] : 0.f;
            }
            *(float4*)&Bs[bk][bn] = bv;
        }
        __syncthreads();
#pragma unroll
        for (int kk = 0; kk < 16; ++kk) {
            float4 a = *(const float4*)&As[kk][ty << 2];
            float4 b = *(const float4*)&Bs[kk][tx << 2];
            acc[0][0] += a.x * b.x; acc[0][1] += a.x * b.y; acc[0][2] += a.x * b.z; acc[0][3] += a.x * b.w;
            acc[1][0] += a.y * b.x; acc[1][1] += a.y * b.y; acc[1][2] += a.y * b.z; acc[1][3] += a.y * b.w;
            acc[2][0] += a.z * b.x; acc[2][1] += a.z * b.y; acc[2][2] += a.z * b.z; acc[2][3] += a.z * b.w;
            acc[3][0] += a.w * b.x; acc[3][1] += a.w * b.y; acc[3][2] += a.w * b.z; acc[3][3] += a.w * b.w;
        }
        __syncthreads();
    }
#pragma unroll
    for (int i = 0; i < 4; ++i) {
        int r = row0 + (ty << 2) + i;
        if (r < M) {
#pragma unroll
            for (int j = 0; j < 4; ++j) {
                int c = col0 + (tx << 2) + j;
                if (c < N) C[(size_t)r * N + c] = acc[i][j];
            }
        }
    }
}

// ---------------- GAT pieces ----------------
// el[n,h] = sum_d h[n,h,d]*al[h,d]; er likewise. One wave per (n,h).
__global__ void gat_elr(const float* __restrict__ h, const float* __restrict__ al,
                        const float* __restrict__ ar, float* __restrict__ el,
                        float* __restrict__ er, int N, int H, int D) {
    int wid = (blockIdx.x * blockDim.x + threadIdx.x) >> 6;
    int lane = threadIdx.x & 63;
    if (wid >= N * H) return;
    int n = wid / H, hh = wid - n * H;
    const float* hp = h + ((size_t)n * H + hh) * D;
    const float* alp = al + (size_t)hh * D;
    const float* arp = ar + (size_t)hh * D;
    float sl = 0.f, sr = 0.f;
    for (int d = lane; d < D; d += 64) {
        float v = hp[d];
        sl += v * alp[d];
        sr += v * arp[d];
    }
    for (int off = 32; off > 0; off >>= 1) {
        sl += __shfl_down(sl, off, 64);
        sr += __shfl_down(sr, off, 64);
    }
    if (lane == 0) { el[wid] = sl; er[wid] = sr; }
}

// One thread per (n,h): 3 passes over in-edges, writes normalized alpha[e*H+h].
__global__ void gat_softmax(const float* __restrict__ el, const float* __restrict__ er,
                            const int* __restrict__ src, const int* __restrict__ rs,
                            const int* __restrict__ eidx, float* __restrict__ alpha,
                            int N, int H) {
    int t = blockIdx.x * blockDim.x + threadIdx.x;
    if (t >= N * H) return;
    int n = t / H, hh = t - n * H;
    int s0 = rs[n], s1 = rs[n + 1];
    if (s0 == s1) return;
    float ern = er[t];
    float mx = -INFINITY;
    for (int j = s0; j < s1; ++j) {
        int e = eidx[j];
        float v = el[src[e] * H + hh] + ern;
        v = (v > 0.f) ? v : NEG_SLOPE * v;
        alpha[(size_t)e * H + hh] = v;
        mx = fmaxf(mx, v);
    }
    float den = 0.f;
    for (int j = s0; j < s1; ++j) {
        int e = eidx[j];
        float ex = expf(alpha[(size_t)e * H + hh] - mx);
        alpha[(size_t)e * H + hh] = ex;
        den += ex;
    }
    float inv = 1.f / den;
    for (int j = s0; j < s1; ++j) {
        int e = eidx[j];
        alpha[(size_t)e * H + hh] *= inv;
    }
}

// out[n, c] = relu( sum_{e in in(n)} alpha[e, c/D] * h[src[e], c] ). Block per node.
__global__ void gat_aggregate(const float* __restrict__ h, const float* __restrict__ alpha,
                              const int* __restrict__ src, const int* __restrict__ rs,
                              const int* __restrict__ eidx, float* __restrict__ out,
                              int N, int H, int D) {
    int n = blockIdx.x;
    int HD = H * D;
    int s0 = rs[n], s1 = rs[n + 1];
    for (int c = threadIdx.x; c < HD; c += blockDim.x) {
        int hh = c / D;
        float acc = 0.f;
        for (int j = s0; j < s1; ++j) {
            int e = eidx[j];
            acc += alpha[(size_t)e * H + hh] * h[(size_t)src[e] * HD + c];
        }
        out[(size_t)n * HD + c] = fmaxf(acc, 0.f);
    }
}

// Graph max-readout: block per graph.
__global__ void seg_max_graph(const float* __restrict__ g, const int* __restrict__ bounds,
                              float* __restrict__ out, int C) {
    int gr = blockIdx.x;
    int n0 = bounds[gr], n1 = bounds[gr + 1];
    for (int c = threadIdx.x; c < C; c += blockDim.x) {
        float m = -INFINITY;
        for (int n = n0; n < n1; ++n) m = fmaxf(m, g[(size_t)n * C + c]);
        out[(size_t)gr * C + c] = m;
    }
}

// ---------------- small dense layers ----------------
// out[b,o] = act( in[b,:] @ W[:,o] + bias[o] ); b = blockIdx.y
__global__ void linear_act(const float* __restrict__ in, const float* __restrict__ W,
                           const float* __restrict__ bias, float* __restrict__ out,
                           int K, int O, int act) {
    int o = blockIdx.x * blockDim.x + threadIdx.x;
    int b = blockIdx.y;
    if (o >= O) return;
    float acc = bias[o];
    const float* ip = in + (size_t)b * K;
    for (int k = 0; k < K; ++k) acc += ip[k] * W[(size_t)k * O + o];
    if (act == 1) acc = fmaxf(acc, 0.f);
    else if (act == 2) acc = 1.f / (1.f + expf(-acc));
    out[(size_t)b * O + o] = acc;
}

// ---------------- TextCNN ----------------
// xT[b,c,l] = pad[b,0,l,c]
__global__ void transpose_pad(const float* __restrict__ pad, float* __restrict__ xT,
                              int B, int L, int C) {
    int idx = blockIdx.x * blockDim.x + threadIdx.x;
    int total = B * L * C;
    if (idx >= total) return;
    int l = idx % L;
    int c = (idx / L) % C;
    int b = idx / (L * C);
    xT[idx] = pad[((size_t)b * L + l) * C + c];
}

// conv1d k=3 VALID, O=128 fixed. grid.x = l-tiles of 64, grid.y = batch.
__global__ __launch_bounds__(256) void conv3k(const float* __restrict__ x,
                                              const float* __restrict__ w,
                                              const float* __restrict__ bias,
                                              float* __restrict__ y,
                                              int Cin, int Lin, int Lout) {
    extern __shared__ float sx[];  // Cin x 66
    int b = blockIdx.y;
    int l0 = blockIdx.x << 6;
    int tid = threadIdx.x;
    int tileL = Lout - l0; if (tileL > 64) tileL = 64;
    int loadL = tileL + 2; { int lim = Lin - l0; if (loadL > lim) loadL = lim; }
    for (int idx = tid; idx < Cin * loadL; idx += 256) {
        int c = idx / loadL, i = idx - c * loadL;
        sx[c * 66 + i] = x[((size_t)b * Cin + c) * Lin + l0 + i];
    }
    __syncthreads();
    int o = tid & 127;
    int pbase = (tid >> 7) << 5;  // 0 or 32
    int npos = tileL - pbase; if (npos > 32) npos = 32; if (npos < 0) npos = 0;
    float acc[32];
    float bv = bias[o];
#pragma unroll
    for (int j = 0; j < 32; ++j) acc[j] = bv;
    const float* wp = w + (size_t)o * Cin * 3;
    for (int c = 0; c < Cin; ++c) {
        float xv[34];
#pragma unroll
        for (int i = 0; i < 34; ++i) xv[i] = sx[c * 66 + pbase + i];
        float w0 = wp[c * 3 + 0], w1 = wp[c * 3 + 1], w2 = wp[c * 3 + 2];
#pragma unroll
        for (int j = 0; j < 32; ++j) acc[j] += w0 * xv[j] + w1 * xv[j + 1] + w2 * xv[j + 2];
    }
    float* yp = y + ((size_t)b * 128 + o) * Lout + l0 + pbase;
#pragma unroll
    for (int j = 0; j < 32; ++j)
        if (j < npos) yp[j] = acc[j];
}

__global__ void maxpool(const float* __restrict__ y, float* __restrict__ p,
                        int BC, int Lin, int k, int s, int Lout) {
    int idx = blockIdx.x * blockDim.x + threadIdx.x;
    if (idx >= BC * Lout) return;
    int lo = idx % Lout, bc = idx / Lout;
    const float* yp = y + (size_t)bc * Lin + lo * s;
    float m = -INFINITY;
    for (int i = 0; i < k; ++i) m = fmaxf(m, yp[i]);
    p[idx] = m;
}

// cat[b, off + c] = (1-w)*g[b,c] + w*s[b,c],  w = sigmoid(w1)
__global__ void combine_branch(const float* __restrict__ g, const float* __restrict__ s,
                               const float* __restrict__ w1, float* __restrict__ cat, int off) {
    int idx = blockIdx.x * blockDim.x + threadIdx.x;
    if (idx >= 16 * 128) return;
    int b = idx >> 7, c = idx & 127;
    float w = 1.f / (1.f + expf(-w1[0]));
    cat[b * 256 + off + c] = (1.f - w) * g[idx] + w * s[idx];
}

// ---------------- host ----------------
extern "C" void kernel_launch(void* const* d_in, const int* in_sizes, int n_in,
                              void* d_out, int out_size, void* d_ws, size_t ws_size,
                              hipStream_t stream) {
    const float* feat[2] = {(const float*)d_in[0], (const float*)d_in[1]};
    const float* pad[2]  = {(const float*)d_in[2], (const float*)d_in[3]};
    const int* src[2]    = {(const int*)d_in[4], (const int*)d_in[6]};
    const int* dst[2]    = {(const int*)d_in[5], (const int*)d_in[7]};
    const int* nid[2]    = {(const int*)d_in[8], (const int*)d_in[9]};
    const float* Wg[3]   = {(const float*)d_in[11], (const float*)d_in[14], (const float*)d_in[17]};
    const float* al[3]   = {(const float*)d_in[12], (const float*)d_in[15], (const float*)d_in[18]};
    const float* ar[3]   = {(const float*)d_in[13], (const float*)d_in[16], (const float*)d_in[19]};
    const float* fcg_w = (const float*)d_in[20]; const float* fcg_b = (const float*)d_in[21];
    const float* c1w = (const float*)d_in[22];   const float* c1b = (const float*)d_in[23];
    const float* c2w = (const float*)d_in[24];   const float* c2b = (const float*)d_in[25];
    const float* c3w = (const float*)d_in[26];   const float* c3b = (const float*)d_in[27];
    const float* tf_w = (const float*)d_in[28];  const float* tf_b = (const float*)d_in[29];
    const float* w1 = (const float*)d_in[30];
    const float* fc1_w = (const float*)d_in[31]; const float* fc1_b = (const float*)d_in[32];
    const float* fc2_w = (const float*)d_in[33]; const float* fc2_b = (const float*)d_in[34];
    const float* outw = (const float*)d_in[35];  const float* outb = (const float*)d_in[36];
    float* out = (float*)d_out;

    const int N = in_sizes[0] / 64;   // 8000
    const int E = in_sizes[4];        // 160000
    const int B = 16, L = 1200;

    char* wsb = (char*)d_ws;
    size_t off = 0;
    auto alloc = [&](size_t elems) -> void* {
        void* p = wsb + off;
        off += (elems * 4 + 255) & ~(size_t)255;
        return p;
    };
    float* h_buf = (float*)alloc((size_t)N * 576);
    float* gA    = (float*)alloc((size_t)N * 576);
    float* gB    = (float*)alloc((size_t)N * 576);
    float* el    = (float*)alloc((size_t)N * 3);
    float* er    = (float*)alloc((size_t)N * 3);
    float* alpha = (float*)alloc((size_t)E * 3);
    int* rs      = (int*)alloc(N + 1);
    int* cnt     = (int*)alloc(N);
    int* eidx    = (int*)alloc(E);
    int* bounds  = (int*)alloc(B + 1);
    float* gmax  = (float*)alloc((size_t)B * 576);
    float* gvec  = (float*)alloc((size_t)B * 128);
    float* xT    = (float*)alloc((size_t)B * 64 * L);
    float* y1    = (float*)alloc((size_t)B * 128 * 1198);
    float* p1    = (float*)alloc((size_t)B * 128 * 399);
    float* y2    = (float*)alloc((size_t)B * 128 * 397);
    float* p2    = (float*)alloc((size_t)B * 128 * 132);
    float* y3    = (float*)alloc((size_t)B * 128 * 130);
    float* sp    = (float*)alloc((size_t)B * 128);
    float* sf    = (float*)alloc((size_t)B * 128);
    float* cat   = (float*)alloc((size_t)B * 256);
    float* f1    = (float*)alloc((size_t)B * 512);
    float* f2    = (float*)alloc((size_t)B * 256);
    (void)ws_size; (void)n_in; (void)out_size;

    for (int br = 0; br < 2; ++br) {
        // --- CSR by dst ---
        zero_i32<<<(N + 255) / 256, 256, 0, stream>>>(cnt, N);
        count_edges<<<(E + 255) / 256, 256, 0, stream>>>(dst[br], cnt, E);
        scan_block<<<1, 1024, 0, stream>>>(cnt, rs, N);
        zero_i32<<<(N + 255) / 256, 256, 0, stream>>>(cnt, N);
        scatter_edges<<<(E + 255) / 256, 256, 0, stream>>>(dst[br], rs, cnt, eidx, E);
        graph_bounds<<<1, 64, 0, stream>>>(nid[br], bounds, N, B);

        // --- 3 GAT layers ---
        const int dims[3][3] = {{64, 3, 64}, {192, 3, 192}, {576, 1, 576}};  // K,H,D
        float* outs[3] = {gA, gB, gA};
        const float* in_ptr = feat[br];
        for (int ly = 0; ly < 3; ++ly) {
            int K = dims[ly][0], H = dims[ly][1], D = dims[ly][2];
            int HD = H * D;
            gemm64<<<dim3(HD / 64, (N + 63) / 64), 256, 0, stream>>>(in_ptr, Wg[ly], h_buf, N, K, HD);
            int waves = N * H;
            gat_elr<<<((size_t)waves * 64 + 255) / 256, 256, 0, stream>>>(h_buf, al[ly], ar[ly], el, er, N, H, D);
            gat_softmax<<<(N * H + 255) / 256, 256, 0, stream>>>(el, er, src[br], rs, eidx, alpha, N, H);
            gat_aggregate<<<N, 256, 0, stream>>>(h_buf, alpha, src[br], rs, eidx, outs[ly], N, H, D);
            in_ptr = outs[ly];
        }
        seg_max_graph<<<B, 256, 0, stream>>>(gA, bounds, gmax, 576);
        linear_act<<<dim3(1, B), 256, 0, stream>>>(gmax, fcg_w, fcg_b, gvec, 576, 128, 1);

        // --- TextCNN ---
        transpose_pad<<<((B * 64 * L) + 255) / 256, 256, 0, stream>>>(pad[br], xT, B, L, 64);
        conv3k<<<dim3(19, B), 256, 64 * 66 * 4, stream>>>(xT, c1w, c1b, y1, 64, 1200, 1198);
        maxpool<<<(B * 128 * 399 + 255) / 256, 256, 0, stream>>>(y1, p1, B * 128, 1198, 3, 3, 399);
        conv3k<<<dim3(7, B), 256, 128 * 66 * 4, stream>>>(p1, c2w, c2b, y2, 128, 399, 397);
        maxpool<<<(B * 128 * 132 + 255) / 256, 256, 0, stream>>>(y2, p2, B * 128, 397, 3, 3, 132);
        conv3k<<<dim3(3, B), 256, 128 * 66 * 4, stream>>>(p2, c3w, c3b, y3, 128, 132, 130);
        maxpool<<<(B * 128 + 255) / 256, 256, 0, stream>>>(y3, sp, B * 128, 130, 130, 1, 1);
        linear_act<<<dim3(1, B), 256, 0, stream>>>(sp, tf_w, tf_b, sf, 128, 128, 1);

        combine_branch<<<(B * 128 + 255) / 256, 256, 0, stream>>>(gvec, sf, w1, cat, br * 128);
    }

    // --- head MLP ---
    linear_act<<<dim3(2, B), 256, 0, stream>>>(cat, fc1_w, fc1_b, f1, 256, 512, 1);
    linear_act<<<dim3(1, B), 256, 0, stream>>>(f1, fc2_w, fc2_b, f2, 512, 256, 1);
    linear_act<<<dim3(1, B), 256, 0, stream>>>(f2, outw, outb, out, 256, 1, 2);
}

// Round 2
// 2600.948 us; speedup vs baseline: 1.2688x; 1.2688x over previous
//
#include <hip/hip_runtime.h>
#include <math.h>

#define NEG_SLOPE 0.2f

// ---------------- utility ----------------
__global__ void zero_i32(int* __restrict__ p, int n) {
    int i = blockIdx.x * blockDim.x + threadIdx.x;
    if (i < n) p[i] = 0;
}

// ---------------- CSR build ----------------
__global__ void count_edges(const int* __restrict__ dst, int* __restrict__ cnt, int E) {
    int i = blockIdx.x * blockDim.x + threadIdx.x;
    if (i < E) atomicAdd(&cnt[dst[i]], 1);
}

__global__ void scan_block(const int* __restrict__ cnt, int* __restrict__ rs, int N) {
    __shared__ int s[1024];
    int tid = threadIdx.x;
    int running = 0;
    for (int base = 0; base < N; base += 1024) {
        int v = (base + tid < N) ? cnt[base + tid] : 0;
        __syncthreads();
        s[tid] = v;
        __syncthreads();
        for (int off = 1; off < 1024; off <<= 1) {
            int t = (tid >= off) ? s[tid - off] : 0;
            __syncthreads();
            if (tid >= off) s[tid] += t;
            __syncthreads();
        }
        if (base + tid < N) rs[base + tid] = running + s[tid] - v;
        running += s[1023];
    }
    if (tid == 0) rs[N] = running;
}

__global__ void scatter_edges(const int* __restrict__ dst, const int* __restrict__ rs,
                              int* __restrict__ fill, int* __restrict__ eidx, int E) {
    int i = blockIdx.x * blockDim.x + threadIdx.x;
    if (i < E) {
        int d = dst[i];
        int pos = atomicAdd(&fill[d], 1);
        eidx[rs[d] + pos] = i;
    }
}

// ---------------- GEMM: C(MxN) = A(MxK) @ B(KxN), fp32, 64x64 tile ----------------
__global__ __launch_bounds__(256) void gemm64(const float* __restrict__ A,
                                              const float* __restrict__ Bw,
                                              float* __restrict__ C, int M, int K, int N) {
    __shared__ float As[16][64];
    __shared__ float Bs[16][64];
    int tid = threadIdx.x;
    int tx = tid & 15, ty = tid >> 4;
    int row0 = blockIdx.y << 6, col0 = blockIdx.x << 6;
    float acc[4][4] = {{0.f}};
    for (int k0 = 0; k0 < K; k0 += 16) {
        {
            int ar = tid >> 2;
            int ac = (tid & 3) << 2;
            int r = row0 + ar, c = k0 + ac;
            float4 av;
            if (r < M && c + 3 < K) av = *(const float4*)&A[(size_t)r * K + c];
            else {
                av.x = (r < M && c + 0 < K) ? A[(size_t)r * K + c + 0] : 0.f;
                av.y = (r < M && c + 1 < K) ? A[(size_t)r * K + c + 1] : 0.f;
                av.z = (r < M && c + 2 < K) ? A[(size_t)r * K + c + 2] : 0.f;
                av.w = (r < M && c + 3 < K) ? A[(size_t)r * K + c + 3] : 0.f;
            }
            As[ac + 0][ar] = av.x; As[ac + 1][ar] = av.y;
            As[ac + 2][ar] = av.z; As[ac + 3][ar] = av.w;
        }
        {
            int bk = tid >> 4;
            int bn = (tid & 15) << 2;
            int r = k0 + bk, c = col0 + bn;
            float4 bv;
            if (r < K && c + 3 < N) bv = *(const float4*)&Bw[(size_t)r * N + c];
            else {
                bv.x = (r < K && c + 0 < N) ? Bw[(size_t)r * N + c + 0] : 0.f;
                bv.y = (r < K && c + 1 < N) ? Bw[(size_t)r * N + c + 1] : 0.f;
                bv.z = (r < K && c + 2 < N) ? Bw[(size_t)r * N + c + 2] : 0.f;
                bv.w = (r < K && c + 3 < N) ? Bw[(size_t)r * N + c + 3] : 0.f;
            }
            *(float4*)&Bs[bk][bn] = bv;
        }
        __syncthreads();
#pragma unroll
        for (int kk = 0; kk < 16; ++kk) {
            float4 a = *(const float4*)&As[kk][ty << 2];
            float4 b = *(const float4*)&Bs[kk][tx << 2];
            acc[0][0] += a.x * b.x; acc[0][1] += a.x * b.y; acc[0][2] += a.x * b.z; acc[0][3] += a.x * b.w;
            acc[1][0] += a.y * b.x; acc[1][1] += a.y * b.y; acc[1][2] += a.y * b.z; acc[1][3] += a.y * b.w;
            acc[2][0] += a.z * b.x; acc[2][1] += a.z * b.y; acc[2][2] += a.z * b.z; acc[2][3] += a.z * b.w;
            acc[3][0] += a.w * b.x; acc[3][1] += a.w * b.y; acc[3][2] += a.w * b.z; acc[3][3] += a.w * b.w;
        }
        __syncthreads();
    }
#pragma unroll
    for (int i = 0; i < 4; ++i) {
        int r = row0 + (ty << 2) + i;
        if (r < M) {
#pragma unroll
            for (int j = 0; j < 4; ++j) {
                int c = col0 + (tx << 2) + j;
                if (c < N) C[(size_t)r * N + c] = acc[i][j];
            }
        }
    }
}

// ---------------- GAT pieces ----------------
__global__ void gat_elr(const float* __restrict__ h, const float* __restrict__ al,
                        const float* __restrict__ ar, float* __restrict__ el,
                        float* __restrict__ er, int N, int H, int D) {
    int wid = (blockIdx.x * blockDim.x + threadIdx.x) >> 6;
    int lane = threadIdx.x & 63;
    if (wid >= N * H) return;
    int n = wid / H, hh = wid - n * H;
    const float* hp = h + ((size_t)n * H + hh) * D;
    const float* alp = al + (size_t)hh * D;
    const float* arp = ar + (size_t)hh * D;
    float sl = 0.f, sr = 0.f;
    for (int d = lane; d < D; d += 64) {
        float v = hp[d];
        sl += v * alp[d];
        sr += v * arp[d];
    }
    for (int off = 32; off > 0; off >>= 1) {
        sl += __shfl_down(sl, off, 64);
        sr += __shfl_down(sr, off, 64);
    }
    if (lane == 0) { el[wid] = sl; er[wid] = sr; }
}

__global__ void gat_softmax(const float* __restrict__ el, const float* __restrict__ er,
                            const int* __restrict__ src, const int* __restrict__ rs,
                            const int* __restrict__ eidx, float* __restrict__ alpha,
                            int N, int H) {
    int t = blockIdx.x * blockDim.x + threadIdx.x;
    if (t >= N * H) return;
    int n = t / H, hh = t - n * H;
    int s0 = rs[n], s1 = rs[n + 1];
    if (s0 == s1) return;
    float ern = er[t];
    float mx = -INFINITY;
    for (int j = s0; j < s1; ++j) {
        int e = eidx[j];
        float v = el[src[e] * H + hh] + ern;
        v = (v > 0.f) ? v : NEG_SLOPE * v;
        alpha[(size_t)e * H + hh] = v;
        mx = fmaxf(mx, v);
    }
    float den = 0.f;
    for (int j = s0; j < s1; ++j) {
        int e = eidx[j];
        float ex = expf(alpha[(size_t)e * H + hh] - mx);
        alpha[(size_t)e * H + hh] = ex;
        den += ex;
    }
    float inv = 1.f / den;
    for (int j = s0; j < s1; ++j) {
        int e = eidx[j];
        alpha[(size_t)e * H + hh] *= inv;
    }
}

__global__ void gat_aggregate(const float* __restrict__ h, const float* __restrict__ alpha,
                              const int* __restrict__ src, const int* __restrict__ rs,
                              const int* __restrict__ eidx, float* __restrict__ out,
                              int N, int H, int D) {
    int n = blockIdx.x;
    int HD = H * D;
    int s0 = rs[n], s1 = rs[n + 1];
    for (int c = threadIdx.x; c < HD; c += blockDim.x) {
        int hh = c / D;
        float acc = 0.f;
        for (int j = s0; j < s1; ++j) {
            int e = eidx[j];
            acc += alpha[(size_t)e * H + hh] * h[(size_t)src[e] * HD + c];
        }
        out[(size_t)n * HD + c] = fmaxf(acc, 0.f);
    }
}

// Graph max-readout over post-ReLU (>=0) values: running max per nid-segment
// within a 32-node chunk, flushed via int-bitcast atomicMax (order-preserving
// for non-negative floats). out must be zeroed first (0 == float 0.0 is a
// valid floor because inputs are post-ReLU and all graphs are non-empty).
__global__ void seg_max_atomic(const float* __restrict__ g, const int* __restrict__ nid,
                               int* __restrict__ out, int N, int C) {
    int n0 = blockIdx.x << 5;
    int n1 = n0 + 32; if (n1 > N) n1 = N;
    if (n0 >= N) return;
    for (int c = threadIdx.x; c < C; c += blockDim.x) {
        int cur = nid[n0];
        float m = 0.f;
        for (int n = n0; n < n1; ++n) {
            int gid = nid[n];
            if (gid != cur) {
                atomicMax(&out[cur * C + c], __float_as_int(m));
                cur = gid; m = 0.f;
            }
            m = fmaxf(m, g[(size_t)n * C + c]);
        }
        atomicMax(&out[cur * C + c], __float_as_int(m));
    }
}

// ---------------- small dense layers ----------------
__global__ void linear_act(const float* __restrict__ in, const float* __restrict__ W,
                           const float* __restrict__ bias, float* __restrict__ out,
                           int K, int O, int act) {
    int o = blockIdx.x * blockDim.x + threadIdx.x;
    int b = blockIdx.y;
    if (o >= O) return;
    float acc = bias[o];
    const float* ip = in + (size_t)b * K;
    for (int k = 0; k < K; ++k) acc += ip[k] * W[(size_t)k * O + o];
    if (act == 1) acc = fmaxf(acc, 0.f);
    else if (act == 2) acc = 1.f / (1.f + expf(-acc));
    out[(size_t)b * O + o] = acc;
}

// ---------------- TextCNN ----------------
__global__ void transpose_pad(const float* __restrict__ pad, float* __restrict__ xT,
                              int B, int L, int C) {
    int idx = blockIdx.x * blockDim.x + threadIdx.x;
    int total = B * L * C;
    if (idx >= total) return;
    int l = idx % L;
    int c = (idx / L) % C;
    int b = idx / (L * C);
    xT[idx] = pad[((size_t)b * L + l) * C + c];
}

__global__ __launch_bounds__(256) void conv3k(const float* __restrict__ x,
                                              const float* __restrict__ w,
                                              const float* __restrict__ bias,
                                              float* __restrict__ y,
                                              int Cin, int Lin, int Lout) {
    extern __shared__ float sx[];  // Cin x 66
    int b = blockIdx.y;
    int l0 = blockIdx.x << 6;
    int tid = threadIdx.x;
    int tileL = Lout - l0; if (tileL > 64) tileL = 64;
    int loadL = tileL + 2; { int lim = Lin - l0; if (loadL > lim) loadL = lim; }
    for (int idx = tid; idx < Cin * loadL; idx += 256) {
        int c = idx / loadL, i = idx - c * loadL;
        sx[c * 66 + i] = x[((size_t)b * Cin + c) * Lin + l0 + i];
    }
    __syncthreads();
    int o = tid & 127;
    int pbase = (tid >> 7) << 5;  // 0 or 32
    int npos = tileL - pbase; if (npos > 32) npos = 32; if (npos < 0) npos = 0;
    float acc[32];
    float bv = bias[o];
#pragma unroll
    for (int j = 0; j < 32; ++j) acc[j] = bv;
    const float* wp = w + (size_t)o * Cin * 3;
    for (int c = 0; c < Cin; ++c) {
        float xv[34];
#pragma unroll
        for (int i = 0; i < 34; ++i) xv[i] = sx[c * 66 + pbase + i];
        float w0 = wp[c * 3 + 0], w1 = wp[c * 3 + 1], w2 = wp[c * 3 + 2];
#pragma unroll
        for (int j = 0; j < 32; ++j) acc[j] += w0 * xv[j] + w1 * xv[j + 1] + w2 * xv[j + 2];
    }
    float* yp = y + ((size_t)b * 128 + o) * Lout + l0 + pbase;
#pragma unroll
    for (int j = 0; j < 32; ++j)
        if (j < npos) yp[j] = acc[j];
}

__global__ void maxpool(const float* __restrict__ y, float* __restrict__ p,
                        int BC, int Lin, int k, int s, int Lout) {
    int idx = blockIdx.x * blockDim.x + threadIdx.x;
    if (idx >= BC * Lout) return;
    int lo = idx % Lout, bc = idx / Lout;
    const float* yp = y + (size_t)bc * Lin + lo * s;
    float m = -INFINITY;
    for (int i = 0; i < k; ++i) m = fmaxf(m, yp[i]);
    p[idx] = m;
}

__global__ void combine_branch(const float* __restrict__ g, const float* __restrict__ s,
                               const float* __restrict__ w1, float* __restrict__ cat, int off) {
    int idx = blockIdx.x * blockDim.x + threadIdx.x;
    if (idx >= 16 * 128) return;
    int b = idx >> 7, c = idx & 127;
    float w = 1.f / (1.f + expf(-w1[0]));
    cat[b * 256 + off + c] = (1.f - w) * g[idx] + w * s[idx];
}

// ---------------- host ----------------
extern "C" void kernel_launch(void* const* d_in, const int* in_sizes, int n_in,
                              void* d_out, int out_size, void* d_ws, size_t ws_size,
                              hipStream_t stream) {
    const float* feat[2] = {(const float*)d_in[0], (const float*)d_in[1]};
    const float* pad[2]  = {(const float*)d_in[2], (const float*)d_in[3]};
    const int* src[2]    = {(const int*)d_in[4], (const int*)d_in[6]};
    const int* dst[2]    = {(const int*)d_in[5], (const int*)d_in[7]};
    const int* nid[2]    = {(const int*)d_in[8], (const int*)d_in[9]};
    const float* Wg[3]   = {(const float*)d_in[11], (const float*)d_in[14], (const float*)d_in[17]};
    const float* al[3]   = {(const float*)d_in[12], (const float*)d_in[15], (const float*)d_in[18]};
    const float* ar[3]   = {(const float*)d_in[13], (const float*)d_in[16], (const float*)d_in[19]};
    const float* fcg_w = (const float*)d_in[20]; const float* fcg_b = (const float*)d_in[21];
    const float* c1w = (const float*)d_in[22];   const float* c1b = (const float*)d_in[23];
    const float* c2w = (const float*)d_in[24];   const float* c2b = (const float*)d_in[25];
    const float* c3w = (const float*)d_in[26];   const float* c3b = (const float*)d_in[27];
    const float* tf_w = (const float*)d_in[28];  const float* tf_b = (const float*)d_in[29];
    const float* w1 = (const float*)d_in[30];
    const float* fc1_w = (const float*)d_in[31]; const float* fc1_b = (const float*)d_in[32];
    const float* fc2_w = (const float*)d_in[33]; const float* fc2_b = (const float*)d_in[34];
    const float* outw = (const float*)d_in[35];  const float* outb = (const float*)d_in[36];
    float* out = (float*)d_out;

    const int N = in_sizes[0] / 64;   // 8000
    const int E = in_sizes[4];        // 160000
    const int B = 16, L = 1200;

    char* wsb = (char*)d_ws;
    size_t off = 0;
    auto alloc = [&](size_t elems) -> void* {
        void* p = wsb + off;
        off += (elems * 4 + 255) & ~(size_t)255;
        return p;
    };
    float* h_buf = (float*)alloc((size_t)N * 576);
    float* gA    = (float*)alloc((size_t)N * 576);
    float* gB    = (float*)alloc((size_t)N * 576);
    float* el    = (float*)alloc((size_t)N * 3);
    float* er    = (float*)alloc((size_t)N * 3);
    float* alpha = (float*)alloc((size_t)E * 3);
    int* rs      = (int*)alloc(N + 1);
    int* cnt     = (int*)alloc(N);
    int* eidx    = (int*)alloc(E);
    int* gmax    = (int*)alloc((size_t)B * 576);   // float bits via atomicMax
    float* gvec  = (float*)alloc((size_t)B * 128);
    float* xT    = (float*)alloc((size_t)B * 64 * L);
    float* y1    = (float*)alloc((size_t)B * 128 * 1198);
    float* p1    = (float*)alloc((size_t)B * 128 * 399);
    float* y2    = (float*)alloc((size_t)B * 128 * 397);
    float* p2    = (float*)alloc((size_t)B * 128 * 132);
    float* y3    = (float*)alloc((size_t)B * 128 * 130);
    float* sp    = (float*)alloc((size_t)B * 128);
    float* sf    = (float*)alloc((size_t)B * 128);
    float* cat   = (float*)alloc((size_t)B * 256);
    float* f1    = (float*)alloc((size_t)B * 512);
    float* f2    = (float*)alloc((size_t)B * 256);
    (void)ws_size; (void)n_in; (void)out_size;

    for (int br = 0; br < 2; ++br) {
        // --- CSR by dst ---
        zero_i32<<<(N + 255) / 256, 256, 0, stream>>>(cnt, N);
        count_edges<<<(E + 255) / 256, 256, 0, stream>>>(dst[br], cnt, E);
        scan_block<<<1, 1024, 0, stream>>>(cnt, rs, N);
        zero_i32<<<(N + 255) / 256, 256, 0, stream>>>(cnt, N);
        scatter_edges<<<(E + 255) / 256, 256, 0, stream>>>(dst[br], rs, cnt, eidx, E);

        // --- 3 GAT layers ---
        const int dims[3][3] = {{64, 3, 64}, {192, 3, 192}, {576, 1, 576}};  // K,H,D
        float* outs[3] = {gA, gB, gA};
        const float* in_ptr = feat[br];
        for (int ly = 0; ly < 3; ++ly) {
            int K = dims[ly][0], H = dims[ly][1], D = dims[ly][2];
            int HD = H * D;
            gemm64<<<dim3(HD / 64, (N + 63) / 64), 256, 0, stream>>>(in_ptr, Wg[ly], h_buf, N, K, HD);
            int waves = N * H;
            gat_elr<<<((size_t)waves * 64 + 255) / 256, 256, 0, stream>>>(h_buf, al[ly], ar[ly], el, er, N, H, D);
            gat_softmax<<<(N * H + 255) / 256, 256, 0, stream>>>(el, er, src[br], rs, eidx, alpha, N, H);
            gat_aggregate<<<N, 256, 0, stream>>>(h_buf, alpha, src[br], rs, eidx, outs[ly], N, H, D);
            in_ptr = outs[ly];
        }
        zero_i32<<<(B * 576 + 255) / 256, 256, 0, stream>>>(gmax, B * 576);
        seg_max_atomic<<<(N + 31) / 32, 256, 0, stream>>>(gA, nid[br], gmax, N, 576);
        linear_act<<<dim3(1, B), 256, 0, stream>>>((const float*)gmax, fcg_w, fcg_b, gvec, 576, 128, 1);

        // --- TextCNN ---
        transpose_pad<<<((B * 64 * L) + 255) / 256, 256, 0, stream>>>(pad[br], xT, B, L, 64);
        conv3k<<<dim3(19, B), 256, 64 * 66 * 4, stream>>>(xT, c1w, c1b, y1, 64, 1200, 1198);
        maxpool<<<(B * 128 * 399 + 255) / 256, 256, 0, stream>>>(y1, p1, B * 128, 1198, 3, 3, 399);
        conv3k<<<dim3(7, B), 256, 128 * 66 * 4, stream>>>(p1, c2w, c2b, y2, 128, 399, 397);
        maxpool<<<(B * 128 * 132 + 255) / 256, 256, 0, stream>>>(y2, p2, B * 128, 397, 3, 3, 132);
        conv3k<<<dim3(3, B), 256, 128 * 66 * 4, stream>>>(p2, c3w, c3b, y3, 128, 132, 130);
        maxpool<<<(B * 128 + 255) / 256, 256, 0, stream>>>(y3, sp, B * 128, 130, 130, 1, 1);
        linear_act<<<dim3(1, B), 256, 0, stream>>>(sp, tf_w, tf_b, sf, 128, 128, 1);

        combine_branch<<<(B * 128 + 255) / 256, 256, 0, stream>>>(gvec, sf, w1, cat, br * 128);
    }

    // --- head MLP ---
    linear_act<<<dim3(2, B), 256, 0, stream>>>(cat, fc1_w, fc1_b, f1, 256, 512, 1);
    linear_act<<<dim3(1, B), 256, 0, stream>>>(f1, fc2_w, fc2_b, f2, 512, 256, 1);
    linear_act<<<dim3(1, B), 256, 0, stream>>>(f2, outw, outb, out, 256, 1, 2);
}

// Round 3
// 2109.713 us; speedup vs baseline: 1.5643x; 1.2328x over previous
//
#include <hip/hip_runtime.h>
#include <math.h>

#define NEG_SLOPE 0.2f

// ---------------- utility ----------------
__global__ void zero_i32(int* __restrict__ p, int n) {
    int i = blockIdx.x * blockDim.x + threadIdx.x;
    if (i < n) p[i] = 0;
}

// ---------------- CSR build ----------------
__global__ void count_edges(const int* __restrict__ dst, int* __restrict__ cnt, int E) {
    int i = blockIdx.x * blockDim.x + threadIdx.x;
    if (i < E) atomicAdd(&cnt[dst[i]], 1);
}

__global__ void scan_block(const int* __restrict__ cnt, int* __restrict__ rs, int N) {
    __shared__ int s[1024];
    int tid = threadIdx.x;
    int running = 0;
    for (int base = 0; base < N; base += 1024) {
        int v = (base + tid < N) ? cnt[base + tid] : 0;
        __syncthreads();
        s[tid] = v;
        __syncthreads();
        for (int off = 1; off < 1024; off <<= 1) {
            int t = (tid >= off) ? s[tid - off] : 0;
            __syncthreads();
            if (tid >= off) s[tid] += t;
            __syncthreads();
        }
        if (base + tid < N) rs[base + tid] = running + s[tid] - v;
        running += s[1023];
    }
    if (tid == 0) rs[N] = running;
}

__global__ void scatter_edges(const int* __restrict__ dst, const int* __restrict__ rs,
                              int* __restrict__ fill, int* __restrict__ eidx, int E) {
    int i = blockIdx.x * blockDim.x + threadIdx.x;
    if (i < E) {
        int d = dst[i];
        int pos = atomicAdd(&fill[d], 1);
        eidx[rs[d] + pos] = i;
    }
}

// ---------------- GEMM: C(MxN) = A(MxK) @ B(KxN), fp32, 64x64 tile ----------------
__global__ __launch_bounds__(256) void gemm64(const float* __restrict__ A,
                                              const float* __restrict__ Bw,
                                              float* __restrict__ C, int M, int K, int N) {
    __shared__ float As[16][64];
    __shared__ float Bs[16][64];
    int tid = threadIdx.x;
    int tx = tid & 15, ty = tid >> 4;
    int row0 = blockIdx.y << 6, col0 = blockIdx.x << 6;
    float acc[4][4] = {{0.f}};
    for (int k0 = 0; k0 < K; k0 += 16) {
        {
            int ar = tid >> 2;
            int ac = (tid & 3) << 2;
            int r = row0 + ar, c = k0 + ac;
            float4 av;
            if (r < M && c + 3 < K) av = *(const float4*)&A[(size_t)r * K + c];
            else {
                av.x = (r < M && c + 0 < K) ? A[(size_t)r * K + c + 0] : 0.f;
                av.y = (r < M && c + 1 < K) ? A[(size_t)r * K + c + 1] : 0.f;
                av.z = (r < M && c + 2 < K) ? A[(size_t)r * K + c + 2] : 0.f;
                av.w = (r < M && c + 3 < K) ? A[(size_t)r * K + c + 3] : 0.f;
            }
            As[ac + 0][ar] = av.x; As[ac + 1][ar] = av.y;
            As[ac + 2][ar] = av.z; As[ac + 3][ar] = av.w;
        }
        {
            int bk = tid >> 4;
            int bn = (tid & 15) << 2;
            int r = k0 + bk, c = col0 + bn;
            float4 bv;
            if (r < K && c + 3 < N) bv = *(const float4*)&Bw[(size_t)r * N + c];
            else {
                bv.x = (r < K && c + 0 < N) ? Bw[(size_t)r * N + c + 0] : 0.f;
                bv.y = (r < K && c + 1 < N) ? Bw[(size_t)r * N + c + 1] : 0.f;
                bv.z = (r < K && c + 2 < N) ? Bw[(size_t)r * N + c + 2] : 0.f;
                bv.w = (r < K && c + 3 < N) ? Bw[(size_t)r * N + c + 3] : 0.f;
            }
            *(float4*)&Bs[bk][bn] = bv;
        }
        __syncthreads();
#pragma unroll
        for (int kk = 0; kk < 16; ++kk) {
            float4 a = *(const float4*)&As[kk][ty << 2];
            float4 b = *(const float4*)&Bs[kk][tx << 2];
            acc[0][0] += a.x * b.x; acc[0][1] += a.x * b.y; acc[0][2] += a.x * b.z; acc[0][3] += a.x * b.w;
            acc[1][0] += a.y * b.x; acc[1][1] += a.y * b.y; acc[1][2] += a.y * b.z; acc[1][3] += a.y * b.w;
            acc[2][0] += a.z * b.x; acc[2][1] += a.z * b.y; acc[2][2] += a.z * b.z; acc[2][3] += a.z * b.w;
            acc[3][0] += a.w * b.x; acc[3][1] += a.w * b.y; acc[3][2] += a.w * b.z; acc[3][3] += a.w * b.w;
        }
        __syncthreads();
    }
#pragma unroll
    for (int i = 0; i < 4; ++i) {
        int r = row0 + (ty << 2) + i;
        if (r < M) {
#pragma unroll
            for (int j = 0; j < 4; ++j) {
                int c = col0 + (tx << 2) + j;
                if (c < N) C[(size_t)r * N + c] = acc[i][j];
            }
        }
    }
}

// ---------------- GAT pieces ----------------
__global__ void gat_elr(const float* __restrict__ h, const float* __restrict__ al,
                        const float* __restrict__ ar, float* __restrict__ el,
                        float* __restrict__ er, int N, int H, int D) {
    int wid = (blockIdx.x * blockDim.x + threadIdx.x) >> 6;
    int lane = threadIdx.x & 63;
    if (wid >= N * H) return;
    int n = wid / H, hh = wid - n * H;
    const float* hp = h + ((size_t)n * H + hh) * D;
    const float* alp = al + (size_t)hh * D;
    const float* arp = ar + (size_t)hh * D;
    float sl = 0.f, sr = 0.f;
    for (int d = lane; d < D; d += 64) {
        float v = hp[d];
        sl += v * alp[d];
        sr += v * arp[d];
    }
    for (int off = 32; off > 0; off >>= 1) {
        sl += __shfl_down(sl, off, 64);
        sr += __shfl_down(sr, off, 64);
    }
    if (lane == 0) { el[wid] = sl; er[wid] = sr; }
}

__global__ void gat_softmax(const float* __restrict__ el, const float* __restrict__ er,
                            const int* __restrict__ src, const int* __restrict__ rs,
                            const int* __restrict__ eidx, float* __restrict__ alpha,
                            int N, int H) {
    int t = blockIdx.x * blockDim.x + threadIdx.x;
    if (t >= N * H) return;
    int n = t / H, hh = t - n * H;
    int s0 = rs[n], s1 = rs[n + 1];
    if (s0 == s1) return;
    float ern = er[t];
    float mx = -INFINITY;
    for (int j = s0; j < s1; ++j) {
        int e = eidx[j];
        float v = el[src[e] * H + hh] + ern;
        v = (v > 0.f) ? v : NEG_SLOPE * v;
        alpha[(size_t)e * H + hh] = v;
        mx = fmaxf(mx, v);
    }
    float den = 0.f;
    for (int j = s0; j < s1; ++j) {
        int e = eidx[j];
        float ex = expf(alpha[(size_t)e * H + hh] - mx);
        alpha[(size_t)e * H + hh] = ex;
        den += ex;
    }
    float inv = 1.f / den;
    for (int j = s0; j < s1; ++j) {
        int e = eidx[j];
        alpha[(size_t)e * H + hh] *= inv;
    }
}

__global__ void gat_aggregate(const float* __restrict__ h, const float* __restrict__ alpha,
                              const int* __restrict__ src, const int* __restrict__ rs,
                              const int* __restrict__ eidx, float* __restrict__ out,
                              int N, int H, int D) {
    int n = blockIdx.x;
    int HD = H * D;
    int s0 = rs[n], s1 = rs[n + 1];
    for (int c = threadIdx.x; c < HD; c += blockDim.x) {
        int hh = c / D;
        float acc = 0.f;
        for (int j = s0; j < s1; ++j) {
            int e = eidx[j];
            acc += alpha[(size_t)e * H + hh] * h[(size_t)src[e] * HD + c];
        }
        out[(size_t)n * HD + c] = fmaxf(acc, 0.f);
    }
}

// Graph max-readout over post-ReLU (>=0) values via int-bitcast atomicMax.
__global__ void seg_max_atomic(const float* __restrict__ g, const int* __restrict__ nid,
                               int* __restrict__ out, int N, int C) {
    int n0 = blockIdx.x << 5;
    int n1 = n0 + 32; if (n1 > N) n1 = N;
    if (n0 >= N) return;
    for (int c = threadIdx.x; c < C; c += blockDim.x) {
        int cur = nid[n0];
        float m = 0.f;
        for (int n = n0; n < n1; ++n) {
            int gid = nid[n];
            if (gid != cur) {
                atomicMax(&out[cur * C + c], __float_as_int(m));
                cur = gid; m = 0.f;
            }
            m = fmaxf(m, g[(size_t)n * C + c]);
        }
        atomicMax(&out[cur * C + c], __float_as_int(m));
    }
}

// ---------------- small dense layers ----------------
// One wave per (o, b): lanes split K (K must not be tiny; any K works), shuffle-reduce.
// grid = (ceil(O/4), B), block = 256 (4 waves).
__global__ void linear_wave(const float* __restrict__ in, const float* __restrict__ W,
                            const float* __restrict__ bias, float* __restrict__ out,
                            int K, int O, int act) {
    int o = blockIdx.x * 4 + (threadIdx.x >> 6);
    int b = blockIdx.y;
    int lane = threadIdx.x & 63;
    if (o >= O) return;
    const float* ip = in + (size_t)b * K;
    float acc = 0.f;
    for (int k = lane; k < K; k += 64)
        acc += ip[k] * W[(size_t)k * O + o];
    for (int off = 32; off > 0; off >>= 1)
        acc += __shfl_down(acc, off, 64);
    if (lane == 0) {
        acc += bias[o];
        if (act == 1) acc = fmaxf(acc, 0.f);
        else if (act == 2) acc = 1.f / (1.f + expf(-acc));
        out[(size_t)b * O + o] = acc;
    }
}

// ---------------- TextCNN ----------------
__global__ void transpose_pad(const float* __restrict__ pad, float* __restrict__ xT,
                              int B, int L, int C) {
    int idx = blockIdx.x * blockDim.x + threadIdx.x;
    int total = B * L * C;
    if (idx >= total) return;
    int l = idx % L;
    int c = (idx / L) % C;
    int b = idx / (L * C);
    xT[idx] = pad[((size_t)b * L + l) * C + c];
}

__global__ __launch_bounds__(256) void conv3k(const float* __restrict__ x,
                                              const float* __restrict__ w,
                                              const float* __restrict__ bias,
                                              float* __restrict__ y,
                                              int Cin, int Lin, int Lout) {
    extern __shared__ float sx[];  // Cin x 66
    int b = blockIdx.y;
    int l0 = blockIdx.x << 6;
    int tid = threadIdx.x;
    int tileL = Lout - l0; if (tileL > 64) tileL = 64;
    int loadL = tileL + 2; { int lim = Lin - l0; if (loadL > lim) loadL = lim; }
    for (int idx = tid; idx < Cin * loadL; idx += 256) {
        int c = idx / loadL, i = idx - c * loadL;
        sx[c * 66 + i] = x[((size_t)b * Cin + c) * Lin + l0 + i];
    }
    __syncthreads();
    int o = tid & 127;
    int pbase = (tid >> 7) << 5;  // 0 or 32
    int npos = tileL - pbase; if (npos > 32) npos = 32; if (npos < 0) npos = 0;
    float acc[32];
    float bv = bias[o];
#pragma unroll
    for (int j = 0; j < 32; ++j) acc[j] = bv;
    const float* wp = w + (size_t)o * Cin * 3;
    for (int c = 0; c < Cin; ++c) {
        float xv[34];
#pragma unroll
        for (int i = 0; i < 34; ++i) xv[i] = sx[c * 66 + pbase + i];
        float w0 = wp[c * 3 + 0], w1 = wp[c * 3 + 1], w2 = wp[c * 3 + 2];
#pragma unroll
        for (int j = 0; j < 32; ++j) acc[j] += w0 * xv[j] + w1 * xv[j + 1] + w2 * xv[j + 2];
    }
    float* yp = y + ((size_t)b * 128 + o) * Lout + l0 + pbase;
#pragma unroll
    for (int j = 0; j < 32; ++j)
        if (j < npos) yp[j] = acc[j];
}

__global__ void maxpool(const float* __restrict__ y, float* __restrict__ p,
                        int BC, int Lin, int k, int s, int Lout) {
    int idx = blockIdx.x * blockDim.x + threadIdx.x;
    if (idx >= BC * Lout) return;
    int lo = idx % Lout, bc = idx / Lout;
    const float* yp = y + (size_t)bc * Lin + lo * s;
    float m = -INFINITY;
    for (int i = 0; i < k; ++i) m = fmaxf(m, yp[i]);
    p[idx] = m;
}

__global__ void combine_branch(const float* __restrict__ g, const float* __restrict__ s,
                               const float* __restrict__ w1, float* __restrict__ cat, int off) {
    int idx = blockIdx.x * blockDim.x + threadIdx.x;
    if (idx >= 16 * 128) return;
    int b = idx >> 7, c = idx & 127;
    float w = 1.f / (1.f + expf(-w1[0]));
    cat[b * 256 + off + c] = (1.f - w) * g[idx] + w * s[idx];
}

// ---------------- host ----------------
extern "C" void kernel_launch(void* const* d_in, const int* in_sizes, int n_in,
                              void* d_out, int out_size, void* d_ws, size_t ws_size,
                              hipStream_t stream) {
    const float* feat[2] = {(const float*)d_in[0], (const float*)d_in[1]};
    const float* pad[2]  = {(const float*)d_in[2], (const float*)d_in[3]};
    const int* src[2]    = {(const int*)d_in[4], (const int*)d_in[6]};
    const int* dst[2]    = {(const int*)d_in[5], (const int*)d_in[7]};
    const int* nid[2]    = {(const int*)d_in[8], (const int*)d_in[9]};
    const float* Wg[3]   = {(const float*)d_in[11], (const float*)d_in[14], (const float*)d_in[17]};
    const float* al[3]   = {(const float*)d_in[12], (const float*)d_in[15], (const float*)d_in[18]};
    const float* ar[3]   = {(const float*)d_in[13], (const float*)d_in[16], (const float*)d_in[19]};
    const float* fcg_w = (const float*)d_in[20]; const float* fcg_b = (const float*)d_in[21];
    const float* c1w = (const float*)d_in[22];   const float* c1b = (const float*)d_in[23];
    const float* c2w = (const float*)d_in[24];   const float* c2b = (const float*)d_in[25];
    const float* c3w = (const float*)d_in[26];   const float* c3b = (const float*)d_in[27];
    const float* tf_w = (const float*)d_in[28];  const float* tf_b = (const float*)d_in[29];
    const float* w1 = (const float*)d_in[30];
    const float* fc1_w = (const float*)d_in[31]; const float* fc1_b = (const float*)d_in[32];
    const float* fc2_w = (const float*)d_in[33]; const float* fc2_b = (const float*)d_in[34];
    const float* outw = (const float*)d_in[35];  const float* outb = (const float*)d_in[36];
    float* out = (float*)d_out;

    const int N = in_sizes[0] / 64;   // 8000
    const int E = in_sizes[4];        // 160000
    const int B = 16, L = 1200;

    char* wsb = (char*)d_ws;
    size_t off = 0;
    auto alloc = [&](size_t elems) -> void* {
        void* p = wsb + off;
        off += (elems * 4 + 255) & ~(size_t)255;
        return p;
    };
    float* h_buf = (float*)alloc((size_t)N * 576);
    float* gA    = (float*)alloc((size_t)N * 576);
    float* gB    = (float*)alloc((size_t)N * 576);
    float* el    = (float*)alloc((size_t)N * 3);
    float* er    = (float*)alloc((size_t)N * 3);
    float* alpha = (float*)alloc((size_t)E * 3);
    int* rs      = (int*)alloc(N + 1);
    int* cnt     = (int*)alloc(N);
    int* eidx    = (int*)alloc(E);
    int* gmax    = (int*)alloc((size_t)B * 576);   // float bits via atomicMax
    float* gvec  = (float*)alloc((size_t)B * 128);
    float* xT    = (float*)alloc((size_t)B * 64 * L);
    float* y1    = (float*)alloc((size_t)B * 128 * 1198);
    float* p1    = (float*)alloc((size_t)B * 128 * 399);
    float* y2    = (float*)alloc((size_t)B * 128 * 397);
    float* p2    = (float*)alloc((size_t)B * 128 * 132);
    float* y3    = (float*)alloc((size_t)B * 128 * 130);
    float* sp    = (float*)alloc((size_t)B * 128);
    float* sf    = (float*)alloc((size_t)B * 128);
    float* cat   = (float*)alloc((size_t)B * 256);
    float* f1    = (float*)alloc((size_t)B * 512);
    float* f2    = (float*)alloc((size_t)B * 256);
    (void)ws_size; (void)n_in; (void)out_size;

    for (int br = 0; br < 2; ++br) {
        // --- CSR by dst ---
        zero_i32<<<(N + 255) / 256, 256, 0, stream>>>(cnt, N);
        count_edges<<<(E + 255) / 256, 256, 0, stream>>>(dst[br], cnt, E);
        scan_block<<<1, 1024, 0, stream>>>(cnt, rs, N);
        zero_i32<<<(N + 255) / 256, 256, 0, stream>>>(cnt, N);
        scatter_edges<<<(E + 255) / 256, 256, 0, stream>>>(dst[br], rs, cnt, eidx, E);

        // --- 3 GAT layers ---
        const int dims[3][3] = {{64, 3, 64}, {192, 3, 192}, {576, 1, 576}};  // K,H,D
        float* outs[3] = {gA, gB, gA};
        const float* in_ptr = feat[br];
        for (int ly = 0; ly < 3; ++ly) {
            int K = dims[ly][0], H = dims[ly][1], D = dims[ly][2];
            int HD = H * D;
            gemm64<<<dim3(HD / 64, (N + 63) / 64), 256, 0, stream>>>(in_ptr, Wg[ly], h_buf, N, K, HD);
            int waves = N * H;
            gat_elr<<<((size_t)waves * 64 + 255) / 256, 256, 0, stream>>>(h_buf, al[ly], ar[ly], el, er, N, H, D);
            gat_softmax<<<(N * H + 255) / 256, 256, 0, stream>>>(el, er, src[br], rs, eidx, alpha, N, H);
            gat_aggregate<<<N, 256, 0, stream>>>(h_buf, alpha, src[br], rs, eidx, outs[ly], N, H, D);
            in_ptr = outs[ly];
        }
        zero_i32<<<(B * 576 + 255) / 256, 256, 0, stream>>>(gmax, B * 576);
        seg_max_atomic<<<(N + 31) / 32, 256, 0, stream>>>(gA, nid[br], gmax, N, 576);
        linear_wave<<<dim3(32, B), 256, 0, stream>>>((const float*)gmax, fcg_w, fcg_b, gvec, 576, 128, 1);

        // --- TextCNN ---
        transpose_pad<<<((B * 64 * L) + 255) / 256, 256, 0, stream>>>(pad[br], xT, B, L, 64);
        conv3k<<<dim3(19, B), 256, 64 * 66 * 4, stream>>>(xT, c1w, c1b, y1, 64, 1200, 1198);
        maxpool<<<(B * 128 * 399 + 255) / 256, 256, 0, stream>>>(y1, p1, B * 128, 1198, 3, 3, 399);
        conv3k<<<dim3(7, B), 256, 128 * 66 * 4, stream>>>(p1, c2w, c2b, y2, 128, 399, 397);
        maxpool<<<(B * 128 * 132 + 255) / 256, 256, 0, stream>>>(y2, p2, B * 128, 397, 3, 3, 132);
        conv3k<<<dim3(3, B), 256, 128 * 66 * 4, stream>>>(p2, c3w, c3b, y3, 128, 132, 130);
        maxpool<<<(B * 128 + 255) / 256, 256, 0, stream>>>(y3, sp, B * 128, 130, 130, 1, 1);
        linear_wave<<<dim3(32, B), 256, 0, stream>>>(sp, tf_w, tf_b, sf, 128, 128, 1);

        combine_branch<<<(B * 128 + 255) / 256, 256, 0, stream>>>(gvec, sf, w1, cat, br * 128);
    }

    // --- head MLP ---
    linear_wave<<<dim3(128, B), 256, 0, stream>>>(cat, fc1_w, fc1_b, f1, 256, 512, 1);
    linear_wave<<<dim3(64, B), 256, 0, stream>>>(f1, fc2_w, fc2_b, f2, 512, 256, 1);
    linear_wave<<<dim3(1, B), 256, 0, stream>>>(f2, outw, outb, out, 256, 1, 2);
}

// Round 4
// 1764.275 us; speedup vs baseline: 1.8705x; 1.1958x over previous
//
#include <hip/hip_runtime.h>
#include <math.h>

#define NEG_SLOPE 0.2f

// ---------------- utility ----------------
__global__ void zero_i32(int* __restrict__ p, int n) {
    int i = blockIdx.x * blockDim.x + threadIdx.x;
    if (i < n) p[i] = 0;
}

// ---------------- CSR build ----------------
__global__ void count_edges(const int* __restrict__ dst, int* __restrict__ cnt, int E) {
    int i = blockIdx.x * blockDim.x + threadIdx.x;
    if (i < E) atomicAdd(&cnt[dst[i]], 1);
}

__global__ void scan_block(const int* __restrict__ cnt, int* __restrict__ rs, int N) {
    __shared__ int s[1024];
    int tid = threadIdx.x;
    int running = 0;
    for (int base = 0; base < N; base += 1024) {
        int v = (base + tid < N) ? cnt[base + tid] : 0;
        __syncthreads();
        s[tid] = v;
        __syncthreads();
        for (int off = 1; off < 1024; off <<= 1) {
            int t = (tid >= off) ? s[tid - off] : 0;
            __syncthreads();
            if (tid >= off) s[tid] += t;
            __syncthreads();
        }
        if (base + tid < N) rs[base + tid] = running + s[tid] - v;
        running += s[1023];
    }
    if (tid == 0) rs[N] = running;
}

__global__ void scatter_edges(const int* __restrict__ dst, const int* __restrict__ rs,
                              int* __restrict__ fill, int* __restrict__ eidx, int E) {
    int i = blockIdx.x * blockDim.x + threadIdx.x;
    if (i < E) {
        int d = dst[i];
        int pos = atomicAdd(&fill[d], 1);
        eidx[rs[d] + pos] = i;
    }
}

// ---------------- GEMM: C(MxN) = A(MxK) @ B(KxN), fp32, 64x64 tile ----------------
__global__ __launch_bounds__(256) void gemm64(const float* __restrict__ A,
                                              const float* __restrict__ Bw,
                                              float* __restrict__ C, int M, int K, int N) {
    __shared__ float As[16][64];
    __shared__ float Bs[16][64];
    int tid = threadIdx.x;
    int tx = tid & 15, ty = tid >> 4;
    int row0 = blockIdx.y << 6, col0 = blockIdx.x << 6;
    float acc[4][4] = {{0.f}};
    for (int k0 = 0; k0 < K; k0 += 16) {
        {
            int ar = tid >> 2;
            int ac = (tid & 3) << 2;
            int r = row0 + ar, c = k0 + ac;
            float4 av;
            if (r < M && c + 3 < K) av = *(const float4*)&A[(size_t)r * K + c];
            else {
                av.x = (r < M && c + 0 < K) ? A[(size_t)r * K + c + 0] : 0.f;
                av.y = (r < M && c + 1 < K) ? A[(size_t)r * K + c + 1] : 0.f;
                av.z = (r < M && c + 2 < K) ? A[(size_t)r * K + c + 2] : 0.f;
                av.w = (r < M && c + 3 < K) ? A[(size_t)r * K + c + 3] : 0.f;
            }
            As[ac + 0][ar] = av.x; As[ac + 1][ar] = av.y;
            As[ac + 2][ar] = av.z; As[ac + 3][ar] = av.w;
        }
        {
            int bk = tid >> 4;
            int bn = (tid & 15) << 2;
            int r = k0 + bk, c = col0 + bn;
            float4 bv;
            if (r < K && c + 3 < N) bv = *(const float4*)&Bw[(size_t)r * N + c];
            else {
                bv.x = (r < K && c + 0 < N) ? Bw[(size_t)r * N + c + 0] : 0.f;
                bv.y = (r < K && c + 1 < N) ? Bw[(size_t)r * N + c + 1] : 0.f;
                bv.z = (r < K && c + 2 < N) ? Bw[(size_t)r * N + c + 2] : 0.f;
                bv.w = (r < K && c + 3 < N) ? Bw[(size_t)r * N + c + 3] : 0.f;
            }
            *(float4*)&Bs[bk][bn] = bv;
        }
        __syncthreads();
#pragma unroll
        for (int kk = 0; kk < 16; ++kk) {
            float4 a = *(const float4*)&As[kk][ty << 2];
            float4 b = *(const float4*)&Bs[kk][tx << 2];
            acc[0][0] += a.x * b.x; acc[0][1] += a.x * b.y; acc[0][2] += a.x * b.z; acc[0][3] += a.x * b.w;
            acc[1][0] += a.y * b.x; acc[1][1] += a.y * b.y; acc[1][2] += a.y * b.z; acc[1][3] += a.y * b.w;
            acc[2][0] += a.z * b.x; acc[2][1] += a.z * b.y; acc[2][2] += a.z * b.z; acc[2][3] += a.z * b.w;
            acc[3][0] += a.w * b.x; acc[3][1] += a.w * b.y; acc[3][2] += a.w * b.z; acc[3][3] += a.w * b.w;
        }
        __syncthreads();
    }
#pragma unroll
    for (int i = 0; i < 4; ++i) {
        int r = row0 + (ty << 2) + i;
        if (r < M) {
#pragma unroll
            for (int j = 0; j < 4; ++j) {
                int c = col0 + (tx << 2) + j;
                if (c < N) C[(size_t)r * N + c] = acc[i][j];
            }
        }
    }
}

// ---------------- GAT pieces ----------------
__global__ void gat_elr(const float* __restrict__ h, const float* __restrict__ al,
                        const float* __restrict__ ar, float* __restrict__ el,
                        float* __restrict__ er, int N, int H, int D) {
    int wid = (blockIdx.x * blockDim.x + threadIdx.x) >> 6;
    int lane = threadIdx.x & 63;
    if (wid >= N * H) return;
    int n = wid / H, hh = wid - n * H;
    const float* hp = h + ((size_t)n * H + hh) * D;
    const float* alp = al + (size_t)hh * D;
    const float* arp = ar + (size_t)hh * D;
    float sl = 0.f, sr = 0.f;
    for (int d = lane; d < D; d += 64) {
        float v = hp[d];
        sl += v * alp[d];
        sr += v * arp[d];
    }
    for (int off = 32; off > 0; off >>= 1) {
        sl += __shfl_down(sl, off, 64);
        sr += __shfl_down(sr, off, 64);
    }
    if (lane == 0) { el[wid] = sl; er[wid] = sr; }
}

__global__ void gat_softmax(const float* __restrict__ el, const float* __restrict__ er,
                            const int* __restrict__ src, const int* __restrict__ rs,
                            const int* __restrict__ eidx, float* __restrict__ alpha,
                            int N, int H) {
    int t = blockIdx.x * blockDim.x + threadIdx.x;
    if (t >= N * H) return;
    int n = t / H, hh = t - n * H;
    int s0 = rs[n], s1 = rs[n + 1];
    if (s0 == s1) return;
    float ern = er[t];
    float mx = -INFINITY;
    for (int j = s0; j < s1; ++j) {
        int e = eidx[j];
        float v = el[src[e] * H + hh] + ern;
        v = (v > 0.f) ? v : NEG_SLOPE * v;
        alpha[(size_t)e * H + hh] = v;
        mx = fmaxf(mx, v);
    }
    float den = 0.f;
    for (int j = s0; j < s1; ++j) {
        int e = eidx[j];
        float ex = expf(alpha[(size_t)e * H + hh] - mx);
        alpha[(size_t)e * H + hh] = ex;
        den += ex;
    }
    float inv = 1.f / den;
    for (int j = s0; j < s1; ++j) {
        int e = eidx[j];
        alpha[(size_t)e * H + hh] *= inv;
    }
}

// Block per node. Edge metadata (src row, per-head alpha) staged into LDS by
// parallel threads (breaks the eidx->src->h dependent-load chain), then each
// compute lane owns ONE float4 column and streams independent dwordx4 gathers.
#define TILE_E 64
__global__ void gat_aggregate(const float4* __restrict__ h4, const float* __restrict__ alpha,
                              const int* __restrict__ src, const int* __restrict__ rs,
                              const int* __restrict__ eidx, float4* __restrict__ out4,
                              int N, int H, int D) {
    __shared__ int s_src[TILE_E];
    __shared__ float s_alpha[TILE_E * 3];
    int n = blockIdx.x;
    int HD4 = (H * D) >> 2;
    int tid = threadIdx.x;
    int s0 = rs[n], s1 = rs[n + 1];
    bool active = tid < HD4;
    int hh = active ? (tid << 2) / D : 0;
    float4 acc = {0.f, 0.f, 0.f, 0.f};
    for (int base = s0; base < s1; base += TILE_E) {
        int cntE = s1 - base; if (cntE > TILE_E) cntE = TILE_E;
        if (tid < cntE) {
            int e = eidx[base + tid];
            s_src[tid] = src[e];
#pragma unroll
            for (int h = 0; h < 3; ++h)
                if (h < H) s_alpha[tid * 3 + h] = alpha[(size_t)e * H + h];
        }
        __syncthreads();
        if (active) {
#pragma unroll 4
            for (int i = 0; i < cntE; ++i) {
                float a = s_alpha[i * 3 + hh];
                float4 hv = h4[(size_t)s_src[i] * HD4 + tid];
                acc.x += a * hv.x; acc.y += a * hv.y;
                acc.z += a * hv.z; acc.w += a * hv.w;
            }
        }
        __syncthreads();
    }
    if (active) {
        acc.x = fmaxf(acc.x, 0.f); acc.y = fmaxf(acc.y, 0.f);
        acc.z = fmaxf(acc.z, 0.f); acc.w = fmaxf(acc.w, 0.f);
        out4[(size_t)n * HD4 + tid] = acc;
    }
}

// Graph max-readout over post-ReLU (>=0) values via int-bitcast atomicMax.
__global__ void seg_max_atomic(const float* __restrict__ g, const int* __restrict__ nid,
                               int* __restrict__ out, int N, int C) {
    int n0 = blockIdx.x << 5;
    int n1 = n0 + 32; if (n1 > N) n1 = N;
    if (n0 >= N) return;
    for (int c = threadIdx.x; c < C; c += blockDim.x) {
        int cur = nid[n0];
        float m = 0.f;
        for (int n = n0; n < n1; ++n) {
            int gid = nid[n];
            if (gid != cur) {
                atomicMax(&out[cur * C + c], __float_as_int(m));
                cur = gid; m = 0.f;
            }
            m = fmaxf(m, g[(size_t)n * C + c]);
        }
        atomicMax(&out[cur * C + c], __float_as_int(m));
    }
}

// ---------------- small dense layers ----------------
__global__ void linear_wave(const float* __restrict__ in, const float* __restrict__ W,
                            const float* __restrict__ bias, float* __restrict__ out,
                            int K, int O, int act) {
    int o = blockIdx.x * 4 + (threadIdx.x >> 6);
    int b = blockIdx.y;
    int lane = threadIdx.x & 63;
    if (o >= O) return;
    const float* ip = in + (size_t)b * K;
    float acc = 0.f;
    for (int k = lane; k < K; k += 64)
        acc += ip[k] * W[(size_t)k * O + o];
    for (int off = 32; off > 0; off >>= 1)
        acc += __shfl_down(acc, off, 64);
    if (lane == 0) {
        acc += bias[o];
        if (act == 1) acc = fmaxf(acc, 0.f);
        else if (act == 2) acc = 1.f / (1.f + expf(-acc));
        out[(size_t)b * O + o] = acc;
    }
}

// ---------------- TextCNN ----------------
__global__ void transpose_pad(const float* __restrict__ pad, float* __restrict__ xT,
                              int B, int L, int C) {
    int idx = blockIdx.x * blockDim.x + threadIdx.x;
    int total = B * L * C;
    if (idx >= total) return;
    int l = idx % L;
    int c = (idx / L) % C;
    int b = idx / (L * C);
    xT[idx] = pad[((size_t)b * L + l) * C + c];
}

__global__ __launch_bounds__(256) void conv3k(const float* __restrict__ x,
                                              const float* __restrict__ w,
                                              const float* __restrict__ bias,
                                              float* __restrict__ y,
                                              int Cin, int Lin, int Lout) {
    extern __shared__ float sx[];  // Cin x 66
    int b = blockIdx.y;
    int l0 = blockIdx.x << 6;
    int tid = threadIdx.x;
    int tileL = Lout - l0; if (tileL > 64) tileL = 64;
    int loadL = tileL + 2; { int lim = Lin - l0; if (loadL > lim) loadL = lim; }
    for (int idx = tid; idx < Cin * loadL; idx += 256) {
        int c = idx / loadL, i = idx - c * loadL;
        sx[c * 66 + i] = x[((size_t)b * Cin + c) * Lin + l0 + i];
    }
    __syncthreads();
    int o = tid & 127;
    int pbase = (tid >> 7) << 5;  // 0 or 32
    int npos = tileL - pbase; if (npos > 32) npos = 32; if (npos < 0) npos = 0;
    float acc[32];
    float bv = bias[o];
#pragma unroll
    for (int j = 0; j < 32; ++j) acc[j] = bv;
    const float* wp = w + (size_t)o * Cin * 3;
    for (int c = 0; c < Cin; ++c) {
        float xv[34];
#pragma unroll
        for (int i = 0; i < 34; ++i) xv[i] = sx[c * 66 + pbase + i];
        float w0 = wp[c * 3 + 0], w1 = wp[c * 3 + 1], w2 = wp[c * 3 + 2];
#pragma unroll
        for (int j = 0; j < 32; ++j) acc[j] += w0 * xv[j] + w1 * xv[j + 1] + w2 * xv[j + 2];
    }
    float* yp = y + ((size_t)b * 128 + o) * Lout + l0 + pbase;
#pragma unroll
    for (int j = 0; j < 32; ++j)
        if (j < npos) yp[j] = acc[j];
}

__global__ void maxpool(const float* __restrict__ y, float* __restrict__ p,
                        int BC, int Lin, int k, int s, int Lout) {
    int idx = blockIdx.x * blockDim.x + threadIdx.x;
    if (idx >= BC * Lout) return;
    int lo = idx % Lout, bc = idx / Lout;
    const float* yp = y + (size_t)bc * Lin + lo * s;
    float m = -INFINITY;
    for (int i = 0; i < k; ++i) m = fmaxf(m, yp[i]);
    p[idx] = m;
}

__global__ void combine_branch(const float* __restrict__ g, const float* __restrict__ s,
                               const float* __restrict__ w1, float* __restrict__ cat, int off) {
    int idx = blockIdx.x * blockDim.x + threadIdx.x;
    if (idx >= 16 * 128) return;
    int b = idx >> 7, c = idx & 127;
    float w = 1.f / (1.f + expf(-w1[0]));
    cat[b * 256 + off + c] = (1.f - w) * g[idx] + w * s[idx];
}

// ---------------- host ----------------
extern "C" void kernel_launch(void* const* d_in, const int* in_sizes, int n_in,
                              void* d_out, int out_size, void* d_ws, size_t ws_size,
                              hipStream_t stream) {
    const float* feat[2] = {(const float*)d_in[0], (const float*)d_in[1]};
    const float* pad[2]  = {(const float*)d_in[2], (const float*)d_in[3]};
    const int* src[2]    = {(const int*)d_in[4], (const int*)d_in[6]};
    const int* dst[2]    = {(const int*)d_in[5], (const int*)d_in[7]};
    const int* nid[2]    = {(const int*)d_in[8], (const int*)d_in[9]};
    const float* Wg[3]   = {(const float*)d_in[11], (const float*)d_in[14], (const float*)d_in[17]};
    const float* al[3]   = {(const float*)d_in[12], (const float*)d_in[15], (const float*)d_in[18]};
    const float* ar[3]   = {(const float*)d_in[13], (const float*)d_in[16], (const float*)d_in[19]};
    const float* fcg_w = (const float*)d_in[20]; const float* fcg_b = (const float*)d_in[21];
    const float* c1w = (const float*)d_in[22];   const float* c1b = (const float*)d_in[23];
    const float* c2w = (const float*)d_in[24];   const float* c2b = (const float*)d_in[25];
    const float* c3w = (const float*)d_in[26];   const float* c3b = (const float*)d_in[27];
    const float* tf_w = (const float*)d_in[28];  const float* tf_b = (const float*)d_in[29];
    const float* w1 = (const float*)d_in[30];
    const float* fc1_w = (const float*)d_in[31]; const float* fc1_b = (const float*)d_in[32];
    const float* fc2_w = (const float*)d_in[33]; const float* fc2_b = (const float*)d_in[34];
    const float* outw = (const float*)d_in[35];  const float* outb = (const float*)d_in[36];
    float* out = (float*)d_out;

    const int N = in_sizes[0] / 64;   // 8000
    const int E = in_sizes[4];        // 160000
    const int B = 16, L = 1200;

    char* wsb = (char*)d_ws;
    size_t off = 0;
    auto alloc = [&](size_t elems) -> void* {
        void* p = wsb + off;
        off += (elems * 4 + 255) & ~(size_t)255;
        return p;
    };
    float* h_buf = (float*)alloc((size_t)N * 576);
    float* gA    = (float*)alloc((size_t)N * 576);
    float* gB    = (float*)alloc((size_t)N * 576);
    float* el    = (float*)alloc((size_t)N * 3);
    float* er    = (float*)alloc((size_t)N * 3);
    float* alpha = (float*)alloc((size_t)E * 3);
    int* rs      = (int*)alloc(N + 1);
    int* cnt     = (int*)alloc(N);
    int* eidx    = (int*)alloc(E);
    int* gmax    = (int*)alloc((size_t)B * 576);   // float bits via atomicMax
    float* gvec  = (float*)alloc((size_t)B * 128);
    float* xT    = (float*)alloc((size_t)B * 64 * L);
    float* y1    = (float*)alloc((size_t)B * 128 * 1198);
    float* p1    = (float*)alloc((size_t)B * 128 * 399);
    float* y2    = (float*)alloc((size_t)B * 128 * 397);
    float* p2    = (float*)alloc((size_t)B * 128 * 132);
    float* y3    = (float*)alloc((size_t)B * 128 * 130);
    float* sp    = (float*)alloc((size_t)B * 128);
    float* sf    = (float*)alloc((size_t)B * 128);
    float* cat   = (float*)alloc((size_t)B * 256);
    float* f1    = (float*)alloc((size_t)B * 512);
    float* f2    = (float*)alloc((size_t)B * 256);
    (void)ws_size; (void)n_in; (void)out_size;

    for (int br = 0; br < 2; ++br) {
        // --- CSR by dst ---
        zero_i32<<<(N + 255) / 256, 256, 0, stream>>>(cnt, N);
        count_edges<<<(E + 255) / 256, 256, 0, stream>>>(dst[br], cnt, E);
        scan_block<<<1, 1024, 0, stream>>>(cnt, rs, N);
        zero_i32<<<(N + 255) / 256, 256, 0, stream>>>(cnt, N);
        scatter_edges<<<(E + 255) / 256, 256, 0, stream>>>(dst[br], rs, cnt, eidx, E);

        // --- 3 GAT layers ---
        const int dims[3][3] = {{64, 3, 64}, {192, 3, 192}, {576, 1, 576}};  // K,H,D
        float* outs[3] = {gA, gB, gA};
        const float* in_ptr = feat[br];
        for (int ly = 0; ly < 3; ++ly) {
            int K = dims[ly][0], H = dims[ly][1], D = dims[ly][2];
            int HD = H * D;
            gemm64<<<dim3(HD / 64, (N + 63) / 64), 256, 0, stream>>>(in_ptr, Wg[ly], h_buf, N, K, HD);
            int waves = N * H;
            gat_elr<<<((size_t)waves * 64 + 255) / 256, 256, 0, stream>>>(h_buf, al[ly], ar[ly], el, er, N, H, D);
            gat_softmax<<<(N * H + 255) / 256, 256, 0, stream>>>(el, er, src[br], rs, eidx, alpha, N, H);
            int aggThreads = (((HD >> 2) + 63) / 64) * 64;   // 64 for HD=192, 192 for HD=576
            gat_aggregate<<<N, aggThreads, 0, stream>>>((const float4*)h_buf, alpha, src[br], rs, eidx,
                                                        (float4*)outs[ly], N, H, D);
            in_ptr = outs[ly];
        }
        zero_i32<<<(B * 576 + 255) / 256, 256, 0, stream>>>(gmax, B * 576);
        seg_max_atomic<<<(N + 31) / 32, 256, 0, stream>>>(gA, nid[br], gmax, N, 576);
        linear_wave<<<dim3(32, B), 256, 0, stream>>>((const float*)gmax, fcg_w, fcg_b, gvec, 576, 128, 1);

        // --- TextCNN ---
        transpose_pad<<<((B * 64 * L) + 255) / 256, 256, 0, stream>>>(pad[br], xT, B, L, 64);
        conv3k<<<dim3(19, B), 256, 64 * 66 * 4, stream>>>(xT, c1w, c1b, y1, 64, 1200, 1198);
        maxpool<<<(B * 128 * 399 + 255) / 256, 256, 0, stream>>>(y1, p1, B * 128, 1198, 3, 3, 399);
        conv3k<<<dim3(7, B), 256, 128 * 66 * 4, stream>>>(p1, c2w, c2b, y2, 128, 399, 397);
        maxpool<<<(B * 128 * 132 + 255) / 256, 256, 0, stream>>>(y2, p2, B * 128, 397, 3, 3, 132);
        conv3k<<<dim3(3, B), 256, 128 * 66 * 4, stream>>>(p2, c3w, c3b, y3, 128, 132, 130);
        maxpool<<<(B * 128 + 255) / 256, 256, 0, stream>>>(y3, sp, B * 128, 130, 130, 1, 1);
        linear_wave<<<dim3(32, B), 256, 0, stream>>>(sp, tf_w, tf_b, sf, 128, 128, 1);

        combine_branch<<<(B * 128 + 255) / 256, 256, 0, stream>>>(gvec, sf, w1, cat, br * 128);
    }

    // --- head MLP ---
    linear_wave<<<dim3(128, B), 256, 0, stream>>>(cat, fc1_w, fc1_b, f1, 256, 512, 1);
    linear_wave<<<dim3(64, B), 256, 0, stream>>>(f1, fc2_w, fc2_b, f2, 512, 256, 1);
    linear_wave<<<dim3(1, B), 256, 0, stream>>>(f2, outw, outb, out, 256, 1, 2);
}

// Round 5
// 1189.395 us; speedup vs baseline: 2.7747x; 1.4833x over previous
//
#include <hip/hip_runtime.h>
#include <math.h>

#define NEG_SLOPE 0.2f

// ---------------- utility ----------------
__global__ void zero_i32(int* __restrict__ p, int n) {
    int i = blockIdx.x * blockDim.x + threadIdx.x;
    if (i < n) p[i] = 0;
}

// ---------------- CSR build ----------------
__global__ void count_edges(const int* __restrict__ dst, int* __restrict__ cnt, int E) {
    int i = blockIdx.x * blockDim.x + threadIdx.x;
    if (i < E) atomicAdd(&cnt[dst[i]], 1);
}

__global__ void scan_block(const int* __restrict__ cnt, int* __restrict__ rs, int N) {
    __shared__ int s[1024];
    int tid = threadIdx.x;
    int running = 0;
    for (int base = 0; base < N; base += 1024) {
        int v = (base + tid < N) ? cnt[base + tid] : 0;
        __syncthreads();
        s[tid] = v;
        __syncthreads();
        for (int off = 1; off < 1024; off <<= 1) {
            int t = (tid >= off) ? s[tid - off] : 0;
            __syncthreads();
            if (tid >= off) s[tid] += t;
            __syncthreads();
        }
        if (base + tid < N) rs[base + tid] = running + s[tid] - v;
        running += s[1023];
    }
    if (tid == 0) rs[N] = running;
}

__global__ void scatter_edges(const int* __restrict__ dst, const int* __restrict__ rs,
                              int* __restrict__ fill, int* __restrict__ eidx, int E) {
    int i = blockIdx.x * blockDim.x + threadIdx.x;
    if (i < E) {
        int d = dst[i];
        int pos = atomicAdd(&fill[d], 1);
        eidx[rs[d] + pos] = i;
    }
}

// ---------------- GEMM: C(MxN) = A(MxK) @ B(KxN), fp32, 64x64 tile ----------------
__global__ __launch_bounds__(256) void gemm64(const float* __restrict__ A,
                                              const float* __restrict__ Bw,
                                              float* __restrict__ C, int M, int K, int N) {
    __shared__ float As[16][64];
    __shared__ float Bs[16][64];
    int tid = threadIdx.x;
    int tx = tid & 15, ty = tid >> 4;
    int row0 = blockIdx.y << 6, col0 = blockIdx.x << 6;
    float acc[4][4] = {{0.f}};
    for (int k0 = 0; k0 < K; k0 += 16) {
        {
            int ar = tid >> 2;
            int ac = (tid & 3) << 2;
            int r = row0 + ar, c = k0 + ac;
            float4 av;
            if (r < M && c + 3 < K) av = *(const float4*)&A[(size_t)r * K + c];
            else {
                av.x = (r < M && c + 0 < K) ? A[(size_t)r * K + c + 0] : 0.f;
                av.y = (r < M && c + 1 < K) ? A[(size_t)r * K + c + 1] : 0.f;
                av.z = (r < M && c + 2 < K) ? A[(size_t)r * K + c + 2] : 0.f;
                av.w = (r < M && c + 3 < K) ? A[(size_t)r * K + c + 3] : 0.f;
            }
            As[ac + 0][ar] = av.x; As[ac + 1][ar] = av.y;
            As[ac + 2][ar] = av.z; As[ac + 3][ar] = av.w;
        }
        {
            int bk = tid >> 4;
            int bn = (tid & 15) << 2;
            int r = k0 + bk, c = col0 + bn;
            float4 bv;
            if (r < K && c + 3 < N) bv = *(const float4*)&Bw[(size_t)r * N + c];
            else {
                bv.x = (r < K && c + 0 < N) ? Bw[(size_t)r * N + c + 0] : 0.f;
                bv.y = (r < K && c + 1 < N) ? Bw[(size_t)r * N + c + 1] : 0.f;
                bv.z = (r < K && c + 2 < N) ? Bw[(size_t)r * N + c + 2] : 0.f;
                bv.w = (r < K && c + 3 < N) ? Bw[(size_t)r * N + c + 3] : 0.f;
            }
            *(float4*)&Bs[bk][bn] = bv;
        }
        __syncthreads();
#pragma unroll
        for (int kk = 0; kk < 16; ++kk) {
            float4 a = *(const float4*)&As[kk][ty << 2];
            float4 b = *(const float4*)&Bs[kk][tx << 2];
            acc[0][0] += a.x * b.x; acc[0][1] += a.x * b.y; acc[0][2] += a.x * b.z; acc[0][3] += a.x * b.w;
            acc[1][0] += a.y * b.x; acc[1][1] += a.y * b.y; acc[1][2] += a.y * b.z; acc[1][3] += a.y * b.w;
            acc[2][0] += a.z * b.x; acc[2][1] += a.z * b.y; acc[2][2] += a.z * b.z; acc[2][3] += a.z * b.w;
            acc[3][0] += a.w * b.x; acc[3][1] += a.w * b.y; acc[3][2] += a.w * b.z; acc[3][3] += a.w * b.w;
        }
        __syncthreads();
    }
#pragma unroll
    for (int i = 0; i < 4; ++i) {
        int r = row0 + (ty << 2) + i;
        if (r < M) {
#pragma unroll
            for (int j = 0; j < 4; ++j) {
                int c = col0 + (tx << 2) + j;
                if (c < N) C[(size_t)r * N + c] = acc[i][j];
            }
        }
    }
}

// ---------------- GAT pieces ----------------
__global__ void gat_elr(const float* __restrict__ h, const float* __restrict__ al,
                        const float* __restrict__ ar, float* __restrict__ el,
                        float* __restrict__ er, int N, int H, int D) {
    int wid = (blockIdx.x * blockDim.x + threadIdx.x) >> 6;
    int lane = threadIdx.x & 63;
    if (wid >= N * H) return;
    int n = wid / H, hh = wid - n * H;
    const float* hp = h + ((size_t)n * H + hh) * D;
    const float* alp = al + (size_t)hh * D;
    const float* arp = ar + (size_t)hh * D;
    float sl = 0.f, sr = 0.f;
    for (int d = lane; d < D; d += 64) {
        float v = hp[d];
        sl += v * alp[d];
        sr += v * arp[d];
    }
    for (int off = 32; off > 0; off >>= 1) {
        sl += __shfl_down(sl, off, 64);
        sr += __shfl_down(sr, off, 64);
    }
    if (lane == 0) { el[wid] = sl; er[wid] = sr; }
}

__device__ __forceinline__ float lrelu(float v) {
    return (v > 0.f) ? v : NEG_SLOPE * v;
}

// One WAVE per node: 64 lanes resolve edge gather chains in parallel.
// Fast path deg<=64 keeps e-values in registers (one global write per edge-head).
__global__ void gat_softmax_wave(const float* __restrict__ el, const float* __restrict__ er,
                                 const int* __restrict__ src, const int* __restrict__ rs,
                                 const int* __restrict__ eidx, float* __restrict__ alpha,
                                 int N, int H) {
    int n = (blockIdx.x * blockDim.x + threadIdx.x) >> 6;
    int lane = threadIdx.x & 63;
    if (n >= N) return;
    int s0 = rs[n], s1 = rs[n + 1];
    int deg = s1 - s0;
    if (deg == 0) return;
    float ern0 = er[n * H + 0];
    float ern1 = (H > 1) ? er[n * H + 1] : 0.f;
    float ern2 = (H > 2) ? er[n * H + 2] : 0.f;
    if (deg <= 64) {
        int e = 0, s = 0;
        float v0 = -INFINITY, v1 = -INFINITY, v2 = -INFINITY;
        if (lane < deg) {
            e = eidx[s0 + lane];
            s = src[e];
            v0 = lrelu(el[s * H + 0] + ern0);
            if (H > 1) {
                v1 = lrelu(el[s * H + 1] + ern1);
                v2 = lrelu(el[s * H + 2] + ern2);
            }
        }
        float m0 = v0, m1 = v1, m2 = v2;
#pragma unroll
        for (int off = 32; off > 0; off >>= 1) {
            m0 = fmaxf(m0, __shfl_xor(m0, off, 64));
            m1 = fmaxf(m1, __shfl_xor(m1, off, 64));
            m2 = fmaxf(m2, __shfl_xor(m2, off, 64));
        }
        float ex0 = (lane < deg) ? expf(v0 - m0) : 0.f;
        float ex1 = (lane < deg && H > 1) ? expf(v1 - m1) : 0.f;
        float ex2 = (lane < deg && H > 2) ? expf(v2 - m2) : 0.f;
        float d0 = ex0, d1 = ex1, d2 = ex2;
#pragma unroll
        for (int off = 32; off > 0; off >>= 1) {
            d0 += __shfl_xor(d0, off, 64);
            d1 += __shfl_xor(d1, off, 64);
            d2 += __shfl_xor(d2, off, 64);
        }
        if (lane < deg) {
            alpha[(size_t)e * H + 0] = ex0 / d0;
            if (H > 1) {
                alpha[(size_t)e * H + 1] = ex1 / d1;
                alpha[(size_t)e * H + 2] = ex2 / d2;
            }
        }
    } else {
        // general path: 3 lane-parallel passes through global alpha
        float m0 = -INFINITY, m1 = -INFINITY, m2 = -INFINITY;
        for (int j = s0 + lane; j < s1; j += 64) {
            int e = eidx[j], s = src[e];
            float v0 = lrelu(el[s * H + 0] + ern0);
            alpha[(size_t)e * H + 0] = v0; m0 = fmaxf(m0, v0);
            if (H > 1) {
                float v1 = lrelu(el[s * H + 1] + ern1);
                float v2 = lrelu(el[s * H + 2] + ern2);
                alpha[(size_t)e * H + 1] = v1; m1 = fmaxf(m1, v1);
                alpha[(size_t)e * H + 2] = v2; m2 = fmaxf(m2, v2);
            }
        }
#pragma unroll
        for (int off = 32; off > 0; off >>= 1) {
            m0 = fmaxf(m0, __shfl_xor(m0, off, 64));
            m1 = fmaxf(m1, __shfl_xor(m1, off, 64));
            m2 = fmaxf(m2, __shfl_xor(m2, off, 64));
        }
        float d0 = 0.f, d1 = 0.f, d2 = 0.f;
        for (int j = s0 + lane; j < s1; j += 64) {
            int e = eidx[j];
            float ex0 = expf(alpha[(size_t)e * H + 0] - m0);
            alpha[(size_t)e * H + 0] = ex0; d0 += ex0;
            if (H > 1) {
                float ex1 = expf(alpha[(size_t)e * H + 1] - m1);
                float ex2 = expf(alpha[(size_t)e * H + 2] - m2);
                alpha[(size_t)e * H + 1] = ex1; d1 += ex1;
                alpha[(size_t)e * H + 2] = ex2; d2 += ex2;
            }
        }
#pragma unroll
        for (int off = 32; off > 0; off >>= 1) {
            d0 += __shfl_xor(d0, off, 64);
            d1 += __shfl_xor(d1, off, 64);
            d2 += __shfl_xor(d2, off, 64);
        }
        float i0 = 1.f / d0;
        float i1 = (H > 1) ? 1.f / d1 : 0.f;
        float i2 = (H > 2) ? 1.f / d2 : 0.f;
        for (int j = s0 + lane; j < s1; j += 64) {
            int e = eidx[j];
            alpha[(size_t)e * H + 0] *= i0;
            if (H > 1) {
                alpha[(size_t)e * H + 1] *= i1;
                alpha[(size_t)e * H + 2] *= i2;
            }
        }
    }
}

// Block per node. Edge metadata staged into LDS by parallel threads, then each
// compute lane owns ONE float4 column and streams independent dwordx4 gathers.
#define TILE_E 64
__global__ void gat_aggregate(const float4* __restrict__ h4, const float* __restrict__ alpha,
                              const int* __restrict__ src, const int* __restrict__ rs,
                              const int* __restrict__ eidx, float4* __restrict__ out4,
                              int N, int H, int D) {
    __shared__ int s_src[TILE_E];
    __shared__ float s_alpha[TILE_E * 3];
    int n = blockIdx.x;
    int HD4 = (H * D) >> 2;
    int tid = threadIdx.x;
    int s0 = rs[n], s1 = rs[n + 1];
    bool active = tid < HD4;
    int hh = active ? (tid << 2) / D : 0;
    float4 acc = {0.f, 0.f, 0.f, 0.f};
    for (int base = s0; base < s1; base += TILE_E) {
        int cntE = s1 - base; if (cntE > TILE_E) cntE = TILE_E;
        if (tid < cntE) {
            int e = eidx[base + tid];
            s_src[tid] = src[e];
#pragma unroll
            for (int h = 0; h < 3; ++h)
                if (h < H) s_alpha[tid * 3 + h] = alpha[(size_t)e * H + h];
        }
        __syncthreads();
        if (active) {
#pragma unroll 4
            for (int i = 0; i < cntE; ++i) {
                float a = s_alpha[i * 3 + hh];
                float4 hv = h4[(size_t)s_src[i] * HD4 + tid];
                acc.x += a * hv.x; acc.y += a * hv.y;
                acc.z += a * hv.z; acc.w += a * hv.w;
            }
        }
        __syncthreads();
    }
    if (active) {
        acc.x = fmaxf(acc.x, 0.f); acc.y = fmaxf(acc.y, 0.f);
        acc.z = fmaxf(acc.z, 0.f); acc.w = fmaxf(acc.w, 0.f);
        out4[(size_t)n * HD4 + tid] = acc;
    }
}

// Graph max-readout over post-ReLU (>=0) values via int-bitcast atomicMax.
__global__ void seg_max_atomic(const float* __restrict__ g, const int* __restrict__ nid,
                               int* __restrict__ out, int N, int C) {
    int n0 = blockIdx.x << 5;
    int n1 = n0 + 32; if (n1 > N) n1 = N;
    if (n0 >= N) return;
    for (int c = threadIdx.x; c < C; c += blockDim.x) {
        int cur = nid[n0];
        float m = 0.f;
        for (int n = n0; n < n1; ++n) {
            int gid = nid[n];
            if (gid != cur) {
                atomicMax(&out[cur * C + c], __float_as_int(m));
                cur = gid; m = 0.f;
            }
            m = fmaxf(m, g[(size_t)n * C + c]);
        }
        atomicMax(&out[cur * C + c], __float_as_int(m));
    }
}

// ---------------- small dense layers ----------------
__global__ void linear_wave(const float* __restrict__ in, const float* __restrict__ W,
                            const float* __restrict__ bias, float* __restrict__ out,
                            int K, int O, int act) {
    int o = blockIdx.x * 4 + (threadIdx.x >> 6);
    int b = blockIdx.y;
    int lane = threadIdx.x & 63;
    if (o >= O) return;
    const float* ip = in + (size_t)b * K;
    float acc = 0.f;
    for (int k = lane; k < K; k += 64)
        acc += ip[k] * W[(size_t)k * O + o];
    for (int off = 32; off > 0; off >>= 1)
        acc += __shfl_down(acc, off, 64);
    if (lane == 0) {
        acc += bias[o];
        if (act == 1) acc = fmaxf(acc, 0.f);
        else if (act == 2) acc = 1.f / (1.f + expf(-acc));
        out[(size_t)b * O + o] = acc;
    }
}

// ---------------- TextCNN ----------------
__global__ void transpose_pad(const float* __restrict__ pad, float* __restrict__ xT,
                              int B, int L, int C) {
    int idx = blockIdx.x * blockDim.x + threadIdx.x;
    int total = B * L * C;
    if (idx >= total) return;
    int l = idx % L;
    int c = (idx / L) % C;
    int b = idx / (L * C);
    xT[idx] = pad[((size_t)b * L + l) * C + c];
}

// conv1d k=3 VALID, 128 outputs. blockDim = 128*G; each thread: 1 output x 16
// positions (acc[16]). l-tile = 16*G. LDS x-tile row stride 68 floats (272B,
// 16B-aligned) so the 18-float window reads are 4xfloat4 + 1xfloat2.
// x reads are uniform across the o-dimension -> LDS broadcast, conflict-free.
#define CSTRIDE 68
__global__ void conv3k_v2(const float* __restrict__ x,
                          const float* __restrict__ w,
                          const float* __restrict__ bias,
                          float* __restrict__ y,
                          int Cin, int Lin, int Lout) {
    extern __shared__ float sx[];  // Cin x CSTRIDE
    int b = blockIdx.y;
    int G = blockDim.x >> 7;
    int tileW = G << 4;
    int l0 = blockIdx.x * tileW;
    int tid = threadIdx.x;
    int tileL = Lout - l0; if (tileL > tileW) tileL = tileW;
    int loadL = tileL + 2;
    for (int idx = tid; idx < Cin * loadL; idx += blockDim.x) {
        int c = idx / loadL, i = idx - c * loadL;
        sx[c * CSTRIDE + i] = x[((size_t)b * Cin + c) * Lin + l0 + i];
    }
    __syncthreads();
    int o = tid & 127;
    int pbase = (tid >> 7) << 4;
    int npos = tileL - pbase; if (npos > 16) npos = 16; if (npos < 0) npos = 0;
    float acc[16];
    float bv = bias[o];
#pragma unroll
    for (int j = 0; j < 16; ++j) acc[j] = bv;
    const float* wp = w + (size_t)o * Cin * 3;
    for (int c = 0; c < Cin; ++c) {
        const float* row = &sx[c * CSTRIDE + pbase];
        float xv[18];
        *(float4*)&xv[0]  = *(const float4*)&row[0];
        *(float4*)&xv[4]  = *(const float4*)&row[4];
        *(float4*)&xv[8]  = *(const float4*)&row[8];
        *(float4*)&xv[12] = *(const float4*)&row[12];
        *(float2*)&xv[16] = *(const float2*)&row[16];
        float w0 = wp[c * 3 + 0], w1 = wp[c * 3 + 1], w2 = wp[c * 3 + 2];
#pragma unroll
        for (int j = 0; j < 16; ++j) acc[j] += w0 * xv[j] + w1 * xv[j + 1] + w2 * xv[j + 2];
    }
    float* yp = y + ((size_t)b * 128 + o) * Lout + l0 + pbase;
#pragma unroll
    for (int j = 0; j < 16; ++j)
        if (j < npos) yp[j] = acc[j];
}

__global__ void maxpool(const float* __restrict__ y, float* __restrict__ p,
                        int BC, int Lin, int k, int s, int Lout) {
    int idx = blockIdx.x * blockDim.x + threadIdx.x;
    if (idx >= BC * Lout) return;
    int lo = idx % Lout, bc = idx / Lout;
    const float* yp = y + (size_t)bc * Lin + lo * s;
    float m = -INFINITY;
    for (int i = 0; i < k; ++i) m = fmaxf(m, yp[i]);
    p[idx] = m;
}

__global__ void combine_branch(const float* __restrict__ g, const float* __restrict__ s,
                               const float* __restrict__ w1, float* __restrict__ cat, int off) {
    int idx = blockIdx.x * blockDim.x + threadIdx.x;
    if (idx >= 16 * 128) return;
    int b = idx >> 7, c = idx & 127;
    float w = 1.f / (1.f + expf(-w1[0]));
    cat[b * 256 + off + c] = (1.f - w) * g[idx] + w * s[idx];
}

// ---------------- host ----------------
extern "C" void kernel_launch(void* const* d_in, const int* in_sizes, int n_in,
                              void* d_out, int out_size, void* d_ws, size_t ws_size,
                              hipStream_t stream) {
    const float* feat[2] = {(const float*)d_in[0], (const float*)d_in[1]};
    const float* pad[2]  = {(const float*)d_in[2], (const float*)d_in[3]};
    const int* src[2]    = {(const int*)d_in[4], (const int*)d_in[6]};
    const int* dst[2]    = {(const int*)d_in[5], (const int*)d_in[7]};
    const int* nid[2]    = {(const int*)d_in[8], (const int*)d_in[9]};
    const float* Wg[3]   = {(const float*)d_in[11], (const float*)d_in[14], (const float*)d_in[17]};
    const float* al[3]   = {(const float*)d_in[12], (const float*)d_in[15], (const float*)d_in[18]};
    const float* ar[3]   = {(const float*)d_in[13], (const float*)d_in[16], (const float*)d_in[19]};
    const float* fcg_w = (const float*)d_in[20]; const float* fcg_b = (const float*)d_in[21];
    const float* c1w = (const float*)d_in[22];   const float* c1b = (const float*)d_in[23];
    const float* c2w = (const float*)d_in[24];   const float* c2b = (const float*)d_in[25];
    const float* c3w = (const float*)d_in[26];   const float* c3b = (const float*)d_in[27];
    const float* tf_w = (const float*)d_in[28];  const float* tf_b = (const float*)d_in[29];
    const float* w1 = (const float*)d_in[30];
    const float* fc1_w = (const float*)d_in[31]; const float* fc1_b = (const float*)d_in[32];
    const float* fc2_w = (const float*)d_in[33]; const float* fc2_b = (const float*)d_in[34];
    const float* outw = (const float*)d_in[35];  const float* outb = (const float*)d_in[36];
    float* out = (float*)d_out;

    const int N = in_sizes[0] / 64;   // 8000
    const int E = in_sizes[4];        // 160000
    const int B = 16, L = 1200;

    char* wsb = (char*)d_ws;
    size_t off = 0;
    auto alloc = [&](size_t elems) -> void* {
        void* p = wsb + off;
        off += (elems * 4 + 255) & ~(size_t)255;
        return p;
    };
    float* h_buf = (float*)alloc((size_t)N * 576);
    float* gA    = (float*)alloc((size_t)N * 576);
    float* gB    = (float*)alloc((size_t)N * 576);
    float* el    = (float*)alloc((size_t)N * 3);
    float* er    = (float*)alloc((size_t)N * 3);
    float* alpha = (float*)alloc((size_t)E * 3);
    int* rs      = (int*)alloc(N + 1);
    int* cnt     = (int*)alloc(N);
    int* eidx    = (int*)alloc(E);
    int* gmax    = (int*)alloc((size_t)B * 576);   // float bits via atomicMax
    float* gvec  = (float*)alloc((size_t)B * 128);
    float* xT    = (float*)alloc((size_t)B * 64 * L);
    float* y1    = (float*)alloc((size_t)B * 128 * 1198);
    float* p1    = (float*)alloc((size_t)B * 128 * 399);
    float* y2    = (float*)alloc((size_t)B * 128 * 397);
    float* p2    = (float*)alloc((size_t)B * 128 * 132);
    float* y3    = (float*)alloc((size_t)B * 128 * 130);
    float* sp    = (float*)alloc((size_t)B * 128);
    float* sf    = (float*)alloc((size_t)B * 128);
    float* cat   = (float*)alloc((size_t)B * 256);
    float* f1    = (float*)alloc((size_t)B * 512);
    float* f2    = (float*)alloc((size_t)B * 256);
    (void)ws_size; (void)n_in; (void)out_size;

    for (int br = 0; br < 2; ++br) {
        // --- CSR by dst ---
        zero_i32<<<(N + 255) / 256, 256, 0, stream>>>(cnt, N);
        count_edges<<<(E + 255) / 256, 256, 0, stream>>>(dst[br], cnt, E);
        scan_block<<<1, 1024, 0, stream>>>(cnt, rs, N);
        zero_i32<<<(N + 255) / 256, 256, 0, stream>>>(cnt, N);
        scatter_edges<<<(E + 255) / 256, 256, 0, stream>>>(dst[br], rs, cnt, eidx, E);

        // --- 3 GAT layers ---
        const int dims[3][3] = {{64, 3, 64}, {192, 3, 192}, {576, 1, 576}};  // K,H,D
        float* outs[3] = {gA, gB, gA};
        const float* in_ptr = feat[br];
        for (int ly = 0; ly < 3; ++ly) {
            int K = dims[ly][0], H = dims[ly][1], D = dims[ly][2];
            int HD = H * D;
            gemm64<<<dim3(HD / 64, (N + 63) / 64), 256, 0, stream>>>(in_ptr, Wg[ly], h_buf, N, K, HD);
            int waves = N * H;
            gat_elr<<<((size_t)waves * 64 + 255) / 256, 256, 0, stream>>>(h_buf, al[ly], ar[ly], el, er, N, H, D);
            gat_softmax_wave<<<((size_t)N * 64 + 255) / 256, 256, 0, stream>>>(el, er, src[br], rs, eidx, alpha, N, H);
            int aggThreads = (((HD >> 2) + 63) / 64) * 64;   // 64 for HD=192, 192 for HD=576
            gat_aggregate<<<N, aggThreads, 0, stream>>>((const float4*)h_buf, alpha, src[br], rs, eidx,
                                                        (float4*)outs[ly], N, H, D);
            in_ptr = outs[ly];
        }
        zero_i32<<<(B * 576 + 255) / 256, 256, 0, stream>>>(gmax, B * 576);
        seg_max_atomic<<<(N + 31) / 32, 256, 0, stream>>>(gA, nid[br], gmax, N, 576);
        linear_wave<<<dim3(32, B), 256, 0, stream>>>((const float*)gmax, fcg_w, fcg_b, gvec, 576, 128, 1);

        // --- TextCNN ---
        transpose_pad<<<((B * 64 * L) + 255) / 256, 256, 0, stream>>>(pad[br], xT, B, L, 64);
        // conv1: tile 64 (G=4, 512 thr), conv2/3: tile 32 (G=2, 256 thr)
        conv3k_v2<<<dim3((1198 + 63) / 64, B), 512, 64 * CSTRIDE * 4, stream>>>(xT, c1w, c1b, y1, 64, 1200, 1198);
        maxpool<<<(B * 128 * 399 + 255) / 256, 256, 0, stream>>>(y1, p1, B * 128, 1198, 3, 3, 399);
        conv3k_v2<<<dim3((397 + 31) / 32, B), 256, 128 * CSTRIDE * 4, stream>>>(p1, c2w, c2b, y2, 128, 399, 397);
        maxpool<<<(B * 128 * 132 + 255) / 256, 256, 0, stream>>>(y2, p2, B * 128, 397, 3, 3, 132);
        conv3k_v2<<<dim3((130 + 31) / 32, B), 256, 128 * CSTRIDE * 4, stream>>>(p2, c3w, c3b, y3, 128, 132, 130);
        maxpool<<<(B * 128 + 255) / 256, 256, 0, stream>>>(y3, sp, B * 128, 130, 130, 1, 1);
        linear_wave<<<dim3(32, B), 256, 0, stream>>>(sp, tf_w, tf_b, sf, 128, 128, 1);

        combine_branch<<<(B * 128 + 255) / 256, 256, 0, stream>>>(gvec, sf, w1, cat, br * 128);
    }

    // --- head MLP ---
    linear_wave<<<dim3(128, B), 256, 0, stream>>>(cat, fc1_w, fc1_b, f1, 256, 512, 1);
    linear_wave<<<dim3(64, B), 256, 0, stream>>>(f1, fc2_w, fc2_b, f2, 512, 256, 1);
    linear_wave<<<dim3(1, B), 256, 0, stream>>>(f2, outw, outb, out, 256, 1, 2);
}

// Round 6
// 1164.965 us; speedup vs baseline: 2.8328x; 1.0210x over previous
//
#include <hip/hip_runtime.h>
#include <hip/hip_bf16.h>
#include <math.h>

#define NEG_SLOPE 0.2f

// ---------------- utility ----------------
__global__ void zero_i32(int* __restrict__ p, int n) {
    int i = blockIdx.x * blockDim.x + threadIdx.x;
    if (i < n) p[i] = 0;
}

// ---------------- CSR build ----------------
__global__ void count_edges(const int* __restrict__ dst, int* __restrict__ cnt, int E) {
    int i = blockIdx.x * blockDim.x + threadIdx.x;
    if (i < E) atomicAdd(&cnt[dst[i]], 1);
}

__global__ void scan_block(const int* __restrict__ cnt, int* __restrict__ rs, int N) {
    __shared__ int s[1024];
    int tid = threadIdx.x;
    int running = 0;
    for (int base = 0; base < N; base += 1024) {
        int v = (base + tid < N) ? cnt[base + tid] : 0;
        __syncthreads();
        s[tid] = v;
        __syncthreads();
        for (int off = 1; off < 1024; off <<= 1) {
            int t = (tid >= off) ? s[tid - off] : 0;
            __syncthreads();
            if (tid >= off) s[tid] += t;
            __syncthreads();
        }
        if (base + tid < N) rs[base + tid] = running + s[tid] - v;
        running += s[1023];
    }
    if (tid == 0) rs[N] = running;
}

__global__ void scatter_edges(const int* __restrict__ dst, const int* __restrict__ rs,
                              int* __restrict__ fill, int* __restrict__ eidx, int E) {
    int i = blockIdx.x * blockDim.x + threadIdx.x;
    if (i < E) {
        int d = dst[i];
        int pos = atomicAdd(&fill[d], 1);
        eidx[rs[d] + pos] = i;
    }
}

// ---------------- bf16 split (fp32 -> hi/lo bf16, x3-K concat) ----------------
__device__ __forceinline__ short f2bf(float x) {
    __hip_bfloat16 h = __float2bfloat16(x);
    return *reinterpret_cast<short*>(&h);
}
__device__ __forceinline__ float bf2f(short s) {
    unsigned int u = ((unsigned int)(unsigned short)s) << 16;
    return __uint_as_float(u);
}

// X (M x K fp32, row-major) -> A3 (M x 3K bf16): [Ah | Al | Ah]
__global__ void split_bf3_x(const float* __restrict__ X, short* __restrict__ A3, int M, int K) {
    int idx = blockIdx.x * blockDim.x + threadIdx.x;
    if (idx >= M * K) return;
    int m = idx / K, k = idx - m * K;
    float x = X[idx];
    short hs = f2bf(x);
    short ls = f2bf(x - bf2f(hs));
    size_t base = (size_t)m * 3 * K;
    A3[base + k] = hs;
    A3[base + K + k] = ls;
    A3[base + 2 * K + k] = hs;
}

// W (K x N fp32) -> W3t (N x 3K bf16, transposed): rows [Wh | Wh | Wl]
__global__ void split_bf3_w(const float* __restrict__ W, short* __restrict__ W3t, int K, int N) {
    int idx = blockIdx.x * blockDim.x + threadIdx.x;
    if (idx >= K * N) return;
    int k = idx / N, n = idx - k * N;
    float x = W[idx];
    short hs = f2bf(x);
    short ls = f2bf(x - bf2f(hs));
    size_t base = (size_t)n * 3 * K;
    W3t[base + k] = hs;
    W3t[base + K + k] = hs;
    W3t[base + 2 * K + k] = ls;
}

// ---------------- MFMA bf16 GEMM-BT: C(MxN) fp32 = A3(MxKp) * W3t(NxKp)^T ----
// Requires M%64==0, N%64==0, Kp%64==0 (true for all call sites).
// 64x64 C-tile, 4 waves: wave w owns rows [w*16,w*16+16) x 64 cols (4 MFMA tiles).
// LDS stride 72 bf16 (144B): 16B-aligned b128 reads, 2-way bank aliasing only.
typedef __attribute__((ext_vector_type(8))) short short8;
typedef __attribute__((ext_vector_type(4))) float floatx4;

__global__ __launch_bounds__(256) void gemm_bf3(const short* __restrict__ A,
                                                const short* __restrict__ Bt,
                                                float* __restrict__ C,
                                                int M, int Kp, int N) {
    __shared__ __align__(16) short sA[64 * 72];
    __shared__ __align__(16) short sB[64 * 72];
    int tid = threadIdx.x;
    int wave = tid >> 6, lane = tid & 63;
    int m = lane & 15, q = lane >> 4;
    int row0 = blockIdx.y << 6, col0 = blockIdx.x << 6;
    floatx4 acc[4];
#pragma unroll
    for (int ct = 0; ct < 4; ++ct) acc[ct] = (floatx4){0.f, 0.f, 0.f, 0.f};
    for (int k0 = 0; k0 < Kp; k0 += 64) {
#pragma unroll
        for (int p = 0; p < 2; ++p) {
            int idx = tid + (p << 8);
            int r = idx >> 3, s = (idx & 7) << 3;
            *(float4*)&sA[r * 72 + s] = *(const float4*)&A[(size_t)(row0 + r) * Kp + k0 + s];
            *(float4*)&sB[r * 72 + s] = *(const float4*)&Bt[(size_t)(col0 + r) * Kp + k0 + s];
        }
        __syncthreads();
#pragma unroll
        for (int kk = 0; kk < 64; kk += 32) {
            short8 a = *(const short8*)&sA[(wave * 16 + m) * 72 + kk + q * 8];
#pragma unroll
            for (int ct = 0; ct < 4; ++ct) {
                short8 b = *(const short8*)&sB[(ct * 16 + m) * 72 + kk + q * 8];
                acc[ct] = __builtin_amdgcn_mfma_f32_16x16x32_bf16(a, b, acc[ct], 0, 0, 0);
            }
        }
        __syncthreads();
    }
#pragma unroll
    for (int ct = 0; ct < 4; ++ct)
#pragma unroll
        for (int r = 0; r < 4; ++r)
            C[(size_t)(row0 + wave * 16 + q * 4 + r) * N + col0 + ct * 16 + m] = acc[ct][r];
}

// ---------------- GAT pieces ----------------
__global__ void gat_elr(const float* __restrict__ h, const float* __restrict__ al,
                        const float* __restrict__ ar, float* __restrict__ el,
                        float* __restrict__ er, int N, int H, int D) {
    int wid = (blockIdx.x * blockDim.x + threadIdx.x) >> 6;
    int lane = threadIdx.x & 63;
    if (wid >= N * H) return;
    int n = wid / H, hh = wid - n * H;
    const float* hp = h + ((size_t)n * H + hh) * D;
    const float* alp = al + (size_t)hh * D;
    const float* arp = ar + (size_t)hh * D;
    float sl = 0.f, sr = 0.f;
    for (int d = lane; d < D; d += 64) {
        float v = hp[d];
        sl += v * alp[d];
        sr += v * arp[d];
    }
    for (int off = 32; off > 0; off >>= 1) {
        sl += __shfl_down(sl, off, 64);
        sr += __shfl_down(sr, off, 64);
    }
    if (lane == 0) { el[wid] = sl; er[wid] = sr; }
}

__device__ __forceinline__ float lrelu(float v) {
    return (v > 0.f) ? v : NEG_SLOPE * v;
}

// One WAVE per node: 64 lanes resolve edge gather chains in parallel.
__global__ void gat_softmax_wave(const float* __restrict__ el, const float* __restrict__ er,
                                 const int* __restrict__ src, const int* __restrict__ rs,
                                 const int* __restrict__ eidx, float* __restrict__ alpha,
                                 int N, int H) {
    int n = (blockIdx.x * blockDim.x + threadIdx.x) >> 6;
    int lane = threadIdx.x & 63;
    if (n >= N) return;
    int s0 = rs[n], s1 = rs[n + 1];
    int deg = s1 - s0;
    if (deg == 0) return;
    float ern0 = er[n * H + 0];
    float ern1 = (H > 1) ? er[n * H + 1] : 0.f;
    float ern2 = (H > 2) ? er[n * H + 2] : 0.f;
    if (deg <= 64) {
        int e = 0, s = 0;
        float v0 = -INFINITY, v1 = -INFINITY, v2 = -INFINITY;
        if (lane < deg) {
            e = eidx[s0 + lane];
            s = src[e];
            v0 = lrelu(el[s * H + 0] + ern0);
            if (H > 1) {
                v1 = lrelu(el[s * H + 1] + ern1);
                v2 = lrelu(el[s * H + 2] + ern2);
            }
        }
        float m0 = v0, m1 = v1, m2 = v2;
#pragma unroll
        for (int off = 32; off > 0; off >>= 1) {
            m0 = fmaxf(m0, __shfl_xor(m0, off, 64));
            m1 = fmaxf(m1, __shfl_xor(m1, off, 64));
            m2 = fmaxf(m2, __shfl_xor(m2, off, 64));
        }
        float ex0 = (lane < deg) ? expf(v0 - m0) : 0.f;
        float ex1 = (lane < deg && H > 1) ? expf(v1 - m1) : 0.f;
        float ex2 = (lane < deg && H > 2) ? expf(v2 - m2) : 0.f;
        float d0 = ex0, d1 = ex1, d2 = ex2;
#pragma unroll
        for (int off = 32; off > 0; off >>= 1) {
            d0 += __shfl_xor(d0, off, 64);
            d1 += __shfl_xor(d1, off, 64);
            d2 += __shfl_xor(d2, off, 64);
        }
        if (lane < deg) {
            alpha[(size_t)e * H + 0] = ex0 / d0;
            if (H > 1) {
                alpha[(size_t)e * H + 1] = ex1 / d1;
                alpha[(size_t)e * H + 2] = ex2 / d2;
            }
        }
    } else {
        float m0 = -INFINITY, m1 = -INFINITY, m2 = -INFINITY;
        for (int j = s0 + lane; j < s1; j += 64) {
            int e = eidx[j], s = src[e];
            float v0 = lrelu(el[s * H + 0] + ern0);
            alpha[(size_t)e * H + 0] = v0; m0 = fmaxf(m0, v0);
            if (H > 1) {
                float v1 = lrelu(el[s * H + 1] + ern1);
                float v2 = lrelu(el[s * H + 2] + ern2);
                alpha[(size_t)e * H + 1] = v1; m1 = fmaxf(m1, v1);
                alpha[(size_t)e * H + 2] = v2; m2 = fmaxf(m2, v2);
            }
        }
#pragma unroll
        for (int off = 32; off > 0; off >>= 1) {
            m0 = fmaxf(m0, __shfl_xor(m0, off, 64));
            m1 = fmaxf(m1, __shfl_xor(m1, off, 64));
            m2 = fmaxf(m2, __shfl_xor(m2, off, 64));
        }
        float d0 = 0.f, d1 = 0.f, d2 = 0.f;
        for (int j = s0 + lane; j < s1; j += 64) {
            int e = eidx[j];
            float ex0 = expf(alpha[(size_t)e * H + 0] - m0);
            alpha[(size_t)e * H + 0] = ex0; d0 += ex0;
            if (H > 1) {
                float ex1 = expf(alpha[(size_t)e * H + 1] - m1);
                float ex2 = expf(alpha[(size_t)e * H + 2] - m2);
                alpha[(size_t)e * H + 1] = ex1; d1 += ex1;
                alpha[(size_t)e * H + 2] = ex2; d2 += ex2;
            }
        }
#pragma unroll
        for (int off = 32; off > 0; off >>= 1) {
            d0 += __shfl_xor(d0, off, 64);
            d1 += __shfl_xor(d1, off, 64);
            d2 += __shfl_xor(d2, off, 64);
        }
        float i0 = 1.f / d0;
        float i1 = (H > 1) ? 1.f / d1 : 0.f;
        float i2 = (H > 2) ? 1.f / d2 : 0.f;
        for (int j = s0 + lane; j < s1; j += 64) {
            int e = eidx[j];
            alpha[(size_t)e * H + 0] *= i0;
            if (H > 1) {
                alpha[(size_t)e * H + 1] *= i1;
                alpha[(size_t)e * H + 2] *= i2;
            }
        }
    }
}

// Block per node. Edge metadata staged into LDS, lanes own float4 columns.
#define TILE_E 64
__global__ void gat_aggregate(const float4* __restrict__ h4, const float* __restrict__ alpha,
                              const int* __restrict__ src, const int* __restrict__ rs,
                              const int* __restrict__ eidx, float4* __restrict__ out4,
                              int N, int H, int D) {
    __shared__ int s_src[TILE_E];
    __shared__ float s_alpha[TILE_E * 3];
    int n = blockIdx.x;
    int HD4 = (H * D) >> 2;
    int tid = threadIdx.x;
    int s0 = rs[n], s1 = rs[n + 1];
    bool active = tid < HD4;
    int hh = active ? (tid << 2) / D : 0;
    float4 acc = {0.f, 0.f, 0.f, 0.f};
    for (int base = s0; base < s1; base += TILE_E) {
        int cntE = s1 - base; if (cntE > TILE_E) cntE = TILE_E;
        if (tid < cntE) {
            int e = eidx[base + tid];
            s_src[tid] = src[e];
#pragma unroll
            for (int h = 0; h < 3; ++h)
                if (h < H) s_alpha[tid * 3 + h] = alpha[(size_t)e * H + h];
        }
        __syncthreads();
        if (active) {
#pragma unroll 4
            for (int i = 0; i < cntE; ++i) {
                float a = s_alpha[i * 3 + hh];
                float4 hv = h4[(size_t)s_src[i] * HD4 + tid];
                acc.x += a * hv.x; acc.y += a * hv.y;
                acc.z += a * hv.z; acc.w += a * hv.w;
            }
        }
        __syncthreads();
    }
    if (active) {
        acc.x = fmaxf(acc.x, 0.f); acc.y = fmaxf(acc.y, 0.f);
        acc.z = fmaxf(acc.z, 0.f); acc.w = fmaxf(acc.w, 0.f);
        out4[(size_t)n * HD4 + tid] = acc;
    }
}

// Graph max-readout over post-ReLU (>=0) values via int-bitcast atomicMax.
__global__ void seg_max_atomic(const float* __restrict__ g, const int* __restrict__ nid,
                               int* __restrict__ out, int N, int C) {
    int n0 = blockIdx.x << 5;
    int n1 = n0 + 32; if (n1 > N) n1 = N;
    if (n0 >= N) return;
    for (int c = threadIdx.x; c < C; c += blockDim.x) {
        int cur = nid[n0];
        float m = 0.f;
        for (int n = n0; n < n1; ++n) {
            int gid = nid[n];
            if (gid != cur) {
                atomicMax(&out[cur * C + c], __float_as_int(m));
                cur = gid; m = 0.f;
            }
            m = fmaxf(m, g[(size_t)n * C + c]);
        }
        atomicMax(&out[cur * C + c], __float_as_int(m));
    }
}

// ---------------- small dense layers ----------------
__global__ void linear_wave(const float* __restrict__ in, const float* __restrict__ W,
                            const float* __restrict__ bias, float* __restrict__ out,
                            int K, int O, int act) {
    int o = blockIdx.x * 4 + (threadIdx.x >> 6);
    int b = blockIdx.y;
    int lane = threadIdx.x & 63;
    if (o >= O) return;
    const float* ip = in + (size_t)b * K;
    float acc = 0.f;
    for (int k = lane; k < K; k += 64)
        acc += ip[k] * W[(size_t)k * O + o];
    for (int off = 32; off > 0; off >>= 1)
        acc += __shfl_down(acc, off, 64);
    if (lane == 0) {
        acc += bias[o];
        if (act == 1) acc = fmaxf(acc, 0.f);
        else if (act == 2) acc = 1.f / (1.f + expf(-acc));
        out[(size_t)b * O + o] = acc;
    }
}

// ---------------- TextCNN ----------------
__global__ void transpose_pad(const float* __restrict__ pad, float* __restrict__ xT,
                              int B, int L, int C) {
    int idx = blockIdx.x * blockDim.x + threadIdx.x;
    int total = B * L * C;
    if (idx >= total) return;
    int l = idx % L;
    int c = (idx / L) % C;
    int b = idx / (L * C);
    xT[idx] = pad[((size_t)b * L + l) * C + c];
}

#define CSTRIDE 68
__global__ void conv3k_v2(const float* __restrict__ x,
                          const float* __restrict__ w,
                          const float* __restrict__ bias,
                          float* __restrict__ y,
                          int Cin, int Lin, int Lout) {
    extern __shared__ float sx[];  // Cin x CSTRIDE
    int b = blockIdx.y;
    int G = blockDim.x >> 7;
    int tileW = G << 4;
    int l0 = blockIdx.x * tileW;
    int tid = threadIdx.x;
    int tileL = Lout - l0; if (tileL > tileW) tileL = tileW;
    int loadL = tileL + 2;
    for (int idx = tid; idx < Cin * loadL; idx += blockDim.x) {
        int c = idx / loadL, i = idx - c * loadL;
        sx[c * CSTRIDE + i] = x[((size_t)b * Cin + c) * Lin + l0 + i];
    }
    __syncthreads();
    int o = tid & 127;
    int pbase = (tid >> 7) << 4;
    int npos = tileL - pbase; if (npos > 16) npos = 16; if (npos < 0) npos = 0;
    float acc[16];
    float bv = bias[o];
#pragma unroll
    for (int j = 0; j < 16; ++j) acc[j] = bv;
    const float* wp = w + (size_t)o * Cin * 3;
    for (int c = 0; c < Cin; ++c) {
        const float* row = &sx[c * CSTRIDE + pbase];
        float xv[18];
        *(float4*)&xv[0]  = *(const float4*)&row[0];
        *(float4*)&xv[4]  = *(const float4*)&row[4];
        *(float4*)&xv[8]  = *(const float4*)&row[8];
        *(float4*)&xv[12] = *(const float4*)&row[12];
        *(float2*)&xv[16] = *(const float2*)&row[16];
        float w0 = wp[c * 3 + 0], w1 = wp[c * 3 + 1], w2 = wp[c * 3 + 2];
#pragma unroll
        for (int j = 0; j < 16; ++j) acc[j] += w0 * xv[j] + w1 * xv[j + 1] + w2 * xv[j + 2];
    }
    float* yp = y + ((size_t)b * 128 + o) * Lout + l0 + pbase;
#pragma unroll
    for (int j = 0; j < 16; ++j)
        if (j < npos) yp[j] = acc[j];
}

__global__ void maxpool(const float* __restrict__ y, float* __restrict__ p,
                        int BC, int Lin, int k, int s, int Lout) {
    int idx = blockIdx.x * blockDim.x + threadIdx.x;
    if (idx >= BC * Lout) return;
    int lo = idx % Lout, bc = idx / Lout;
    const float* yp = y + (size_t)bc * Lin + lo * s;
    float m = -INFINITY;
    for (int i = 0; i < k; ++i) m = fmaxf(m, yp[i]);
    p[idx] = m;
}

__global__ void combine_branch(const float* __restrict__ g, const float* __restrict__ s,
                               const float* __restrict__ w1, float* __restrict__ cat, int off) {
    int idx = blockIdx.x * blockDim.x + threadIdx.x;
    if (idx >= 16 * 128) return;
    int b = idx >> 7, c = idx & 127;
    float w = 1.f / (1.f + expf(-w1[0]));
    cat[b * 256 + off + c] = (1.f - w) * g[idx] + w * s[idx];
}

// ---------------- host ----------------
extern "C" void kernel_launch(void* const* d_in, const int* in_sizes, int n_in,
                              void* d_out, int out_size, void* d_ws, size_t ws_size,
                              hipStream_t stream) {
    const float* feat[2] = {(const float*)d_in[0], (const float*)d_in[1]};
    const float* pad[2]  = {(const float*)d_in[2], (const float*)d_in[3]};
    const int* src[2]    = {(const int*)d_in[4], (const int*)d_in[6]};
    const int* dst[2]    = {(const int*)d_in[5], (const int*)d_in[7]};
    const int* nid[2]    = {(const int*)d_in[8], (const int*)d_in[9]};
    const float* Wg[3]   = {(const float*)d_in[11], (const float*)d_in[14], (const float*)d_in[17]};
    const float* al[3]   = {(const float*)d_in[12], (const float*)d_in[15], (const float*)d_in[18]};
    const float* ar[3]   = {(const float*)d_in[13], (const float*)d_in[16], (const float*)d_in[19]};
    const float* fcg_w = (const float*)d_in[20]; const float* fcg_b = (const float*)d_in[21];
    const float* c1w = (const float*)d_in[22];   const float* c1b = (const float*)d_in[23];
    const float* c2w = (const float*)d_in[24];   const float* c2b = (const float*)d_in[25];
    const float* c3w = (const float*)d_in[26];   const float* c3b = (const float*)d_in[27];
    const float* tf_w = (const float*)d_in[28];  const float* tf_b = (const float*)d_in[29];
    const float* w1 = (const float*)d_in[30];
    const float* fc1_w = (const float*)d_in[31]; const float* fc1_b = (const float*)d_in[32];
    const float* fc2_w = (const float*)d_in[33]; const float* fc2_b = (const float*)d_in[34];
    const float* outw = (const float*)d_in[35];  const float* outb = (const float*)d_in[36];
    float* out = (float*)d_out;

    const int N = in_sizes[0] / 64;   // 8000
    const int E = in_sizes[4];        // 160000
    const int B = 16, L = 1200;

    char* wsb = (char*)d_ws;
    size_t off = 0;
    auto allocB = [&](size_t bytes) -> void* {
        void* p = wsb + off;
        off += (bytes + 255) & ~(size_t)255;
        return p;
    };
    auto alloc = [&](size_t elems) -> void* { return allocB(elems * 4); };

    float* h_buf = (float*)alloc((size_t)N * 576);
    float* gA    = (float*)alloc((size_t)N * 576);
    float* gB    = (float*)alloc((size_t)N * 576);
    float* el    = (float*)alloc((size_t)N * 3);
    float* er    = (float*)alloc((size_t)N * 3);
    float* alpha = (float*)alloc((size_t)E * 3);
    int* rs      = (int*)alloc(N + 1);
    int* cnt     = (int*)alloc(N);
    int* eidx    = (int*)alloc(E);
    int* gmax    = (int*)alloc((size_t)B * 576);
    float* gvec  = (float*)alloc((size_t)B * 128);
    float* sp    = (float*)alloc((size_t)B * 128);
    float* sf    = (float*)alloc((size_t)B * 128);
    float* cat   = (float*)alloc((size_t)B * 256);
    float* f1    = (float*)alloc((size_t)B * 512);
    float* f2    = (float*)alloc((size_t)B * 256);
    // W3t buffers (bf16 shorts), hoisted out of the branch loop:
    short* w3t1  = (short*)allocB((size_t)192 * 3 * 64 * 2);    // N=192 x 3K(64)
    short* w3t2  = (short*)allocB((size_t)576 * 3 * 192 * 2);   // N=576 x 3K(192)
    short* w3t3  = (short*)allocB((size_t)576 * 3 * 576 * 2);   // N=576 x 3K(576)
    // UNION: A3 (bf16 activations, max 8000 x 1728 = 27.65 MB) aliases the
    // TextCNN scratch (disjoint lifetimes within a branch iteration).
    char* uni = (char*)allocB(28 * 1024 * 1024);
    short* A3 = (short*)uni;
    float* xT = (float*)uni;
    float* y1 = xT + (size_t)B * 64 * L;
    float* p1 = y1 + (size_t)B * 128 * 1198;
    float* y2 = p1 + (size_t)B * 128 * 399;
    float* p2 = y2 + (size_t)B * 128 * 397;
    float* y3 = p2 + (size_t)B * 128 * 132;
    (void)ws_size; (void)n_in; (void)out_size;

    // Weight splits (identical across branches)
    split_bf3_w<<<(64 * 192 + 255) / 256, 256, 0, stream>>>(Wg[0], w3t1, 64, 192);
    split_bf3_w<<<(192 * 576 + 255) / 256, 256, 0, stream>>>(Wg[1], w3t2, 192, 576);
    split_bf3_w<<<(576 * 576 + 255) / 256, 256, 0, stream>>>(Wg[2], w3t3, 576, 576);
    short* w3t[3] = {w3t1, w3t2, w3t3};

    for (int br = 0; br < 2; ++br) {
        // --- CSR by dst ---
        zero_i32<<<(N + 255) / 256, 256, 0, stream>>>(cnt, N);
        count_edges<<<(E + 255) / 256, 256, 0, stream>>>(dst[br], cnt, E);
        scan_block<<<1, 1024, 0, stream>>>(cnt, rs, N);
        zero_i32<<<(N + 255) / 256, 256, 0, stream>>>(cnt, N);
        scatter_edges<<<(E + 255) / 256, 256, 0, stream>>>(dst[br], rs, cnt, eidx, E);

        // --- 3 GAT layers ---
        const int dims[3][3] = {{64, 3, 64}, {192, 3, 192}, {576, 1, 576}};  // K,H,D
        float* outs[3] = {gA, gB, gA};
        const float* in_ptr = feat[br];
        for (int ly = 0; ly < 3; ++ly) {
            int K = dims[ly][0], H = dims[ly][1], D = dims[ly][2];
            int HD = H * D;
            split_bf3_x<<<((size_t)N * K + 255) / 256, 256, 0, stream>>>(in_ptr, A3, N, K);
            gemm_bf3<<<dim3(HD / 64, N / 64), 256, 0, stream>>>(A3, w3t[ly], h_buf, N, 3 * K, HD);
            int waves = N * H;
            gat_elr<<<((size_t)waves * 64 + 255) / 256, 256, 0, stream>>>(h_buf, al[ly], ar[ly], el, er, N, H, D);
            gat_softmax_wave<<<((size_t)N * 64 + 255) / 256, 256, 0, stream>>>(el, er, src[br], rs, eidx, alpha, N, H);
            int aggThreads = (((HD >> 2) + 63) / 64) * 64;
            gat_aggregate<<<N, aggThreads, 0, stream>>>((const float4*)h_buf, alpha, src[br], rs, eidx,
                                                        (float4*)outs[ly], N, H, D);
            in_ptr = outs[ly];
        }
        zero_i32<<<(B * 576 + 255) / 256, 256, 0, stream>>>(gmax, B * 576);
        seg_max_atomic<<<(N + 31) / 32, 256, 0, stream>>>(gA, nid[br], gmax, N, 576);
        linear_wave<<<dim3(32, B), 256, 0, stream>>>((const float*)gmax, fcg_w, fcg_b, gvec, 576, 128, 1);

        // --- TextCNN (reuses the A3 union region; A3 dead by here) ---
        transpose_pad<<<((B * 64 * L) + 255) / 256, 256, 0, stream>>>(pad[br], xT, B, L, 64);
        conv3k_v2<<<dim3((1198 + 63) / 64, B), 512, 64 * CSTRIDE * 4, stream>>>(xT, c1w, c1b, y1, 64, 1200, 1198);
        maxpool<<<(B * 128 * 399 + 255) / 256, 256, 0, stream>>>(y1, p1, B * 128, 1198, 3, 3, 399);
        conv3k_v2<<<dim3((397 + 31) / 32, B), 256, 128 * CSTRIDE * 4, stream>>>(p1, c2w, c2b, y2, 128, 399, 397);
        maxpool<<<(B * 128 * 132 + 255) / 256, 256, 0, stream>>>(y2, p2, B * 128, 397, 3, 3, 132);
        conv3k_v2<<<dim3((130 + 31) / 32, B), 256, 128 * CSTRIDE * 4, stream>>>(p2, c3w, c3b, y3, 128, 132, 130);
        maxpool<<<(B * 128 + 255) / 256, 256, 0, stream>>>(y3, sp, B * 128, 130, 130, 1, 1);
        linear_wave<<<dim3(32, B), 256, 0, stream>>>(sp, tf_w, tf_b, sf, 128, 128, 1);

        combine_branch<<<(B * 128 + 255) / 256, 256, 0, stream>>>(gvec, sf, w1, cat, br * 128);
    }

    // --- head MLP ---
    linear_wave<<<dim3(128, B), 256, 0, stream>>>(cat, fc1_w, fc1_b, f1, 256, 512, 1);
    linear_wave<<<dim3(64, B), 256, 0, stream>>>(f1, fc2_w, fc2_b, f2, 512, 256, 1);
    linear_wave<<<dim3(1, B), 256, 0, stream>>>(f2, outw, outb, out, 256, 1, 2);
}

// Round 7
// 1107.186 us; speedup vs baseline: 2.9807x; 1.0522x over previous
//
#include <hip/hip_runtime.h>
#include <hip/hip_bf16.h>
#include <math.h>

#define NEG_SLOPE 0.2f

// ---------------- utility ----------------
__global__ void zero_i32(int* __restrict__ p, int n) {
    int i = blockIdx.x * blockDim.x + threadIdx.x;
    if (i < n) p[i] = 0;
}

// ---------------- CSR build ----------------
__global__ void count_edges(const int* __restrict__ dst, int* __restrict__ cnt, int E) {
    int i = blockIdx.x * blockDim.x + threadIdx.x;
    if (i < E) atomicAdd(&cnt[dst[i]], 1);
}

__global__ void scan_block(const int* __restrict__ cnt, int* __restrict__ rs, int N) {
    __shared__ int s[1024];
    int tid = threadIdx.x;
    int running = 0;
    for (int base = 0; base < N; base += 1024) {
        int v = (base + tid < N) ? cnt[base + tid] : 0;
        __syncthreads();
        s[tid] = v;
        __syncthreads();
        for (int off = 1; off < 1024; off <<= 1) {
            int t = (tid >= off) ? s[tid - off] : 0;
            __syncthreads();
            if (tid >= off) s[tid] += t;
            __syncthreads();
        }
        if (base + tid < N) rs[base + tid] = running + s[tid] - v;
        running += s[1023];
    }
    if (tid == 0) rs[N] = running;
}

__global__ void scatter_edges(const int* __restrict__ dst, const int* __restrict__ rs,
                              int* __restrict__ fill, int* __restrict__ eidx, int E) {
    int i = blockIdx.x * blockDim.x + threadIdx.x;
    if (i < E) {
        int d = dst[i];
        int pos = atomicAdd(&fill[d], 1);
        eidx[rs[d] + pos] = i;
    }
}

// ---------------- bf16 hi/lo helpers ----------------
__device__ __forceinline__ short f2bf(float x) {
    __hip_bfloat16 h = __float2bfloat16(x);
    return *reinterpret_cast<short*>(&h);
}
__device__ __forceinline__ float bf2f(short s) {
    unsigned int u = ((unsigned int)(unsigned short)s) << 16;
    return __uint_as_float(u);
}

// W (K x N fp32) -> W2t (N x 2K bf16, transposed): rows [Wh | Wl]
__global__ void split_bf2_w(const float* __restrict__ W, short* __restrict__ W2t, int K, int N) {
    int idx = blockIdx.x * blockDim.x + threadIdx.x;
    if (idx >= K * N) return;
    int k = idx / N, n = idx - k * N;
    float x = W[idx];
    short hs = f2bf(x);
    short ls = f2bf(x - bf2f(hs));
    size_t base = (size_t)n * 2 * K;
    W2t[base + k] = hs;
    W2t[base + K + k] = ls;
}

// ---------------- MFMA bf16-split GEMM: C(MxN) fp32 = A(MxK fp32) * W(KxN)  --
// Bt = W2t (N x 2K bf16, rows [Wh|Wl]). fp32 A is converted to (hi,lo) bf16
// in-register while staging to LDS; per 32-k chunk we accumulate
// Ah*Wh + Al*Wh + Ah*Wl (3 MFMAs per tile) which recovers ~fp32 precision.
// C-tile 64 rows x 192 cols, 4 waves (wave = 16 rows x 192 cols = 12 tiles).
// Requires M%64==0, N%192==0, K%32==0 (true for all call sites).
// LDS row stride 72 shorts (144B = 16B-aligned, 4-bank offset/row -> 2-way).
typedef __attribute__((ext_vector_type(8))) short short8;
typedef __attribute__((ext_vector_type(4))) short short4v;
typedef __attribute__((ext_vector_type(4))) float floatx4;

__global__ __launch_bounds__(256) void gemm_bf3_v2(const float* __restrict__ A,
                                                   const short* __restrict__ Bt,
                                                   float* __restrict__ C,
                                                   int M, int K, int N) {
    __shared__ __align__(16) short sA[64 * 72];   // rows: [Ah(32) | Al(32) | pad8]
    __shared__ __align__(16) short sB[192 * 72];  // rows: [Wh(32) | Wl(32) | pad8]
    int tid = threadIdx.x;
    int wave = tid >> 6, lane = tid & 63;
    int m = lane & 15, q = lane >> 4;
    int row0 = blockIdx.y << 6;
    int col0 = blockIdx.x * 192;
    int K2 = K * 2;
    floatx4 acc[12];
#pragma unroll
    for (int ct = 0; ct < 12; ++ct) acc[ct] = (floatx4){0.f, 0.f, 0.f, 0.f};

    for (int k0 = 0; k0 < K; k0 += 32) {
        // --- stage A: 64 rows x 32 fp32 -> hi/lo bf16 (2 tasks/thread) ---
#pragma unroll
        for (int p = 0; p < 2; ++p) {
            int t = tid + (p << 8);
            int r = t >> 3, c = (t & 7) << 2;       // row, fp32-k-slot*4
            float4 av = *(const float4*)&A[(size_t)(row0 + r) * K + k0 + c];
            short4v hs, ls;
            hs[0] = f2bf(av.x); ls[0] = f2bf(av.x - bf2f(hs[0]));
            hs[1] = f2bf(av.y); ls[1] = f2bf(av.y - bf2f(hs[1]));
            hs[2] = f2bf(av.z); ls[2] = f2bf(av.z - bf2f(hs[2]));
            hs[3] = f2bf(av.w); ls[3] = f2bf(av.w - bf2f(hs[3]));
            *(short4v*)&sA[r * 72 + c] = hs;
            *(short4v*)&sA[r * 72 + 32 + c] = ls;
        }
        // --- stage B: 192 rows x (Wh32|Wl32) bf16 (6 tasks/thread) ---
#pragma unroll
        for (int p = 0; p < 6; ++p) {
            int t = tid + (p << 8);
            int n = t >> 3, sub = t & 7;            // 8 x 8-short slots per row
            int srcoff = k0 + (sub << 3) + ((sub >= 4) ? (K - 32) : 0);
            *(float4*)&sB[n * 72 + (sub << 3)] =
                *(const float4*)&Bt[(size_t)(col0 + n) * K2 + srcoff];
        }
        __syncthreads();
        short8 a_hi = *(const short8*)&sA[(wave * 16 + m) * 72 + q * 8];
        short8 a_lo = *(const short8*)&sA[(wave * 16 + m) * 72 + 32 + q * 8];
#pragma unroll
        for (int ct = 0; ct < 12; ++ct) {
            short8 b_hi = *(const short8*)&sB[(ct * 16 + m) * 72 + q * 8];
            short8 b_lo = *(const short8*)&sB[(ct * 16 + m) * 72 + 32 + q * 8];
            acc[ct] = __builtin_amdgcn_mfma_f32_16x16x32_bf16(a_hi, b_hi, acc[ct], 0, 0, 0);
            acc[ct] = __builtin_amdgcn_mfma_f32_16x16x32_bf16(a_lo, b_hi, acc[ct], 0, 0, 0);
            acc[ct] = __builtin_amdgcn_mfma_f32_16x16x32_bf16(a_hi, b_lo, acc[ct], 0, 0, 0);
        }
        __syncthreads();
    }
#pragma unroll
    for (int ct = 0; ct < 12; ++ct)
#pragma unroll
        for (int r = 0; r < 4; ++r)
            C[(size_t)(row0 + wave * 16 + q * 4 + r) * N + col0 + ct * 16 + m] = acc[ct][r];
}

// ---------------- GAT pieces ----------------
__global__ void gat_elr(const float* __restrict__ h, const float* __restrict__ al,
                        const float* __restrict__ ar, float* __restrict__ el,
                        float* __restrict__ er, int N, int H, int D) {
    int wid = (blockIdx.x * blockDim.x + threadIdx.x) >> 6;
    int lane = threadIdx.x & 63;
    if (wid >= N * H) return;
    int n = wid / H, hh = wid - n * H;
    const float* hp = h + ((size_t)n * H + hh) * D;
    const float* alp = al + (size_t)hh * D;
    const float* arp = ar + (size_t)hh * D;
    float sl = 0.f, sr = 0.f;
    for (int d = lane; d < D; d += 64) {
        float v = hp[d];
        sl += v * alp[d];
        sr += v * arp[d];
    }
    for (int off = 32; off > 0; off >>= 1) {
        sl += __shfl_down(sl, off, 64);
        sr += __shfl_down(sr, off, 64);
    }
    if (lane == 0) { el[wid] = sl; er[wid] = sr; }
}

__device__ __forceinline__ float lrelu(float v) {
    return (v > 0.f) ? v : NEG_SLOPE * v;
}

// One WAVE per node: 64 lanes resolve edge gather chains in parallel.
__global__ void gat_softmax_wave(const float* __restrict__ el, const float* __restrict__ er,
                                 const int* __restrict__ src, const int* __restrict__ rs,
                                 const int* __restrict__ eidx, float* __restrict__ alpha,
                                 int N, int H) {
    int n = (blockIdx.x * blockDim.x + threadIdx.x) >> 6;
    int lane = threadIdx.x & 63;
    if (n >= N) return;
    int s0 = rs[n], s1 = rs[n + 1];
    int deg = s1 - s0;
    if (deg == 0) return;
    float ern0 = er[n * H + 0];
    float ern1 = (H > 1) ? er[n * H + 1] : 0.f;
    float ern2 = (H > 2) ? er[n * H + 2] : 0.f;
    if (deg <= 64) {
        int e = 0, s = 0;
        float v0 = -INFINITY, v1 = -INFINITY, v2 = -INFINITY;
        if (lane < deg) {
            e = eidx[s0 + lane];
            s = src[e];
            v0 = lrelu(el[s * H + 0] + ern0);
            if (H > 1) {
                v1 = lrelu(el[s * H + 1] + ern1);
                v2 = lrelu(el[s * H + 2] + ern2);
            }
        }
        float m0 = v0, m1 = v1, m2 = v2;
#pragma unroll
        for (int off = 32; off > 0; off >>= 1) {
            m0 = fmaxf(m0, __shfl_xor(m0, off, 64));
            m1 = fmaxf(m1, __shfl_xor(m1, off, 64));
            m2 = fmaxf(m2, __shfl_xor(m2, off, 64));
        }
        float ex0 = (lane < deg) ? expf(v0 - m0) : 0.f;
        float ex1 = (lane < deg && H > 1) ? expf(v1 - m1) : 0.f;
        float ex2 = (lane < deg && H > 2) ? expf(v2 - m2) : 0.f;
        float d0 = ex0, d1 = ex1, d2 = ex2;
#pragma unroll
        for (int off = 32; off > 0; off >>= 1) {
            d0 += __shfl_xor(d0, off, 64);
            d1 += __shfl_xor(d1, off, 64);
            d2 += __shfl_xor(d2, off, 64);
        }
        if (lane < deg) {
            alpha[(size_t)e * H + 0] = ex0 / d0;
            if (H > 1) {
                alpha[(size_t)e * H + 1] = ex1 / d1;
                alpha[(size_t)e * H + 2] = ex2 / d2;
            }
        }
    } else {
        float m0 = -INFINITY, m1 = -INFINITY, m2 = -INFINITY;
        for (int j = s0 + lane; j < s1; j += 64) {
            int e = eidx[j], s = src[e];
            float v0 = lrelu(el[s * H + 0] + ern0);
            alpha[(size_t)e * H + 0] = v0; m0 = fmaxf(m0, v0);
            if (H > 1) {
                float v1 = lrelu(el[s * H + 1] + ern1);
                float v2 = lrelu(el[s * H + 2] + ern2);
                alpha[(size_t)e * H + 1] = v1; m1 = fmaxf(m1, v1);
                alpha[(size_t)e * H + 2] = v2; m2 = fmaxf(m2, v2);
            }
        }
#pragma unroll
        for (int off = 32; off > 0; off >>= 1) {
            m0 = fmaxf(m0, __shfl_xor(m0, off, 64));
            m1 = fmaxf(m1, __shfl_xor(m1, off, 64));
            m2 = fmaxf(m2, __shfl_xor(m2, off, 64));
        }
        float d0 = 0.f, d1 = 0.f, d2 = 0.f;
        for (int j = s0 + lane; j < s1; j += 64) {
            int e = eidx[j];
            float ex0 = expf(alpha[(size_t)e * H + 0] - m0);
            alpha[(size_t)e * H + 0] = ex0; d0 += ex0;
            if (H > 1) {
                float ex1 = expf(alpha[(size_t)e * H + 1] - m1);
                float ex2 = expf(alpha[(size_t)e * H + 2] - m2);
                alpha[(size_t)e * H + 1] = ex1; d1 += ex1;
                alpha[(size_t)e * H + 2] = ex2; d2 += ex2;
            }
        }
#pragma unroll
        for (int off = 32; off > 0; off >>= 1) {
            d0 += __shfl_xor(d0, off, 64);
            d1 += __shfl_xor(d1, off, 64);
            d2 += __shfl_xor(d2, off, 64);
        }
        float i0 = 1.f / d0;
        float i1 = (H > 1) ? 1.f / d1 : 0.f;
        float i2 = (H > 2) ? 1.f / d2 : 0.f;
        for (int j = s0 + lane; j < s1; j += 64) {
            int e = eidx[j];
            alpha[(size_t)e * H + 0] *= i0;
            if (H > 1) {
                alpha[(size_t)e * H + 1] *= i1;
                alpha[(size_t)e * H + 2] *= i2;
            }
        }
    }
}

// Block per node. Edge metadata staged into LDS, lanes own float4 columns.
#define TILE_E 64
__global__ void gat_aggregate(const float4* __restrict__ h4, const float* __restrict__ alpha,
                              const int* __restrict__ src, const int* __restrict__ rs,
                              const int* __restrict__ eidx, float4* __restrict__ out4,
                              int N, int H, int D) {
    __shared__ int s_src[TILE_E];
    __shared__ float s_alpha[TILE_E * 3];
    int n = blockIdx.x;
    int HD4 = (H * D) >> 2;
    int tid = threadIdx.x;
    int s0 = rs[n], s1 = rs[n + 1];
    bool active = tid < HD4;
    int hh = active ? (tid << 2) / D : 0;
    float4 acc = {0.f, 0.f, 0.f, 0.f};
    for (int base = s0; base < s1; base += TILE_E) {
        int cntE = s1 - base; if (cntE > TILE_E) cntE = TILE_E;
        if (tid < cntE) {
            int e = eidx[base + tid];
            s_src[tid] = src[e];
#pragma unroll
            for (int h = 0; h < 3; ++h)
                if (h < H) s_alpha[tid * 3 + h] = alpha[(size_t)e * H + h];
        }
        __syncthreads();
        if (active) {
#pragma unroll 4
            for (int i = 0; i < cntE; ++i) {
                float a = s_alpha[i * 3 + hh];
                float4 hv = h4[(size_t)s_src[i] * HD4 + tid];
                acc.x += a * hv.x; acc.y += a * hv.y;
                acc.z += a * hv.z; acc.w += a * hv.w;
            }
        }
        __syncthreads();
    }
    if (active) {
        acc.x = fmaxf(acc.x, 0.f); acc.y = fmaxf(acc.y, 0.f);
        acc.z = fmaxf(acc.z, 0.f); acc.w = fmaxf(acc.w, 0.f);
        out4[(size_t)n * HD4 + tid] = acc;
    }
}

// Graph max-readout over post-ReLU (>=0) values via int-bitcast atomicMax.
__global__ void seg_max_atomic(const float* __restrict__ g, const int* __restrict__ nid,
                               int* __restrict__ out, int N, int C) {
    int n0 = blockIdx.x << 5;
    int n1 = n0 + 32; if (n1 > N) n1 = N;
    if (n0 >= N) return;
    for (int c = threadIdx.x; c < C; c += blockDim.x) {
        int cur = nid[n0];
        float m = 0.f;
        for (int n = n0; n < n1; ++n) {
            int gid = nid[n];
            if (gid != cur) {
                atomicMax(&out[cur * C + c], __float_as_int(m));
                cur = gid; m = 0.f;
            }
            m = fmaxf(m, g[(size_t)n * C + c]);
        }
        atomicMax(&out[cur * C + c], __float_as_int(m));
    }
}

// ---------------- small dense layers ----------------
__global__ void linear_wave(const float* __restrict__ in, const float* __restrict__ W,
                            const float* __restrict__ bias, float* __restrict__ out,
                            int K, int O, int act) {
    int o = blockIdx.x * 4 + (threadIdx.x >> 6);
    int b = blockIdx.y;
    int lane = threadIdx.x & 63;
    if (o >= O) return;
    const float* ip = in + (size_t)b * K;
    float acc = 0.f;
    for (int k = lane; k < K; k += 64)
        acc += ip[k] * W[(size_t)k * O + o];
    for (int off = 32; off > 0; off >>= 1)
        acc += __shfl_down(acc, off, 64);
    if (lane == 0) {
        acc += bias[o];
        if (act == 1) acc = fmaxf(acc, 0.f);
        else if (act == 2) acc = 1.f / (1.f + expf(-acc));
        out[(size_t)b * O + o] = acc;
    }
}

// ---------------- TextCNN ----------------
__global__ void transpose_pad(const float* __restrict__ pad, float* __restrict__ xT,
                              int B, int L, int C) {
    int idx = blockIdx.x * blockDim.x + threadIdx.x;
    int total = B * L * C;
    if (idx >= total) return;
    int l = idx % L;
    int c = (idx / L) % C;
    int b = idx / (L * C);
    xT[idx] = pad[((size_t)b * L + l) * C + c];
}

#define CSTRIDE 68
__global__ void conv3k_v2(const float* __restrict__ x,
                          const float* __restrict__ w,
                          const float* __restrict__ bias,
                          float* __restrict__ y,
                          int Cin, int Lin, int Lout) {
    extern __shared__ float sx[];  // Cin x CSTRIDE
    int b = blockIdx.y;
    int G = blockDim.x >> 7;
    int tileW = G << 4;
    int l0 = blockIdx.x * tileW;
    int tid = threadIdx.x;
    int tileL = Lout - l0; if (tileL > tileW) tileL = tileW;
    int loadL = tileL + 2;
    for (int idx = tid; idx < Cin * loadL; idx += blockDim.x) {
        int c = idx / loadL, i = idx - c * loadL;
        sx[c * CSTRIDE + i] = x[((size_t)b * Cin + c) * Lin + l0 + i];
    }
    __syncthreads();
    int o = tid & 127;
    int pbase = (tid >> 7) << 4;
    int npos = tileL - pbase; if (npos > 16) npos = 16; if (npos < 0) npos = 0;
    float acc[16];
    float bv = bias[o];
#pragma unroll
    for (int j = 0; j < 16; ++j) acc[j] = bv;
    const float* wp = w + (size_t)o * Cin * 3;
    for (int c = 0; c < Cin; ++c) {
        const float* row = &sx[c * CSTRIDE + pbase];
        float xv[18];
        *(float4*)&xv[0]  = *(const float4*)&row[0];
        *(float4*)&xv[4]  = *(const float4*)&row[4];
        *(float4*)&xv[8]  = *(const float4*)&row[8];
        *(float4*)&xv[12] = *(const float4*)&row[12];
        *(float2*)&xv[16] = *(const float2*)&row[16];
        float w0 = wp[c * 3 + 0], w1 = wp[c * 3 + 1], w2 = wp[c * 3 + 2];
#pragma unroll
        for (int j = 0; j < 16; ++j) acc[j] += w0 * xv[j] + w1 * xv[j + 1] + w2 * xv[j + 2];
    }
    float* yp = y + ((size_t)b * 128 + o) * Lout + l0 + pbase;
#pragma unroll
    for (int j = 0; j < 16; ++j)
        if (j < npos) yp[j] = acc[j];
}

__global__ void maxpool(const float* __restrict__ y, float* __restrict__ p,
                        int BC, int Lin, int k, int s, int Lout) {
    int idx = blockIdx.x * blockDim.x + threadIdx.x;
    if (idx >= BC * Lout) return;
    int lo = idx % Lout, bc = idx / Lout;
    const float* yp = y + (size_t)bc * Lin + lo * s;
    float m = -INFINITY;
    for (int i = 0; i < k; ++i) m = fmaxf(m, yp[i]);
    p[idx] = m;
}

__global__ void combine_branch(const float* __restrict__ g, const float* __restrict__ s,
                               const float* __restrict__ w1, float* __restrict__ cat, int off) {
    int idx = blockIdx.x * blockDim.x + threadIdx.x;
    if (idx >= 16 * 128) return;
    int b = idx >> 7, c = idx & 127;
    float w = 1.f / (1.f + expf(-w1[0]));
    cat[b * 256 + off + c] = (1.f - w) * g[idx] + w * s[idx];
}

// ---------------- host ----------------
extern "C" void kernel_launch(void* const* d_in, const int* in_sizes, int n_in,
                              void* d_out, int out_size, void* d_ws, size_t ws_size,
                              hipStream_t stream) {
    const float* feat[2] = {(const float*)d_in[0], (const float*)d_in[1]};
    const float* pad[2]  = {(const float*)d_in[2], (const float*)d_in[3]};
    const int* src[2]    = {(const int*)d_in[4], (const int*)d_in[6]};
    const int* dst[2]    = {(const int*)d_in[5], (const int*)d_in[7]};
    const int* nid[2]    = {(const int*)d_in[8], (const int*)d_in[9]};
    const float* Wg[3]   = {(const float*)d_in[11], (const float*)d_in[14], (const float*)d_in[17]};
    const float* al[3]   = {(const float*)d_in[12], (const float*)d_in[15], (const float*)d_in[18]};
    const float* ar[3]   = {(const float*)d_in[13], (const float*)d_in[16], (const float*)d_in[19]};
    const float* fcg_w = (const float*)d_in[20]; const float* fcg_b = (const float*)d_in[21];
    const float* c1w = (const float*)d_in[22];   const float* c1b = (const float*)d_in[23];
    const float* c2w = (const float*)d_in[24];   const float* c2b = (const float*)d_in[25];
    const float* c3w = (const float*)d_in[26];   const float* c3b = (const float*)d_in[27];
    const float* tf_w = (const float*)d_in[28];  const float* tf_b = (const float*)d_in[29];
    const float* w1 = (const float*)d_in[30];
    const float* fc1_w = (const float*)d_in[31]; const float* fc1_b = (const float*)d_in[32];
    const float* fc2_w = (const float*)d_in[33]; const float* fc2_b = (const float*)d_in[34];
    const float* outw = (const float*)d_in[35];  const float* outb = (const float*)d_in[36];
    float* out = (float*)d_out;

    const int N = in_sizes[0] / 64;   // 8000
    const int E = in_sizes[4];        // 160000
    const int B = 16, L = 1200;

    char* wsb = (char*)d_ws;
    size_t off = 0;
    auto allocB = [&](size_t bytes) -> void* {
        void* p = wsb + off;
        off += (bytes + 255) & ~(size_t)255;
        return p;
    };
    auto alloc = [&](size_t elems) -> void* { return allocB(elems * 4); };

    float* h_buf = (float*)alloc((size_t)N * 576);
    float* gA    = (float*)alloc((size_t)N * 576);
    float* gB    = (float*)alloc((size_t)N * 576);
    float* el    = (float*)alloc((size_t)N * 3);
    float* er    = (float*)alloc((size_t)N * 3);
    float* alpha = (float*)alloc((size_t)E * 3);
    int* rs      = (int*)alloc(N + 1);
    int* cnt     = (int*)alloc(N);
    int* eidx    = (int*)alloc(E);
    int* gmax    = (int*)alloc((size_t)B * 576);
    float* gvec  = (float*)alloc((size_t)B * 128);
    float* sp    = (float*)alloc((size_t)B * 128);
    float* sf    = (float*)alloc((size_t)B * 128);
    float* cat   = (float*)alloc((size_t)B * 256);
    float* f1    = (float*)alloc((size_t)B * 512);
    float* f2    = (float*)alloc((size_t)B * 256);
    // W2t buffers (bf16 shorts, [Wh|Wl] rows), hoisted out of the branch loop:
    short* w2t1  = (short*)allocB((size_t)192 * 2 * 64 * 2);
    short* w2t2  = (short*)allocB((size_t)576 * 2 * 192 * 2);
    short* w2t3  = (short*)allocB((size_t)576 * 2 * 576 * 2);
    // TextCNN scratch
    float* xT = (float*)alloc((size_t)B * 64 * L);
    float* y1 = (float*)alloc((size_t)B * 128 * 1198);
    float* p1 = (float*)alloc((size_t)B * 128 * 399);
    float* y2 = (float*)alloc((size_t)B * 128 * 397);
    float* p2 = (float*)alloc((size_t)B * 128 * 132);
    float* y3 = (float*)alloc((size_t)B * 128 * 130);
    (void)ws_size; (void)n_in; (void)out_size;

    // Weight splits (identical across branches)
    split_bf2_w<<<(64 * 192 + 255) / 256, 256, 0, stream>>>(Wg[0], w2t1, 64, 192);
    split_bf2_w<<<(192 * 576 + 255) / 256, 256, 0, stream>>>(Wg[1], w2t2, 192, 576);
    split_bf2_w<<<(576 * 576 + 255) / 256, 256, 0, stream>>>(Wg[2], w2t3, 576, 576);
    short* w2t[3] = {w2t1, w2t2, w2t3};

    for (int br = 0; br < 2; ++br) {
        // --- CSR by dst ---
        zero_i32<<<(N + 255) / 256, 256, 0, stream>>>(cnt, N);
        count_edges<<<(E + 255) / 256, 256, 0, stream>>>(dst[br], cnt, E);
        scan_block<<<1, 1024, 0, stream>>>(cnt, rs, N);
        zero_i32<<<(N + 255) / 256, 256, 0, stream>>>(cnt, N);
        scatter_edges<<<(E + 255) / 256, 256, 0, stream>>>(dst[br], rs, cnt, eidx, E);

        // --- 3 GAT layers ---
        const int dims[3][3] = {{64, 3, 64}, {192, 3, 192}, {576, 1, 576}};  // K,H,D
        float* outs[3] = {gA, gB, gA};
        const float* in_ptr = feat[br];
        for (int ly = 0; ly < 3; ++ly) {
            int K = dims[ly][0], H = dims[ly][1], D = dims[ly][2];
            int HD = H * D;
            gemm_bf3_v2<<<dim3(HD / 192, N / 64), 256, 0, stream>>>(in_ptr, w2t[ly], h_buf, N, K, HD);
            int waves = N * H;
            gat_elr<<<((size_t)waves * 64 + 255) / 256, 256, 0, stream>>>(h_buf, al[ly], ar[ly], el, er, N, H, D);
            gat_softmax_wave<<<((size_t)N * 64 + 255) / 256, 256, 0, stream>>>(el, er, src[br], rs, eidx, alpha, N, H);
            int aggThreads = (((HD >> 2) + 63) / 64) * 64;
            gat_aggregate<<<N, aggThreads, 0, stream>>>((const float4*)h_buf, alpha, src[br], rs, eidx,
                                                        (float4*)outs[ly], N, H, D);
            in_ptr = outs[ly];
        }
        zero_i32<<<(B * 576 + 255) / 256, 256, 0, stream>>>(gmax, B * 576);
        seg_max_atomic<<<(N + 31) / 32, 256, 0, stream>>>(gA, nid[br], gmax, N, 576);
        linear_wave<<<dim3(32, B), 256, 0, stream>>>((const float*)gmax, fcg_w, fcg_b, gvec, 576, 128, 1);

        // --- TextCNN ---
        transpose_pad<<<((B * 64 * L) + 255) / 256, 256, 0, stream>>>(pad[br], xT, B, L, 64);
        conv3k_v2<<<dim3((1198 + 63) / 64, B), 512, 64 * CSTRIDE * 4, stream>>>(xT, c1w, c1b, y1, 64, 1200, 1198);
        maxpool<<<(B * 128 * 399 + 255) / 256, 256, 0, stream>>>(y1, p1, B * 128, 1198, 3, 3, 399);
        conv3k_v2<<<dim3((397 + 31) / 32, B), 256, 128 * CSTRIDE * 4, stream>>>(p1, c2w, c2b, y2, 128, 399, 397);
        maxpool<<<(B * 128 * 132 + 255) / 256, 256, 0, stream>>>(y2, p2, B * 128, 397, 3, 3, 132);
        conv3k_v2<<<dim3((130 + 31) / 32, B), 256, 128 * CSTRIDE * 4, stream>>>(p2, c3w, c3b, y3, 128, 132, 130);
        maxpool<<<(B * 128 + 255) / 256, 256, 0, stream>>>(y3, sp, B * 128, 130, 130, 1, 1);
        linear_wave<<<dim3(32, B), 256, 0, stream>>>(sp, tf_w, tf_b, sf, 128, 128, 1);

        combine_branch<<<(B * 128 + 255) / 256, 256, 0, stream>>>(gvec, sf, w1, cat, br * 128);
    }

    // --- head MLP ---
    linear_wave<<<dim3(128, B), 256, 0, stream>>>(cat, fc1_w, fc1_b, f1, 256, 512, 1);
    linear_wave<<<dim3(64, B), 256, 0, stream>>>(f1, fc2_w, fc2_b, f2, 512, 256, 1);
    linear_wave<<<dim3(1, B), 256, 0, stream>>>(f2, outw, outb, out, 256, 1, 2);
}

// Round 8
// 838.176 us; speedup vs baseline: 3.9373x; 1.3209x over previous
//
#include <hip/hip_runtime.h>
#include <hip/hip_bf16.h>
#include <math.h>

#define NEG_SLOPE 0.2f

// ---------------- utility ----------------
__global__ void zero_i32(int* __restrict__ p, int n) {
    int i = blockIdx.x * blockDim.x + threadIdx.x;
    if (i < n) p[i] = 0;
}

// ---------------- CSR build (both branches in one dispatch) ----------------
__global__ void count_edges2(const int* __restrict__ dst0, const int* __restrict__ dst1,
                             int* __restrict__ cnt, int N, int E) {
    int i = blockIdx.x * blockDim.x + threadIdx.x;
    if (i >= 2 * E) return;
    int br = i >= E;
    int j = i - br * E;
    const int* d = br ? dst1 : dst0;
    atomicAdd(&cnt[br * N + d[j]], 1);
}

__global__ void scan_block(const int* __restrict__ cnt_all, int* __restrict__ rs_all, int N) {
    __shared__ int s[1024];
    int br = blockIdx.x;
    const int* cnt = cnt_all + br * N;
    int* rs = rs_all + br * (N + 1);
    int tid = threadIdx.x;
    int running = 0;
    for (int base = 0; base < N; base += 1024) {
        int v = (base + tid < N) ? cnt[base + tid] : 0;
        __syncthreads();
        s[tid] = v;
        __syncthreads();
        for (int off = 1; off < 1024; off <<= 1) {
            int t = (tid >= off) ? s[tid - off] : 0;
            __syncthreads();
            if (tid >= off) s[tid] += t;
            __syncthreads();
        }
        if (base + tid < N) rs[base + tid] = running + s[tid] - v;
        running += s[1023];
    }
    if (tid == 0) rs[N] = running;
}

__global__ void scatter_edges2(const int* __restrict__ dst0, const int* __restrict__ dst1,
                               const int* __restrict__ rs_all, int* __restrict__ fill_all,
                               int* __restrict__ eidx_all, int N, int E) {
    int i = blockIdx.x * blockDim.x + threadIdx.x;
    if (i >= 2 * E) return;
    int br = i >= E;
    int j = i - br * E;
    const int* d = br ? dst1 : dst0;
    int dd = d[j];
    int pos = atomicAdd(&fill_all[br * N + dd], 1);
    eidx_all[br * E + rs_all[br * (N + 1) + dd] + pos] = j;
}

// ---------------- bf16 hi/lo helpers ----------------
__device__ __forceinline__ short f2bf(float x) {
    __hip_bfloat16 h = __float2bfloat16(x);
    return *reinterpret_cast<short*>(&h);
}
__device__ __forceinline__ float bf2f(short s) {
    unsigned int u = ((unsigned int)(unsigned short)s) << 16;
    return __uint_as_float(u);
}

// W (K x N fp32) -> W2t (N x 2K bf16, transposed): rows [Wh | Wl]
__global__ void split_bf2_w(const float* __restrict__ W, short* __restrict__ W2t, int K, int N) {
    int idx = blockIdx.x * blockDim.x + threadIdx.x;
    if (idx >= K * N) return;
    int k = idx / N, n = idx - k * N;
    float x = W[idx];
    short hs = f2bf(x);
    short ls = f2bf(x - bf2f(hs));
    size_t base = (size_t)n * 2 * K;
    W2t[base + k] = hs;
    W2t[base + K + k] = ls;
}

// ---------------- MFMA bf16-split GEMM v3 ----------------------------------
// C = A(fp32 MxK) * W(KxN) via bf16 hi/lo split (Ah*Wh + Al*Wh + Ah*Wl).
// Tile: 32 rows x 192 cols, 4 waves. Wave w owns 32 rows x 48 cols (2x3
// MFMA tiles) -> per 32-k chunk: 4 A b128 + 6 B b128 LDS reads vs 18 MFMAs
// (balanced). grid = (N/192, M/32, 2 branches). LDS row stride 72 shorts.
typedef __attribute__((ext_vector_type(8))) short short8;
typedef __attribute__((ext_vector_type(4))) short short4v;
typedef __attribute__((ext_vector_type(4))) float floatx4;

__global__ __launch_bounds__(256) void gemm_bf3_v3(const float* __restrict__ A0,
                                                   const float* __restrict__ A1,
                                                   const short* __restrict__ Bt,
                                                   float* __restrict__ C,
                                                   int M, int K, int N, size_t cBrStride) {
    __shared__ __align__(16) short sA[32 * 72];   // rows: [Ah(32) | Al(32) | pad8]
    __shared__ __align__(16) short sB[192 * 72];  // rows: [Wh(32) | Wl(32) | pad8]
    int tid = threadIdx.x;
    int wave = tid >> 6, lane = tid & 63;
    int m = lane & 15, q = lane >> 4;
    int row0 = blockIdx.y << 5;
    int col0 = blockIdx.x * 192;
    const float* A = blockIdx.z ? A1 : A0;
    float* Cb = C + blockIdx.z * cBrStride;
    int K2 = K * 2;
    floatx4 acc[2][3];
#pragma unroll
    for (int rt = 0; rt < 2; ++rt)
#pragma unroll
        for (int ct = 0; ct < 3; ++ct) acc[rt][ct] = (floatx4){0.f, 0.f, 0.f, 0.f};

    for (int k0 = 0; k0 < K; k0 += 32) {
        // stage A: 32 rows x 32 fp32 -> hi/lo bf16 (1 float4 per thread)
        {
            int r = tid >> 3, c = (tid & 7) << 2;
            float4 av = *(const float4*)&A[(size_t)(row0 + r) * K + k0 + c];
            short4v hs, ls;
            hs[0] = f2bf(av.x); ls[0] = f2bf(av.x - bf2f(hs[0]));
            hs[1] = f2bf(av.y); ls[1] = f2bf(av.y - bf2f(hs[1]));
            hs[2] = f2bf(av.z); ls[2] = f2bf(av.z - bf2f(hs[2]));
            hs[3] = f2bf(av.w); ls[3] = f2bf(av.w - bf2f(hs[3]));
            *(short4v*)&sA[r * 72 + c] = hs;
            *(short4v*)&sA[r * 72 + 32 + c] = ls;
        }
        // stage B: 192 rows x (Wh32|Wl32) bf16 (6 float4 per thread)
#pragma unroll
        for (int p = 0; p < 6; ++p) {
            int t = tid + (p << 8);
            int n = t >> 3, sub = t & 7;
            int srcoff = k0 + (sub << 3) + ((sub >= 4) ? (K - 32) : 0);
            *(float4*)&sB[n * 72 + (sub << 3)] =
                *(const float4*)&Bt[(size_t)(col0 + n) * K2 + srcoff];
        }
        __syncthreads();
        short8 a_hi[2], a_lo[2];
#pragma unroll
        for (int rt = 0; rt < 2; ++rt) {
            a_hi[rt] = *(const short8*)&sA[(rt * 16 + m) * 72 + q * 8];
            a_lo[rt] = *(const short8*)&sA[(rt * 16 + m) * 72 + 32 + q * 8];
        }
#pragma unroll
        for (int ct = 0; ct < 3; ++ct) {
            short8 b_hi = *(const short8*)&sB[(wave * 48 + ct * 16 + m) * 72 + q * 8];
            short8 b_lo = *(const short8*)&sB[(wave * 48 + ct * 16 + m) * 72 + 32 + q * 8];
#pragma unroll
            for (int rt = 0; rt < 2; ++rt) {
                acc[rt][ct] = __builtin_amdgcn_mfma_f32_16x16x32_bf16(a_hi[rt], b_hi, acc[rt][ct], 0, 0, 0);
                acc[rt][ct] = __builtin_amdgcn_mfma_f32_16x16x32_bf16(a_lo[rt], b_hi, acc[rt][ct], 0, 0, 0);
                acc[rt][ct] = __builtin_amdgcn_mfma_f32_16x16x32_bf16(a_hi[rt], b_lo, acc[rt][ct], 0, 0, 0);
            }
        }
        __syncthreads();
    }
#pragma unroll
    for (int rt = 0; rt < 2; ++rt)
#pragma unroll
        for (int ct = 0; ct < 3; ++ct)
#pragma unroll
            for (int r = 0; r < 4; ++r)
                Cb[(size_t)(row0 + rt * 16 + q * 4 + r) * N + col0 + wave * 48 + ct * 16 + m] = acc[rt][ct][r];
}

// ---------------- GAT pieces (branch-fused) ----------------
__global__ void gat_elr(const float* __restrict__ h, const float* __restrict__ al,
                        const float* __restrict__ ar, float* __restrict__ el,
                        float* __restrict__ er, int N, int H, int D,
                        size_t hBr, size_t eBr) {
    int wid = (blockIdx.x * blockDim.x + threadIdx.x) >> 6;
    int lane = threadIdx.x & 63;
    if (wid >= 2 * N * H) return;
    int br = wid / (N * H);
    int loc = wid - br * N * H;
    int n = loc / H, hh = loc - n * H;
    const float* hp = h + br * hBr + ((size_t)n * H + hh) * D;
    const float* alp = al + (size_t)hh * D;
    const float* arp = ar + (size_t)hh * D;
    float sl = 0.f, sr = 0.f;
    for (int d = lane; d < D; d += 64) {
        float v = hp[d];
        sl += v * alp[d];
        sr += v * arp[d];
    }
    for (int off = 32; off > 0; off >>= 1) {
        sl += __shfl_down(sl, off, 64);
        sr += __shfl_down(sr, off, 64);
    }
    if (lane == 0) { el[br * eBr + loc] = sl; er[br * eBr + loc] = sr; }
}

__device__ __forceinline__ float lrelu(float v) {
    return (v > 0.f) ? v : NEG_SLOPE * v;
}

__global__ void gat_softmax_wave(const float* __restrict__ el_all, const float* __restrict__ er_all,
                                 const int* __restrict__ src0, const int* __restrict__ src1,
                                 const int* __restrict__ rs_all, const int* __restrict__ eidx_all,
                                 float* __restrict__ alpha_all, int N, int H, int E,
                                 size_t eBr, size_t aBr) {
    int g = (blockIdx.x * blockDim.x + threadIdx.x) >> 6;
    int lane = threadIdx.x & 63;
    if (g >= 2 * N) return;
    int br = g / N;
    int n = g - br * N;
    const int* src = br ? src1 : src0;
    const int* rs = rs_all + br * (N + 1);
    const int* eidx = eidx_all + br * E;
    const float* el = el_all + br * eBr;
    const float* er = er_all + br * eBr;
    float* alpha = alpha_all + br * aBr;
    int s0 = rs[n], s1 = rs[n + 1];
    int deg = s1 - s0;
    if (deg == 0) return;
    float ern0 = er[n * H + 0];
    float ern1 = (H > 1) ? er[n * H + 1] : 0.f;
    float ern2 = (H > 2) ? er[n * H + 2] : 0.f;
    if (deg <= 64) {
        int e = 0, s = 0;
        float v0 = -INFINITY, v1 = -INFINITY, v2 = -INFINITY;
        if (lane < deg) {
            e = eidx[s0 + lane];
            s = src[e];
            v0 = lrelu(el[s * H + 0] + ern0);
            if (H > 1) {
                v1 = lrelu(el[s * H + 1] + ern1);
                v2 = lrelu(el[s * H + 2] + ern2);
            }
        }
        float m0 = v0, m1 = v1, m2 = v2;
#pragma unroll
        for (int off = 32; off > 0; off >>= 1) {
            m0 = fmaxf(m0, __shfl_xor(m0, off, 64));
            m1 = fmaxf(m1, __shfl_xor(m1, off, 64));
            m2 = fmaxf(m2, __shfl_xor(m2, off, 64));
        }
        float ex0 = (lane < deg) ? expf(v0 - m0) : 0.f;
        float ex1 = (lane < deg && H > 1) ? expf(v1 - m1) : 0.f;
        float ex2 = (lane < deg && H > 2) ? expf(v2 - m2) : 0.f;
        float d0 = ex0, d1 = ex1, d2 = ex2;
#pragma unroll
        for (int off = 32; off > 0; off >>= 1) {
            d0 += __shfl_xor(d0, off, 64);
            d1 += __shfl_xor(d1, off, 64);
            d2 += __shfl_xor(d2, off, 64);
        }
        if (lane < deg) {
            alpha[(size_t)e * H + 0] = ex0 / d0;
            if (H > 1) {
                alpha[(size_t)e * H + 1] = ex1 / d1;
                alpha[(size_t)e * H + 2] = ex2 / d2;
            }
        }
    } else {
        float m0 = -INFINITY, m1 = -INFINITY, m2 = -INFINITY;
        for (int j = s0 + lane; j < s1; j += 64) {
            int e = eidx[j], s = src[e];
            float v0 = lrelu(el[s * H + 0] + ern0);
            alpha[(size_t)e * H + 0] = v0; m0 = fmaxf(m0, v0);
            if (H > 1) {
                float v1 = lrelu(el[s * H + 1] + ern1);
                float v2 = lrelu(el[s * H + 2] + ern2);
                alpha[(size_t)e * H + 1] = v1; m1 = fmaxf(m1, v1);
                alpha[(size_t)e * H + 2] = v2; m2 = fmaxf(m2, v2);
            }
        }
#pragma unroll
        for (int off = 32; off > 0; off >>= 1) {
            m0 = fmaxf(m0, __shfl_xor(m0, off, 64));
            m1 = fmaxf(m1, __shfl_xor(m1, off, 64));
            m2 = fmaxf(m2, __shfl_xor(m2, off, 64));
        }
        float d0 = 0.f, d1 = 0.f, d2 = 0.f;
        for (int j = s0 + lane; j < s1; j += 64) {
            int e = eidx[j];
            float ex0 = expf(alpha[(size_t)e * H + 0] - m0);
            alpha[(size_t)e * H + 0] = ex0; d0 += ex0;
            if (H > 1) {
                float ex1 = expf(alpha[(size_t)e * H + 1] - m1);
                float ex2 = expf(alpha[(size_t)e * H + 2] - m2);
                alpha[(size_t)e * H + 1] = ex1; d1 += ex1;
                alpha[(size_t)e * H + 2] = ex2; d2 += ex2;
            }
        }
#pragma unroll
        for (int off = 32; off > 0; off >>= 1) {
            d0 += __shfl_xor(d0, off, 64);
            d1 += __shfl_xor(d1, off, 64);
            d2 += __shfl_xor(d2, off, 64);
        }
        float i0 = 1.f / d0;
        float i1 = (H > 1) ? 1.f / d1 : 0.f;
        float i2 = (H > 2) ? 1.f / d2 : 0.f;
        for (int j = s0 + lane; j < s1; j += 64) {
            int e = eidx[j];
            alpha[(size_t)e * H + 0] *= i0;
            if (H > 1) {
                alpha[(size_t)e * H + 1] *= i1;
                alpha[(size_t)e * H + 2] *= i2;
            }
        }
    }
}

#define TILE_E 64
__global__ void gat_aggregate(const float4* __restrict__ h4_all, const float* __restrict__ alpha_all,
                              const int* __restrict__ src0, const int* __restrict__ src1,
                              const int* __restrict__ rs_all, const int* __restrict__ eidx_all,
                              float4* __restrict__ out4_all, int N, int H, int D, int E,
                              size_t h4Br, size_t aBr, size_t o4Br) {
    __shared__ int s_src[TILE_E];
    __shared__ float s_alpha[TILE_E * 3];
    int n = blockIdx.x;
    int br = blockIdx.y;
    const int* src = br ? src1 : src0;
    const int* rs = rs_all + br * (N + 1);
    const int* eidx = eidx_all + br * E;
    const float4* h4 = h4_all + br * h4Br;
    const float* alpha = alpha_all + br * aBr;
    float4* out4 = out4_all + br * o4Br;
    int HD4 = (H * D) >> 2;
    int tid = threadIdx.x;
    int s0 = rs[n], s1 = rs[n + 1];
    bool active = tid < HD4;
    int hh = active ? (tid << 2) / D : 0;
    float4 acc = {0.f, 0.f, 0.f, 0.f};
    for (int base = s0; base < s1; base += TILE_E) {
        int cntE = s1 - base; if (cntE > TILE_E) cntE = TILE_E;
        if (tid < cntE) {
            int e = eidx[base + tid];
            s_src[tid] = src[e];
#pragma unroll
            for (int h = 0; h < 3; ++h)
                if (h < H) s_alpha[tid * 3 + h] = alpha[(size_t)e * H + h];
        }
        __syncthreads();
        if (active) {
#pragma unroll 4
            for (int i = 0; i < cntE; ++i) {
                float a = s_alpha[i * 3 + hh];
                float4 hv = h4[(size_t)s_src[i] * HD4 + tid];
                acc.x += a * hv.x; acc.y += a * hv.y;
                acc.z += a * hv.z; acc.w += a * hv.w;
            }
        }
        __syncthreads();
    }
    if (active) {
        acc.x = fmaxf(acc.x, 0.f); acc.y = fmaxf(acc.y, 0.f);
        acc.z = fmaxf(acc.z, 0.f); acc.w = fmaxf(acc.w, 0.f);
        out4[(size_t)n * HD4 + tid] = acc;
    }
}

// Graph max-readout (post-ReLU >=0) via int-bitcast atomicMax. grid.y = branch.
__global__ void seg_max_atomic(const float* __restrict__ g_all, const int* __restrict__ nid,
                               int* __restrict__ out_all, int N, int C,
                               size_t gBr, size_t oBr) {
    int br = blockIdx.y;
    const float* g = g_all + br * gBr;
    int* out = out_all + br * oBr;
    int n0 = blockIdx.x << 5;
    int n1 = n0 + 32; if (n1 > N) n1 = N;
    if (n0 >= N) return;
    for (int c = threadIdx.x; c < C; c += blockDim.x) {
        int cur = nid[n0];
        float m = 0.f;
        for (int n = n0; n < n1; ++n) {
            int gid = nid[n];
            if (gid != cur) {
                atomicMax(&out[cur * C + c], __float_as_int(m));
                cur = gid; m = 0.f;
            }
            m = fmaxf(m, g[(size_t)n * C + c]);
        }
        atomicMax(&out[cur * C + c], __float_as_int(m));
    }
}

// ---------------- small dense layers (grid.z = branch; strides may be 0) ----
__global__ void linear_wave(const float* __restrict__ in, const float* __restrict__ W,
                            const float* __restrict__ bias, float* __restrict__ out,
                            int K, int O, int act, size_t inBr, size_t outBr) {
    int o = blockIdx.x * 4 + (threadIdx.x >> 6);
    int b = blockIdx.y;
    int lane = threadIdx.x & 63;
    if (o >= O) return;
    const float* ip = in + blockIdx.z * inBr + (size_t)b * K;
    float acc = 0.f;
    for (int k = lane; k < K; k += 64)
        acc += ip[k] * W[(size_t)k * O + o];
    for (int off = 32; off > 0; off >>= 1)
        acc += __shfl_down(acc, off, 64);
    if (lane == 0) {
        acc += bias[o];
        if (act == 1) acc = fmaxf(acc, 0.f);
        else if (act == 2) acc = 1.f / (1.f + expf(-acc));
        out[blockIdx.z * outBr + (size_t)b * O + o] = acc;
    }
}

// ---------------- TextCNN (branch-fused) ----------------
__global__ void transpose_pad2(const float* __restrict__ pad0, const float* __restrict__ pad1,
                               float* __restrict__ xT, int B, int L, int C) {
    int idx = blockIdx.x * blockDim.x + threadIdx.x;
    int per = B * L * C;
    if (idx >= 2 * per) return;
    int br = idx >= per;
    int loc = idx - br * per;
    const float* pad = br ? pad1 : pad0;
    int l = loc % L;
    int c = (loc / L) % C;
    int b = loc / (L * C);
    xT[idx] = pad[((size_t)b * L + l) * C + c];
}

#define CSTRIDE 68
__global__ void conv3k_v2(const float* __restrict__ x,
                          const float* __restrict__ w,
                          const float* __restrict__ bias,
                          float* __restrict__ y,
                          int Cin, int Lin, int Lout, size_t xBr, size_t yBr) {
    extern __shared__ float sx[];  // Cin x CSTRIDE
    int b = blockIdx.y;
    const float* xb = x + blockIdx.z * xBr;
    float* yb = y + blockIdx.z * yBr;
    int G = blockDim.x >> 7;
    int tileW = G << 4;
    int l0 = blockIdx.x * tileW;
    int tid = threadIdx.x;
    int tileL = Lout - l0; if (tileL > tileW) tileL = tileW;
    int loadL = tileL + 2;
    for (int idx = tid; idx < Cin * loadL; idx += blockDim.x) {
        int c = idx / loadL, i = idx - c * loadL;
        sx[c * CSTRIDE + i] = xb[((size_t)b * Cin + c) * Lin + l0 + i];
    }
    __syncthreads();
    int o = tid & 127;
    int pbase = (tid >> 7) << 4;
    int npos = tileL - pbase; if (npos > 16) npos = 16; if (npos < 0) npos = 0;
    float acc[16];
    float bv = bias[o];
#pragma unroll
    for (int j = 0; j < 16; ++j) acc[j] = bv;
    const float* wp = w + (size_t)o * Cin * 3;
    for (int c = 0; c < Cin; ++c) {
        const float* row = &sx[c * CSTRIDE + pbase];
        float xv[18];
        *(float4*)&xv[0]  = *(const float4*)&row[0];
        *(float4*)&xv[4]  = *(const float4*)&row[4];
        *(float4*)&xv[8]  = *(const float4*)&row[8];
        *(float4*)&xv[12] = *(const float4*)&row[12];
        *(float2*)&xv[16] = *(const float2*)&row[16];
        float w0 = wp[c * 3 + 0], w1 = wp[c * 3 + 1], w2 = wp[c * 3 + 2];
#pragma unroll
        for (int j = 0; j < 16; ++j) acc[j] += w0 * xv[j] + w1 * xv[j + 1] + w2 * xv[j + 2];
    }
    float* yp = yb + ((size_t)b * 128 + o) * Lout + l0 + pbase;
#pragma unroll
    for (int j = 0; j < 16; ++j)
        if (j < npos) yp[j] = acc[j];
}

__global__ void maxpool(const float* __restrict__ y, float* __restrict__ p,
                        int BC, int Lin, int k, int s, int Lout) {
    int idx = blockIdx.x * blockDim.x + threadIdx.x;
    if (idx >= BC * Lout) return;
    int lo = idx % Lout, bc = idx / Lout;
    const float* yp = y + (size_t)bc * Lin + lo * s;
    float m = -INFINITY;
    for (int i = 0; i < k; ++i) m = fmaxf(m, yp[i]);
    p[idx] = m;
}

// cat[b, br*128 + c] over both branches in one launch (gvec/sf are [2][B*128])
__global__ void combine_branch2(const float* __restrict__ g, const float* __restrict__ s,
                                const float* __restrict__ w1, float* __restrict__ cat, int B) {
    int idx = blockIdx.x * blockDim.x + threadIdx.x;
    int per = B * 128;
    if (idx >= 2 * per) return;
    int br = idx >= per;
    int loc = idx - br * per;
    int b = loc >> 7, c = loc & 127;
    float w = 1.f / (1.f + expf(-w1[0]));
    cat[b * 256 + br * 128 + c] = (1.f - w) * g[idx] + w * s[idx];
}

// ---------------- host ----------------
extern "C" void kernel_launch(void* const* d_in, const int* in_sizes, int n_in,
                              void* d_out, int out_size, void* d_ws, size_t ws_size,
                              hipStream_t stream) {
    const float* feat[2] = {(const float*)d_in[0], (const float*)d_in[1]};
    const float* pad[2]  = {(const float*)d_in[2], (const float*)d_in[3]};
    const int* src[2]    = {(const int*)d_in[4], (const int*)d_in[6]};
    const int* dst[2]    = {(const int*)d_in[5], (const int*)d_in[7]};
    const int* nid[2]    = {(const int*)d_in[8], (const int*)d_in[9]};
    const float* Wg[3]   = {(const float*)d_in[11], (const float*)d_in[14], (const float*)d_in[17]};
    const float* al[3]   = {(const float*)d_in[12], (const float*)d_in[15], (const float*)d_in[18]};
    const float* ar[3]   = {(const float*)d_in[13], (const float*)d_in[16], (const float*)d_in[19]};
    const float* fcg_w = (const float*)d_in[20]; const float* fcg_b = (const float*)d_in[21];
    const float* c1w = (const float*)d_in[22];   const float* c1b = (const float*)d_in[23];
    const float* c2w = (const float*)d_in[24];   const float* c2b = (const float*)d_in[25];
    const float* c3w = (const float*)d_in[26];   const float* c3b = (const float*)d_in[27];
    const float* tf_w = (const float*)d_in[28];  const float* tf_b = (const float*)d_in[29];
    const float* w1 = (const float*)d_in[30];
    const float* fc1_w = (const float*)d_in[31]; const float* fc1_b = (const float*)d_in[32];
    const float* fc2_w = (const float*)d_in[33]; const float* fc2_b = (const float*)d_in[34];
    const float* outw = (const float*)d_in[35];  const float* outb = (const float*)d_in[36];
    float* out = (float*)d_out;

    const int N = in_sizes[0] / 64;   // 8000
    const int E = in_sizes[4];        // 160000
    const int B = 16, L = 1200;
    const size_t NS = (size_t)N * 576;       // per-branch stride for h/gA/gB

    char* wsb = (char*)d_ws;
    size_t off = 0;
    auto allocB = [&](size_t bytes) -> void* {
        void* p = wsb + off;
        off += (bytes + 255) & ~(size_t)255;
        return p;
    };
    auto alloc = [&](size_t elems) -> void* { return allocB(elems * 4); };

    float* h_buf = (float*)alloc(2 * NS);
    float* gA    = (float*)alloc(2 * NS);
    float* el    = (float*)alloc(2 * (size_t)N * 3);
    float* er    = (float*)alloc(2 * (size_t)N * 3);
    float* alpha = (float*)alloc(2 * (size_t)E * 3);
    int* rs      = (int*)alloc(2 * (N + 1));
    int* cnt     = (int*)alloc(2 * N);
    int* eidx    = (int*)alloc(2 * E);
    int* gmax    = (int*)alloc(2 * (size_t)B * 576);
    float* gvec  = (float*)alloc(2 * (size_t)B * 128);
    float* sp    = (float*)alloc(2 * (size_t)B * 128);
    float* sf    = (float*)alloc(2 * (size_t)B * 128);
    float* cat   = (float*)alloc((size_t)B * 256);
    float* f1    = (float*)alloc((size_t)B * 512);
    float* f2    = (float*)alloc((size_t)B * 256);
    short* w2t1  = (short*)allocB((size_t)192 * 2 * 64 * 2);
    short* w2t2  = (short*)allocB((size_t)576 * 2 * 192 * 2);
    short* w2t3  = (short*)allocB((size_t)576 * 2 * 576 * 2);
    // UNION: gB (layer-2 output, 2*NS floats) aliases TextCNN scratch
    // (gB dead after layer-3 gemm; TextCNN runs after the GAT stack).
    size_t tcnn_elems = 2 * ((size_t)B * 64 * L + (size_t)B * 128 * (1198 + 399 + 397 + 132 + 130));
    size_t uni_elems = 2 * NS > tcnn_elems ? 2 * NS : tcnn_elems;
    float* uni = (float*)alloc(uni_elems);
    float* gB = uni;
    float* xT = uni;
    float* y1 = xT + 2 * (size_t)B * 64 * L;
    float* p1 = y1 + 2 * (size_t)B * 128 * 1198;
    float* y2 = p1 + 2 * (size_t)B * 128 * 399;
    float* p2 = y2 + 2 * (size_t)B * 128 * 397;
    float* y3 = p2 + 2 * (size_t)B * 128 * 132;
    (void)ws_size; (void)n_in; (void)out_size;

    // Weight splits (shared by both branches)
    split_bf2_w<<<(64 * 192 + 255) / 256, 256, 0, stream>>>(Wg[0], w2t1, 64, 192);
    split_bf2_w<<<(192 * 576 + 255) / 256, 256, 0, stream>>>(Wg[1], w2t2, 192, 576);
    split_bf2_w<<<(576 * 576 + 255) / 256, 256, 0, stream>>>(Wg[2], w2t3, 576, 576);
    short* w2t[3] = {w2t1, w2t2, w2t3};

    // --- CSR for both branches ---
    zero_i32<<<(2 * N + 255) / 256, 256, 0, stream>>>(cnt, 2 * N);
    count_edges2<<<(2 * E + 255) / 256, 256, 0, stream>>>(dst[0], dst[1], cnt, N, E);
    scan_block<<<2, 1024, 0, stream>>>(cnt, rs, N);
    zero_i32<<<(2 * N + 255) / 256, 256, 0, stream>>>(cnt, 2 * N);
    scatter_edges2<<<(2 * E + 255) / 256, 256, 0, stream>>>(dst[0], dst[1], rs, cnt, eidx, N, E);

    // --- 3 GAT layers, both branches per dispatch ---
    const int dims[3][3] = {{64, 3, 64}, {192, 3, 192}, {576, 1, 576}};  // K,H,D
    float* outs[3] = {gA, gB, gA};
    const float* inp0 = feat[0];
    const float* inp1 = feat[1];
    for (int ly = 0; ly < 3; ++ly) {
        int K = dims[ly][0], H = dims[ly][1], D = dims[ly][2];
        int HD = H * D;
        gemm_bf3_v3<<<dim3(HD / 192, N / 32, 2), 256, 0, stream>>>(inp0, inp1, w2t[ly], h_buf, N, K, HD, NS);
        int waves2 = 2 * N * H;
        gat_elr<<<((size_t)waves2 * 64 + 255) / 256, 256, 0, stream>>>(h_buf, al[ly], ar[ly], el, er,
                                                                       N, H, D, NS, (size_t)N * 3);
        gat_softmax_wave<<<((size_t)2 * N * 64 + 255) / 256, 256, 0, stream>>>(
            el, er, src[0], src[1], rs, eidx, alpha, N, H, E, (size_t)N * 3, (size_t)E * 3);
        int aggThreads = (((HD >> 2) + 63) / 64) * 64;
        gat_aggregate<<<dim3(N, 2), aggThreads, 0, stream>>>(
            (const float4*)h_buf, alpha, src[0], src[1], rs, eidx, (float4*)outs[ly],
            N, H, D, E, NS / 4, (size_t)E * 3, NS / 4);
        inp0 = outs[ly];
        inp1 = outs[ly] + NS;
    }
    zero_i32<<<(2 * B * 576 + 255) / 256, 256, 0, stream>>>(gmax, 2 * B * 576);
    seg_max_atomic<<<dim3((N + 31) / 32, 2), 256, 0, stream>>>(gA, nid[0], gmax, N, 576,
                                                               NS, (size_t)B * 576);
    linear_wave<<<dim3(32, B, 2), 256, 0, stream>>>((const float*)gmax, fcg_w, fcg_b, gvec,
                                                    576, 128, 1, (size_t)B * 576, (size_t)B * 128);

    // --- TextCNN, both branches per dispatch (gB dead now; union is safe) ---
    transpose_pad2<<<((2 * B * 64 * L) + 255) / 256, 256, 0, stream>>>(pad[0], pad[1], xT, B, L, 64);
    conv3k_v2<<<dim3((1198 + 63) / 64, B, 2), 512, 64 * CSTRIDE * 4, stream>>>(
        xT, c1w, c1b, y1, 64, 1200, 1198, (size_t)B * 64 * L, (size_t)B * 128 * 1198);
    maxpool<<<(2 * B * 128 * 399 + 255) / 256, 256, 0, stream>>>(y1, p1, 2 * B * 128, 1198, 3, 3, 399);
    conv3k_v2<<<dim3((397 + 31) / 32, B, 2), 256, 128 * CSTRIDE * 4, stream>>>(
        p1, c2w, c2b, y2, 128, 399, 397, (size_t)B * 128 * 399, (size_t)B * 128 * 397);
    maxpool<<<(2 * B * 128 * 132 + 255) / 256, 256, 0, stream>>>(y2, p2, 2 * B * 128, 397, 3, 3, 132);
    conv3k_v2<<<dim3((130 + 31) / 32, B, 2), 256, 128 * CSTRIDE * 4, stream>>>(
        p2, c3w, c3b, y3, 128, 132, 130, (size_t)B * 128 * 132, (size_t)B * 128 * 130);
    maxpool<<<(2 * B * 128 + 255) / 256, 256, 0, stream>>>(y3, sp, 2 * B * 128, 130, 130, 1, 1);
    linear_wave<<<dim3(32, B, 2), 256, 0, stream>>>(sp, tf_w, tf_b, sf, 128, 128, 1,
                                                    (size_t)B * 128, (size_t)B * 128);
    combine_branch2<<<(2 * B * 128 + 255) / 256, 256, 0, stream>>>(gvec, sf, w1, cat, B);

    // --- head MLP ---
    linear_wave<<<dim3(128, B, 1), 256, 0, stream>>>(cat, fc1_w, fc1_b, f1, 256, 512, 1, 0, 0);
    linear_wave<<<dim3(64, B, 1), 256, 0, stream>>>(f1, fc2_w, fc2_b, f2, 512, 256, 1, 0, 0);
    linear_wave<<<dim3(1, B, 1), 256, 0, stream>>>(f2, outw, outb, out, 256, 1, 2, 0, 0);
}

// Round 9
// 836.173 us; speedup vs baseline: 3.9468x; 1.0024x over previous
//
#include <hip/hip_runtime.h>
#include <hip/hip_bf16.h>
#include <math.h>

#define NEG_SLOPE 0.2f

// ---------------- utility ----------------
__global__ void zero_i32(int* __restrict__ p, int n) {
    int i = blockIdx.x * blockDim.x + threadIdx.x;
    if (i < n) p[i] = 0;
}

// ---------------- CSR build (both branches in one dispatch) ----------------
__global__ void count_edges2(const int* __restrict__ dst0, const int* __restrict__ dst1,
                             int* __restrict__ cnt, int N, int E) {
    int i = blockIdx.x * blockDim.x + threadIdx.x;
    if (i >= 2 * E) return;
    int br = i >= E;
    int j = i - br * E;
    const int* d = br ? dst1 : dst0;
    atomicAdd(&cnt[br * N + d[j]], 1);
}

__global__ void scan_block(const int* __restrict__ cnt_all, int* __restrict__ rs_all, int N) {
    __shared__ int s[1024];
    int br = blockIdx.x;
    const int* cnt = cnt_all + br * N;
    int* rs = rs_all + br * (N + 1);
    int tid = threadIdx.x;
    int running = 0;
    for (int base = 0; base < N; base += 1024) {
        int v = (base + tid < N) ? cnt[base + tid] : 0;
        __syncthreads();
        s[tid] = v;
        __syncthreads();
        for (int off = 1; off < 1024; off <<= 1) {
            int t = (tid >= off) ? s[tid - off] : 0;
            __syncthreads();
            if (tid >= off) s[tid] += t;
            __syncthreads();
        }
        if (base + tid < N) rs[base + tid] = running + s[tid] - v;
        running += s[1023];
    }
    if (tid == 0) rs[N] = running;
}

__global__ void scatter_edges2(const int* __restrict__ dst0, const int* __restrict__ dst1,
                               const int* __restrict__ rs_all, int* __restrict__ fill_all,
                               int* __restrict__ eidx_all, int N, int E) {
    int i = blockIdx.x * blockDim.x + threadIdx.x;
    if (i >= 2 * E) return;
    int br = i >= E;
    int j = i - br * E;
    const int* d = br ? dst1 : dst0;
    int dd = d[j];
    int pos = atomicAdd(&fill_all[br * N + dd], 1);
    eidx_all[br * E + rs_all[br * (N + 1) + dd] + pos] = j;
}

// ---------------- bf16 hi/lo helpers ----------------
__device__ __forceinline__ short f2bf(float x) {
    __hip_bfloat16 h = __float2bfloat16(x);
    return *reinterpret_cast<short*>(&h);
}
__device__ __forceinline__ float bf2f(short s) {
    unsigned int u = ((unsigned int)(unsigned short)s) << 16;
    return __uint_as_float(u);
}

// W (K x N fp32) -> W2t (N x 2K bf16, transposed): rows [Wh | Wl]
__global__ void split_bf2_w(const float* __restrict__ W, short* __restrict__ W2t, int K, int N) {
    int idx = blockIdx.x * blockDim.x + threadIdx.x;
    if (idx >= K * N) return;
    int k = idx / N, n = idx - k * N;
    float x = W[idx];
    short hs = f2bf(x);
    short ls = f2bf(x - bf2f(hs));
    size_t base = (size_t)n * 2 * K;
    W2t[base + k] = hs;
    W2t[base + K + k] = ls;
}

// ---------------- MFMA bf16-split GEMM v3 ----------------------------------
typedef __attribute__((ext_vector_type(8))) short short8;
typedef __attribute__((ext_vector_type(4))) short short4v;
typedef __attribute__((ext_vector_type(4))) float floatx4;

__global__ __launch_bounds__(256) void gemm_bf3_v3(const float* __restrict__ A0,
                                                   const float* __restrict__ A1,
                                                   const short* __restrict__ Bt,
                                                   float* __restrict__ C,
                                                   int M, int K, int N, size_t cBrStride) {
    __shared__ __align__(16) short sA[32 * 72];   // rows: [Ah(32) | Al(32) | pad8]
    __shared__ __align__(16) short sB[192 * 72];  // rows: [Wh(32) | Wl(32) | pad8]
    int tid = threadIdx.x;
    int wave = tid >> 6, lane = tid & 63;
    int m = lane & 15, q = lane >> 4;
    int row0 = blockIdx.y << 5;
    int col0 = blockIdx.x * 192;
    const float* A = blockIdx.z ? A1 : A0;
    float* Cb = C + blockIdx.z * cBrStride;
    int K2 = K * 2;
    floatx4 acc[2][3];
#pragma unroll
    for (int rt = 0; rt < 2; ++rt)
#pragma unroll
        for (int ct = 0; ct < 3; ++ct) acc[rt][ct] = (floatx4){0.f, 0.f, 0.f, 0.f};

    for (int k0 = 0; k0 < K; k0 += 32) {
        {
            int r = tid >> 3, c = (tid & 7) << 2;
            float4 av = *(const float4*)&A[(size_t)(row0 + r) * K + k0 + c];
            short4v hs, ls;
            hs[0] = f2bf(av.x); ls[0] = f2bf(av.x - bf2f(hs[0]));
            hs[1] = f2bf(av.y); ls[1] = f2bf(av.y - bf2f(hs[1]));
            hs[2] = f2bf(av.z); ls[2] = f2bf(av.z - bf2f(hs[2]));
            hs[3] = f2bf(av.w); ls[3] = f2bf(av.w - bf2f(hs[3]));
            *(short4v*)&sA[r * 72 + c] = hs;
            *(short4v*)&sA[r * 72 + 32 + c] = ls;
        }
#pragma unroll
        for (int p = 0; p < 6; ++p) {
            int t = tid + (p << 8);
            int n = t >> 3, sub = t & 7;
            int srcoff = k0 + (sub << 3) + ((sub >= 4) ? (K - 32) : 0);
            *(float4*)&sB[n * 72 + (sub << 3)] =
                *(const float4*)&Bt[(size_t)(col0 + n) * K2 + srcoff];
        }
        __syncthreads();
        short8 a_hi[2], a_lo[2];
#pragma unroll
        for (int rt = 0; rt < 2; ++rt) {
            a_hi[rt] = *(const short8*)&sA[(rt * 16 + m) * 72 + q * 8];
            a_lo[rt] = *(const short8*)&sA[(rt * 16 + m) * 72 + 32 + q * 8];
        }
#pragma unroll
        for (int ct = 0; ct < 3; ++ct) {
            short8 b_hi = *(const short8*)&sB[(wave * 48 + ct * 16 + m) * 72 + q * 8];
            short8 b_lo = *(const short8*)&sB[(wave * 48 + ct * 16 + m) * 72 + 32 + q * 8];
#pragma unroll
            for (int rt = 0; rt < 2; ++rt) {
                acc[rt][ct] = __builtin_amdgcn_mfma_f32_16x16x32_bf16(a_hi[rt], b_hi, acc[rt][ct], 0, 0, 0);
                acc[rt][ct] = __builtin_amdgcn_mfma_f32_16x16x32_bf16(a_lo[rt], b_hi, acc[rt][ct], 0, 0, 0);
                acc[rt][ct] = __builtin_amdgcn_mfma_f32_16x16x32_bf16(a_hi[rt], b_lo, acc[rt][ct], 0, 0, 0);
            }
        }
        __syncthreads();
    }
#pragma unroll
    for (int rt = 0; rt < 2; ++rt)
#pragma unroll
        for (int ct = 0; ct < 3; ++ct)
#pragma unroll
            for (int r = 0; r < 4; ++r)
                Cb[(size_t)(row0 + rt * 16 + q * 4 + r) * N + col0 + wave * 48 + ct * 16 + m] = acc[rt][ct][r];
}

// ---------------- GAT pieces (branch-fused) ----------------
__global__ void gat_elr(const float* __restrict__ h, const float* __restrict__ al,
                        const float* __restrict__ ar, float* __restrict__ el,
                        float* __restrict__ er, int N, int H, int D,
                        size_t hBr, size_t eBr) {
    int wid = (blockIdx.x * blockDim.x + threadIdx.x) >> 6;
    int lane = threadIdx.x & 63;
    if (wid >= 2 * N * H) return;
    int br = wid / (N * H);
    int loc = wid - br * N * H;
    int n = loc / H, hh = loc - n * H;
    const float* hp = h + br * hBr + ((size_t)n * H + hh) * D;
    const float* alp = al + (size_t)hh * D;
    const float* arp = ar + (size_t)hh * D;
    float sl = 0.f, sr = 0.f;
    for (int d = lane; d < D; d += 64) {
        float v = hp[d];
        sl += v * alp[d];
        sr += v * arp[d];
    }
    for (int off = 32; off > 0; off >>= 1) {
        sl += __shfl_down(sl, off, 64);
        sr += __shfl_down(sr, off, 64);
    }
    if (lane == 0) { el[br * eBr + loc] = sl; er[br * eBr + loc] = sr; }
}

__device__ __forceinline__ float lrelu(float v) {
    return (v > 0.f) ? v : NEG_SLOPE * v;
}

__global__ void gat_softmax_wave(const float* __restrict__ el_all, const float* __restrict__ er_all,
                                 const int* __restrict__ src0, const int* __restrict__ src1,
                                 const int* __restrict__ rs_all, const int* __restrict__ eidx_all,
                                 float* __restrict__ alpha_all, int N, int H, int E,
                                 size_t eBr, size_t aBr) {
    int g = (blockIdx.x * blockDim.x + threadIdx.x) >> 6;
    int lane = threadIdx.x & 63;
    if (g >= 2 * N) return;
    int br = g / N;
    int n = g - br * N;
    const int* src = br ? src1 : src0;
    const int* rs = rs_all + br * (N + 1);
    const int* eidx = eidx_all + br * E;
    const float* el = el_all + br * eBr;
    const float* er = er_all + br * eBr;
    float* alpha = alpha_all + br * aBr;
    int s0 = rs[n], s1 = rs[n + 1];
    int deg = s1 - s0;
    if (deg == 0) return;
    float ern0 = er[n * H + 0];
    float ern1 = (H > 1) ? er[n * H + 1] : 0.f;
    float ern2 = (H > 2) ? er[n * H + 2] : 0.f;
    if (deg <= 64) {
        int e = 0, s = 0;
        float v0 = -INFINITY, v1 = -INFINITY, v2 = -INFINITY;
        if (lane < deg) {
            e = eidx[s0 + lane];
            s = src[e];
            v0 = lrelu(el[s * H + 0] + ern0);
            if (H > 1) {
                v1 = lrelu(el[s * H + 1] + ern1);
                v2 = lrelu(el[s * H + 2] + ern2);
            }
        }
        float m0 = v0, m1 = v1, m2 = v2;
#pragma unroll
        for (int off = 32; off > 0; off >>= 1) {
            m0 = fmaxf(m0, __shfl_xor(m0, off, 64));
            m1 = fmaxf(m1, __shfl_xor(m1, off, 64));
            m2 = fmaxf(m2, __shfl_xor(m2, off, 64));
        }
        float ex0 = (lane < deg) ? expf(v0 - m0) : 0.f;
        float ex1 = (lane < deg && H > 1) ? expf(v1 - m1) : 0.f;
        float ex2 = (lane < deg && H > 2) ? expf(v2 - m2) : 0.f;
        float d0 = ex0, d1 = ex1, d2 = ex2;
#pragma unroll
        for (int off = 32; off > 0; off >>= 1) {
            d0 += __shfl_xor(d0, off, 64);
            d1 += __shfl_xor(d1, off, 64);
            d2 += __shfl_xor(d2, off, 64);
        }
        if (lane < deg) {
            alpha[(size_t)e * H + 0] = ex0 / d0;
            if (H > 1) {
                alpha[(size_t)e * H + 1] = ex1 / d1;
                alpha[(size_t)e * H + 2] = ex2 / d2;
            }
        }
    } else {
        float m0 = -INFINITY, m1 = -INFINITY, m2 = -INFINITY;
        for (int j = s0 + lane; j < s1; j += 64) {
            int e = eidx[j], s = src[e];
            float v0 = lrelu(el[s * H + 0] + ern0);
            alpha[(size_t)e * H + 0] = v0; m0 = fmaxf(m0, v0);
            if (H > 1) {
                float v1 = lrelu(el[s * H + 1] + ern1);
                float v2 = lrelu(el[s * H + 2] + ern2);
                alpha[(size_t)e * H + 1] = v1; m1 = fmaxf(m1, v1);
                alpha[(size_t)e * H + 2] = v2; m2 = fmaxf(m2, v2);
            }
        }
#pragma unroll
        for (int off = 32; off > 0; off >>= 1) {
            m0 = fmaxf(m0, __shfl_xor(m0, off, 64));
            m1 = fmaxf(m1, __shfl_xor(m1, off, 64));
            m2 = fmaxf(m2, __shfl_xor(m2, off, 64));
        }
        float d0 = 0.f, d1 = 0.f, d2 = 0.f;
        for (int j = s0 + lane; j < s1; j += 64) {
            int e = eidx[j];
            float ex0 = expf(alpha[(size_t)e * H + 0] - m0);
            alpha[(size_t)e * H + 0] = ex0; d0 += ex0;
            if (H > 1) {
                float ex1 = expf(alpha[(size_t)e * H + 1] - m1);
                float ex2 = expf(alpha[(size_t)e * H + 2] - m2);
                alpha[(size_t)e * H + 1] = ex1; d1 += ex1;
                alpha[(size_t)e * H + 2] = ex2; d2 += ex2;
            }
        }
#pragma unroll
        for (int off = 32; off > 0; off >>= 1) {
            d0 += __shfl_xor(d0, off, 64);
            d1 += __shfl_xor(d1, off, 64);
            d2 += __shfl_xor(d2, off, 64);
        }
        float i0 = 1.f / d0;
        float i1 = (H > 1) ? 1.f / d1 : 0.f;
        float i2 = (H > 2) ? 1.f / d2 : 0.f;
        for (int j = s0 + lane; j < s1; j += 64) {
            int e = eidx[j];
            alpha[(size_t)e * H + 0] *= i0;
            if (H > 1) {
                alpha[(size_t)e * H + 1] *= i1;
                alpha[(size_t)e * H + 2] *= i2;
            }
        }
    }
}

// ---------------- column-chunked, XCD-affine aggregate ----------------------
// grid = (CH, ceil(N/NPB), 2 branches). Chunk = LANES float4-cols; with CH a
// divisor/multiple of 8 the chunk pins to an XCD (linear%8 == blockIdx.x for
// CH=8), so each XCD's L2 only caches its own N x chunk slice of h:
//   HD=576: CH=8, LANES=18 -> 2.3 MB/XCD;  HD=192: CH=4, LANES=12 -> 1.5 MB.
// Edge meta for the NPB-node window (contiguous in eidx, CSR by dst) is
// staged into LDS cooperatively; each (node,lane) group streams its gathers.
#define ETILE 1024
__global__ __launch_bounds__(256) void gat_aggregate_ch(
        const float4* __restrict__ h4_all, const float* __restrict__ alpha_all,
        const int* __restrict__ src0, const int* __restrict__ src1,
        const int* __restrict__ rs_all, const int* __restrict__ eidx_all,
        float4* __restrict__ out4_all, int N, int H, int D, int E,
        int LANES, int NPB, size_t h4Br, size_t aBr, size_t o4Br) {
    __shared__ int s_src[ETILE];
    __shared__ float s_alpha[ETILE * 3];
    int br = blockIdx.z;
    const int* src = br ? src1 : src0;
    const int* rs = rs_all + br * (N + 1);
    const int* eidx = eidx_all + br * E;
    const float4* h4 = h4_all + br * h4Br;
    const float* alpha = alpha_all + br * aBr;
    float4* out4 = out4_all + br * o4Br;
    int HD4 = (H * D) >> 2;
    int c0 = blockIdx.x * LANES;
    int tid = threadIdx.x;
    int n0 = blockIdx.y * NPB;
    int nEnd = n0 + NPB; if (nEnd > N) nEnd = N;
    if (n0 >= N) return;
    int lane = tid % LANES;
    int nsub = tid / LANES;
    int n = n0 + nsub;
    bool active = (tid < NPB * LANES) && (n < N);
    int myLo = 0, myHi = 0, hh = 0;
    if (active) {
        myLo = rs[n]; myHi = rs[n + 1];
        hh = ((c0 + lane) << 2) / D;
    }
    float4 acc = {0.f, 0.f, 0.f, 0.f};
    int eLo = rs[n0];
    int eHiAll = rs[nEnd];
    for (int base = eLo; base < eHiAll; base += ETILE) {
        int cnt = eHiAll - base; if (cnt > ETILE) cnt = ETILE;
        __syncthreads();
        for (int t = tid; t < cnt; t += blockDim.x) {
            int e = eidx[base + t];
            s_src[t] = src[e];
#pragma unroll
            for (int h = 0; h < 3; ++h)
                if (h < H) s_alpha[t * H + h] = alpha[(size_t)e * H + h];
        }
        __syncthreads();
        if (active) {
            int lo = myLo > base ? myLo : base;
            int hi = myHi < base + cnt ? myHi : base + cnt;
#pragma unroll 4
            for (int j = lo - base; j < hi - base; ++j) {
                float a = s_alpha[j * H + hh];
                float4 hv = h4[(size_t)s_src[j] * HD4 + c0 + lane];
                acc.x += a * hv.x; acc.y += a * hv.y;
                acc.z += a * hv.z; acc.w += a * hv.w;
            }
        }
    }
    if (active) {
        acc.x = fmaxf(acc.x, 0.f); acc.y = fmaxf(acc.y, 0.f);
        acc.z = fmaxf(acc.z, 0.f); acc.w = fmaxf(acc.w, 0.f);
        out4[(size_t)n * HD4 + c0 + lane] = acc;
    }
}

// Graph max-readout (post-ReLU >=0) via int-bitcast atomicMax. grid.y = branch.
__global__ void seg_max_atomic(const float* __restrict__ g_all, const int* __restrict__ nid,
                               int* __restrict__ out_all, int N, int C,
                               size_t gBr, size_t oBr) {
    int br = blockIdx.y;
    const float* g = g_all + br * gBr;
    int* out = out_all + br * oBr;
    int n0 = blockIdx.x << 5;
    int n1 = n0 + 32; if (n1 > N) n1 = N;
    if (n0 >= N) return;
    for (int c = threadIdx.x; c < C; c += blockDim.x) {
        int cur = nid[n0];
        float m = 0.f;
        for (int n = n0; n < n1; ++n) {
            int gid = nid[n];
            if (gid != cur) {
                atomicMax(&out[cur * C + c], __float_as_int(m));
                cur = gid; m = 0.f;
            }
            m = fmaxf(m, g[(size_t)n * C + c]);
        }
        atomicMax(&out[cur * C + c], __float_as_int(m));
    }
}

// ---------------- small dense layers (grid.z = branch; strides may be 0) ----
__global__ void linear_wave(const float* __restrict__ in, const float* __restrict__ W,
                            const float* __restrict__ bias, float* __restrict__ out,
                            int K, int O, int act, size_t inBr, size_t outBr) {
    int o = blockIdx.x * 4 + (threadIdx.x >> 6);
    int b = blockIdx.y;
    int lane = threadIdx.x & 63;
    if (o >= O) return;
    const float* ip = in + blockIdx.z * inBr + (size_t)b * K;
    float acc = 0.f;
    for (int k = lane; k < K; k += 64)
        acc += ip[k] * W[(size_t)k * O + o];
    for (int off = 32; off > 0; off >>= 1)
        acc += __shfl_down(acc, off, 64);
    if (lane == 0) {
        acc += bias[o];
        if (act == 1) acc = fmaxf(acc, 0.f);
        else if (act == 2) acc = 1.f / (1.f + expf(-acc));
        out[blockIdx.z * outBr + (size_t)b * O + o] = acc;
    }
}

// ---------------- TextCNN (branch-fused) ----------------
__global__ void transpose_pad2(const float* __restrict__ pad0, const float* __restrict__ pad1,
                               float* __restrict__ xT, int B, int L, int C) {
    int idx = blockIdx.x * blockDim.x + threadIdx.x;
    int per = B * L * C;
    if (idx >= 2 * per) return;
    int br = idx >= per;
    int loc = idx - br * per;
    const float* pad = br ? pad1 : pad0;
    int l = loc % L;
    int c = (loc / L) % C;
    int b = loc / (L * C);
    xT[idx] = pad[((size_t)b * L + l) * C + c];
}

#define CSTRIDE 68
__global__ void conv3k_v2(const float* __restrict__ x,
                          const float* __restrict__ w,
                          const float* __restrict__ bias,
                          float* __restrict__ y,
                          int Cin, int Lin, int Lout, size_t xBr, size_t yBr) {
    extern __shared__ float sx[];  // Cin x CSTRIDE
    int b = blockIdx.y;
    const float* xb = x + blockIdx.z * xBr;
    float* yb = y + blockIdx.z * yBr;
    int G = blockDim.x >> 7;
    int tileW = G << 4;
    int l0 = blockIdx.x * tileW;
    int tid = threadIdx.x;
    int tileL = Lout - l0; if (tileL > tileW) tileL = tileW;
    int loadL = tileL + 2;
    for (int idx = tid; idx < Cin * loadL; idx += blockDim.x) {
        int c = idx / loadL, i = idx - c * loadL;
        sx[c * CSTRIDE + i] = xb[((size_t)b * Cin + c) * Lin + l0 + i];
    }
    __syncthreads();
    int o = tid & 127;
    int pbase = (tid >> 7) << 4;
    int npos = tileL - pbase; if (npos > 16) npos = 16; if (npos < 0) npos = 0;
    float acc[16];
    float bv = bias[o];
#pragma unroll
    for (int j = 0; j < 16; ++j) acc[j] = bv;
    const float* wp = w + (size_t)o * Cin * 3;
    for (int c = 0; c < Cin; ++c) {
        const float* row = &sx[c * CSTRIDE + pbase];
        float xv[18];
        *(float4*)&xv[0]  = *(const float4*)&row[0];
        *(float4*)&xv[4]  = *(const float4*)&row[4];
        *(float4*)&xv[8]  = *(const float4*)&row[8];
        *(float4*)&xv[12] = *(const float4*)&row[12];
        *(float2*)&xv[16] = *(const float2*)&row[16];
        float w0 = wp[c * 3 + 0], w1 = wp[c * 3 + 1], w2 = wp[c * 3 + 2];
#pragma unroll
        for (int j = 0; j < 16; ++j) acc[j] += w0 * xv[j] + w1 * xv[j + 1] + w2 * xv[j + 2];
    }
    float* yp = yb + ((size_t)b * 128 + o) * Lout + l0 + pbase;
#pragma unroll
    for (int j = 0; j < 16; ++j)
        if (j < npos) yp[j] = acc[j];
}

__global__ void maxpool(const float* __restrict__ y, float* __restrict__ p,
                        int BC, int Lin, int k, int s, int Lout) {
    int idx = blockIdx.x * blockDim.x + threadIdx.x;
    if (idx >= BC * Lout) return;
    int lo = idx % Lout, bc = idx / Lout;
    const float* yp = y + (size_t)bc * Lin + lo * s;
    float m = -INFINITY;
    for (int i = 0; i < k; ++i) m = fmaxf(m, yp[i]);
    p[idx] = m;
}

// cat[b, br*128 + c] over both branches in one launch (gvec/sf are [2][B*128])
__global__ void combine_branch2(const float* __restrict__ g, const float* __restrict__ s,
                                const float* __restrict__ w1, float* __restrict__ cat, int B) {
    int idx = blockIdx.x * blockDim.x + threadIdx.x;
    int per = B * 128;
    if (idx >= 2 * per) return;
    int br = idx >= per;
    int loc = idx - br * per;
    int b = loc >> 7, c = loc & 127;
    float w = 1.f / (1.f + expf(-w1[0]));
    cat[b * 256 + br * 128 + c] = (1.f - w) * g[idx] + w * s[idx];
}

// ---------------- host ----------------
extern "C" void kernel_launch(void* const* d_in, const int* in_sizes, int n_in,
                              void* d_out, int out_size, void* d_ws, size_t ws_size,
                              hipStream_t stream) {
    const float* feat[2] = {(const float*)d_in[0], (const float*)d_in[1]};
    const float* pad[2]  = {(const float*)d_in[2], (const float*)d_in[3]};
    const int* src[2]    = {(const int*)d_in[4], (const int*)d_in[6]};
    const int* dst[2]    = {(const int*)d_in[5], (const int*)d_in[7]};
    const int* nid[2]    = {(const int*)d_in[8], (const int*)d_in[9]};
    const float* Wg[3]   = {(const float*)d_in[11], (const float*)d_in[14], (const float*)d_in[17]};
    const float* al[3]   = {(const float*)d_in[12], (const float*)d_in[15], (const float*)d_in[18]};
    const float* ar[3]   = {(const float*)d_in[13], (const float*)d_in[16], (const float*)d_in[19]};
    const float* fcg_w = (const float*)d_in[20]; const float* fcg_b = (const float*)d_in[21];
    const float* c1w = (const float*)d_in[22];   const float* c1b = (const float*)d_in[23];
    const float* c2w = (const float*)d_in[24];   const float* c2b = (const float*)d_in[25];
    const float* c3w = (const float*)d_in[26];   const float* c3b = (const float*)d_in[27];
    const float* tf_w = (const float*)d_in[28];  const float* tf_b = (const float*)d_in[29];
    const float* w1 = (const float*)d_in[30];
    const float* fc1_w = (const float*)d_in[31]; const float* fc1_b = (const float*)d_in[32];
    const float* fc2_w = (const float*)d_in[33]; const float* fc2_b = (const float*)d_in[34];
    const float* outw = (const float*)d_in[35];  const float* outb = (const float*)d_in[36];
    float* out = (float*)d_out;

    const int N = in_sizes[0] / 64;   // 8000
    const int E = in_sizes[4];        // 160000
    const int B = 16, L = 1200;
    const size_t NS = (size_t)N * 576;

    char* wsb = (char*)d_ws;
    size_t off = 0;
    auto allocB = [&](size_t bytes) -> void* {
        void* p = wsb + off;
        off += (bytes + 255) & ~(size_t)255;
        return p;
    };
    auto alloc = [&](size_t elems) -> void* { return allocB(elems * 4); };

    float* h_buf = (float*)alloc(2 * NS);
    float* gA    = (float*)alloc(2 * NS);
    float* el    = (float*)alloc(2 * (size_t)N * 3);
    float* er    = (float*)alloc(2 * (size_t)N * 3);
    float* alpha = (float*)alloc(2 * (size_t)E * 3);
    int* rs      = (int*)alloc(2 * (N + 1));
    int* cnt     = (int*)alloc(2 * N);
    int* eidx    = (int*)alloc(2 * E);
    int* gmax    = (int*)alloc(2 * (size_t)B * 576);
    float* gvec  = (float*)alloc(2 * (size_t)B * 128);
    float* sp    = (float*)alloc(2 * (size_t)B * 128);
    float* sf    = (float*)alloc(2 * (size_t)B * 128);
    float* cat   = (float*)alloc((size_t)B * 256);
    float* f1    = (float*)alloc((size_t)B * 512);
    float* f2    = (float*)alloc((size_t)B * 256);
    short* w2t1  = (short*)allocB((size_t)192 * 2 * 64 * 2);
    short* w2t2  = (short*)allocB((size_t)576 * 2 * 192 * 2);
    short* w2t3  = (short*)allocB((size_t)576 * 2 * 576 * 2);
    size_t tcnn_elems = 2 * ((size_t)B * 64 * L + (size_t)B * 128 * (1198 + 399 + 397 + 132 + 130));
    size_t uni_elems = 2 * NS > tcnn_elems ? 2 * NS : tcnn_elems;
    float* uni = (float*)alloc(uni_elems);
    float* gB = uni;
    float* xT = uni;
    float* y1 = xT + 2 * (size_t)B * 64 * L;
    float* p1 = y1 + 2 * (size_t)B * 128 * 1198;
    float* y2 = p1 + 2 * (size_t)B * 128 * 399;
    float* p2 = y2 + 2 * (size_t)B * 128 * 397;
    float* y3 = p2 + 2 * (size_t)B * 128 * 132;
    (void)ws_size; (void)n_in; (void)out_size;

    split_bf2_w<<<(64 * 192 + 255) / 256, 256, 0, stream>>>(Wg[0], w2t1, 64, 192);
    split_bf2_w<<<(192 * 576 + 255) / 256, 256, 0, stream>>>(Wg[1], w2t2, 192, 576);
    split_bf2_w<<<(576 * 576 + 255) / 256, 256, 0, stream>>>(Wg[2], w2t3, 576, 576);
    short* w2t[3] = {w2t1, w2t2, w2t3};

    // --- CSR for both branches ---
    zero_i32<<<(2 * N + 255) / 256, 256, 0, stream>>>(cnt, 2 * N);
    count_edges2<<<(2 * E + 255) / 256, 256, 0, stream>>>(dst[0], dst[1], cnt, N, E);
    scan_block<<<2, 1024, 0, stream>>>(cnt, rs, N);
    zero_i32<<<(2 * N + 255) / 256, 256, 0, stream>>>(cnt, 2 * N);
    scatter_edges2<<<(2 * E + 255) / 256, 256, 0, stream>>>(dst[0], dst[1], rs, cnt, eidx, N, E);

    // --- 3 GAT layers, both branches per dispatch ---
    const int dims[3][3] = {{64, 3, 64}, {192, 3, 192}, {576, 1, 576}};  // K,H,D
    float* outs[3] = {gA, gB, gA};
    const float* inp0 = feat[0];
    const float* inp1 = feat[1];
    for (int ly = 0; ly < 3; ++ly) {
        int K = dims[ly][0], H = dims[ly][1], D = dims[ly][2];
        int HD = H * D;
        gemm_bf3_v3<<<dim3(HD / 192, N / 32, 2), 256, 0, stream>>>(inp0, inp1, w2t[ly], h_buf, N, K, HD, NS);
        int waves2 = 2 * N * H;
        gat_elr<<<((size_t)waves2 * 64 + 255) / 256, 256, 0, stream>>>(h_buf, al[ly], ar[ly], el, er,
                                                                       N, H, D, NS, (size_t)N * 3);
        gat_softmax_wave<<<((size_t)2 * N * 64 + 255) / 256, 256, 0, stream>>>(
            el, er, src[0], src[1], rs, eidx, alpha, N, H, E, (size_t)N * 3, (size_t)E * 3);
        // chunked aggregate: HD=576 -> CH=8/LANES=18/NPB=14; HD=192 -> CH=4/LANES=12/NPB=20
        int CH, LANES, NPB;
        if (HD == 576) { CH = 8; LANES = 18; NPB = 14; }
        else           { CH = 4; LANES = 12; NPB = 20; }
        gat_aggregate_ch<<<dim3(CH, (N + NPB - 1) / NPB, 2), 256, 0, stream>>>(
            (const float4*)h_buf, alpha, src[0], src[1], rs, eidx, (float4*)outs[ly],
            N, H, D, E, LANES, NPB, NS / 4, (size_t)E * 3, NS / 4);
        inp0 = outs[ly];
        inp1 = outs[ly] + NS;
    }
    zero_i32<<<(2 * B * 576 + 255) / 256, 256, 0, stream>>>(gmax, 2 * B * 576);
    seg_max_atomic<<<dim3((N + 31) / 32, 2), 256, 0, stream>>>(gA, nid[0], gmax, N, 576,
                                                               NS, (size_t)B * 576);
    linear_wave<<<dim3(32, B, 2), 256, 0, stream>>>((const float*)gmax, fcg_w, fcg_b, gvec,
                                                    576, 128, 1, (size_t)B * 576, (size_t)B * 128);

    // --- TextCNN, both branches per dispatch (gB dead now; union is safe) ---
    transpose_pad2<<<((2 * B * 64 * L) + 255) / 256, 256, 0, stream>>>(pad[0], pad[1], xT, B, L, 64);
    conv3k_v2<<<dim3((1198 + 63) / 64, B, 2), 512, 64 * CSTRIDE * 4, stream>>>(
        xT, c1w, c1b, y1, 64, 1200, 1198, (size_t)B * 64 * L, (size_t)B * 128 * 1198);
    maxpool<<<(2 * B * 128 * 399 + 255) / 256, 256, 0, stream>>>(y1, p1, 2 * B * 128, 1198, 3, 3, 399);
    conv3k_v2<<<dim3((397 + 31) / 32, B, 2), 256, 128 * CSTRIDE * 4, stream>>>(
        p1, c2w, c2b, y2, 128, 399, 397, (size_t)B * 128 * 399, (size_t)B * 128 * 397);
    maxpool<<<(2 * B * 128 * 132 + 255) / 256, 256, 0, stream>>>(y2, p2, 2 * B * 128, 397, 3, 3, 132);
    conv3k_v2<<<dim3((130 + 31) / 32, B, 2), 256, 128 * CSTRIDE * 4, stream>>>(
        p2, c3w, c3b, y3, 128, 132, 130, (size_t)B * 128 * 132, (size_t)B * 128 * 130);
    maxpool<<<(2 * B * 128 + 255) / 256, 256, 0, stream>>>(y3, sp, 2 * B * 128, 130, 130, 1, 1);
    linear_wave<<<dim3(32, B, 2), 256, 0, stream>>>(sp, tf_w, tf_b, sf, 128, 128, 1,
                                                    (size_t)B * 128, (size_t)B * 128);
    combine_branch2<<<(2 * B * 128 + 255) / 256, 256, 0, stream>>>(gvec, sf, w1, cat, B);

    // --- head MLP ---
    linear_wave<<<dim3(128, B, 1), 256, 0, stream>>>(cat, fc1_w, fc1_b, f1, 256, 512, 1, 0, 0);
    linear_wave<<<dim3(64, B, 1), 256, 0, stream>>>(f1, fc2_w, fc2_b, f2, 512, 256, 1, 0, 0);
    linear_wave<<<dim3(1, B, 1), 256, 0, stream>>>(f2, outw, outb, out, 256, 1, 2, 0, 0);
}

// Round 10
// 754.157 us; speedup vs baseline: 4.3760x; 1.1088x over previous
//
#include <hip/hip_runtime.h>
#include <hip/hip_bf16.h>
#include <math.h>

#define NEG_SLOPE 0.2f

// ---------------- utility ----------------
__global__ void zero_i32(int* __restrict__ p, int n) {
    int i = blockIdx.x * blockDim.x + threadIdx.x;
    if (i < n) p[i] = 0;
}

// ---------------- CSR build (both branches in one dispatch) ----------------
__global__ void count_edges2(const int* __restrict__ dst0, const int* __restrict__ dst1,
                             int* __restrict__ cnt, int N, int E) {
    int i = blockIdx.x * blockDim.x + threadIdx.x;
    if (i >= 2 * E) return;
    int br = i >= E;
    int j = i - br * E;
    const int* d = br ? dst1 : dst0;
    atomicAdd(&cnt[br * N + d[j]], 1);
}

__global__ void scan_block(const int* __restrict__ cnt_all, int* __restrict__ rs_all, int N) {
    __shared__ int s[1024];
    int br = blockIdx.x;
    const int* cnt = cnt_all + br * N;
    int* rs = rs_all + br * (N + 1);
    int tid = threadIdx.x;
    int running = 0;
    for (int base = 0; base < N; base += 1024) {
        int v = (base + tid < N) ? cnt[base + tid] : 0;
        __syncthreads();
        s[tid] = v;
        __syncthreads();
        for (int off = 1; off < 1024; off <<= 1) {
            int t = (tid >= off) ? s[tid - off] : 0;
            __syncthreads();
            if (tid >= off) s[tid] += t;
            __syncthreads();
        }
        if (base + tid < N) rs[base + tid] = running + s[tid] - v;
        running += s[1023];
    }
    if (tid == 0) rs[N] = running;
}

__global__ void scatter_edges2(const int* __restrict__ dst0, const int* __restrict__ dst1,
                               const int* __restrict__ rs_all, int* __restrict__ fill_all,
                               int* __restrict__ eidx_all, int N, int E) {
    int i = blockIdx.x * blockDim.x + threadIdx.x;
    if (i >= 2 * E) return;
    int br = i >= E;
    int j = i - br * E;
    const int* d = br ? dst1 : dst0;
    int dd = d[j];
    int pos = atomicAdd(&fill_all[br * N + dd], 1);
    eidx_all[br * E + rs_all[br * (N + 1) + dd] + pos] = j;
}

// ---------------- bf16 hi/lo helpers ----------------
__device__ __forceinline__ short f2bf(float x) {
    __hip_bfloat16 h = __float2bfloat16(x);
    return *reinterpret_cast<short*>(&h);
}
__device__ __forceinline__ float bf2f(short s) {
    unsigned int u = ((unsigned int)(unsigned short)s) << 16;
    return __uint_as_float(u);
}

// W (K x N fp32) -> W2t (N x 2K bf16, transposed): rows [Wh | Wl]
__global__ void split_bf2_w(const float* __restrict__ W, short* __restrict__ W2t, int K, int N) {
    int idx = blockIdx.x * blockDim.x + threadIdx.x;
    if (idx >= K * N) return;
    int k = idx / N, n = idx - k * N;
    float x = W[idx];
    short hs = f2bf(x);
    short ls = f2bf(x - bf2f(hs));
    size_t base = (size_t)n * 2 * K;
    W2t[base + k] = hs;
    W2t[base + K + k] = ls;
}

// ---------------- MFMA bf16-split GEMM v3 (+ bf16 mirror of C) --------------
typedef __attribute__((ext_vector_type(8))) short short8;
typedef __attribute__((ext_vector_type(4))) short short4v;
typedef __attribute__((ext_vector_type(4))) float floatx4;

__global__ __launch_bounds__(256) void gemm_bf3_v3(const float* __restrict__ A0,
                                                   const float* __restrict__ A1,
                                                   const short* __restrict__ Bt,
                                                   float* __restrict__ C,
                                                   unsigned short* __restrict__ Cbf,
                                                   int M, int K, int N, size_t cBrStride) {
    __shared__ __align__(16) short sA[32 * 72];   // rows: [Ah(32) | Al(32) | pad8]
    __shared__ __align__(16) short sB[192 * 72];  // rows: [Wh(32) | Wl(32) | pad8]
    int tid = threadIdx.x;
    int wave = tid >> 6, lane = tid & 63;
    int m = lane & 15, q = lane >> 4;
    int row0 = blockIdx.y << 5;
    int col0 = blockIdx.x * 192;
    const float* A = blockIdx.z ? A1 : A0;
    float* Cb = C + blockIdx.z * cBrStride;
    unsigned short* Cbfb = Cbf + blockIdx.z * cBrStride;
    int K2 = K * 2;
    floatx4 acc[2][3];
#pragma unroll
    for (int rt = 0; rt < 2; ++rt)
#pragma unroll
        for (int ct = 0; ct < 3; ++ct) acc[rt][ct] = (floatx4){0.f, 0.f, 0.f, 0.f};

    for (int k0 = 0; k0 < K; k0 += 32) {
        {
            int r = tid >> 3, c = (tid & 7) << 2;
            float4 av = *(const float4*)&A[(size_t)(row0 + r) * K + k0 + c];
            short4v hs, ls;
            hs[0] = f2bf(av.x); ls[0] = f2bf(av.x - bf2f(hs[0]));
            hs[1] = f2bf(av.y); ls[1] = f2bf(av.y - bf2f(hs[1]));
            hs[2] = f2bf(av.z); ls[2] = f2bf(av.z - bf2f(hs[2]));
            hs[3] = f2bf(av.w); ls[3] = f2bf(av.w - bf2f(hs[3]));
            *(short4v*)&sA[r * 72 + c] = hs;
            *(short4v*)&sA[r * 72 + 32 + c] = ls;
        }
#pragma unroll
        for (int p = 0; p < 6; ++p) {
            int t = tid + (p << 8);
            int n = t >> 3, sub = t & 7;
            int srcoff = k0 + (sub << 3) + ((sub >= 4) ? (K - 32) : 0);
            *(float4*)&sB[n * 72 + (sub << 3)] =
                *(const float4*)&Bt[(size_t)(col0 + n) * K2 + srcoff];
        }
        __syncthreads();
        short8 a_hi[2], a_lo[2];
#pragma unroll
        for (int rt = 0; rt < 2; ++rt) {
            a_hi[rt] = *(const short8*)&sA[(rt * 16 + m) * 72 + q * 8];
            a_lo[rt] = *(const short8*)&sA[(rt * 16 + m) * 72 + 32 + q * 8];
        }
#pragma unroll
        for (int ct = 0; ct < 3; ++ct) {
            short8 b_hi = *(const short8*)&sB[(wave * 48 + ct * 16 + m) * 72 + q * 8];
            short8 b_lo = *(const short8*)&sB[(wave * 48 + ct * 16 + m) * 72 + 32 + q * 8];
#pragma unroll
            for (int rt = 0; rt < 2; ++rt) {
                acc[rt][ct] = __builtin_amdgcn_mfma_f32_16x16x32_bf16(a_hi[rt], b_hi, acc[rt][ct], 0, 0, 0);
                acc[rt][ct] = __builtin_amdgcn_mfma_f32_16x16x32_bf16(a_lo[rt], b_hi, acc[rt][ct], 0, 0, 0);
                acc[rt][ct] = __builtin_amdgcn_mfma_f32_16x16x32_bf16(a_hi[rt], b_lo, acc[rt][ct], 0, 0, 0);
            }
        }
        __syncthreads();
    }
#pragma unroll
    for (int rt = 0; rt < 2; ++rt)
#pragma unroll
        for (int ct = 0; ct < 3; ++ct)
#pragma unroll
            for (int r = 0; r < 4; ++r) {
                size_t idx = (size_t)(row0 + rt * 16 + q * 4 + r) * N + col0 + wave * 48 + ct * 16 + m;
                float v = acc[rt][ct][r];
                Cb[idx] = v;
                Cbfb[idx] = (unsigned short)f2bf(v);
            }
}

// ---------------- GAT pieces (branch-fused) ----------------
__global__ void gat_elr(const float* __restrict__ h, const float* __restrict__ al,
                        const float* __restrict__ ar, float* __restrict__ el,
                        float* __restrict__ er, int N, int H, int D,
                        size_t hBr, size_t eBr) {
    int wid = (blockIdx.x * blockDim.x + threadIdx.x) >> 6;
    int lane = threadIdx.x & 63;
    if (wid >= 2 * N * H) return;
    int br = wid / (N * H);
    int loc = wid - br * N * H;
    int n = loc / H, hh = loc - n * H;
    const float* hp = h + br * hBr + ((size_t)n * H + hh) * D;
    const float* alp = al + (size_t)hh * D;
    const float* arp = ar + (size_t)hh * D;
    float sl = 0.f, sr = 0.f;
    for (int d = lane; d < D; d += 64) {
        float v = hp[d];
        sl += v * alp[d];
        sr += v * arp[d];
    }
    for (int off = 32; off > 0; off >>= 1) {
        sl += __shfl_down(sl, off, 64);
        sr += __shfl_down(sr, off, 64);
    }
    if (lane == 0) { el[br * eBr + loc] = sl; er[br * eBr + loc] = sr; }
}

__device__ __forceinline__ float lrelu(float v) {
    return (v > 0.f) ? v : NEG_SLOPE * v;
}

__global__ void gat_softmax_wave(const float* __restrict__ el_all, const float* __restrict__ er_all,
                                 const int* __restrict__ src0, const int* __restrict__ src1,
                                 const int* __restrict__ rs_all, const int* __restrict__ eidx_all,
                                 float* __restrict__ alpha_all, int N, int H, int E,
                                 size_t eBr, size_t aBr) {
    int g = (blockIdx.x * blockDim.x + threadIdx.x) >> 6;
    int lane = threadIdx.x & 63;
    if (g >= 2 * N) return;
    int br = g / N;
    int n = g - br * N;
    const int* src = br ? src1 : src0;
    const int* rs = rs_all + br * (N + 1);
    const int* eidx = eidx_all + br * E;
    const float* el = el_all + br * eBr;
    const float* er = er_all + br * eBr;
    float* alpha = alpha_all + br * aBr;
    int s0 = rs[n], s1 = rs[n + 1];
    int deg = s1 - s0;
    if (deg == 0) return;
    float ern0 = er[n * H + 0];
    float ern1 = (H > 1) ? er[n * H + 1] : 0.f;
    float ern2 = (H > 2) ? er[n * H + 2] : 0.f;
    if (deg <= 64) {
        int e = 0, s = 0;
        float v0 = -INFINITY, v1 = -INFINITY, v2 = -INFINITY;
        if (lane < deg) {
            e = eidx[s0 + lane];
            s = src[e];
            v0 = lrelu(el[s * H + 0] + ern0);
            if (H > 1) {
                v1 = lrelu(el[s * H + 1] + ern1);
                v2 = lrelu(el[s * H + 2] + ern2);
            }
        }
        float m0 = v0, m1 = v1, m2 = v2;
#pragma unroll
        for (int off = 32; off > 0; off >>= 1) {
            m0 = fmaxf(m0, __shfl_xor(m0, off, 64));
            m1 = fmaxf(m1, __shfl_xor(m1, off, 64));
            m2 = fmaxf(m2, __shfl_xor(m2, off, 64));
        }
        float ex0 = (lane < deg) ? expf(v0 - m0) : 0.f;
        float ex1 = (lane < deg && H > 1) ? expf(v1 - m1) : 0.f;
        float ex2 = (lane < deg && H > 2) ? expf(v2 - m2) : 0.f;
        float d0 = ex0, d1 = ex1, d2 = ex2;
#pragma unroll
        for (int off = 32; off > 0; off >>= 1) {
            d0 += __shfl_xor(d0, off, 64);
            d1 += __shfl_xor(d1, off, 64);
            d2 += __shfl_xor(d2, off, 64);
        }
        if (lane < deg) {
            alpha[(size_t)e * H + 0] = ex0 / d0;
            if (H > 1) {
                alpha[(size_t)e * H + 1] = ex1 / d1;
                alpha[(size_t)e * H + 2] = ex2 / d2;
            }
        }
    } else {
        float m0 = -INFINITY, m1 = -INFINITY, m2 = -INFINITY;
        for (int j = s0 + lane; j < s1; j += 64) {
            int e = eidx[j], s = src[e];
            float v0 = lrelu(el[s * H + 0] + ern0);
            alpha[(size_t)e * H + 0] = v0; m0 = fmaxf(m0, v0);
            if (H > 1) {
                float v1 = lrelu(el[s * H + 1] + ern1);
                float v2 = lrelu(el[s * H + 2] + ern2);
                alpha[(size_t)e * H + 1] = v1; m1 = fmaxf(m1, v1);
                alpha[(size_t)e * H + 2] = v2; m2 = fmaxf(m2, v2);
            }
        }
#pragma unroll
        for (int off = 32; off > 0; off >>= 1) {
            m0 = fmaxf(m0, __shfl_xor(m0, off, 64));
            m1 = fmaxf(m1, __shfl_xor(m1, off, 64));
            m2 = fmaxf(m2, __shfl_xor(m2, off, 64));
        }
        float d0 = 0.f, d1 = 0.f, d2 = 0.f;
        for (int j = s0 + lane; j < s1; j += 64) {
            int e = eidx[j];
            float ex0 = expf(alpha[(size_t)e * H + 0] - m0);
            alpha[(size_t)e * H + 0] = ex0; d0 += ex0;
            if (H > 1) {
                float ex1 = expf(alpha[(size_t)e * H + 1] - m1);
                float ex2 = expf(alpha[(size_t)e * H + 2] - m2);
                alpha[(size_t)e * H + 1] = ex1; d1 += ex1;
                alpha[(size_t)e * H + 2] = ex2; d2 += ex2;
            }
        }
#pragma unroll
        for (int off = 32; off > 0; off >>= 1) {
            d0 += __shfl_xor(d0, off, 64);
            d1 += __shfl_xor(d1, off, 64);
            d2 += __shfl_xor(d2, off, 64);
        }
        float i0 = 1.f / d0;
        float i1 = (H > 1) ? 1.f / d1 : 0.f;
        float i2 = (H > 2) ? 1.f / d2 : 0.f;
        for (int j = s0 + lane; j < s1; j += 64) {
            int e = eidx[j];
            alpha[(size_t)e * H + 0] *= i0;
            if (H > 1) {
                alpha[(size_t)e * H + 1] *= i1;
                alpha[(size_t)e * H + 2] *= i2;
            }
        }
    }
}

// ---------------- aggregate (R8 layout, bf16 h) ----------------
// Block per node; edge metadata staged to LDS by parallel threads; each active
// lane owns 4 columns read as ushort4 (8B) from the bf16 mirror of h.
#define TILE_E 64
__global__ void gat_aggregate(const unsigned short* __restrict__ hb_all,
                              const float* __restrict__ alpha_all,
                              const int* __restrict__ src0, const int* __restrict__ src1,
                              const int* __restrict__ rs_all, const int* __restrict__ eidx_all,
                              float4* __restrict__ out4_all, int N, int H, int D, int E,
                              size_t hBr, size_t aBr, size_t o4Br) {
    __shared__ int s_src[TILE_E];
    __shared__ float s_alpha[TILE_E * 3];
    int n = blockIdx.x;
    int br = blockIdx.y;
    const int* src = br ? src1 : src0;
    const int* rs = rs_all + br * (N + 1);
    const int* eidx = eidx_all + br * E;
    const unsigned short* hb = hb_all + br * hBr;
    const float* alpha = alpha_all + br * aBr;
    float4* out4 = out4_all + br * o4Br;
    int HD = H * D;
    int HD4 = HD >> 2;
    int tid = threadIdx.x;
    int s0 = rs[n], s1 = rs[n + 1];
    bool active = tid < HD4;
    int hh = active ? (tid << 2) / D : 0;
    float4 acc = {0.f, 0.f, 0.f, 0.f};
    for (int base = s0; base < s1; base += TILE_E) {
        int cntE = s1 - base; if (cntE > TILE_E) cntE = TILE_E;
        if (tid < cntE) {
            int e = eidx[base + tid];
            s_src[tid] = src[e];
#pragma unroll
            for (int h = 0; h < 3; ++h)
                if (h < H) s_alpha[tid * 3 + h] = alpha[(size_t)e * H + h];
        }
        __syncthreads();
        if (active) {
#pragma unroll 4
            for (int i = 0; i < cntE; ++i) {
                float a = s_alpha[i * 3 + hh];
                ushort4 hv = *(const ushort4*)&hb[(size_t)s_src[i] * HD + (tid << 2)];
                acc.x += a * __uint_as_float((unsigned int)hv.x << 16);
                acc.y += a * __uint_as_float((unsigned int)hv.y << 16);
                acc.z += a * __uint_as_float((unsigned int)hv.z << 16);
                acc.w += a * __uint_as_float((unsigned int)hv.w << 16);
            }
        }
        __syncthreads();
    }
    if (active) {
        acc.x = fmaxf(acc.x, 0.f); acc.y = fmaxf(acc.y, 0.f);
        acc.z = fmaxf(acc.z, 0.f); acc.w = fmaxf(acc.w, 0.f);
        out4[(size_t)n * HD4 + tid] = acc;
    }
}

// Graph max-readout (post-ReLU >=0) via int-bitcast atomicMax. grid.y = branch.
__global__ void seg_max_atomic(const float* __restrict__ g_all, const int* __restrict__ nid,
                               int* __restrict__ out_all, int N, int C,
                               size_t gBr, size_t oBr) {
    int br = blockIdx.y;
    const float* g = g_all + br * gBr;
    int* out = out_all + br * oBr;
    int n0 = blockIdx.x << 5;
    int n1 = n0 + 32; if (n1 > N) n1 = N;
    if (n0 >= N) return;
    for (int c = threadIdx.x; c < C; c += blockDim.x) {
        int cur = nid[n0];
        float m = 0.f;
        for (int n = n0; n < n1; ++n) {
            int gid = nid[n];
            if (gid != cur) {
                atomicMax(&out[cur * C + c], __float_as_int(m));
                cur = gid; m = 0.f;
            }
            m = fmaxf(m, g[(size_t)n * C + c]);
        }
        atomicMax(&out[cur * C + c], __float_as_int(m));
    }
}

// ---------------- small dense layers (grid.z = branch; strides may be 0) ----
__global__ void linear_wave(const float* __restrict__ in, const float* __restrict__ W,
                            const float* __restrict__ bias, float* __restrict__ out,
                            int K, int O, int act, size_t inBr, size_t outBr) {
    int o = blockIdx.x * 4 + (threadIdx.x >> 6);
    int b = blockIdx.y;
    int lane = threadIdx.x & 63;
    if (o >= O) return;
    const float* ip = in + blockIdx.z * inBr + (size_t)b * K;
    float acc = 0.f;
    for (int k = lane; k < K; k += 64)
        acc += ip[k] * W[(size_t)k * O + o];
    for (int off = 32; off > 0; off >>= 1)
        acc += __shfl_down(acc, off, 64);
    if (lane == 0) {
        acc += bias[o];
        if (act == 1) acc = fmaxf(acc, 0.f);
        else if (act == 2) acc = 1.f / (1.f + expf(-acc));
        out[blockIdx.z * outBr + (size_t)b * O + o] = acc;
    }
}

// ---------------- TextCNN (branch-fused) ----------------
__global__ void transpose_pad2(const float* __restrict__ pad0, const float* __restrict__ pad1,
                               float* __restrict__ xT, int B, int L, int C) {
    int idx = blockIdx.x * blockDim.x + threadIdx.x;
    int per = B * L * C;
    if (idx >= 2 * per) return;
    int br = idx >= per;
    int loc = idx - br * per;
    const float* pad = br ? pad1 : pad0;
    int l = loc % L;
    int c = (loc / L) % C;
    int b = loc / (L * C);
    xT[idx] = pad[((size_t)b * L + l) * C + c];
}

#define CSTRIDE 68
__global__ void conv3k_v2(const float* __restrict__ x,
                          const float* __restrict__ w,
                          const float* __restrict__ bias,
                          float* __restrict__ y,
                          int Cin, int Lin, int Lout, size_t xBr, size_t yBr) {
    extern __shared__ float sx[];  // Cin x CSTRIDE
    int b = blockIdx.y;
    const float* xb = x + blockIdx.z * xBr;
    float* yb = y + blockIdx.z * yBr;
    int G = blockDim.x >> 7;
    int tileW = G << 4;
    int l0 = blockIdx.x * tileW;
    int tid = threadIdx.x;
    int tileL = Lout - l0; if (tileL > tileW) tileL = tileW;
    int loadL = tileL + 2;
    for (int idx = tid; idx < Cin * loadL; idx += blockDim.x) {
        int c = idx / loadL, i = idx - c * loadL;
        sx[c * CSTRIDE + i] = xb[((size_t)b * Cin + c) * Lin + l0 + i];
    }
    __syncthreads();
    int o = tid & 127;
    int pbase = (tid >> 7) << 4;
    int npos = tileL - pbase; if (npos > 16) npos = 16; if (npos < 0) npos = 0;
    float acc[16];
    float bv = bias[o];
#pragma unroll
    for (int j = 0; j < 16; ++j) acc[j] = bv;
    const float* wp = w + (size_t)o * Cin * 3;
    for (int c = 0; c < Cin; ++c) {
        const float* row = &sx[c * CSTRIDE + pbase];
        float xv[18];
        *(float4*)&xv[0]  = *(const float4*)&row[0];
        *(float4*)&xv[4]  = *(const float4*)&row[4];
        *(float4*)&xv[8]  = *(const float4*)&row[8];
        *(float4*)&xv[12] = *(const float4*)&row[12];
        *(float2*)&xv[16] = *(const float2*)&row[16];
        float w0 = wp[c * 3 + 0], w1 = wp[c * 3 + 1], w2 = wp[c * 3 + 2];
#pragma unroll
        for (int j = 0; j < 16; ++j) acc[j] += w0 * xv[j] + w1 * xv[j + 1] + w2 * xv[j + 2];
    }
    float* yp = yb + ((size_t)b * 128 + o) * Lout + l0 + pbase;
#pragma unroll
    for (int j = 0; j < 16; ++j)
        if (j < npos) yp[j] = acc[j];
}

__global__ void maxpool(const float* __restrict__ y, float* __restrict__ p,
                        int BC, int Lin, int k, int s, int Lout) {
    int idx = blockIdx.x * blockDim.x + threadIdx.x;
    if (idx >= BC * Lout) return;
    int lo = idx % Lout, bc = idx / Lout;
    const float* yp = y + (size_t)bc * Lin + lo * s;
    float m = -INFINITY;
    for (int i = 0; i < k; ++i) m = fmaxf(m, yp[i]);
    p[idx] = m;
}

// cat[b, br*128 + c] over both branches in one launch (gvec/sf are [2][B*128])
__global__ void combine_branch2(const float* __restrict__ g, const float* __restrict__ s,
                                const float* __restrict__ w1, float* __restrict__ cat, int B) {
    int idx = blockIdx.x * blockDim.x + threadIdx.x;
    int per = B * 128;
    if (idx >= 2 * per) return;
    int br = idx >= per;
    int loc = idx - br * per;
    int b = loc >> 7, c = loc & 127;
    float w = 1.f / (1.f + expf(-w1[0]));
    cat[b * 256 + br * 128 + c] = (1.f - w) * g[idx] + w * s[idx];
}

// ---------------- host ----------------
extern "C" void kernel_launch(void* const* d_in, const int* in_sizes, int n_in,
                              void* d_out, int out_size, void* d_ws, size_t ws_size,
                              hipStream_t stream) {
    const float* feat[2] = {(const float*)d_in[0], (const float*)d_in[1]};
    const float* pad[2]  = {(const float*)d_in[2], (const float*)d_in[3]};
    const int* src[2]    = {(const int*)d_in[4], (const int*)d_in[6]};
    const int* dst[2]    = {(const int*)d_in[5], (const int*)d_in[7]};
    const int* nid[2]    = {(const int*)d_in[8], (const int*)d_in[9]};
    const float* Wg[3]   = {(const float*)d_in[11], (const float*)d_in[14], (const float*)d_in[17]};
    const float* al[3]   = {(const float*)d_in[12], (const float*)d_in[15], (const float*)d_in[18]};
    const float* ar[3]   = {(const float*)d_in[13], (const float*)d_in[16], (const float*)d_in[19]};
    const float* fcg_w = (const float*)d_in[20]; const float* fcg_b = (const float*)d_in[21];
    const float* c1w = (const float*)d_in[22];   const float* c1b = (const float*)d_in[23];
    const float* c2w = (const float*)d_in[24];   const float* c2b = (const float*)d_in[25];
    const float* c3w = (const float*)d_in[26];   const float* c3b = (const float*)d_in[27];
    const float* tf_w = (const float*)d_in[28];  const float* tf_b = (const float*)d_in[29];
    const float* w1 = (const float*)d_in[30];
    const float* fc1_w = (const float*)d_in[31]; const float* fc1_b = (const float*)d_in[32];
    const float* fc2_w = (const float*)d_in[33]; const float* fc2_b = (const float*)d_in[34];
    const float* outw = (const float*)d_in[35];  const float* outb = (const float*)d_in[36];
    float* out = (float*)d_out;

    const int N = in_sizes[0] / 64;   // 8000
    const int E = in_sizes[4];        // 160000
    const int B = 16, L = 1200;
    const size_t NS = (size_t)N * 576;

    char* wsb = (char*)d_ws;
    size_t off = 0;
    auto allocB = [&](size_t bytes) -> void* {
        void* p = wsb + off;
        off += (bytes + 255) & ~(size_t)255;
        return p;
    };
    auto alloc = [&](size_t elems) -> void* { return allocB(elems * 4); };

    float* h_buf = (float*)alloc(2 * NS);
    unsigned short* h_bf = (unsigned short*)allocB(2 * NS * 2);   // bf16 mirror of h
    float* gA    = (float*)alloc(2 * NS);
    float* el    = (float*)alloc(2 * (size_t)N * 3);
    float* er    = (float*)alloc(2 * (size_t)N * 3);
    float* alpha = (float*)alloc(2 * (size_t)E * 3);
    int* rs      = (int*)alloc(2 * (N + 1));
    int* cnt     = (int*)alloc(2 * N);
    int* eidx    = (int*)alloc(2 * E);
    int* gmax    = (int*)alloc(2 * (size_t)B * 576);
    float* gvec  = (float*)alloc(2 * (size_t)B * 128);
    float* sp    = (float*)alloc(2 * (size_t)B * 128);
    float* sf    = (float*)alloc(2 * (size_t)B * 128);
    float* cat   = (float*)alloc((size_t)B * 256);
    float* f1    = (float*)alloc((size_t)B * 512);
    float* f2    = (float*)alloc((size_t)B * 256);
    short* w2t1  = (short*)allocB((size_t)192 * 2 * 64 * 2);
    short* w2t2  = (short*)allocB((size_t)576 * 2 * 192 * 2);
    short* w2t3  = (short*)allocB((size_t)576 * 2 * 576 * 2);
    size_t tcnn_elems = 2 * ((size_t)B * 64 * L + (size_t)B * 128 * (1198 + 399 + 397 + 132 + 130));
    size_t uni_elems = 2 * NS > tcnn_elems ? 2 * NS : tcnn_elems;
    float* uni = (float*)alloc(uni_elems);
    float* gB = uni;
    float* xT = uni;
    float* y1 = xT + 2 * (size_t)B * 64 * L;
    float* p1 = y1 + 2 * (size_t)B * 128 * 1198;
    float* y2 = p1 + 2 * (size_t)B * 128 * 399;
    float* p2 = y2 + 2 * (size_t)B * 128 * 397;
    float* y3 = p2 + 2 * (size_t)B * 128 * 132;
    (void)ws_size; (void)n_in; (void)out_size;

    split_bf2_w<<<(64 * 192 + 255) / 256, 256, 0, stream>>>(Wg[0], w2t1, 64, 192);
    split_bf2_w<<<(192 * 576 + 255) / 256, 256, 0, stream>>>(Wg[1], w2t2, 192, 576);
    split_bf2_w<<<(576 * 576 + 255) / 256, 256, 0, stream>>>(Wg[2], w2t3, 576, 576);
    short* w2t[3] = {w2t1, w2t2, w2t3};

    // --- CSR for both branches ---
    zero_i32<<<(2 * N + 255) / 256, 256, 0, stream>>>(cnt, 2 * N);
    count_edges2<<<(2 * E + 255) / 256, 256, 0, stream>>>(dst[0], dst[1], cnt, N, E);
    scan_block<<<2, 1024, 0, stream>>>(cnt, rs, N);
    zero_i32<<<(2 * N + 255) / 256, 256, 0, stream>>>(cnt, 2 * N);
    scatter_edges2<<<(2 * E + 255) / 256, 256, 0, stream>>>(dst[0], dst[1], rs, cnt, eidx, N, E);

    // --- 3 GAT layers, both branches per dispatch ---
    const int dims[3][3] = {{64, 3, 64}, {192, 3, 192}, {576, 1, 576}};  // K,H,D
    float* outs[3] = {gA, gB, gA};
    const float* inp0 = feat[0];
    const float* inp1 = feat[1];
    for (int ly = 0; ly < 3; ++ly) {
        int K = dims[ly][0], H = dims[ly][1], D = dims[ly][2];
        int HD = H * D;
        gemm_bf3_v3<<<dim3(HD / 192, N / 32, 2), 256, 0, stream>>>(inp0, inp1, w2t[ly], h_buf, h_bf,
                                                                   N, K, HD, NS);
        int waves2 = 2 * N * H;
        gat_elr<<<((size_t)waves2 * 64 + 255) / 256, 256, 0, stream>>>(h_buf, al[ly], ar[ly], el, er,
                                                                       N, H, D, NS, (size_t)N * 3);
        gat_softmax_wave<<<((size_t)2 * N * 64 + 255) / 256, 256, 0, stream>>>(
            el, er, src[0], src[1], rs, eidx, alpha, N, H, E, (size_t)N * 3, (size_t)E * 3);
        int aggThreads = (((HD >> 2) + 63) / 64) * 64;   // 64 for HD=192, 192 for HD=576
        gat_aggregate<<<dim3(N, 2), aggThreads, 0, stream>>>(
            h_bf, alpha, src[0], src[1], rs, eidx, (float4*)outs[ly],
            N, H, D, E, NS, (size_t)E * 3, NS / 4);
        inp0 = outs[ly];
        inp1 = outs[ly] + NS;
    }
    zero_i32<<<(2 * B * 576 + 255) / 256, 256, 0, stream>>>(gmax, 2 * B * 576);
    seg_max_atomic<<<dim3((N + 31) / 32, 2), 256, 0, stream>>>(gA, nid[0], gmax, N, 576,
                                                               NS, (size_t)B * 576);
    linear_wave<<<dim3(32, B, 2), 256, 0, stream>>>((const float*)gmax, fcg_w, fcg_b, gvec,
                                                    576, 128, 1, (size_t)B * 576, (size_t)B * 128);

    // --- TextCNN, both branches per dispatch (gB dead now; union is safe) ---
    transpose_pad2<<<((2 * B * 64 * L) + 255) / 256, 256, 0, stream>>>(pad[0], pad[1], xT, B, L, 64);
    conv3k_v2<<<dim3((1198 + 63) / 64, B, 2), 512, 64 * CSTRIDE * 4, stream>>>(
        xT, c1w, c1b, y1, 64, 1200, 1198, (size_t)B * 64 * L, (size_t)B * 128 * 1198);
    maxpool<<<(2 * B * 128 * 399 + 255) / 256, 256, 0, stream>>>(y1, p1, 2 * B * 128, 1198, 3, 3, 399);
    conv3k_v2<<<dim3((397 + 31) / 32, B, 2), 256, 128 * CSTRIDE * 4, stream>>>(
        p1, c2w, c2b, y2, 128, 399, 397, (size_t)B * 128 * 399, (size_t)B * 128 * 397);
    maxpool<<<(2 * B * 128 * 132 + 255) / 256, 256, 0, stream>>>(y2, p2, 2 * B * 128, 397, 3, 3, 132);
    conv3k_v2<<<dim3((130 + 31) / 32, B, 2), 256, 128 * CSTRIDE * 4, stream>>>(
        p2, c3w, c3b, y3, 128, 132, 130, (size_t)B * 128 * 132, (size_t)B * 128 * 130);
    maxpool<<<(2 * B * 128 + 255) / 256, 256, 0, stream>>>(y3, sp, 2 * B * 128, 130, 130, 1, 1);
    linear_wave<<<dim3(32, B, 2), 256, 0, stream>>>(sp, tf_w, tf_b, sf, 128, 128, 1,
                                                    (size_t)B * 128, (size_t)B * 128);
    combine_branch2<<<(2 * B * 128 + 255) / 256, 256, 0, stream>>>(gvec, sf, w1, cat, B);

    // --- head MLP ---
    linear_wave<<<dim3(128, B, 1), 256, 0, stream>>>(cat, fc1_w, fc1_b, f1, 256, 512, 1, 0, 0);
    linear_wave<<<dim3(64, B, 1), 256, 0, stream>>>(f1, fc2_w, fc2_b, f2, 512, 256, 1, 0, 0);
    linear_wave<<<dim3(1, B, 1), 256, 0, stream>>>(f2, outw, outb, out, 256, 1, 2, 0, 0);
}

// Round 11
// 741.857 us; speedup vs baseline: 4.4485x; 1.0166x over previous
//
#include <hip/hip_runtime.h>
#include <hip/hip_bf16.h>
#include <math.h>

#define NEG_SLOPE 0.2f

// ---------------- utility ----------------
__global__ void zero_i32(int* __restrict__ p, int n) {
    int i = blockIdx.x * blockDim.x + threadIdx.x;
    if (i < n) p[i] = 0;
}

// ---------------- CSR build (both branches in one dispatch) ----------------
__global__ void count_edges2(const int* __restrict__ dst0, const int* __restrict__ dst1,
                             int* __restrict__ cnt, int N, int E) {
    int i = blockIdx.x * blockDim.x + threadIdx.x;
    if (i >= 2 * E) return;
    int br = i >= E;
    int j = i - br * E;
    const int* d = br ? dst1 : dst0;
    atomicAdd(&cnt[br * N + d[j]], 1);
}

__global__ void scan_block(const int* __restrict__ cnt_all, int* __restrict__ rs_all, int N) {
    __shared__ int s[1024];
    int br = blockIdx.x;
    const int* cnt = cnt_all + br * N;
    int* rs = rs_all + br * (N + 1);
    int tid = threadIdx.x;
    int running = 0;
    for (int base = 0; base < N; base += 1024) {
        int v = (base + tid < N) ? cnt[base + tid] : 0;
        __syncthreads();
        s[tid] = v;
        __syncthreads();
        for (int off = 1; off < 1024; off <<= 1) {
            int t = (tid >= off) ? s[tid - off] : 0;
            __syncthreads();
            if (tid >= off) s[tid] += t;
            __syncthreads();
        }
        if (base + tid < N) rs[base + tid] = running + s[tid] - v;
        running += s[1023];
    }
    if (tid == 0) rs[N] = running;
}

__global__ void scatter_edges2(const int* __restrict__ dst0, const int* __restrict__ dst1,
                               const int* __restrict__ rs_all, int* __restrict__ fill_all,
                               int* __restrict__ eidx_all, int N, int E) {
    int i = blockIdx.x * blockDim.x + threadIdx.x;
    if (i >= 2 * E) return;
    int br = i >= E;
    int j = i - br * E;
    const int* d = br ? dst1 : dst0;
    int dd = d[j];
    int pos = atomicAdd(&fill_all[br * N + dd], 1);
    eidx_all[br * E + rs_all[br * (N + 1) + dd] + pos] = j;
}

// ---------------- bf16 hi/lo helpers ----------------
__device__ __forceinline__ short f2bf(float x) {
    __hip_bfloat16 h = __float2bfloat16(x);
    return *reinterpret_cast<short*>(&h);
}
__device__ __forceinline__ float bf2f(short s) {
    unsigned int u = ((unsigned int)(unsigned short)s) << 16;
    return __uint_as_float(u);
}

// W (K x N fp32) -> W2t (N x 2K bf16, transposed): rows [Wh | Wl]
__global__ void split_bf2_w(const float* __restrict__ W, short* __restrict__ W2t, int K, int N) {
    int idx = blockIdx.x * blockDim.x + threadIdx.x;
    if (idx >= K * N) return;
    int k = idx / N, n = idx - k * N;
    float x = W[idx];
    short hs = f2bf(x);
    short ls = f2bf(x - bf2f(hs));
    size_t base = (size_t)n * 2 * K;
    W2t[base + k] = hs;
    W2t[base + K + k] = ls;
}

// conv weights [128][Cin][3] -> wt[(c*3+j)][128]  (coalesced per-lane reads)
__global__ void transpose_cw(const float* __restrict__ w, float* __restrict__ wt, int Cin) {
    int idx = blockIdx.x * blockDim.x + threadIdx.x;
    int tot = 128 * Cin * 3;
    if (idx >= tot) return;
    int o = idx / (Cin * 3);
    int r = idx - o * (Cin * 3);          // r = c*3 + j
    wt[r * 128 + o] = w[idx];
}

// ---------------- MFMA bf16-split GEMM v3 (+ bf16 mirror of C) --------------
typedef __attribute__((ext_vector_type(8))) short short8;
typedef __attribute__((ext_vector_type(4))) short short4v;
typedef __attribute__((ext_vector_type(4))) float floatx4;

__global__ __launch_bounds__(256) void gemm_bf3_v3(const float* __restrict__ A0,
                                                   const float* __restrict__ A1,
                                                   const short* __restrict__ Bt,
                                                   float* __restrict__ C,
                                                   unsigned short* __restrict__ Cbf,
                                                   int M, int K, int N, size_t cBrStride) {
    __shared__ __align__(16) short sA[32 * 72];   // rows: [Ah(32) | Al(32) | pad8]
    __shared__ __align__(16) short sB[192 * 72];  // rows: [Wh(32) | Wl(32) | pad8]
    int tid = threadIdx.x;
    int wave = tid >> 6, lane = tid & 63;
    int m = lane & 15, q = lane >> 4;
    int row0 = blockIdx.y << 5;
    int col0 = blockIdx.x * 192;
    const float* A = blockIdx.z ? A1 : A0;
    float* Cb = C + blockIdx.z * cBrStride;
    unsigned short* Cbfb = Cbf + blockIdx.z * cBrStride;
    int K2 = K * 2;
    floatx4 acc[2][3];
#pragma unroll
    for (int rt = 0; rt < 2; ++rt)
#pragma unroll
        for (int ct = 0; ct < 3; ++ct) acc[rt][ct] = (floatx4){0.f, 0.f, 0.f, 0.f};

    for (int k0 = 0; k0 < K; k0 += 32) {
        {
            int r = tid >> 3, c = (tid & 7) << 2;
            float4 av = *(const float4*)&A[(size_t)(row0 + r) * K + k0 + c];
            short4v hs, ls;
            hs[0] = f2bf(av.x); ls[0] = f2bf(av.x - bf2f(hs[0]));
            hs[1] = f2bf(av.y); ls[1] = f2bf(av.y - bf2f(hs[1]));
            hs[2] = f2bf(av.z); ls[2] = f2bf(av.z - bf2f(hs[2]));
            hs[3] = f2bf(av.w); ls[3] = f2bf(av.w - bf2f(hs[3]));
            *(short4v*)&sA[r * 72 + c] = hs;
            *(short4v*)&sA[r * 72 + 32 + c] = ls;
        }
#pragma unroll
        for (int p = 0; p < 6; ++p) {
            int t = tid + (p << 8);
            int n = t >> 3, sub = t & 7;
            int srcoff = k0 + (sub << 3) + ((sub >= 4) ? (K - 32) : 0);
            *(float4*)&sB[n * 72 + (sub << 3)] =
                *(const float4*)&Bt[(size_t)(col0 + n) * K2 + srcoff];
        }
        __syncthreads();
        short8 a_hi[2], a_lo[2];
#pragma unroll
        for (int rt = 0; rt < 2; ++rt) {
            a_hi[rt] = *(const short8*)&sA[(rt * 16 + m) * 72 + q * 8];
            a_lo[rt] = *(const short8*)&sA[(rt * 16 + m) * 72 + 32 + q * 8];
        }
#pragma unroll
        for (int ct = 0; ct < 3; ++ct) {
            short8 b_hi = *(const short8*)&sB[(wave * 48 + ct * 16 + m) * 72 + q * 8];
            short8 b_lo = *(const short8*)&sB[(wave * 48 + ct * 16 + m) * 72 + 32 + q * 8];
#pragma unroll
            for (int rt = 0; rt < 2; ++rt) {
                acc[rt][ct] = __builtin_amdgcn_mfma_f32_16x16x32_bf16(a_hi[rt], b_hi, acc[rt][ct], 0, 0, 0);
                acc[rt][ct] = __builtin_amdgcn_mfma_f32_16x16x32_bf16(a_lo[rt], b_hi, acc[rt][ct], 0, 0, 0);
                acc[rt][ct] = __builtin_amdgcn_mfma_f32_16x16x32_bf16(a_hi[rt], b_lo, acc[rt][ct], 0, 0, 0);
            }
        }
        __syncthreads();
    }
#pragma unroll
    for (int rt = 0; rt < 2; ++rt)
#pragma unroll
        for (int ct = 0; ct < 3; ++ct)
#pragma unroll
            for (int r = 0; r < 4; ++r) {
                size_t idx = (size_t)(row0 + rt * 16 + q * 4 + r) * N + col0 + wave * 48 + ct * 16 + m;
                float v = acc[rt][ct][r];
                Cb[idx] = v;
                Cbfb[idx] = (unsigned short)f2bf(v);
            }
}

// ---------------- GAT pieces (branch-fused) ----------------
__global__ void gat_elr(const float* __restrict__ h, const float* __restrict__ al,
                        const float* __restrict__ ar, float* __restrict__ el,
                        float* __restrict__ er, int N, int H, int D,
                        size_t hBr, size_t eBr) {
    int wid = (blockIdx.x * blockDim.x + threadIdx.x) >> 6;
    int lane = threadIdx.x & 63;
    if (wid >= 2 * N * H) return;
    int br = wid / (N * H);
    int loc = wid - br * N * H;
    int n = loc / H, hh = loc - n * H;
    const float* hp = h + br * hBr + ((size_t)n * H + hh) * D;
    const float* alp = al + (size_t)hh * D;
    const float* arp = ar + (size_t)hh * D;
    float sl = 0.f, sr = 0.f;
    for (int d = lane; d < D; d += 64) {
        float v = hp[d];
        sl += v * alp[d];
        sr += v * arp[d];
    }
    for (int off = 32; off > 0; off >>= 1) {
        sl += __shfl_down(sl, off, 64);
        sr += __shfl_down(sr, off, 64);
    }
    if (lane == 0) { el[br * eBr + loc] = sl; er[br * eBr + loc] = sr; }
}

__device__ __forceinline__ float lrelu(float v) {
    return (v > 0.f) ? v : NEG_SLOPE * v;
}

__global__ void gat_softmax_wave(const float* __restrict__ el_all, const float* __restrict__ er_all,
                                 const int* __restrict__ src0, const int* __restrict__ src1,
                                 const int* __restrict__ rs_all, const int* __restrict__ eidx_all,
                                 float* __restrict__ alpha_all, int N, int H, int E,
                                 size_t eBr, size_t aBr) {
    int g = (blockIdx.x * blockDim.x + threadIdx.x) >> 6;
    int lane = threadIdx.x & 63;
    if (g >= 2 * N) return;
    int br = g / N;
    int n = g - br * N;
    const int* src = br ? src1 : src0;
    const int* rs = rs_all + br * (N + 1);
    const int* eidx = eidx_all + br * E;
    const float* el = el_all + br * eBr;
    const float* er = er_all + br * eBr;
    float* alpha = alpha_all + br * aBr;
    int s0 = rs[n], s1 = rs[n + 1];
    int deg = s1 - s0;
    if (deg == 0) return;
    float ern0 = er[n * H + 0];
    float ern1 = (H > 1) ? er[n * H + 1] : 0.f;
    float ern2 = (H > 2) ? er[n * H + 2] : 0.f;
    if (deg <= 64) {
        int e = 0, s = 0;
        float v0 = -INFINITY, v1 = -INFINITY, v2 = -INFINITY;
        if (lane < deg) {
            e = eidx[s0 + lane];
            s = src[e];
            v0 = lrelu(el[s * H + 0] + ern0);
            if (H > 1) {
                v1 = lrelu(el[s * H + 1] + ern1);
                v2 = lrelu(el[s * H + 2] + ern2);
            }
        }
        float m0 = v0, m1 = v1, m2 = v2;
#pragma unroll
        for (int off = 32; off > 0; off >>= 1) {
            m0 = fmaxf(m0, __shfl_xor(m0, off, 64));
            m1 = fmaxf(m1, __shfl_xor(m1, off, 64));
            m2 = fmaxf(m2, __shfl_xor(m2, off, 64));
        }
        float ex0 = (lane < deg) ? expf(v0 - m0) : 0.f;
        float ex1 = (lane < deg && H > 1) ? expf(v1 - m1) : 0.f;
        float ex2 = (lane < deg && H > 2) ? expf(v2 - m2) : 0.f;
        float d0 = ex0, d1 = ex1, d2 = ex2;
#pragma unroll
        for (int off = 32; off > 0; off >>= 1) {
            d0 += __shfl_xor(d0, off, 64);
            d1 += __shfl_xor(d1, off, 64);
            d2 += __shfl_xor(d2, off, 64);
        }
        if (lane < deg) {
            alpha[(size_t)e * H + 0] = ex0 / d0;
            if (H > 1) {
                alpha[(size_t)e * H + 1] = ex1 / d1;
                alpha[(size_t)e * H + 2] = ex2 / d2;
            }
        }
    } else {
        float m0 = -INFINITY, m1 = -INFINITY, m2 = -INFINITY;
        for (int j = s0 + lane; j < s1; j += 64) {
            int e = eidx[j], s = src[e];
            float v0 = lrelu(el[s * H + 0] + ern0);
            alpha[(size_t)e * H + 0] = v0; m0 = fmaxf(m0, v0);
            if (H > 1) {
                float v1 = lrelu(el[s * H + 1] + ern1);
                float v2 = lrelu(el[s * H + 2] + ern2);
                alpha[(size_t)e * H + 1] = v1; m1 = fmaxf(m1, v1);
                alpha[(size_t)e * H + 2] = v2; m2 = fmaxf(m2, v2);
            }
        }
#pragma unroll
        for (int off = 32; off > 0; off >>= 1) {
            m0 = fmaxf(m0, __shfl_xor(m0, off, 64));
            m1 = fmaxf(m1, __shfl_xor(m1, off, 64));
            m2 = fmaxf(m2, __shfl_xor(m2, off, 64));
        }
        float d0 = 0.f, d1 = 0.f, d2 = 0.f;
        for (int j = s0 + lane; j < s1; j += 64) {
            int e = eidx[j];
            float ex0 = expf(alpha[(size_t)e * H + 0] - m0);
            alpha[(size_t)e * H + 0] = ex0; d0 += ex0;
            if (H > 1) {
                float ex1 = expf(alpha[(size_t)e * H + 1] - m1);
                float ex2 = expf(alpha[(size_t)e * H + 2] - m2);
                alpha[(size_t)e * H + 1] = ex1; d1 += ex1;
                alpha[(size_t)e * H + 2] = ex2; d2 += ex2;
            }
        }
#pragma unroll
        for (int off = 32; off > 0; off >>= 1) {
            d0 += __shfl_xor(d0, off, 64);
            d1 += __shfl_xor(d1, off, 64);
            d2 += __shfl_xor(d2, off, 64);
        }
        float i0 = 1.f / d0;
        float i1 = (H > 1) ? 1.f / d1 : 0.f;
        float i2 = (H > 2) ? 1.f / d2 : 0.f;
        for (int j = s0 + lane; j < s1; j += 64) {
            int e = eidx[j];
            alpha[(size_t)e * H + 0] *= i0;
            if (H > 1) {
                alpha[(size_t)e * H + 1] *= i1;
                alpha[(size_t)e * H + 2] *= i2;
            }
        }
    }
}

// ---------------- aggregate (bf16 h) ----------------
#define TILE_E 64
__global__ void gat_aggregate(const unsigned short* __restrict__ hb_all,
                              const float* __restrict__ alpha_all,
                              const int* __restrict__ src0, const int* __restrict__ src1,
                              const int* __restrict__ rs_all, const int* __restrict__ eidx_all,
                              float4* __restrict__ out4_all, int N, int H, int D, int E,
                              size_t hBr, size_t aBr, size_t o4Br) {
    __shared__ int s_src[TILE_E];
    __shared__ float s_alpha[TILE_E * 3];
    int n = blockIdx.x;
    int br = blockIdx.y;
    const int* src = br ? src1 : src0;
    const int* rs = rs_all + br * (N + 1);
    const int* eidx = eidx_all + br * E;
    const unsigned short* hb = hb_all + br * hBr;
    const float* alpha = alpha_all + br * aBr;
    float4* out4 = out4_all + br * o4Br;
    int HD = H * D;
    int HD4 = HD >> 2;
    int tid = threadIdx.x;
    int s0 = rs[n], s1 = rs[n + 1];
    bool active = tid < HD4;
    int hh = active ? (tid << 2) / D : 0;
    float4 acc = {0.f, 0.f, 0.f, 0.f};
    for (int base = s0; base < s1; base += TILE_E) {
        int cntE = s1 - base; if (cntE > TILE_E) cntE = TILE_E;
        if (tid < cntE) {
            int e = eidx[base + tid];
            s_src[tid] = src[e];
#pragma unroll
            for (int h = 0; h < 3; ++h)
                if (h < H) s_alpha[tid * 3 + h] = alpha[(size_t)e * H + h];
        }
        __syncthreads();
        if (active) {
#pragma unroll 4
            for (int i = 0; i < cntE; ++i) {
                float a = s_alpha[i * 3 + hh];
                ushort4 hv = *(const ushort4*)&hb[(size_t)s_src[i] * HD + (tid << 2)];
                acc.x += a * __uint_as_float((unsigned int)hv.x << 16);
                acc.y += a * __uint_as_float((unsigned int)hv.y << 16);
                acc.z += a * __uint_as_float((unsigned int)hv.z << 16);
                acc.w += a * __uint_as_float((unsigned int)hv.w << 16);
            }
        }
        __syncthreads();
    }
    if (active) {
        acc.x = fmaxf(acc.x, 0.f); acc.y = fmaxf(acc.y, 0.f);
        acc.z = fmaxf(acc.z, 0.f); acc.w = fmaxf(acc.w, 0.f);
        out4[(size_t)n * HD4 + tid] = acc;
    }
}

// Graph max-readout (post-ReLU >=0) via int-bitcast atomicMax. grid.y = branch.
__global__ void seg_max_atomic(const float* __restrict__ g_all, const int* __restrict__ nid,
                               int* __restrict__ out_all, int N, int C,
                               size_t gBr, size_t oBr) {
    int br = blockIdx.y;
    const float* g = g_all + br * gBr;
    int* out = out_all + br * oBr;
    int n0 = blockIdx.x << 5;
    int n1 = n0 + 32; if (n1 > N) n1 = N;
    if (n0 >= N) return;
    for (int c = threadIdx.x; c < C; c += blockDim.x) {
        int cur = nid[n0];
        float m = 0.f;
        for (int n = n0; n < n1; ++n) {
            int gid = nid[n];
            if (gid != cur) {
                atomicMax(&out[cur * C + c], __float_as_int(m));
                cur = gid; m = 0.f;
            }
            m = fmaxf(m, g[(size_t)n * C + c]);
        }
        atomicMax(&out[cur * C + c], __float_as_int(m));
    }
}

// ---------------- small dense layers (grid.z = branch; strides may be 0) ----
__global__ void linear_wave(const float* __restrict__ in, const float* __restrict__ W,
                            const float* __restrict__ bias, float* __restrict__ out,
                            int K, int O, int act, size_t inBr, size_t outBr) {
    int o = blockIdx.x * 4 + (threadIdx.x >> 6);
    int b = blockIdx.y;
    int lane = threadIdx.x & 63;
    if (o >= O) return;
    const float* ip = in + blockIdx.z * inBr + (size_t)b * K;
    float acc = 0.f;
    for (int k = lane; k < K; k += 64)
        acc += ip[k] * W[(size_t)k * O + o];
    for (int off = 32; off > 0; off >>= 1)
        acc += __shfl_down(acc, off, 64);
    if (lane == 0) {
        acc += bias[o];
        if (act == 1) acc = fmaxf(acc, 0.f);
        else if (act == 2) acc = 1.f / (1.f + expf(-acc));
        out[blockIdx.z * outBr + (size_t)b * O + o] = acc;
    }
}

// ---------------- TextCNN (branch-fused) ----------------
__global__ void transpose_pad2(const float* __restrict__ pad0, const float* __restrict__ pad1,
                               float* __restrict__ xT, int B, int L, int C) {
    int idx = blockIdx.x * blockDim.x + threadIdx.x;
    int per = B * L * C;
    if (idx >= 2 * per) return;
    int br = idx >= per;
    int loc = idx - br * per;
    const float* pad = br ? pad1 : pad0;
    int l = loc % L;
    int c = (loc / L) % C;
    int b = loc / (L * C);
    xT[idx] = pad[((size_t)b * L + l) * C + c];
}

// conv1d k=3 VALID, 128 outputs; weights pre-transposed wt[(c*3+j)][128] so a
// wave's 64 lanes (consecutive o) read consecutive floats — coalesced.
#define CSTRIDE 68
__global__ void conv3k_v3(const float* __restrict__ x,
                          const float* __restrict__ wt,
                          const float* __restrict__ bias,
                          float* __restrict__ y,
                          int Cin, int Lin, int Lout, size_t xBr, size_t yBr) {
    extern __shared__ float sx[];  // Cin x CSTRIDE
    int b = blockIdx.y;
    const float* xb = x + blockIdx.z * xBr;
    float* yb = y + blockIdx.z * yBr;
    int G = blockDim.x >> 7;
    int tileW = G << 4;
    int l0 = blockIdx.x * tileW;
    int tid = threadIdx.x;
    int tileL = Lout - l0; if (tileL > tileW) tileL = tileW;
    int loadL = tileL + 2;
    for (int idx = tid; idx < Cin * loadL; idx += blockDim.x) {
        int c = idx / loadL, i = idx - c * loadL;
        sx[c * CSTRIDE + i] = xb[((size_t)b * Cin + c) * Lin + l0 + i];
    }
    __syncthreads();
    int o = tid & 127;
    int pbase = (tid >> 7) << 4;
    int npos = tileL - pbase; if (npos > 16) npos = 16; if (npos < 0) npos = 0;
    float acc[16];
    float bv = bias[o];
#pragma unroll
    for (int j = 0; j < 16; ++j) acc[j] = bv;
    for (int c = 0; c < Cin; ++c) {
        const float* row = &sx[c * CSTRIDE + pbase];
        float xv[18];
        *(float4*)&xv[0]  = *(const float4*)&row[0];
        *(float4*)&xv[4]  = *(const float4*)&row[4];
        *(float4*)&xv[8]  = *(const float4*)&row[8];
        *(float4*)&xv[12] = *(const float4*)&row[12];
        *(float2*)&xv[16] = *(const float2*)&row[16];
        const float* wp = &wt[(size_t)c * 3 * 128 + o];
        float w0 = wp[0], w1 = wp[128], w2 = wp[256];
#pragma unroll
        for (int j = 0; j < 16; ++j) acc[j] += w0 * xv[j] + w1 * xv[j + 1] + w2 * xv[j + 2];
    }
    float* yp = yb + ((size_t)b * 128 + o) * Lout + l0 + pbase;
#pragma unroll
    for (int j = 0; j < 16; ++j)
        if (j < npos) yp[j] = acc[j];
}

__global__ void maxpool(const float* __restrict__ y, float* __restrict__ p,
                        int BC, int Lin, int k, int s, int Lout) {
    int idx = blockIdx.x * blockDim.x + threadIdx.x;
    if (idx >= BC * Lout) return;
    int lo = idx % Lout, bc = idx / Lout;
    const float* yp = y + (size_t)bc * Lin + lo * s;
    float m = -INFINITY;
    for (int i = 0; i < k; ++i) m = fmaxf(m, yp[i]);
    p[idx] = m;
}

// cat[b, br*128 + c] over both branches in one launch (gvec/sf are [2][B*128])
__global__ void combine_branch2(const float* __restrict__ g, const float* __restrict__ s,
                                const float* __restrict__ w1, float* __restrict__ cat, int B) {
    int idx = blockIdx.x * blockDim.x + threadIdx.x;
    int per = B * 128;
    if (idx >= 2 * per) return;
    int br = idx >= per;
    int loc = idx - br * per;
    int b = loc >> 7, c = loc & 127;
    float w = 1.f / (1.f + expf(-w1[0]));
    cat[b * 256 + br * 128 + c] = (1.f - w) * g[idx] + w * s[idx];
}

// ---------------- host ----------------
extern "C" void kernel_launch(void* const* d_in, const int* in_sizes, int n_in,
                              void* d_out, int out_size, void* d_ws, size_t ws_size,
                              hipStream_t stream) {
    const float* feat[2] = {(const float*)d_in[0], (const float*)d_in[1]};
    const float* pad[2]  = {(const float*)d_in[2], (const float*)d_in[3]};
    const int* src[2]    = {(const int*)d_in[4], (const int*)d_in[6]};
    const int* dst[2]    = {(const int*)d_in[5], (const int*)d_in[7]};
    const int* nid[2]    = {(const int*)d_in[8], (const int*)d_in[9]};
    const float* Wg[3]   = {(const float*)d_in[11], (const float*)d_in[14], (const float*)d_in[17]};
    const float* al[3]   = {(const float*)d_in[12], (const float*)d_in[15], (const float*)d_in[18]};
    const float* ar[3]   = {(const float*)d_in[13], (const float*)d_in[16], (const float*)d_in[19]};
    const float* fcg_w = (const float*)d_in[20]; const float* fcg_b = (const float*)d_in[21];
    const float* c1w = (const float*)d_in[22];   const float* c1b = (const float*)d_in[23];
    const float* c2w = (const float*)d_in[24];   const float* c2b = (const float*)d_in[25];
    const float* c3w = (const float*)d_in[26];   const float* c3b = (const float*)d_in[27];
    const float* tf_w = (const float*)d_in[28];  const float* tf_b = (const float*)d_in[29];
    const float* w1 = (const float*)d_in[30];
    const float* fc1_w = (const float*)d_in[31]; const float* fc1_b = (const float*)d_in[32];
    const float* fc2_w = (const float*)d_in[33]; const float* fc2_b = (const float*)d_in[34];
    const float* outw = (const float*)d_in[35];  const float* outb = (const float*)d_in[36];
    float* out = (float*)d_out;

    const int N = in_sizes[0] / 64;   // 8000
    const int E = in_sizes[4];        // 160000
    const int B = 16, L = 1200;
    const size_t NS = (size_t)N * 576;

    char* wsb = (char*)d_ws;
    size_t off = 0;
    auto allocB = [&](size_t bytes) -> void* {
        void* p = wsb + off;
        off += (bytes + 255) & ~(size_t)255;
        return p;
    };
    auto alloc = [&](size_t elems) -> void* { return allocB(elems * 4); };

    float* h_buf = (float*)alloc(2 * NS);
    unsigned short* h_bf = (unsigned short*)allocB(2 * NS * 2);   // bf16 mirror of h
    float* gA    = (float*)alloc(2 * NS);
    float* el    = (float*)alloc(2 * (size_t)N * 3);
    float* er    = (float*)alloc(2 * (size_t)N * 3);
    float* alpha = (float*)alloc(2 * (size_t)E * 3);
    int* rs      = (int*)alloc(2 * (N + 1));
    int* cnt     = (int*)alloc(2 * N);
    int* eidx    = (int*)alloc(2 * E);
    int* gmax    = (int*)alloc(2 * (size_t)B * 576);
    float* gvec  = (float*)alloc(2 * (size_t)B * 128);
    float* sp    = (float*)alloc(2 * (size_t)B * 128);
    float* sf    = (float*)alloc(2 * (size_t)B * 128);
    float* cat   = (float*)alloc((size_t)B * 256);
    float* f1    = (float*)alloc((size_t)B * 512);
    float* f2    = (float*)alloc((size_t)B * 256);
    short* w2t1  = (short*)allocB((size_t)192 * 2 * 64 * 2);
    short* w2t2  = (short*)allocB((size_t)576 * 2 * 192 * 2);
    short* w2t3  = (short*)allocB((size_t)576 * 2 * 576 * 2);
    float* wt1   = (float*)alloc((size_t)192 * 128);   // conv weights transposed
    float* wt2   = (float*)alloc((size_t)384 * 128);
    float* wt3   = (float*)alloc((size_t)384 * 128);
    size_t tcnn_elems = 2 * ((size_t)B * 64 * L + (size_t)B * 128 * (1198 + 399 + 397 + 132 + 130));
    size_t uni_elems = 2 * NS > tcnn_elems ? 2 * NS : tcnn_elems;
    float* uni = (float*)alloc(uni_elems);
    float* gB = uni;
    float* xT = uni;
    float* y1 = xT + 2 * (size_t)B * 64 * L;
    float* p1 = y1 + 2 * (size_t)B * 128 * 1198;
    float* y2 = p1 + 2 * (size_t)B * 128 * 399;
    float* p2 = y2 + 2 * (size_t)B * 128 * 397;
    float* y3 = p2 + 2 * (size_t)B * 128 * 132;
    (void)ws_size; (void)n_in; (void)out_size;

    split_bf2_w<<<(64 * 192 + 255) / 256, 256, 0, stream>>>(Wg[0], w2t1, 64, 192);
    split_bf2_w<<<(192 * 576 + 255) / 256, 256, 0, stream>>>(Wg[1], w2t2, 192, 576);
    split_bf2_w<<<(576 * 576 + 255) / 256, 256, 0, stream>>>(Wg[2], w2t3, 576, 576);
    transpose_cw<<<(128 * 192 + 255) / 256, 256, 0, stream>>>(c1w, wt1, 64);
    transpose_cw<<<(128 * 384 + 255) / 256, 256, 0, stream>>>(c2w, wt2, 128);
    transpose_cw<<<(128 * 384 + 255) / 256, 256, 0, stream>>>(c3w, wt3, 128);
    short* w2t[3] = {w2t1, w2t2, w2t3};

    // --- CSR for both branches ---
    zero_i32<<<(2 * N + 255) / 256, 256, 0, stream>>>(cnt, 2 * N);
    count_edges2<<<(2 * E + 255) / 256, 256, 0, stream>>>(dst[0], dst[1], cnt, N, E);
    scan_block<<<2, 1024, 0, stream>>>(cnt, rs, N);
    zero_i32<<<(2 * N + 255) / 256, 256, 0, stream>>>(cnt, 2 * N);
    scatter_edges2<<<(2 * E + 255) / 256, 256, 0, stream>>>(dst[0], dst[1], rs, cnt, eidx, N, E);

    // --- 3 GAT layers, both branches per dispatch ---
    const int dims[3][3] = {{64, 3, 64}, {192, 3, 192}, {576, 1, 576}};  // K,H,D
    float* outs[3] = {gA, gB, gA};
    const float* inp0 = feat[0];
    const float* inp1 = feat[1];
    for (int ly = 0; ly < 3; ++ly) {
        int K = dims[ly][0], H = dims[ly][1], D = dims[ly][2];
        int HD = H * D;
        gemm_bf3_v3<<<dim3(HD / 192, N / 32, 2), 256, 0, stream>>>(inp0, inp1, w2t[ly], h_buf, h_bf,
                                                                   N, K, HD, NS);
        int waves2 = 2 * N * H;
        gat_elr<<<((size_t)waves2 * 64 + 255) / 256, 256, 0, stream>>>(h_buf, al[ly], ar[ly], el, er,
                                                                       N, H, D, NS, (size_t)N * 3);
        gat_softmax_wave<<<((size_t)2 * N * 64 + 255) / 256, 256, 0, stream>>>(
            el, er, src[0], src[1], rs, eidx, alpha, N, H, E, (size_t)N * 3, (size_t)E * 3);
        int aggThreads = (((HD >> 2) + 63) / 64) * 64;   // 64 for HD=192, 192 for HD=576
        gat_aggregate<<<dim3(N, 2), aggThreads, 0, stream>>>(
            h_bf, alpha, src[0], src[1], rs, eidx, (float4*)outs[ly],
            N, H, D, E, NS, (size_t)E * 3, NS / 4);
        inp0 = outs[ly];
        inp1 = outs[ly] + NS;
    }
    zero_i32<<<(2 * B * 576 + 255) / 256, 256, 0, stream>>>(gmax, 2 * B * 576);
    seg_max_atomic<<<dim3((N + 31) / 32, 2), 256, 0, stream>>>(gA, nid[0], gmax, N, 576,
                                                               NS, (size_t)B * 576);
    linear_wave<<<dim3(32, B, 2), 256, 0, stream>>>((const float*)gmax, fcg_w, fcg_b, gvec,
                                                    576, 128, 1, (size_t)B * 576, (size_t)B * 128);

    // --- TextCNN, both branches per dispatch (gB dead now; union is safe) ---
    transpose_pad2<<<((2 * B * 64 * L) + 255) / 256, 256, 0, stream>>>(pad[0], pad[1], xT, B, L, 64);
    conv3k_v3<<<dim3((1198 + 63) / 64, B, 2), 512, 64 * CSTRIDE * 4, stream>>>(
        xT, wt1, c1b, y1, 64, 1200, 1198, (size_t)B * 64 * L, (size_t)B * 128 * 1198);
    maxpool<<<(2 * B * 128 * 399 + 255) / 256, 256, 0, stream>>>(y1, p1, 2 * B * 128, 1198, 3, 3, 399);
    conv3k_v3<<<dim3((397 + 31) / 32, B, 2), 256, 128 * CSTRIDE * 4, stream>>>(
        p1, wt2, c2b, y2, 128, 399, 397, (size_t)B * 128 * 399, (size_t)B * 128 * 397);
    maxpool<<<(2 * B * 128 * 132 + 255) / 256, 256, 0, stream>>>(y2, p2, 2 * B * 128, 397, 3, 3, 132);
    conv3k_v3<<<dim3((130 + 31) / 32, B, 2), 256, 128 * CSTRIDE * 4, stream>>>(
        p2, wt3, c3b, y3, 128, 132, 130, (size_t)B * 128 * 132, (size_t)B * 128 * 130);
    maxpool<<<(2 * B * 128 + 255) / 256, 256, 0, stream>>>(y3, sp, 2 * B * 128, 130, 130, 1, 1);
    linear_wave<<<dim3(32, B, 2), 256, 0, stream>>>(sp, tf_w, tf_b, sf, 128, 128, 1,
                                                    (size_t)B * 128, (size_t)B * 128);
    combine_branch2<<<(2 * B * 128 + 255) / 256, 256, 0, stream>>>(gvec, sf, w1, cat, B);

    // --- head MLP ---
    linear_wave<<<dim3(128, B, 1), 256, 0, stream>>>(cat, fc1_w, fc1_b, f1, 256, 512, 1, 0, 0);
    linear_wave<<<dim3(64, B, 1), 256, 0, stream>>>(f1, fc2_w, fc2_b, f2, 512, 256, 1, 0, 0);
    linear_wave<<<dim3(1, B, 1), 256, 0, stream>>>(f2, outw, outb, out, 256, 1, 2, 0, 0);
}

// Round 12
// 667.093 us; speedup vs baseline: 4.9471x; 1.1121x over previous
//
#include <hip/hip_runtime.h>
#include <hip/hip_bf16.h>
#include <math.h>

#define NEG_SLOPE 0.2f

// ---------------- utility ----------------
__global__ void zero_i32(int* __restrict__ p, int n) {
    int i = blockIdx.x * blockDim.x + threadIdx.x;
    if (i < n) p[i] = 0;
}

// ---------------- CSR build (both branches in one dispatch) ----------------
__global__ void count_edges2(const int* __restrict__ dst0, const int* __restrict__ dst1,
                             int* __restrict__ cnt, int N, int E) {
    int i = blockIdx.x * blockDim.x + threadIdx.x;
    if (i >= 2 * E) return;
    int br = i >= E;
    int j = i - br * E;
    const int* d = br ? dst1 : dst0;
    atomicAdd(&cnt[br * N + d[j]], 1);
}

__global__ void scan_block(const int* __restrict__ cnt_all, int* __restrict__ rs_all, int N) {
    __shared__ int s[1024];
    int br = blockIdx.x;
    const int* cnt = cnt_all + br * N;
    int* rs = rs_all + br * (N + 1);
    int tid = threadIdx.x;
    int running = 0;
    for (int base = 0; base < N; base += 1024) {
        int v = (base + tid < N) ? cnt[base + tid] : 0;
        __syncthreads();
        s[tid] = v;
        __syncthreads();
        for (int off = 1; off < 1024; off <<= 1) {
            int t = (tid >= off) ? s[tid - off] : 0;
            __syncthreads();
            if (tid >= off) s[tid] += t;
            __syncthreads();
        }
        if (base + tid < N) rs[base + tid] = running + s[tid] - v;
        running += s[1023];
    }
    if (tid == 0) rs[N] = running;
}

__global__ void scatter_edges2(const int* __restrict__ dst0, const int* __restrict__ dst1,
                               const int* __restrict__ rs_all, int* __restrict__ fill_all,
                               int* __restrict__ eidx_all, int N, int E) {
    int i = blockIdx.x * blockDim.x + threadIdx.x;
    if (i >= 2 * E) return;
    int br = i >= E;
    int j = i - br * E;
    const int* d = br ? dst1 : dst0;
    int dd = d[j];
    int pos = atomicAdd(&fill_all[br * N + dd], 1);
    eidx_all[br * E + rs_all[br * (N + 1) + dd] + pos] = j;
}

// ---------------- bf16 hi/lo helpers ----------------
__device__ __forceinline__ short f2bf(float x) {
    __hip_bfloat16 h = __float2bfloat16(x);
    return *reinterpret_cast<short*>(&h);
}
__device__ __forceinline__ float bf2f(short s) {
    unsigned int u = ((unsigned int)(unsigned short)s) << 16;
    return __uint_as_float(u);
}
__device__ __forceinline__ float us2f(unsigned short s) {
    return __uint_as_float((unsigned int)s << 16);
}

// W (K x N fp32) -> W2t (N x 2K bf16, transposed): rows [Wh | Wl]
__global__ void split_bf2_w(const float* __restrict__ W, short* __restrict__ W2t, int K, int N) {
    int idx = blockIdx.x * blockDim.x + threadIdx.x;
    if (idx >= K * N) return;
    int k = idx / N, n = idx - k * N;
    float x = W[idx];
    short hs = f2bf(x);
    short ls = f2bf(x - bf2f(hs));
    size_t base = (size_t)n * 2 * K;
    W2t[base + k] = hs;
    W2t[base + K + k] = ls;
}

// conv weights [128][Cin][3] (contiguous = [out][Kp]) -> rows [out][Kp hi | Kp lo]
__global__ void split_bf2_cw(const float* __restrict__ w, short* __restrict__ w2, int Kp) {
    int idx = blockIdx.x * blockDim.x + threadIdx.x;
    if (idx >= 128 * Kp) return;
    int o = idx / Kp, k = idx - o * Kp;
    float x = w[idx];
    short hs = f2bf(x);
    short ls = f2bf(x - bf2f(hs));
    size_t base = (size_t)o * 2 * Kp;
    w2[base + k] = hs;
    w2[base + Kp + k] = ls;
}

// ---------------- MFMA bf16-split GEMM v3 (bf16-only output) ----------------
typedef __attribute__((ext_vector_type(8))) short short8;
typedef __attribute__((ext_vector_type(4))) short short4v;
typedef __attribute__((ext_vector_type(4))) float floatx4;

__global__ __launch_bounds__(256) void gemm_bf3_v3(const float* __restrict__ A0,
                                                   const float* __restrict__ A1,
                                                   const short* __restrict__ Bt,
                                                   unsigned short* __restrict__ Cbf,
                                                   int M, int K, int N, size_t cBrStride) {
    __shared__ __align__(16) short sA[32 * 72];   // rows: [Ah(32) | Al(32) | pad8]
    __shared__ __align__(16) short sB[192 * 72];  // rows: [Wh(32) | Wl(32) | pad8]
    int tid = threadIdx.x;
    int wave = tid >> 6, lane = tid & 63;
    int m = lane & 15, q = lane >> 4;
    int row0 = blockIdx.y << 5;
    int col0 = blockIdx.x * 192;
    const float* A = blockIdx.z ? A1 : A0;
    unsigned short* Cbfb = Cbf + blockIdx.z * cBrStride;
    int K2 = K * 2;
    floatx4 acc[2][3];
#pragma unroll
    for (int rt = 0; rt < 2; ++rt)
#pragma unroll
        for (int ct = 0; ct < 3; ++ct) acc[rt][ct] = (floatx4){0.f, 0.f, 0.f, 0.f};

    for (int k0 = 0; k0 < K; k0 += 32) {
        {
            int r = tid >> 3, c = (tid & 7) << 2;
            float4 av = *(const float4*)&A[(size_t)(row0 + r) * K + k0 + c];
            short4v hs, ls;
            hs[0] = f2bf(av.x); ls[0] = f2bf(av.x - bf2f(hs[0]));
            hs[1] = f2bf(av.y); ls[1] = f2bf(av.y - bf2f(hs[1]));
            hs[2] = f2bf(av.z); ls[2] = f2bf(av.z - bf2f(hs[2]));
            hs[3] = f2bf(av.w); ls[3] = f2bf(av.w - bf2f(hs[3]));
            *(short4v*)&sA[r * 72 + c] = hs;
            *(short4v*)&sA[r * 72 + 32 + c] = ls;
        }
#pragma unroll
        for (int p = 0; p < 6; ++p) {
            int t = tid + (p << 8);
            int n = t >> 3, sub = t & 7;
            int srcoff = k0 + (sub << 3) + ((sub >= 4) ? (K - 32) : 0);
            *(float4*)&sB[n * 72 + (sub << 3)] =
                *(const float4*)&Bt[(size_t)(col0 + n) * K2 + srcoff];
        }
        __syncthreads();
        short8 a_hi[2], a_lo[2];
#pragma unroll
        for (int rt = 0; rt < 2; ++rt) {
            a_hi[rt] = *(const short8*)&sA[(rt * 16 + m) * 72 + q * 8];
            a_lo[rt] = *(const short8*)&sA[(rt * 16 + m) * 72 + 32 + q * 8];
        }
#pragma unroll
        for (int ct = 0; ct < 3; ++ct) {
            short8 b_hi = *(const short8*)&sB[(wave * 48 + ct * 16 + m) * 72 + q * 8];
            short8 b_lo = *(const short8*)&sB[(wave * 48 + ct * 16 + m) * 72 + 32 + q * 8];
#pragma unroll
            for (int rt = 0; rt < 2; ++rt) {
                acc[rt][ct] = __builtin_amdgcn_mfma_f32_16x16x32_bf16(a_hi[rt], b_hi, acc[rt][ct], 0, 0, 0);
                acc[rt][ct] = __builtin_amdgcn_mfma_f32_16x16x32_bf16(a_lo[rt], b_hi, acc[rt][ct], 0, 0, 0);
                acc[rt][ct] = __builtin_amdgcn_mfma_f32_16x16x32_bf16(a_hi[rt], b_lo, acc[rt][ct], 0, 0, 0);
            }
        }
        __syncthreads();
    }
#pragma unroll
    for (int rt = 0; rt < 2; ++rt)
#pragma unroll
        for (int ct = 0; ct < 3; ++ct)
#pragma unroll
            for (int r = 0; r < 4; ++r) {
                size_t idx = (size_t)(row0 + rt * 16 + q * 4 + r) * N + col0 + wave * 48 + ct * 16 + m;
                Cbfb[idx] = (unsigned short)f2bf(acc[rt][ct][r]);
            }
}

// ---------------- GAT pieces (branch-fused; h in bf16) ----------------
__global__ void gat_elr(const unsigned short* __restrict__ h, const float* __restrict__ al,
                        const float* __restrict__ ar, float* __restrict__ el,
                        float* __restrict__ er, int N, int H, int D,
                        size_t hBr, size_t eBr) {
    int wid = (blockIdx.x * blockDim.x + threadIdx.x) >> 6;
    int lane = threadIdx.x & 63;
    if (wid >= 2 * N * H) return;
    int br = wid / (N * H);
    int loc = wid - br * N * H;
    int n = loc / H, hh = loc - n * H;
    const unsigned short* hp = h + br * hBr + ((size_t)n * H + hh) * D;
    const float* alp = al + (size_t)hh * D;
    const float* arp = ar + (size_t)hh * D;
    float sl = 0.f, sr = 0.f;
    for (int d = lane; d < D; d += 64) {
        float v = us2f(hp[d]);
        sl += v * alp[d];
        sr += v * arp[d];
    }
    for (int off = 32; off > 0; off >>= 1) {
        sl += __shfl_down(sl, off, 64);
        sr += __shfl_down(sr, off, 64);
    }
    if (lane == 0) { el[br * eBr + loc] = sl; er[br * eBr + loc] = sr; }
}

__device__ __forceinline__ float lrelu(float v) {
    return (v > 0.f) ? v : NEG_SLOPE * v;
}

__global__ void gat_softmax_wave(const float* __restrict__ el_all, const float* __restrict__ er_all,
                                 const int* __restrict__ src0, const int* __restrict__ src1,
                                 const int* __restrict__ rs_all, const int* __restrict__ eidx_all,
                                 float* __restrict__ alpha_all, int N, int H, int E,
                                 size_t eBr, size_t aBr) {
    int g = (blockIdx.x * blockDim.x + threadIdx.x) >> 6;
    int lane = threadIdx.x & 63;
    if (g >= 2 * N) return;
    int br = g / N;
    int n = g - br * N;
    const int* src = br ? src1 : src0;
    const int* rs = rs_all + br * (N + 1);
    const int* eidx = eidx_all + br * E;
    const float* el = el_all + br * eBr;
    const float* er = er_all + br * eBr;
    float* alpha = alpha_all + br * aBr;
    int s0 = rs[n], s1 = rs[n + 1];
    int deg = s1 - s0;
    if (deg == 0) return;
    float ern0 = er[n * H + 0];
    float ern1 = (H > 1) ? er[n * H + 1] : 0.f;
    float ern2 = (H > 2) ? er[n * H + 2] : 0.f;
    if (deg <= 64) {
        int e = 0, s = 0;
        float v0 = -INFINITY, v1 = -INFINITY, v2 = -INFINITY;
        if (lane < deg) {
            e = eidx[s0 + lane];
            s = src[e];
            v0 = lrelu(el[s * H + 0] + ern0);
            if (H > 1) {
                v1 = lrelu(el[s * H + 1] + ern1);
                v2 = lrelu(el[s * H + 2] + ern2);
            }
        }
        float m0 = v0, m1 = v1, m2 = v2;
#pragma unroll
        for (int off = 32; off > 0; off >>= 1) {
            m0 = fmaxf(m0, __shfl_xor(m0, off, 64));
            m1 = fmaxf(m1, __shfl_xor(m1, off, 64));
            m2 = fmaxf(m2, __shfl_xor(m2, off, 64));
        }
        float ex0 = (lane < deg) ? expf(v0 - m0) : 0.f;
        float ex1 = (lane < deg && H > 1) ? expf(v1 - m1) : 0.f;
        float ex2 = (lane < deg && H > 2) ? expf(v2 - m2) : 0.f;
        float d0 = ex0, d1 = ex1, d2 = ex2;
#pragma unroll
        for (int off = 32; off > 0; off >>= 1) {
            d0 += __shfl_xor(d0, off, 64);
            d1 += __shfl_xor(d1, off, 64);
            d2 += __shfl_xor(d2, off, 64);
        }
        if (lane < deg) {
            alpha[(size_t)e * H + 0] = ex0 / d0;
            if (H > 1) {
                alpha[(size_t)e * H + 1] = ex1 / d1;
                alpha[(size_t)e * H + 2] = ex2 / d2;
            }
        }
    } else {
        float m0 = -INFINITY, m1 = -INFINITY, m2 = -INFINITY;
        for (int j = s0 + lane; j < s1; j += 64) {
            int e = eidx[j], s = src[e];
            float v0 = lrelu(el[s * H + 0] + ern0);
            alpha[(size_t)e * H + 0] = v0; m0 = fmaxf(m0, v0);
            if (H > 1) {
                float v1 = lrelu(el[s * H + 1] + ern1);
                float v2 = lrelu(el[s * H + 2] + ern2);
                alpha[(size_t)e * H + 1] = v1; m1 = fmaxf(m1, v1);
                alpha[(size_t)e * H + 2] = v2; m2 = fmaxf(m2, v2);
            }
        }
#pragma unroll
        for (int off = 32; off > 0; off >>= 1) {
            m0 = fmaxf(m0, __shfl_xor(m0, off, 64));
            m1 = fmaxf(m1, __shfl_xor(m1, off, 64));
            m2 = fmaxf(m2, __shfl_xor(m2, off, 64));
        }
        float d0 = 0.f, d1 = 0.f, d2 = 0.f;
        for (int j = s0 + lane; j < s1; j += 64) {
            int e = eidx[j];
            float ex0 = expf(alpha[(size_t)e * H + 0] - m0);
            alpha[(size_t)e * H + 0] = ex0; d0 += ex0;
            if (H > 1) {
                float ex1 = expf(alpha[(size_t)e * H + 1] - m1);
                float ex2 = expf(alpha[(size_t)e * H + 2] - m2);
                alpha[(size_t)e * H + 1] = ex1; d1 += ex1;
                alpha[(size_t)e * H + 2] = ex2; d2 += ex2;
            }
        }
#pragma unroll
        for (int off = 32; off > 0; off >>= 1) {
            d0 += __shfl_xor(d0, off, 64);
            d1 += __shfl_xor(d1, off, 64);
            d2 += __shfl_xor(d2, off, 64);
        }
        float i0 = 1.f / d0;
        float i1 = (H > 1) ? 1.f / d1 : 0.f;
        float i2 = (H > 2) ? 1.f / d2 : 0.f;
        for (int j = s0 + lane; j < s1; j += 64) {
            int e = eidx[j];
            alpha[(size_t)e * H + 0] *= i0;
            if (H > 1) {
                alpha[(size_t)e * H + 1] *= i1;
                alpha[(size_t)e * H + 2] *= i2;
            }
        }
    }
}

// ---------------- aggregate (bf16 h) ----------------
#define TILE_E 64
__global__ void gat_aggregate(const unsigned short* __restrict__ hb_all,
                              const float* __restrict__ alpha_all,
                              const int* __restrict__ src0, const int* __restrict__ src1,
                              const int* __restrict__ rs_all, const int* __restrict__ eidx_all,
                              float4* __restrict__ out4_all, int N, int H, int D, int E,
                              size_t hBr, size_t aBr, size_t o4Br) {
    __shared__ int s_src[TILE_E];
    __shared__ float s_alpha[TILE_E * 3];
    int n = blockIdx.x;
    int br = blockIdx.y;
    const int* src = br ? src1 : src0;
    const int* rs = rs_all + br * (N + 1);
    const int* eidx = eidx_all + br * E;
    const unsigned short* hb = hb_all + br * hBr;
    const float* alpha = alpha_all + br * aBr;
    float4* out4 = out4_all + br * o4Br;
    int HD = H * D;
    int HD4 = HD >> 2;
    int tid = threadIdx.x;
    int s0 = rs[n], s1 = rs[n + 1];
    bool active = tid < HD4;
    int hh = active ? (tid << 2) / D : 0;
    float4 acc = {0.f, 0.f, 0.f, 0.f};
    for (int base = s0; base < s1; base += TILE_E) {
        int cntE = s1 - base; if (cntE > TILE_E) cntE = TILE_E;
        if (tid < cntE) {
            int e = eidx[base + tid];
            s_src[tid] = src[e];
#pragma unroll
            for (int h = 0; h < 3; ++h)
                if (h < H) s_alpha[tid * 3 + h] = alpha[(size_t)e * H + h];
        }
        __syncthreads();
        if (active) {
#pragma unroll 4
            for (int i = 0; i < cntE; ++i) {
                float a = s_alpha[i * 3 + hh];
                ushort4 hv = *(const ushort4*)&hb[(size_t)s_src[i] * HD + (tid << 2)];
                acc.x += a * us2f(hv.x);
                acc.y += a * us2f(hv.y);
                acc.z += a * us2f(hv.z);
                acc.w += a * us2f(hv.w);
            }
        }
        __syncthreads();
    }
    if (active) {
        acc.x = fmaxf(acc.x, 0.f); acc.y = fmaxf(acc.y, 0.f);
        acc.z = fmaxf(acc.z, 0.f); acc.w = fmaxf(acc.w, 0.f);
        out4[(size_t)n * HD4 + tid] = acc;
    }
}

// Graph max-readout (post-ReLU >=0) via int-bitcast atomicMax. grid.y = branch.
__global__ void seg_max_atomic(const float* __restrict__ g_all, const int* __restrict__ nid,
                               int* __restrict__ out_all, int N, int C,
                               size_t gBr, size_t oBr) {
    int br = blockIdx.y;
    const float* g = g_all + br * gBr;
    int* out = out_all + br * oBr;
    int n0 = blockIdx.x << 5;
    int n1 = n0 + 32; if (n1 > N) n1 = N;
    if (n0 >= N) return;
    for (int c = threadIdx.x; c < C; c += blockDim.x) {
        int cur = nid[n0];
        float m = 0.f;
        for (int n = n0; n < n1; ++n) {
            int gid = nid[n];
            if (gid != cur) {
                atomicMax(&out[cur * C + c], __float_as_int(m));
                cur = gid; m = 0.f;
            }
            m = fmaxf(m, g[(size_t)n * C + c]);
        }
        atomicMax(&out[cur * C + c], __float_as_int(m));
    }
}

// ---------------- small dense layers (grid.z = branch; strides may be 0) ----
__global__ void linear_wave(const float* __restrict__ in, const float* __restrict__ W,
                            const float* __restrict__ bias, float* __restrict__ out,
                            int K, int O, int act, size_t inBr, size_t outBr) {
    int o = blockIdx.x * 4 + (threadIdx.x >> 6);
    int b = blockIdx.y;
    int lane = threadIdx.x & 63;
    if (o >= O) return;
    const float* ip = in + blockIdx.z * inBr + (size_t)b * K;
    float acc = 0.f;
    for (int k = lane; k < K; k += 64)
        acc += ip[k] * W[(size_t)k * O + o];
    for (int off = 32; off > 0; off >>= 1)
        acc += __shfl_down(acc, off, 64);
    if (lane == 0) {
        acc += bias[o];
        if (act == 1) acc = fmaxf(acc, 0.f);
        else if (act == 2) acc = 1.f / (1.f + expf(-acc));
        out[blockIdx.z * outBr + (size_t)b * O + o] = acc;
    }
}

// ---------------- TextCNN (branch-fused) ----------------
__global__ void transpose_pad2(const float* __restrict__ pad0, const float* __restrict__ pad1,
                               float* __restrict__ xT, int B, int L, int C) {
    int idx = blockIdx.x * blockDim.x + threadIdx.x;
    int per = B * L * C;
    if (idx >= 2 * per) return;
    int br = idx >= per;
    int loc = idx - br * per;
    const float* pad = br ? pad1 : pad0;
    int l = loc % L;
    int c = (loc / L) % C;
    int b = loc / (L * C);
    xT[idx] = pad[((size_t)b * L + l) * C + c];
}

// ---------------- conv1d k=3 as MFMA (im2col on the fly) --------------------
// C[pos][out] = sum_{k=c*3+j} x[c][l0+pos+j] * w[out][k], K' = Cin*3.
// Block: 64 pos x 128 out, 4 waves (wave = 32 pos x 64 out = 2x4 MFMA tiles).
// x-tile staged fp32 in LDS once; A-fragments built by scalar reads +
// in-register hi/lo bf16 split; B staged per 32-k chunk (rows [hi32|lo32]).
// Same fragment/epilogue mapping as gemm_bf3_v3 (verified).
__global__ __launch_bounds__(256) void conv_mfma(const float* __restrict__ x,
                                                 const short* __restrict__ w2,
                                                 const float* __restrict__ bias,
                                                 float* __restrict__ y,
                                                 int Cin, int Lin, int Lout,
                                                 size_t xBr, size_t yBr) {
    extern __shared__ __align__(16) char smem[];
    float* sx = (float*)smem;                         // Cin x 68 fp32
    short* sB = (short*)(smem + (size_t)Cin * 68 * 4); // 128 x 72 shorts
    int Kp = Cin * 3;
    int K2 = Kp * 2;
    int b = blockIdx.y;
    const float* xb = x + blockIdx.z * xBr + (size_t)b * Cin * Lin;
    float* yb = y + blockIdx.z * yBr + (size_t)b * 128 * Lout;
    int l0 = blockIdx.x << 6;
    int tid = threadIdx.x;
    int wave = tid >> 6, lane = tid & 63;
    int m = lane & 15, q = lane >> 4;
    int wrow = (wave & 1) << 5;   // pos offset 0/32
    int wcol = (wave >> 1) << 6;  // out offset 0/64
    // stage x tile (rows clipped to Lin; tail positions are discarded on store)
    int loadL = Lin - l0; if (loadL > 66) loadL = 66;
    for (int idx = tid; idx < Cin * loadL; idx += 256) {
        int c = idx / loadL, i = idx - c * loadL;
        sx[c * 68 + i] = xb[(size_t)c * Lin + l0 + i];
    }
    floatx4 acc[2][4];
#pragma unroll
    for (int rt = 0; rt < 2; ++rt)
#pragma unroll
        for (int ct = 0; ct < 4; ++ct) acc[rt][ct] = (floatx4){0.f, 0.f, 0.f, 0.f};

    for (int k0 = 0; k0 < Kp; k0 += 32) {
        // stage B chunk: 128 out x (32 hi | 32 lo)
#pragma unroll
        for (int p = 0; p < 4; ++p) {
            int t = tid + (p << 8);
            int o = t >> 3, slot = t & 7;
            int srcoff = k0 + ((slot & 3) << 3) + ((slot >= 4) ? Kp : 0);
            *(float4*)&sB[o * 72 + (slot << 3)] = *(const float4*)&w2[(size_t)o * K2 + srcoff];
        }
        __syncthreads();   // covers sx staging on first iteration too
        short8 a_hi[2], a_lo[2];
#pragma unroll
        for (int rt = 0; rt < 2; ++rt) {
            int pos = wrow + rt * 16 + m;
#pragma unroll
            for (int kk = 0; kk < 8; ++kk) {
                int k = k0 + q * 8 + kk;
                int c = k / 3, j = k - c * 3;
                float v = sx[c * 68 + pos + j];
                short hv = f2bf(v);
                a_hi[rt][kk] = hv;
                a_lo[rt][kk] = f2bf(v - bf2f(hv));
            }
        }
#pragma unroll
        for (int ct = 0; ct < 4; ++ct) {
            short8 b_hi = *(const short8*)&sB[(wcol + ct * 16 + m) * 72 + q * 8];
            short8 b_lo = *(const short8*)&sB[(wcol + ct * 16 + m) * 72 + 32 + q * 8];
#pragma unroll
            for (int rt = 0; rt < 2; ++rt) {
                acc[rt][ct] = __builtin_amdgcn_mfma_f32_16x16x32_bf16(a_hi[rt], b_hi, acc[rt][ct], 0, 0, 0);
                acc[rt][ct] = __builtin_amdgcn_mfma_f32_16x16x32_bf16(a_lo[rt], b_hi, acc[rt][ct], 0, 0, 0);
                acc[rt][ct] = __builtin_amdgcn_mfma_f32_16x16x32_bf16(a_hi[rt], b_lo, acc[rt][ct], 0, 0, 0);
            }
        }
        __syncthreads();
    }
#pragma unroll
    for (int ct = 0; ct < 4; ++ct) {
        int o = wcol + ct * 16 + m;
        float bv = bias[o];
#pragma unroll
        for (int rt = 0; rt < 2; ++rt)
#pragma unroll
            for (int r = 0; r < 4; ++r) {
                int pos = wrow + rt * 16 + q * 4 + r;
                if (l0 + pos < Lout)
                    yb[(size_t)o * Lout + l0 + pos] = acc[rt][ct][r] + bv;
            }
    }
}

__global__ void maxpool(const float* __restrict__ y, float* __restrict__ p,
                        int BC, int Lin, int k, int s, int Lout) {
    int idx = blockIdx.x * blockDim.x + threadIdx.x;
    if (idx >= BC * Lout) return;
    int lo = idx % Lout, bc = idx / Lout;
    const float* yp = y + (size_t)bc * Lin + lo * s;
    float m = -INFINITY;
    for (int i = 0; i < k; ++i) m = fmaxf(m, yp[i]);
    p[idx] = m;
}

// cat[b, br*128 + c] over both branches in one launch (gvec/sf are [2][B*128])
__global__ void combine_branch2(const float* __restrict__ g, const float* __restrict__ s,
                                const float* __restrict__ w1, float* __restrict__ cat, int B) {
    int idx = blockIdx.x * blockDim.x + threadIdx.x;
    int per = B * 128;
    if (idx >= 2 * per) return;
    int br = idx >= per;
    int loc = idx - br * per;
    int b = loc >> 7, c = loc & 127;
    float w = 1.f / (1.f + expf(-w1[0]));
    cat[b * 256 + br * 128 + c] = (1.f - w) * g[idx] + w * s[idx];
}

// ---------------- host ----------------
extern "C" void kernel_launch(void* const* d_in, const int* in_sizes, int n_in,
                              void* d_out, int out_size, void* d_ws, size_t ws_size,
                              hipStream_t stream) {
    const float* feat[2] = {(const float*)d_in[0], (const float*)d_in[1]};
    const float* pad[2]  = {(const float*)d_in[2], (const float*)d_in[3]};
    const int* src[2]    = {(const int*)d_in[4], (const int*)d_in[6]};
    const int* dst[2]    = {(const int*)d_in[5], (const int*)d_in[7]};
    const int* nid[2]    = {(const int*)d_in[8], (const int*)d_in[9]};
    const float* Wg[3]   = {(const float*)d_in[11], (const float*)d_in[14], (const float*)d_in[17]};
    const float* al[3]   = {(const float*)d_in[12], (const float*)d_in[15], (const float*)d_in[18]};
    const float* ar[3]   = {(const float*)d_in[13], (const float*)d_in[16], (const float*)d_in[19]};
    const float* fcg_w = (const float*)d_in[20]; const float* fcg_b = (const float*)d_in[21];
    const float* c1w = (const float*)d_in[22];   const float* c1b = (const float*)d_in[23];
    const float* c2w = (const float*)d_in[24];   const float* c2b = (const float*)d_in[25];
    const float* c3w = (const float*)d_in[26];   const float* c3b = (const float*)d_in[27];
    const float* tf_w = (const float*)d_in[28];  const float* tf_b = (const float*)d_in[29];
    const float* w1 = (const float*)d_in[30];
    const float* fc1_w = (const float*)d_in[31]; const float* fc1_b = (const float*)d_in[32];
    const float* fc2_w = (const float*)d_in[33]; const float* fc2_b = (const float*)d_in[34];
    const float* outw = (const float*)d_in[35];  const float* outb = (const float*)d_in[36];
    float* out = (float*)d_out;

    const int N = in_sizes[0] / 64;   // 8000
    const int E = in_sizes[4];        // 160000
    const int B = 16, L = 1200;
    const size_t NS = (size_t)N * 576;

    char* wsb = (char*)d_ws;
    size_t off = 0;
    auto allocB = [&](size_t bytes) -> void* {
        void* p = wsb + off;
        off += (bytes + 255) & ~(size_t)255;
        return p;
    };
    auto alloc = [&](size_t elems) -> void* { return allocB(elems * 4); };

    unsigned short* h_bf = (unsigned short*)allocB(2 * NS * 2);   // h in bf16 only
    float* gA    = (float*)alloc(2 * NS);
    float* el    = (float*)alloc(2 * (size_t)N * 3);
    float* er    = (float*)alloc(2 * (size_t)N * 3);
    float* alpha = (float*)alloc(2 * (size_t)E * 3);
    int* rs      = (int*)alloc(2 * (N + 1));
    int* cnt     = (int*)alloc(2 * N);
    int* eidx    = (int*)alloc(2 * E);
    int* gmax    = (int*)alloc(2 * (size_t)B * 576);
    float* gvec  = (float*)alloc(2 * (size_t)B * 128);
    float* sp    = (float*)alloc(2 * (size_t)B * 128);
    float* sf    = (float*)alloc(2 * (size_t)B * 128);
    float* cat   = (float*)alloc((size_t)B * 256);
    float* f1    = (float*)alloc((size_t)B * 512);
    float* f2    = (float*)alloc((size_t)B * 256);
    short* w2t1  = (short*)allocB((size_t)192 * 2 * 64 * 2);
    short* w2t2  = (short*)allocB((size_t)576 * 2 * 192 * 2);
    short* w2t3  = (short*)allocB((size_t)576 * 2 * 576 * 2);
    short* cw1   = (short*)allocB((size_t)128 * 2 * 192 * 2);   // conv w hi/lo
    short* cw2   = (short*)allocB((size_t)128 * 2 * 384 * 2);
    short* cw3   = (short*)allocB((size_t)128 * 2 * 384 * 2);
    size_t tcnn_elems = 2 * ((size_t)B * 64 * L + (size_t)B * 128 * (1198 + 399 + 397 + 132 + 130));
    size_t uni_elems = 2 * NS > tcnn_elems ? 2 * NS : tcnn_elems;
    float* uni = (float*)alloc(uni_elems);
    float* gB = uni;
    float* xT = uni;
    float* y1 = xT + 2 * (size_t)B * 64 * L;
    float* p1 = y1 + 2 * (size_t)B * 128 * 1198;
    float* y2 = p1 + 2 * (size_t)B * 128 * 399;
    float* p2 = y2 + 2 * (size_t)B * 128 * 397;
    float* y3 = p2 + 2 * (size_t)B * 128 * 132;
    (void)ws_size; (void)n_in; (void)out_size;

    split_bf2_w<<<(64 * 192 + 255) / 256, 256, 0, stream>>>(Wg[0], w2t1, 64, 192);
    split_bf2_w<<<(192 * 576 + 255) / 256, 256, 0, stream>>>(Wg[1], w2t2, 192, 576);
    split_bf2_w<<<(576 * 576 + 255) / 256, 256, 0, stream>>>(Wg[2], w2t3, 576, 576);
    split_bf2_cw<<<(128 * 192 + 255) / 256, 256, 0, stream>>>(c1w, cw1, 192);
    split_bf2_cw<<<(128 * 384 + 255) / 256, 256, 0, stream>>>(c2w, cw2, 384);
    split_bf2_cw<<<(128 * 384 + 255) / 256, 256, 0, stream>>>(c3w, cw3, 384);
    short* w2t[3] = {w2t1, w2t2, w2t3};

    // --- CSR for both branches ---
    zero_i32<<<(2 * N + 255) / 256, 256, 0, stream>>>(cnt, 2 * N);
    count_edges2<<<(2 * E + 255) / 256, 256, 0, stream>>>(dst[0], dst[1], cnt, N, E);
    scan_block<<<2, 1024, 0, stream>>>(cnt, rs, N);
    zero_i32<<<(2 * N + 255) / 256, 256, 0, stream>>>(cnt, 2 * N);
    scatter_edges2<<<(2 * E + 255) / 256, 256, 0, stream>>>(dst[0], dst[1], rs, cnt, eidx, N, E);

    // --- 3 GAT layers, both branches per dispatch ---
    const int dims[3][3] = {{64, 3, 64}, {192, 3, 192}, {576, 1, 576}};  // K,H,D
    float* outs[3] = {gA, gB, gA};
    const float* inp0 = feat[0];
    const float* inp1 = feat[1];
    for (int ly = 0; ly < 3; ++ly) {
        int K = dims[ly][0], H = dims[ly][1], D = dims[ly][2];
        int HD = H * D;
        gemm_bf3_v3<<<dim3(HD / 192, N / 32, 2), 256, 0, stream>>>(inp0, inp1, w2t[ly], h_bf,
                                                                   N, K, HD, NS);
        int waves2 = 2 * N * H;
        gat_elr<<<((size_t)waves2 * 64 + 255) / 256, 256, 0, stream>>>(h_bf, al[ly], ar[ly], el, er,
                                                                       N, H, D, NS, (size_t)N * 3);
        gat_softmax_wave<<<((size_t)2 * N * 64 + 255) / 256, 256, 0, stream>>>(
            el, er, src[0], src[1], rs, eidx, alpha, N, H, E, (size_t)N * 3, (size_t)E * 3);
        int aggThreads = (((HD >> 2) + 63) / 64) * 64;   // 64 for HD=192, 192 for HD=576
        gat_aggregate<<<dim3(N, 2), aggThreads, 0, stream>>>(
            h_bf, alpha, src[0], src[1], rs, eidx, (float4*)outs[ly],
            N, H, D, E, NS, (size_t)E * 3, NS / 4);
        inp0 = outs[ly];
        inp1 = outs[ly] + NS;
    }
    zero_i32<<<(2 * B * 576 + 255) / 256, 256, 0, stream>>>(gmax, 2 * B * 576);
    seg_max_atomic<<<dim3((N + 31) / 32, 2), 256, 0, stream>>>(gA, nid[0], gmax, N, 576,
                                                               NS, (size_t)B * 576);
    linear_wave<<<dim3(32, B, 2), 256, 0, stream>>>((const float*)gmax, fcg_w, fcg_b, gvec,
                                                    576, 128, 1, (size_t)B * 576, (size_t)B * 128);

    // --- TextCNN (MFMA convs), both branches per dispatch ---
    transpose_pad2<<<((2 * B * 64 * L) + 255) / 256, 256, 0, stream>>>(pad[0], pad[1], xT, B, L, 64);
    conv_mfma<<<dim3(19, B, 2), 256, 64 * 68 * 4 + 128 * 72 * 2, stream>>>(
        xT, cw1, c1b, y1, 64, 1200, 1198, (size_t)B * 64 * L, (size_t)B * 128 * 1198);
    maxpool<<<(2 * B * 128 * 399 + 255) / 256, 256, 0, stream>>>(y1, p1, 2 * B * 128, 1198, 3, 3, 399);
    conv_mfma<<<dim3(7, B, 2), 256, 128 * 68 * 4 + 128 * 72 * 2, stream>>>(
        p1, cw2, c2b, y2, 128, 399, 397, (size_t)B * 128 * 399, (size_t)B * 128 * 397);
    maxpool<<<(2 * B * 128 * 132 + 255) / 256, 256, 0, stream>>>(y2, p2, 2 * B * 128, 397, 3, 3, 132);
    conv_mfma<<<dim3(3, B, 2), 256, 128 * 68 * 4 + 128 * 72 * 2, stream>>>(
        p2, cw3, c3b, y3, 128, 132, 130, (size_t)B * 128 * 132, (size_t)B * 128 * 130);
    maxpool<<<(2 * B * 128 + 255) / 256, 256, 0, stream>>>(y3, sp, 2 * B * 128, 130, 130, 1, 1);
    linear_wave<<<dim3(32, B, 2), 256, 0, stream>>>(sp, tf_w, tf_b, sf, 128, 128, 1,
                                                    (size_t)B * 128, (size_t)B * 128);
    combine_branch2<<<(2 * B * 128 + 255) / 256, 256, 0, stream>>>(gvec, sf, w1, cat, B);

    // --- head MLP ---
    linear_wave<<<dim3(128, B, 1), 256, 0, stream>>>(cat, fc1_w, fc1_b, f1, 256, 512, 1, 0, 0);
    linear_wave<<<dim3(64, B, 1), 256, 0, stream>>>(f1, fc2_w, fc2_b, f2, 512, 256, 1, 0, 0);
    linear_wave<<<dim3(1, B, 1), 256, 0, stream>>>(f2, outw, outb, out, 256, 1, 2, 0, 0);
}

// Round 13
// 639.250 us; speedup vs baseline: 5.1626x; 1.0436x over previous
//
#include <hip/hip_runtime.h>
#include <hip/hip_bf16.h>
#include <math.h>

#define NEG_SLOPE 0.2f

// ---------------- utility ----------------
__global__ void zero_i32(int* __restrict__ p, int n) {
    int i = blockIdx.x * blockDim.x + threadIdx.x;
    if (i < n) p[i] = 0;
}

// ---------------- CSR build (both branches in one dispatch) ----------------
__global__ void count_edges2(const int* __restrict__ dst0, const int* __restrict__ dst1,
                             int* __restrict__ cnt, int N, int E) {
    int i = blockIdx.x * blockDim.x + threadIdx.x;
    if (i >= 2 * E) return;
    int br = i >= E;
    int j = i - br * E;
    const int* d = br ? dst1 : dst0;
    atomicAdd(&cnt[br * N + d[j]], 1);
}

__global__ void scan_block(const int* __restrict__ cnt_all, int* __restrict__ rs_all, int N) {
    __shared__ int s[1024];
    int br = blockIdx.x;
    const int* cnt = cnt_all + br * N;
    int* rs = rs_all + br * (N + 1);
    int tid = threadIdx.x;
    int running = 0;
    for (int base = 0; base < N; base += 1024) {
        int v = (base + tid < N) ? cnt[base + tid] : 0;
        __syncthreads();
        s[tid] = v;
        __syncthreads();
        for (int off = 1; off < 1024; off <<= 1) {
            int t = (tid >= off) ? s[tid - off] : 0;
            __syncthreads();
            if (tid >= off) s[tid] += t;
            __syncthreads();
        }
        if (base + tid < N) rs[base + tid] = running + s[tid] - v;
        running += s[1023];
    }
    if (tid == 0) rs[N] = running;
}

__global__ void scatter_edges2(const int* __restrict__ dst0, const int* __restrict__ dst1,
                               const int* __restrict__ rs_all, int* __restrict__ fill_all,
                               int* __restrict__ eidx_all, int N, int E) {
    int i = blockIdx.x * blockDim.x + threadIdx.x;
    if (i >= 2 * E) return;
    int br = i >= E;
    int j = i - br * E;
    const int* d = br ? dst1 : dst0;
    int dd = d[j];
    int pos = atomicAdd(&fill_all[br * N + dd], 1);
    eidx_all[br * E + rs_all[br * (N + 1) + dd] + pos] = j;
}

// ---------------- bf16 hi/lo helpers ----------------
__device__ __forceinline__ short f2bf(float x) {
    __hip_bfloat16 h = __float2bfloat16(x);
    return *reinterpret_cast<short*>(&h);
}
__device__ __forceinline__ float bf2f(short s) {
    unsigned int u = ((unsigned int)(unsigned short)s) << 16;
    return __uint_as_float(u);
}
__device__ __forceinline__ float us2f(unsigned short s) {
    return __uint_as_float((unsigned int)s << 16);
}

// W (K x N fp32) -> W2t (N x 2K bf16, transposed): rows [Wh | Wl]
__global__ void split_bf2_w(const float* __restrict__ W, short* __restrict__ W2t, int K, int N) {
    int idx = blockIdx.x * blockDim.x + threadIdx.x;
    if (idx >= K * N) return;
    int k = idx / N, n = idx - k * N;
    float x = W[idx];
    short hs = f2bf(x);
    short ls = f2bf(x - bf2f(hs));
    size_t base = (size_t)n * 2 * K;
    W2t[base + k] = hs;
    W2t[base + K + k] = ls;
}

// conv weights [128][Cin][3] (contiguous = [out][Kp]) -> rows [out][Kp hi | Kp lo]
__global__ void split_bf2_cw(const float* __restrict__ w, short* __restrict__ w2, int Kp) {
    int idx = blockIdx.x * blockDim.x + threadIdx.x;
    if (idx >= 128 * Kp) return;
    int o = idx / Kp, k = idx - o * Kp;
    float x = w[idx];
    short hs = f2bf(x);
    short ls = f2bf(x - bf2f(hs));
    size_t base = (size_t)o * 2 * Kp;
    w2[base + k] = hs;
    w2[base + Kp + k] = ls;
}

// ---------------- MFMA bf16-split GEMM v4 (bf16-only output) ----------------
// Tile 64 rows x 192 cols, 4 waves; wave w owns ALL 64 rows x 48 cols
// (4 row-tiles x 3 col-tiles): per 32-k chunk 14 ds_read_b128 vs 36 MFMA
// (balanced 1:1). LDS row stride 72 shorts.
typedef __attribute__((ext_vector_type(8))) short short8;
typedef __attribute__((ext_vector_type(4))) short short4v;
typedef __attribute__((ext_vector_type(4))) float floatx4;

__global__ __launch_bounds__(256) void gemm_bf3_v4(const float* __restrict__ A0,
                                                   const float* __restrict__ A1,
                                                   const short* __restrict__ Bt,
                                                   unsigned short* __restrict__ Cbf,
                                                   int M, int K, int N, size_t cBrStride) {
    __shared__ __align__(16) short sA[64 * 72];   // rows: [Ah(32) | Al(32) | pad8]
    __shared__ __align__(16) short sB[192 * 72];  // rows: [Wh(32) | Wl(32) | pad8]
    int tid = threadIdx.x;
    int wave = tid >> 6, lane = tid & 63;
    int m = lane & 15, q = lane >> 4;
    int row0 = blockIdx.y << 6;
    int col0 = blockIdx.x * 192;
    const float* A = blockIdx.z ? A1 : A0;
    unsigned short* Cbfb = Cbf + blockIdx.z * cBrStride;
    int K2 = K * 2;
    floatx4 acc[4][3];
#pragma unroll
    for (int rt = 0; rt < 4; ++rt)
#pragma unroll
        for (int ct = 0; ct < 3; ++ct) acc[rt][ct] = (floatx4){0.f, 0.f, 0.f, 0.f};

    for (int k0 = 0; k0 < K; k0 += 32) {
        // stage A: 64 rows x 32 fp32 -> hi/lo bf16 (2 float4 per thread)
#pragma unroll
        for (int p = 0; p < 2; ++p) {
            int t = tid + (p << 8);
            int r = t >> 3, c = (t & 7) << 2;
            float4 av = *(const float4*)&A[(size_t)(row0 + r) * K + k0 + c];
            short4v hs, ls;
            hs[0] = f2bf(av.x); ls[0] = f2bf(av.x - bf2f(hs[0]));
            hs[1] = f2bf(av.y); ls[1] = f2bf(av.y - bf2f(hs[1]));
            hs[2] = f2bf(av.z); ls[2] = f2bf(av.z - bf2f(hs[2]));
            hs[3] = f2bf(av.w); ls[3] = f2bf(av.w - bf2f(hs[3]));
            *(short4v*)&sA[r * 72 + c] = hs;
            *(short4v*)&sA[r * 72 + 32 + c] = ls;
        }
        // stage B: 192 rows x (Wh32|Wl32) bf16 (6 float4 per thread)
#pragma unroll
        for (int p = 0; p < 6; ++p) {
            int t = tid + (p << 8);
            int n = t >> 3, sub = t & 7;
            int srcoff = k0 + (sub << 3) + ((sub >= 4) ? (K - 32) : 0);
            *(float4*)&sB[n * 72 + (sub << 3)] =
                *(const float4*)&Bt[(size_t)(col0 + n) * K2 + srcoff];
        }
        __syncthreads();
        short8 a_hi[4], a_lo[4];
#pragma unroll
        for (int rt = 0; rt < 4; ++rt) {
            a_hi[rt] = *(const short8*)&sA[(rt * 16 + m) * 72 + q * 8];
            a_lo[rt] = *(const short8*)&sA[(rt * 16 + m) * 72 + 32 + q * 8];
        }
#pragma unroll
        for (int ct = 0; ct < 3; ++ct) {
            short8 b_hi = *(const short8*)&sB[(wave * 48 + ct * 16 + m) * 72 + q * 8];
            short8 b_lo = *(const short8*)&sB[(wave * 48 + ct * 16 + m) * 72 + 32 + q * 8];
#pragma unroll
            for (int rt = 0; rt < 4; ++rt) {
                acc[rt][ct] = __builtin_amdgcn_mfma_f32_16x16x32_bf16(a_hi[rt], b_hi, acc[rt][ct], 0, 0, 0);
                acc[rt][ct] = __builtin_amdgcn_mfma_f32_16x16x32_bf16(a_lo[rt], b_hi, acc[rt][ct], 0, 0, 0);
                acc[rt][ct] = __builtin_amdgcn_mfma_f32_16x16x32_bf16(a_hi[rt], b_lo, acc[rt][ct], 0, 0, 0);
            }
        }
        __syncthreads();
    }
#pragma unroll
    for (int rt = 0; rt < 4; ++rt)
#pragma unroll
        for (int ct = 0; ct < 3; ++ct)
#pragma unroll
            for (int r = 0; r < 4; ++r) {
                size_t idx = (size_t)(row0 + rt * 16 + q * 4 + r) * N + col0 + wave * 48 + ct * 16 + m;
                Cbfb[idx] = (unsigned short)f2bf(acc[rt][ct][r]);
            }
}

// ---------------- GAT pieces (branch-fused; h in bf16) ----------------
__global__ void gat_elr(const unsigned short* __restrict__ h, const float* __restrict__ al,
                        const float* __restrict__ ar, float* __restrict__ el,
                        float* __restrict__ er, int N, int H, int D,
                        size_t hBr, size_t eBr) {
    int wid = (blockIdx.x * blockDim.x + threadIdx.x) >> 6;
    int lane = threadIdx.x & 63;
    if (wid >= 2 * N * H) return;
    int br = wid / (N * H);
    int loc = wid - br * N * H;
    int n = loc / H, hh = loc - n * H;
    const unsigned short* hp = h + br * hBr + ((size_t)n * H + hh) * D;
    const float* alp = al + (size_t)hh * D;
    const float* arp = ar + (size_t)hh * D;
    float sl = 0.f, sr = 0.f;
    for (int d = lane; d < D; d += 64) {
        float v = us2f(hp[d]);
        sl += v * alp[d];
        sr += v * arp[d];
    }
    for (int off = 32; off > 0; off >>= 1) {
        sl += __shfl_down(sl, off, 64);
        sr += __shfl_down(sr, off, 64);
    }
    if (lane == 0) { el[br * eBr + loc] = sl; er[br * eBr + loc] = sr; }
}

__device__ __forceinline__ float lrelu(float v) {
    return (v > 0.f) ? v : NEG_SLOPE * v;
}

__global__ void gat_softmax_wave(const float* __restrict__ el_all, const float* __restrict__ er_all,
                                 const int* __restrict__ src0, const int* __restrict__ src1,
                                 const int* __restrict__ rs_all, const int* __restrict__ eidx_all,
                                 float* __restrict__ alpha_all, int N, int H, int E,
                                 size_t eBr, size_t aBr) {
    int g = (blockIdx.x * blockDim.x + threadIdx.x) >> 6;
    int lane = threadIdx.x & 63;
    if (g >= 2 * N) return;
    int br = g / N;
    int n = g - br * N;
    const int* src = br ? src1 : src0;
    const int* rs = rs_all + br * (N + 1);
    const int* eidx = eidx_all + br * E;
    const float* el = el_all + br * eBr;
    const float* er = er_all + br * eBr;
    float* alpha = alpha_all + br * aBr;
    int s0 = rs[n], s1 = rs[n + 1];
    int deg = s1 - s0;
    if (deg == 0) return;
    float ern0 = er[n * H + 0];
    float ern1 = (H > 1) ? er[n * H + 1] : 0.f;
    float ern2 = (H > 2) ? er[n * H + 2] : 0.f;
    if (deg <= 64) {
        int e = 0, s = 0;
        float v0 = -INFINITY, v1 = -INFINITY, v2 = -INFINITY;
        if (lane < deg) {
            e = eidx[s0 + lane];
            s = src[e];
            v0 = lrelu(el[s * H + 0] + ern0);
            if (H > 1) {
                v1 = lrelu(el[s * H + 1] + ern1);
                v2 = lrelu(el[s * H + 2] + ern2);
            }
        }
        float m0 = v0, m1 = v1, m2 = v2;
#pragma unroll
        for (int off = 32; off > 0; off >>= 1) {
            m0 = fmaxf(m0, __shfl_xor(m0, off, 64));
            m1 = fmaxf(m1, __shfl_xor(m1, off, 64));
            m2 = fmaxf(m2, __shfl_xor(m2, off, 64));
        }
        float ex0 = (lane < deg) ? expf(v0 - m0) : 0.f;
        float ex1 = (lane < deg && H > 1) ? expf(v1 - m1) : 0.f;
        float ex2 = (lane < deg && H > 2) ? expf(v2 - m2) : 0.f;
        float d0 = ex0, d1 = ex1, d2 = ex2;
#pragma unroll
        for (int off = 32; off > 0; off >>= 1) {
            d0 += __shfl_xor(d0, off, 64);
            d1 += __shfl_xor(d1, off, 64);
            d2 += __shfl_xor(d2, off, 64);
        }
        if (lane < deg) {
            alpha[(size_t)e * H + 0] = ex0 / d0;
            if (H > 1) {
                alpha[(size_t)e * H + 1] = ex1 / d1;
                alpha[(size_t)e * H + 2] = ex2 / d2;
            }
        }
    } else {
        float m0 = -INFINITY, m1 = -INFINITY, m2 = -INFINITY;
        for (int j = s0 + lane; j < s1; j += 64) {
            int e = eidx[j], s = src[e];
            float v0 = lrelu(el[s * H + 0] + ern0);
            alpha[(size_t)e * H + 0] = v0; m0 = fmaxf(m0, v0);
            if (H > 1) {
                float v1 = lrelu(el[s * H + 1] + ern1);
                float v2 = lrelu(el[s * H + 2] + ern2);
                alpha[(size_t)e * H + 1] = v1; m1 = fmaxf(m1, v1);
                alpha[(size_t)e * H + 2] = v2; m2 = fmaxf(m2, v2);
            }
        }
#pragma unroll
        for (int off = 32; off > 0; off >>= 1) {
            m0 = fmaxf(m0, __shfl_xor(m0, off, 64));
            m1 = fmaxf(m1, __shfl_xor(m1, off, 64));
            m2 = fmaxf(m2, __shfl_xor(m2, off, 64));
        }
        float d0 = 0.f, d1 = 0.f, d2 = 0.f;
        for (int j = s0 + lane; j < s1; j += 64) {
            int e = eidx[j];
            float ex0 = expf(alpha[(size_t)e * H + 0] - m0);
            alpha[(size_t)e * H + 0] = ex0; d0 += ex0;
            if (H > 1) {
                float ex1 = expf(alpha[(size_t)e * H + 1] - m1);
                float ex2 = expf(alpha[(size_t)e * H + 2] - m2);
                alpha[(size_t)e * H + 1] = ex1; d1 += ex1;
                alpha[(size_t)e * H + 2] = ex2; d2 += ex2;
            }
        }
#pragma unroll
        for (int off = 32; off > 0; off >>= 1) {
            d0 += __shfl_xor(d0, off, 64);
            d1 += __shfl_xor(d1, off, 64);
            d2 += __shfl_xor(d2, off, 64);
        }
        float i0 = 1.f / d0;
        float i1 = (H > 1) ? 1.f / d1 : 0.f;
        float i2 = (H > 2) ? 1.f / d2 : 0.f;
        for (int j = s0 + lane; j < s1; j += 64) {
            int e = eidx[j];
            alpha[(size_t)e * H + 0] *= i0;
            if (H > 1) {
                alpha[(size_t)e * H + 1] *= i1;
                alpha[(size_t)e * H + 2] *= i2;
            }
        }
    }
}

// ---------------- aggregate (bf16 h) ----------------
#define TILE_E 64
__global__ void gat_aggregate(const unsigned short* __restrict__ hb_all,
                              const float* __restrict__ alpha_all,
                              const int* __restrict__ src0, const int* __restrict__ src1,
                              const int* __restrict__ rs_all, const int* __restrict__ eidx_all,
                              float4* __restrict__ out4_all, int N, int H, int D, int E,
                              size_t hBr, size_t aBr, size_t o4Br) {
    __shared__ int s_src[TILE_E];
    __shared__ float s_alpha[TILE_E * 3];
    int n = blockIdx.x;
    int br = blockIdx.y;
    const int* src = br ? src1 : src0;
    const int* rs = rs_all + br * (N + 1);
    const int* eidx = eidx_all + br * E;
    const unsigned short* hb = hb_all + br * hBr;
    const float* alpha = alpha_all + br * aBr;
    float4* out4 = out4_all + br * o4Br;
    int HD = H * D;
    int HD4 = HD >> 2;
    int tid = threadIdx.x;
    int s0 = rs[n], s1 = rs[n + 1];
    bool active = tid < HD4;
    int hh = active ? (tid << 2) / D : 0;
    float4 acc = {0.f, 0.f, 0.f, 0.f};
    for (int base = s0; base < s1; base += TILE_E) {
        int cntE = s1 - base; if (cntE > TILE_E) cntE = TILE_E;
        if (tid < cntE) {
            int e = eidx[base + tid];
            s_src[tid] = src[e];
#pragma unroll
            for (int h = 0; h < 3; ++h)
                if (h < H) s_alpha[tid * 3 + h] = alpha[(size_t)e * H + h];
        }
        __syncthreads();
        if (active) {
#pragma unroll 4
            for (int i = 0; i < cntE; ++i) {
                float a = s_alpha[i * 3 + hh];
                ushort4 hv = *(const ushort4*)&hb[(size_t)s_src[i] * HD + (tid << 2)];
                acc.x += a * us2f(hv.x);
                acc.y += a * us2f(hv.y);
                acc.z += a * us2f(hv.z);
                acc.w += a * us2f(hv.w);
            }
        }
        __syncthreads();
    }
    if (active) {
        acc.x = fmaxf(acc.x, 0.f); acc.y = fmaxf(acc.y, 0.f);
        acc.z = fmaxf(acc.z, 0.f); acc.w = fmaxf(acc.w, 0.f);
        out4[(size_t)n * HD4 + tid] = acc;
    }
}

// Graph max-readout (post-ReLU >=0) via int-bitcast atomicMax. grid.y = branch.
__global__ void seg_max_atomic(const float* __restrict__ g_all, const int* __restrict__ nid,
                               int* __restrict__ out_all, int N, int C,
                               size_t gBr, size_t oBr) {
    int br = blockIdx.y;
    const float* g = g_all + br * gBr;
    int* out = out_all + br * oBr;
    int n0 = blockIdx.x << 5;
    int n1 = n0 + 32; if (n1 > N) n1 = N;
    if (n0 >= N) return;
    for (int c = threadIdx.x; c < C; c += blockDim.x) {
        int cur = nid[n0];
        float m = 0.f;
        for (int n = n0; n < n1; ++n) {
            int gid = nid[n];
            if (gid != cur) {
                atomicMax(&out[cur * C + c], __float_as_int(m));
                cur = gid; m = 0.f;
            }
            m = fmaxf(m, g[(size_t)n * C + c]);
        }
        atomicMax(&out[cur * C + c], __float_as_int(m));
    }
}

// ---------------- small dense layers (grid.z = branch; strides may be 0) ----
__global__ void linear_wave(const float* __restrict__ in, const float* __restrict__ W,
                            const float* __restrict__ bias, float* __restrict__ out,
                            int K, int O, int act, size_t inBr, size_t outBr) {
    int o = blockIdx.x * 4 + (threadIdx.x >> 6);
    int b = blockIdx.y;
    int lane = threadIdx.x & 63;
    if (o >= O) return;
    const float* ip = in + blockIdx.z * inBr + (size_t)b * K;
    float acc = 0.f;
    for (int k = lane; k < K; k += 64)
        acc += ip[k] * W[(size_t)k * O + o];
    for (int off = 32; off > 0; off >>= 1)
        acc += __shfl_down(acc, off, 64);
    if (lane == 0) {
        acc += bias[o];
        if (act == 1) acc = fmaxf(acc, 0.f);
        else if (act == 2) acc = 1.f / (1.f + expf(-acc));
        out[blockIdx.z * outBr + (size_t)b * O + o] = acc;
    }
}

// ---------------- TextCNN (branch-fused) ----------------
__global__ void transpose_pad2(const float* __restrict__ pad0, const float* __restrict__ pad1,
                               float* __restrict__ xT, int B, int L, int C) {
    int idx = blockIdx.x * blockDim.x + threadIdx.x;
    int per = B * L * C;
    if (idx >= 2 * per) return;
    int br = idx >= per;
    int loc = idx - br * per;
    const float* pad = br ? pad1 : pad0;
    int l = loc % L;
    int c = (loc / L) % C;
    int b = loc / (L * C);
    xT[idx] = pad[((size_t)b * L + l) * C + c];
}

// ---------------- conv1d k=3 as MFMA (im2col on the fly) --------------------
__global__ __launch_bounds__(256) void conv_mfma(const float* __restrict__ x,
                                                 const short* __restrict__ w2,
                                                 const float* __restrict__ bias,
                                                 float* __restrict__ y,
                                                 int Cin, int Lin, int Lout,
                                                 size_t xBr, size_t yBr) {
    extern __shared__ __align__(16) char smem[];
    float* sx = (float*)smem;                         // Cin x 68 fp32
    short* sB = (short*)(smem + (size_t)Cin * 68 * 4); // 128 x 72 shorts
    int Kp = Cin * 3;
    int K2 = Kp * 2;
    int b = blockIdx.y;
    const float* xb = x + blockIdx.z * xBr + (size_t)b * Cin * Lin;
    float* yb = y + blockIdx.z * yBr + (size_t)b * 128 * Lout;
    int l0 = blockIdx.x << 6;
    int tid = threadIdx.x;
    int wave = tid >> 6, lane = tid & 63;
    int m = lane & 15, q = lane >> 4;
    int wrow = (wave & 1) << 5;   // pos offset 0/32
    int wcol = (wave >> 1) << 6;  // out offset 0/64
    int loadL = Lin - l0; if (loadL > 66) loadL = 66;
    for (int idx = tid; idx < Cin * loadL; idx += 256) {
        int c = idx / loadL, i = idx - c * loadL;
        sx[c * 68 + i] = xb[(size_t)c * Lin + l0 + i];
    }
    floatx4 acc[2][4];
#pragma unroll
    for (int rt = 0; rt < 2; ++rt)
#pragma unroll
        for (int ct = 0; ct < 4; ++ct) acc[rt][ct] = (floatx4){0.f, 0.f, 0.f, 0.f};

    for (int k0 = 0; k0 < Kp; k0 += 32) {
#pragma unroll
        for (int p = 0; p < 4; ++p) {
            int t = tid + (p << 8);
            int o = t >> 3, slot = t & 7;
            int srcoff = k0 + ((slot & 3) << 3) + ((slot >= 4) ? Kp : 0);
            *(float4*)&sB[o * 72 + (slot << 3)] = *(const float4*)&w2[(size_t)o * K2 + srcoff];
        }
        __syncthreads();
        short8 a_hi[2], a_lo[2];
#pragma unroll
        for (int rt = 0; rt < 2; ++rt) {
            int pos = wrow + rt * 16 + m;
#pragma unroll
            for (int kk = 0; kk < 8; ++kk) {
                int k = k0 + q * 8 + kk;
                int c = k / 3, j = k - c * 3;
                float v = sx[c * 68 + pos + j];
                short hv = f2bf(v);
                a_hi[rt][kk] = hv;
                a_lo[rt][kk] = f2bf(v - bf2f(hv));
            }
        }
#pragma unroll
        for (int ct = 0; ct < 4; ++ct) {
            short8 b_hi = *(const short8*)&sB[(wcol + ct * 16 + m) * 72 + q * 8];
            short8 b_lo = *(const short8*)&sB[(wcol + ct * 16 + m) * 72 + 32 + q * 8];
#pragma unroll
            for (int rt = 0; rt < 2; ++rt) {
                acc[rt][ct] = __builtin_amdgcn_mfma_f32_16x16x32_bf16(a_hi[rt], b_hi, acc[rt][ct], 0, 0, 0);
                acc[rt][ct] = __builtin_amdgcn_mfma_f32_16x16x32_bf16(a_lo[rt], b_hi, acc[rt][ct], 0, 0, 0);
                acc[rt][ct] = __builtin_amdgcn_mfma_f32_16x16x32_bf16(a_hi[rt], b_lo, acc[rt][ct], 0, 0, 0);
            }
        }
        __syncthreads();
    }
#pragma unroll
    for (int ct = 0; ct < 4; ++ct) {
        int o = wcol + ct * 16 + m;
        float bv = bias[o];
#pragma unroll
        for (int rt = 0; rt < 2; ++rt)
#pragma unroll
            for (int r = 0; r < 4; ++r) {
                int pos = wrow + rt * 16 + q * 4 + r;
                if (l0 + pos < Lout)
                    yb[(size_t)o * Lout + l0 + pos] = acc[rt][ct][r] + bv;
            }
    }
}

__global__ void maxpool(const float* __restrict__ y, float* __restrict__ p,
                        int BC, int Lin, int k, int s, int Lout) {
    int idx = blockIdx.x * blockDim.x + threadIdx.x;
    if (idx >= BC * Lout) return;
    int lo = idx % Lout, bc = idx / Lout;
    const float* yp = y + (size_t)bc * Lin + lo * s;
    float m = -INFINITY;
    for (int i = 0; i < k; ++i) m = fmaxf(m, yp[i]);
    p[idx] = m;
}

// cat[b, br*128 + c] over both branches in one launch (gvec/sf are [2][B*128])
__global__ void combine_branch2(const float* __restrict__ g, const float* __restrict__ s,
                                const float* __restrict__ w1, float* __restrict__ cat, int B) {
    int idx = blockIdx.x * blockDim.x + threadIdx.x;
    int per = B * 128;
    if (idx >= 2 * per) return;
    int br = idx >= per;
    int loc = idx - br * per;
    int b = loc >> 7, c = loc & 127;
    float w = 1.f / (1.f + expf(-w1[0]));
    cat[b * 256 + br * 128 + c] = (1.f - w) * g[idx] + w * s[idx];
}

// ---------------- host ----------------
extern "C" void kernel_launch(void* const* d_in, const int* in_sizes, int n_in,
                              void* d_out, int out_size, void* d_ws, size_t ws_size,
                              hipStream_t stream) {
    const float* feat[2] = {(const float*)d_in[0], (const float*)d_in[1]};
    const float* pad[2]  = {(const float*)d_in[2], (const float*)d_in[3]};
    const int* src[2]    = {(const int*)d_in[4], (const int*)d_in[6]};
    const int* dst[2]    = {(const int*)d_in[5], (const int*)d_in[7]};
    const int* nid[2]    = {(const int*)d_in[8], (const int*)d_in[9]};
    const float* Wg[3]   = {(const float*)d_in[11], (const float*)d_in[14], (const float*)d_in[17]};
    const float* al[3]   = {(const float*)d_in[12], (const float*)d_in[15], (const float*)d_in[18]};
    const float* ar[3]   = {(const float*)d_in[13], (const float*)d_in[16], (const float*)d_in[19]};
    const float* fcg_w = (const float*)d_in[20]; const float* fcg_b = (const float*)d_in[21];
    const float* c1w = (const float*)d_in[22];   const float* c1b = (const float*)d_in[23];
    const float* c2w = (const float*)d_in[24];   const float* c2b = (const float*)d_in[25];
    const float* c3w = (const float*)d_in[26];   const float* c3b = (const float*)d_in[27];
    const float* tf_w = (const float*)d_in[28];  const float* tf_b = (const float*)d_in[29];
    const float* w1 = (const float*)d_in[30];
    const float* fc1_w = (const float*)d_in[31]; const float* fc1_b = (const float*)d_in[32];
    const float* fc2_w = (const float*)d_in[33]; const float* fc2_b = (const float*)d_in[34];
    const float* outw = (const float*)d_in[35];  const float* outb = (const float*)d_in[36];
    float* out = (float*)d_out;

    const int N = in_sizes[0] / 64;   // 8000
    const int E = in_sizes[4];        // 160000
    const int B = 16, L = 1200;
    const size_t NS = (size_t)N * 576;

    char* wsb = (char*)d_ws;
    size_t off = 0;
    auto allocB = [&](size_t bytes) -> void* {
        void* p = wsb + off;
        off += (bytes + 255) & ~(size_t)255;
        return p;
    };
    auto alloc = [&](size_t elems) -> void* { return allocB(elems * 4); };

    unsigned short* h_bf = (unsigned short*)allocB(2 * NS * 2);   // h in bf16 only
    float* gA    = (float*)alloc(2 * NS);
    float* el    = (float*)alloc(2 * (size_t)N * 3);
    float* er    = (float*)alloc(2 * (size_t)N * 3);
    float* alpha = (float*)alloc(2 * (size_t)E * 3);
    int* rs      = (int*)alloc(2 * (N + 1));
    int* cnt     = (int*)alloc(2 * N);
    int* eidx    = (int*)alloc(2 * E);
    int* gmax    = (int*)alloc(2 * (size_t)B * 576);
    float* gvec  = (float*)alloc(2 * (size_t)B * 128);
    float* sp    = (float*)alloc(2 * (size_t)B * 128);
    float* sf    = (float*)alloc(2 * (size_t)B * 128);
    float* cat   = (float*)alloc((size_t)B * 256);
    float* f1    = (float*)alloc((size_t)B * 512);
    float* f2    = (float*)alloc((size_t)B * 256);
    short* w2t1  = (short*)allocB((size_t)192 * 2 * 64 * 2);
    short* w2t2  = (short*)allocB((size_t)576 * 2 * 192 * 2);
    short* w2t3  = (short*)allocB((size_t)576 * 2 * 576 * 2);
    short* cw1   = (short*)allocB((size_t)128 * 2 * 192 * 2);   // conv w hi/lo
    short* cw2   = (short*)allocB((size_t)128 * 2 * 384 * 2);
    short* cw3   = (short*)allocB((size_t)128 * 2 * 384 * 2);
    size_t tcnn_elems = 2 * ((size_t)B * 64 * L + (size_t)B * 128 * (1198 + 399 + 397 + 132 + 130));
    size_t uni_elems = 2 * NS > tcnn_elems ? 2 * NS : tcnn_elems;
    float* uni = (float*)alloc(uni_elems);
    float* gB = uni;
    float* xT = uni;
    float* y1 = xT + 2 * (size_t)B * 64 * L;
    float* p1 = y1 + 2 * (size_t)B * 128 * 1198;
    float* y2 = p1 + 2 * (size_t)B * 128 * 399;
    float* p2 = y2 + 2 * (size_t)B * 128 * 397;
    float* y3 = p2 + 2 * (size_t)B * 128 * 132;
    (void)ws_size; (void)n_in; (void)out_size;

    split_bf2_w<<<(64 * 192 + 255) / 256, 256, 0, stream>>>(Wg[0], w2t1, 64, 192);
    split_bf2_w<<<(192 * 576 + 255) / 256, 256, 0, stream>>>(Wg[1], w2t2, 192, 576);
    split_bf2_w<<<(576 * 576 + 255) / 256, 256, 0, stream>>>(Wg[2], w2t3, 576, 576);
    split_bf2_cw<<<(128 * 192 + 255) / 256, 256, 0, stream>>>(c1w, cw1, 192);
    split_bf2_cw<<<(128 * 384 + 255) / 256, 256, 0, stream>>>(c2w, cw2, 384);
    split_bf2_cw<<<(128 * 384 + 255) / 256, 256, 0, stream>>>(c3w, cw3, 384);
    short* w2t[3] = {w2t1, w2t2, w2t3};

    // --- CSR for both branches ---
    zero_i32<<<(2 * N + 255) / 256, 256, 0, stream>>>(cnt, 2 * N);
    count_edges2<<<(2 * E + 255) / 256, 256, 0, stream>>>(dst[0], dst[1], cnt, N, E);
    scan_block<<<2, 1024, 0, stream>>>(cnt, rs, N);
    zero_i32<<<(2 * N + 255) / 256, 256, 0, stream>>>(cnt, 2 * N);
    scatter_edges2<<<(2 * E + 255) / 256, 256, 0, stream>>>(dst[0], dst[1], rs, cnt, eidx, N, E);

    // --- 3 GAT layers, both branches per dispatch ---
    const int dims[3][3] = {{64, 3, 64}, {192, 3, 192}, {576, 1, 576}};  // K,H,D
    float* outs[3] = {gA, gB, gA};
    const float* inp0 = feat[0];
    const float* inp1 = feat[1];
    for (int ly = 0; ly < 3; ++ly) {
        int K = dims[ly][0], H = dims[ly][1], D = dims[ly][2];
        int HD = H * D;
        gemm_bf3_v4<<<dim3(HD / 192, N / 64, 2), 256, 0, stream>>>(inp0, inp1, w2t[ly], h_bf,
                                                                   N, K, HD, NS);
        int waves2 = 2 * N * H;
        gat_elr<<<((size_t)waves2 * 64 + 255) / 256, 256, 0, stream>>>(h_bf, al[ly], ar[ly], el, er,
                                                                       N, H, D, NS, (size_t)N * 3);
        gat_softmax_wave<<<((size_t)2 * N * 64 + 255) / 256, 256, 0, stream>>>(
            el, er, src[0], src[1], rs, eidx, alpha, N, H, E, (size_t)N * 3, (size_t)E * 3);
        int aggThreads = (((HD >> 2) + 63) / 64) * 64;   // 64 for HD=192, 192 for HD=576
        gat_aggregate<<<dim3(N, 2), aggThreads, 0, stream>>>(
            h_bf, alpha, src[0], src[1], rs, eidx, (float4*)outs[ly],
            N, H, D, E, NS, (size_t)E * 3, NS / 4);
        inp0 = outs[ly];
        inp1 = outs[ly] + NS;
    }
    zero_i32<<<(2 * B * 576 + 255) / 256, 256, 0, stream>>>(gmax, 2 * B * 576);
    seg_max_atomic<<<dim3((N + 31) / 32, 2), 256, 0, stream>>>(gA, nid[0], gmax, N, 576,
                                                               NS, (size_t)B * 576);
    linear_wave<<<dim3(32, B, 2), 256, 0, stream>>>((const float*)gmax, fcg_w, fcg_b, gvec,
                                                    576, 128, 1, (size_t)B * 576, (size_t)B * 128);

    // --- TextCNN (MFMA convs), both branches per dispatch ---
    transpose_pad2<<<((2 * B * 64 * L) + 255) / 256, 256, 0, stream>>>(pad[0], pad[1], xT, B, L, 64);
    conv_mfma<<<dim3(19, B, 2), 256, 64 * 68 * 4 + 128 * 72 * 2, stream>>>(
        xT, cw1, c1b, y1, 64, 1200, 1198, (size_t)B * 64 * L, (size_t)B * 128 * 1198);
    maxpool<<<(2 * B * 128 * 399 + 255) / 256, 256, 0, stream>>>(y1, p1, 2 * B * 128, 1198, 3, 3, 399);
    conv_mfma<<<dim3(7, B, 2), 256, 128 * 68 * 4 + 128 * 72 * 2, stream>>>(
        p1, cw2, c2b, y2, 128, 399, 397, (size_t)B * 128 * 399, (size_t)B * 128 * 397);
    maxpool<<<(2 * B * 128 * 132 + 255) / 256, 256, 0, stream>>>(y2, p2, 2 * B * 128, 397, 3, 3, 132);
    conv_mfma<<<dim3(3, B, 2), 256, 128 * 68 * 4 + 128 * 72 * 2, stream>>>(
        p2, cw3, c3b, y3, 128, 132, 130, (size_t)B * 128 * 132, (size_t)B * 128 * 130);
    maxpool<<<(2 * B * 128 + 255) / 256, 256, 0, stream>>>(y3, sp, 2 * B * 128, 130, 130, 1, 1);
    linear_wave<<<dim3(32, B, 2), 256, 0, stream>>>(sp, tf_w, tf_b, sf, 128, 128, 1,
                                                    (size_t)B * 128, (size_t)B * 128);
    combine_branch2<<<(2 * B * 128 + 255) / 256, 256, 0, stream>>>(gvec, sf, w1, cat, B);

    // --- head MLP ---
    linear_wave<<<dim3(128, B, 1), 256, 0, stream>>>(cat, fc1_w, fc1_b, f1, 256, 512, 1, 0, 0);
    linear_wave<<<dim3(64, B, 1), 256, 0, stream>>>(f1, fc2_w, fc2_b, f2, 512, 256, 1, 0, 0);
    linear_wave<<<dim3(1, B, 1), 256, 0, stream>>>(f2, outw, outb, out, 256, 1, 2, 0, 0);
}

// Round 14
// 592.127 us; speedup vs baseline: 5.5734x; 1.0796x over previous
//
#include <hip/hip_runtime.h>
#include <hip/hip_bf16.h>
#include <math.h>

#define NEG_SLOPE 0.2f

// ---------------- utility ----------------
__global__ void zero_i32(int* __restrict__ p, int n) {
    int i = blockIdx.x * blockDim.x + threadIdx.x;
    if (i < n) p[i] = 0;
}

// ---------------- CSR build (both branches in one dispatch) ----------------
__global__ void count_edges2(const int* __restrict__ dst0, const int* __restrict__ dst1,
                             int* __restrict__ cnt, int N, int E) {
    int i = blockIdx.x * blockDim.x + threadIdx.x;
    if (i >= 2 * E) return;
    int br = i >= E;
    int j = i - br * E;
    const int* d = br ? dst1 : dst0;
    atomicAdd(&cnt[br * N + d[j]], 1);
}

__global__ void scan_block(const int* __restrict__ cnt_all, int* __restrict__ rs_all, int N) {
    __shared__ int s[1024];
    int br = blockIdx.x;
    const int* cnt = cnt_all + br * N;
    int* rs = rs_all + br * (N + 1);
    int tid = threadIdx.x;
    int running = 0;
    for (int base = 0; base < N; base += 1024) {
        int v = (base + tid < N) ? cnt[base + tid] : 0;
        __syncthreads();
        s[tid] = v;
        __syncthreads();
        for (int off = 1; off < 1024; off <<= 1) {
            int t = (tid >= off) ? s[tid - off] : 0;
            __syncthreads();
            if (tid >= off) s[tid] += t;
            __syncthreads();
        }
        if (base + tid < N) rs[base + tid] = running + s[tid] - v;
        running += s[1023];
    }
    if (tid == 0) rs[N] = running;
}

__global__ void scatter_edges2(const int* __restrict__ dst0, const int* __restrict__ dst1,
                               const int* __restrict__ rs_all, int* __restrict__ fill_all,
                               int* __restrict__ eidx_all, int N, int E) {
    int i = blockIdx.x * blockDim.x + threadIdx.x;
    if (i >= 2 * E) return;
    int br = i >= E;
    int j = i - br * E;
    const int* d = br ? dst1 : dst0;
    int dd = d[j];
    int pos = atomicAdd(&fill_all[br * N + dd], 1);
    eidx_all[br * E + rs_all[br * (N + 1) + dd] + pos] = j;
}

// ---------------- bf16 hi/lo helpers ----------------
__device__ __forceinline__ short f2bf(float x) {
    __hip_bfloat16 h = __float2bfloat16(x);
    return *reinterpret_cast<short*>(&h);
}
__device__ __forceinline__ float bf2f(short s) {
    unsigned int u = ((unsigned int)(unsigned short)s) << 16;
    return __uint_as_float(u);
}
__device__ __forceinline__ float us2f(unsigned short s) {
    return __uint_as_float((unsigned int)s << 16);
}

// ---------------- merged weight prep (all 6 splits, one dispatch) -----------
// GEMM weights: W (K x N fp32) -> W2t (N x 2K bf16): rows [Wh | Wl]
// conv weights: [128][Kp] fp32 -> rows [out][Kp hi | Kp lo]
__device__ __forceinline__ void split_w_elem(const float* W, short* W2t, int K, int N, int idx) {
    int k = idx / N, n = idx - k * N;
    float x = W[idx];
    short hs = f2bf(x);
    short ls = f2bf(x - bf2f(hs));
    size_t base = (size_t)n * 2 * K;
    W2t[base + k] = hs;
    W2t[base + K + k] = ls;
}
__device__ __forceinline__ void split_cw_elem(const float* w, short* w2, int Kp, int idx) {
    int o = idx / Kp, k = idx - o * Kp;
    float x = w[idx];
    short hs = f2bf(x);
    short ls = f2bf(x - bf2f(hs));
    size_t base = (size_t)o * 2 * Kp;
    w2[base + k] = hs;
    w2[base + Kp + k] = ls;
}
__global__ void prep_weights(const float* __restrict__ Wg1, const float* __restrict__ Wg2,
                             const float* __restrict__ Wg3, const float* __restrict__ c1w,
                             const float* __restrict__ c2w, const float* __restrict__ c3w,
                             short* __restrict__ w2t1, short* __restrict__ w2t2,
                             short* __restrict__ w2t3, short* __restrict__ cw1,
                             short* __restrict__ cw2, short* __restrict__ cw3) {
    int idx = blockIdx.x * blockDim.x + threadIdx.x;
    if (idx < 12288)       split_w_elem(Wg1, w2t1, 64, 192, idx);
    else if (idx < 122880) split_w_elem(Wg2, w2t2, 192, 576, idx - 12288);
    else if (idx < 454656) split_w_elem(Wg3, w2t3, 576, 576, idx - 122880);
    else if (idx < 479232) split_cw_elem(c1w, cw1, 192, idx - 454656);
    else if (idx < 528384) split_cw_elem(c2w, cw2, 384, idx - 479232);
    else if (idx < 577536) split_cw_elem(c3w, cw3, 384, idx - 528384);
}

// ---------------- MFMA bf16-split GEMM v4 (bf16-only output) ----------------
typedef __attribute__((ext_vector_type(8))) short short8;
typedef __attribute__((ext_vector_type(4))) short short4v;
typedef __attribute__((ext_vector_type(4))) float floatx4;

__global__ __launch_bounds__(256) void gemm_bf3_v4(const float* __restrict__ A0,
                                                   const float* __restrict__ A1,
                                                   const short* __restrict__ Bt,
                                                   unsigned short* __restrict__ Cbf,
                                                   int M, int K, int N, size_t cBrStride) {
    __shared__ __align__(16) short sA[64 * 72];   // rows: [Ah(32) | Al(32) | pad8]
    __shared__ __align__(16) short sB[192 * 72];  // rows: [Wh(32) | Wl(32) | pad8]
    int tid = threadIdx.x;
    int wave = tid >> 6, lane = tid & 63;
    int m = lane & 15, q = lane >> 4;
    int row0 = blockIdx.y << 6;
    int col0 = blockIdx.x * 192;
    const float* A = blockIdx.z ? A1 : A0;
    unsigned short* Cbfb = Cbf + blockIdx.z * cBrStride;
    int K2 = K * 2;
    floatx4 acc[4][3];
#pragma unroll
    for (int rt = 0; rt < 4; ++rt)
#pragma unroll
        for (int ct = 0; ct < 3; ++ct) acc[rt][ct] = (floatx4){0.f, 0.f, 0.f, 0.f};

    for (int k0 = 0; k0 < K; k0 += 32) {
#pragma unroll
        for (int p = 0; p < 2; ++p) {
            int t = tid + (p << 8);
            int r = t >> 3, c = (t & 7) << 2;
            float4 av = *(const float4*)&A[(size_t)(row0 + r) * K + k0 + c];
            short4v hs, ls;
            hs[0] = f2bf(av.x); ls[0] = f2bf(av.x - bf2f(hs[0]));
            hs[1] = f2bf(av.y); ls[1] = f2bf(av.y - bf2f(hs[1]));
            hs[2] = f2bf(av.z); ls[2] = f2bf(av.z - bf2f(hs[2]));
            hs[3] = f2bf(av.w); ls[3] = f2bf(av.w - bf2f(hs[3]));
            *(short4v*)&sA[r * 72 + c] = hs;
            *(short4v*)&sA[r * 72 + 32 + c] = ls;
        }
#pragma unroll
        for (int p = 0; p < 6; ++p) {
            int t = tid + (p << 8);
            int n = t >> 3, sub = t & 7;
            int srcoff = k0 + (sub << 3) + ((sub >= 4) ? (K - 32) : 0);
            *(float4*)&sB[n * 72 + (sub << 3)] =
                *(const float4*)&Bt[(size_t)(col0 + n) * K2 + srcoff];
        }
        __syncthreads();
        short8 a_hi[4], a_lo[4];
#pragma unroll
        for (int rt = 0; rt < 4; ++rt) {
            a_hi[rt] = *(const short8*)&sA[(rt * 16 + m) * 72 + q * 8];
            a_lo[rt] = *(const short8*)&sA[(rt * 16 + m) * 72 + 32 + q * 8];
        }
#pragma unroll
        for (int ct = 0; ct < 3; ++ct) {
            short8 b_hi = *(const short8*)&sB[(wave * 48 + ct * 16 + m) * 72 + q * 8];
            short8 b_lo = *(const short8*)&sB[(wave * 48 + ct * 16 + m) * 72 + 32 + q * 8];
#pragma unroll
            for (int rt = 0; rt < 4; ++rt) {
                acc[rt][ct] = __builtin_amdgcn_mfma_f32_16x16x32_bf16(a_hi[rt], b_hi, acc[rt][ct], 0, 0, 0);
                acc[rt][ct] = __builtin_amdgcn_mfma_f32_16x16x32_bf16(a_lo[rt], b_hi, acc[rt][ct], 0, 0, 0);
                acc[rt][ct] = __builtin_amdgcn_mfma_f32_16x16x32_bf16(a_hi[rt], b_lo, acc[rt][ct], 0, 0, 0);
            }
        }
        __syncthreads();
    }
#pragma unroll
    for (int rt = 0; rt < 4; ++rt)
#pragma unroll
        for (int ct = 0; ct < 3; ++ct)
#pragma unroll
            for (int r = 0; r < 4; ++r) {
                size_t idx = (size_t)(row0 + rt * 16 + q * 4 + r) * N + col0 + wave * 48 + ct * 16 + m;
                Cbfb[idx] = (unsigned short)f2bf(acc[rt][ct][r]);
            }
}

// ---------------- GAT pieces (branch-fused; h in bf16) ----------------
__global__ void gat_elr(const unsigned short* __restrict__ h, const float* __restrict__ al,
                        const float* __restrict__ ar, float* __restrict__ el,
                        float* __restrict__ er, int N, int H, int D,
                        size_t hBr, size_t eBr) {
    int wid = (blockIdx.x * blockDim.x + threadIdx.x) >> 6;
    int lane = threadIdx.x & 63;
    if (wid >= 2 * N * H) return;
    int br = wid / (N * H);
    int loc = wid - br * N * H;
    int n = loc / H, hh = loc - n * H;
    const unsigned short* hp = h + br * hBr + ((size_t)n * H + hh) * D;
    const float* alp = al + (size_t)hh * D;
    const float* arp = ar + (size_t)hh * D;
    float sl = 0.f, sr = 0.f;
    for (int d = lane; d < D; d += 64) {
        float v = us2f(hp[d]);
        sl += v * alp[d];
        sr += v * arp[d];
    }
    for (int off = 32; off > 0; off >>= 1) {
        sl += __shfl_down(sl, off, 64);
        sr += __shfl_down(sr, off, 64);
    }
    if (lane == 0) { el[br * eBr + loc] = sl; er[br * eBr + loc] = sr; }
}

__device__ __forceinline__ float lrelu(float v) {
    return (v > 0.f) ? v : NEG_SLOPE * v;
}

// ---------------- fused softmax + aggregate (block per node) ----------------
// Wave 0 computes edge softmax straight into LDS (s_src, s_alpha); all waves
// then aggregate bf16 h rows. deg<=64 fast path is register-resident and
// bit-identical to the previous two-kernel math.
#define TILE_E 64
__global__ void gat_softagg(const unsigned short* __restrict__ hb_all,
                            const float* __restrict__ el_all, const float* __restrict__ er_all,
                            const int* __restrict__ src0, const int* __restrict__ src1,
                            const int* __restrict__ rs_all, const int* __restrict__ eidx_all,
                            float4* __restrict__ out4_all, int N, int H, int D, int E,
                            size_t hBr, size_t eBr, size_t o4Br) {
    __shared__ int s_src[TILE_E];
    __shared__ float s_alpha[TILE_E * 3];
    __shared__ float s_stat[6];
    int n = blockIdx.x;
    int br = blockIdx.y;
    const int* src = br ? src1 : src0;
    const int* rs = rs_all + br * (N + 1);
    const int* eidx = eidx_all + br * E;
    const unsigned short* hb = hb_all + br * hBr;
    const float* el = el_all + br * eBr;
    const float* er = er_all + br * eBr;
    float4* out4 = out4_all + br * o4Br;
    int HD = H * D;
    int HD4 = HD >> 2;
    int tid = threadIdx.x;
    int s0 = rs[n], s1 = rs[n + 1];
    int deg = s1 - s0;
    bool activeC = tid < HD4;
    int hh = activeC ? (tid << 2) / D : 0;
    float4 acc = {0.f, 0.f, 0.f, 0.f};

    if (deg > 0 && deg <= 64) {
        if (tid < 64) {
            int lane = tid;
            float ern0 = er[n * H + 0];
            float ern1 = (H > 1) ? er[n * H + 1] : 0.f;
            float ern2 = (H > 2) ? er[n * H + 2] : 0.f;
            int s = 0;
            float v0 = -INFINITY, v1 = -INFINITY, v2 = -INFINITY;
            if (lane < deg) {
                int e = eidx[s0 + lane];
                s = src[e];
                v0 = lrelu(el[s * H + 0] + ern0);
                if (H > 1) {
                    v1 = lrelu(el[s * H + 1] + ern1);
                    v2 = lrelu(el[s * H + 2] + ern2);
                }
            }
            float m0 = v0, m1 = v1, m2 = v2;
#pragma unroll
            for (int off = 32; off > 0; off >>= 1) {
                m0 = fmaxf(m0, __shfl_xor(m0, off, 64));
                m1 = fmaxf(m1, __shfl_xor(m1, off, 64));
                m2 = fmaxf(m2, __shfl_xor(m2, off, 64));
            }
            float ex0 = (lane < deg) ? expf(v0 - m0) : 0.f;
            float ex1 = (lane < deg && H > 1) ? expf(v1 - m1) : 0.f;
            float ex2 = (lane < deg && H > 2) ? expf(v2 - m2) : 0.f;
            float d0 = ex0, d1 = ex1, d2 = ex2;
#pragma unroll
            for (int off = 32; off > 0; off >>= 1) {
                d0 += __shfl_xor(d0, off, 64);
                d1 += __shfl_xor(d1, off, 64);
                d2 += __shfl_xor(d2, off, 64);
            }
            if (lane < deg) {
                s_src[lane] = s;
                s_alpha[lane * 3 + 0] = ex0 / d0;
                if (H > 1) {
                    s_alpha[lane * 3 + 1] = ex1 / d1;
                    s_alpha[lane * 3 + 2] = ex2 / d2;
                }
            }
        }
        __syncthreads();
        if (activeC) {
#pragma unroll 8
            for (int i = 0; i < deg; ++i) {
                float a = s_alpha[i * 3 + hh];
                ushort4 hv = *(const ushort4*)&hb[(size_t)s_src[i] * HD + (tid << 2)];
                acc.x += a * us2f(hv.x);
                acc.y += a * us2f(hv.y);
                acc.z += a * us2f(hv.z);
                acc.w += a * us2f(hv.w);
            }
        }
    } else if (deg > 64) {
        // general path: wave 0 computes (m, 1/den); tiles recompute alpha
        if (tid < 64) {
            int lane = tid;
            float ern0 = er[n * H + 0];
            float ern1 = (H > 1) ? er[n * H + 1] : 0.f;
            float ern2 = (H > 2) ? er[n * H + 2] : 0.f;
            float m0 = -INFINITY, m1 = -INFINITY, m2 = -INFINITY;
            for (int j = s0 + lane; j < s1; j += 64) {
                int e = eidx[j], s = src[e];
                m0 = fmaxf(m0, lrelu(el[s * H + 0] + ern0));
                if (H > 1) {
                    m1 = fmaxf(m1, lrelu(el[s * H + 1] + ern1));
                    m2 = fmaxf(m2, lrelu(el[s * H + 2] + ern2));
                }
            }
#pragma unroll
            for (int off = 32; off > 0; off >>= 1) {
                m0 = fmaxf(m0, __shfl_xor(m0, off, 64));
                m1 = fmaxf(m1, __shfl_xor(m1, off, 64));
                m2 = fmaxf(m2, __shfl_xor(m2, off, 64));
            }
            float d0 = 0.f, d1 = 0.f, d2 = 0.f;
            for (int j = s0 + lane; j < s1; j += 64) {
                int e = eidx[j], s = src[e];
                d0 += expf(lrelu(el[s * H + 0] + ern0) - m0);
                if (H > 1) {
                    d1 += expf(lrelu(el[s * H + 1] + ern1) - m1);
                    d2 += expf(lrelu(el[s * H + 2] + ern2) - m2);
                }
            }
#pragma unroll
            for (int off = 32; off > 0; off >>= 1) {
                d0 += __shfl_xor(d0, off, 64);
                d1 += __shfl_xor(d1, off, 64);
                d2 += __shfl_xor(d2, off, 64);
            }
            if (lane == 0) {
                s_stat[0] = m0; s_stat[1] = m1; s_stat[2] = m2;
                s_stat[3] = 1.f / d0;
                s_stat[4] = (H > 1) ? 1.f / d1 : 0.f;
                s_stat[5] = (H > 2) ? 1.f / d2 : 0.f;
            }
        }
        __syncthreads();
        float m0 = s_stat[0], m1 = s_stat[1], m2 = s_stat[2];
        float i0 = s_stat[3], i1 = s_stat[4], i2 = s_stat[5];
        for (int base = s0; base < s1; base += TILE_E) {
            int cnt = s1 - base; if (cnt > TILE_E) cnt = TILE_E;
            __syncthreads();
            if (tid < cnt) {
                int e = eidx[base + tid], s = src[e];
                s_src[tid] = s;
                s_alpha[tid * 3 + 0] = expf(lrelu(el[s * H + 0] + er[n * H + 0]) - m0) * i0;
                if (H > 1) {
                    s_alpha[tid * 3 + 1] = expf(lrelu(el[s * H + 1] + er[n * H + 1]) - m1) * i1;
                    s_alpha[tid * 3 + 2] = expf(lrelu(el[s * H + 2] + er[n * H + 2]) - m2) * i2;
                }
            }
            __syncthreads();
            if (activeC) {
#pragma unroll 4
                for (int i = 0; i < cnt; ++i) {
                    float a = s_alpha[i * 3 + hh];
                    ushort4 hv = *(const ushort4*)&hb[(size_t)s_src[i] * HD + (tid << 2)];
                    acc.x += a * us2f(hv.x);
                    acc.y += a * us2f(hv.y);
                    acc.z += a * us2f(hv.z);
                    acc.w += a * us2f(hv.w);
                }
            }
        }
    }
    if (activeC) {
        acc.x = fmaxf(acc.x, 0.f); acc.y = fmaxf(acc.y, 0.f);
        acc.z = fmaxf(acc.z, 0.f); acc.w = fmaxf(acc.w, 0.f);
        out4[(size_t)n * HD4 + tid] = acc;
    }
}

// Graph max-readout (post-ReLU >=0) via int-bitcast atomicMax. grid.y = branch.
__global__ void seg_max_atomic(const float* __restrict__ g_all, const int* __restrict__ nid,
                               int* __restrict__ out_all, int N, int C,
                               size_t gBr, size_t oBr) {
    int br = blockIdx.y;
    const float* g = g_all + br * gBr;
    int* out = out_all + br * oBr;
    int n0 = blockIdx.x << 5;
    int n1 = n0 + 32; if (n1 > N) n1 = N;
    if (n0 >= N) return;
    for (int c = threadIdx.x; c < C; c += blockDim.x) {
        int cur = nid[n0];
        float m = 0.f;
        for (int n = n0; n < n1; ++n) {
            int gid = nid[n];
            if (gid != cur) {
                atomicMax(&out[cur * C + c], __float_as_int(m));
                cur = gid; m = 0.f;
            }
            m = fmaxf(m, g[(size_t)n * C + c]);
        }
        atomicMax(&out[cur * C + c], __float_as_int(m));
    }
}

// ---------------- small dense layers (grid.z = branch; strides may be 0) ----
__global__ void linear_wave(const float* __restrict__ in, const float* __restrict__ W,
                            const float* __restrict__ bias, float* __restrict__ out,
                            int K, int O, int act, size_t inBr, size_t outBr) {
    int o = blockIdx.x * 4 + (threadIdx.x >> 6);
    int b = blockIdx.y;
    int lane = threadIdx.x & 63;
    if (o >= O) return;
    const float* ip = in + blockIdx.z * inBr + (size_t)b * K;
    float acc = 0.f;
    for (int k = lane; k < K; k += 64)
        acc += ip[k] * W[(size_t)k * O + o];
    for (int off = 32; off > 0; off >>= 1)
        acc += __shfl_down(acc, off, 64);
    if (lane == 0) {
        acc += bias[o];
        if (act == 1) acc = fmaxf(acc, 0.f);
        else if (act == 2) acc = 1.f / (1.f + expf(-acc));
        out[blockIdx.z * outBr + (size_t)b * O + o] = acc;
    }
}

// ---------------- TextCNN (branch-fused) ----------------
__global__ void transpose_pad2(const float* __restrict__ pad0, const float* __restrict__ pad1,
                               float* __restrict__ xT, int B, int L, int C) {
    int idx = blockIdx.x * blockDim.x + threadIdx.x;
    int per = B * L * C;
    if (idx >= 2 * per) return;
    int br = idx >= per;
    int loc = idx - br * per;
    const float* pad = br ? pad1 : pad0;
    int l = loc % L;
    int c = (loc / L) % C;
    int b = loc / (L * C);
    xT[idx] = pad[((size_t)b * L + l) * C + c];
}

// ---------------- conv1d k=3 as MFMA (im2col on the fly) --------------------
__global__ __launch_bounds__(256) void conv_mfma(const float* __restrict__ x,
                                                 const short* __restrict__ w2,
                                                 const float* __restrict__ bias,
                                                 float* __restrict__ y,
                                                 int Cin, int Lin, int Lout,
                                                 size_t xBr, size_t yBr) {
    extern __shared__ __align__(16) char smem[];
    float* sx = (float*)smem;                          // Cin x 68 fp32
    short* sB = (short*)(smem + (size_t)Cin * 68 * 4); // 128 x 72 shorts
    int Kp = Cin * 3;
    int K2 = Kp * 2;
    int b = blockIdx.y;
    const float* xb = x + blockIdx.z * xBr + (size_t)b * Cin * Lin;
    float* yb = y + blockIdx.z * yBr + (size_t)b * 128 * Lout;
    int l0 = blockIdx.x << 6;
    int tid = threadIdx.x;
    int wave = tid >> 6, lane = tid & 63;
    int m = lane & 15, q = lane >> 4;
    int wrow = (wave & 1) << 5;
    int wcol = (wave >> 1) << 6;
    int loadL = Lin - l0; if (loadL > 66) loadL = 66;
    for (int idx = tid; idx < Cin * loadL; idx += 256) {
        int c = idx / loadL, i = idx - c * loadL;
        sx[c * 68 + i] = xb[(size_t)c * Lin + l0 + i];
    }
    floatx4 acc[2][4];
#pragma unroll
    for (int rt = 0; rt < 2; ++rt)
#pragma unroll
        for (int ct = 0; ct < 4; ++ct) acc[rt][ct] = (floatx4){0.f, 0.f, 0.f, 0.f};

    for (int k0 = 0; k0 < Kp; k0 += 32) {
#pragma unroll
        for (int p = 0; p < 4; ++p) {
            int t = tid + (p << 8);
            int o = t >> 3, slot = t & 7;
            int srcoff = k0 + ((slot & 3) << 3) + ((slot >= 4) ? Kp : 0);
            *(float4*)&sB[o * 72 + (slot << 3)] = *(const float4*)&w2[(size_t)o * K2 + srcoff];
        }
        __syncthreads();
        short8 a_hi[2], a_lo[2];
#pragma unroll
        for (int rt = 0; rt < 2; ++rt) {
            int pos = wrow + rt * 16 + m;
#pragma unroll
            for (int kk = 0; kk < 8; ++kk) {
                int k = k0 + q * 8 + kk;
                int c = k / 3, j = k - c * 3;
                float v = sx[c * 68 + pos + j];
                short hv = f2bf(v);
                a_hi[rt][kk] = hv;
                a_lo[rt][kk] = f2bf(v - bf2f(hv));
            }
        }
#pragma unroll
        for (int ct = 0; ct < 4; ++ct) {
            short8 b_hi = *(const short8*)&sB[(wcol + ct * 16 + m) * 72 + q * 8];
            short8 b_lo = *(const short8*)&sB[(wcol + ct * 16 + m) * 72 + 32 + q * 8];
#pragma unroll
            for (int rt = 0; rt < 2; ++rt) {
                acc[rt][ct] = __builtin_amdgcn_mfma_f32_16x16x32_bf16(a_hi[rt], b_hi, acc[rt][ct], 0, 0, 0);
                acc[rt][ct] = __builtin_amdgcn_mfma_f32_16x16x32_bf16(a_lo[rt], b_hi, acc[rt][ct], 0, 0, 0);
                acc[rt][ct] = __builtin_amdgcn_mfma_f32_16x16x32_bf16(a_hi[rt], b_lo, acc[rt][ct], 0, 0, 0);
            }
        }
        __syncthreads();
    }
#pragma unroll
    for (int ct = 0; ct < 4; ++ct) {
        int o = wcol + ct * 16 + m;
        float bv = bias[o];
#pragma unroll
        for (int rt = 0; rt < 2; ++rt)
#pragma unroll
            for (int r = 0; r < 4; ++r) {
                int pos = wrow + rt * 16 + q * 4 + r;
                if (l0 + pos < Lout)
                    yb[(size_t)o * Lout + l0 + pos] = acc[rt][ct][r] + bv;
            }
    }
}

__global__ void maxpool(const float* __restrict__ y, float* __restrict__ p,
                        int BC, int Lin, int k, int s, int Lout) {
    int idx = blockIdx.x * blockDim.x + threadIdx.x;
    if (idx >= BC * Lout) return;
    int lo = idx % Lout, bc = idx / Lout;
    const float* yp = y + (size_t)bc * Lin + lo * s;
    float m = -INFINITY;
    for (int i = 0; i < k; ++i) m = fmaxf(m, yp[i]);
    p[idx] = m;
}

// cat[b, br*128 + c] over both branches in one launch (gvec/sf are [2][B*128])
__global__ void combine_branch2(const float* __restrict__ g, const float* __restrict__ s,
                                const float* __restrict__ w1, float* __restrict__ cat, int B) {
    int idx = blockIdx.x * blockDim.x + threadIdx.x;
    int per = B * 128;
    if (idx >= 2 * per) return;
    int br = idx >= per;
    int loc = idx - br * per;
    int b = loc >> 7, c = loc & 127;
    float w = 1.f / (1.f + expf(-w1[0]));
    cat[b * 256 + br * 128 + c] = (1.f - w) * g[idx] + w * s[idx];
}

// ---------------- host ----------------
extern "C" void kernel_launch(void* const* d_in, const int* in_sizes, int n_in,
                              void* d_out, int out_size, void* d_ws, size_t ws_size,
                              hipStream_t stream) {
    const float* feat[2] = {(const float*)d_in[0], (const float*)d_in[1]};
    const float* pad[2]  = {(const float*)d_in[2], (const float*)d_in[3]};
    const int* src[2]    = {(const int*)d_in[4], (const int*)d_in[6]};
    const int* dst[2]    = {(const int*)d_in[5], (const int*)d_in[7]};
    const int* nid[2]    = {(const int*)d_in[8], (const int*)d_in[9]};
    const float* Wg[3]   = {(const float*)d_in[11], (const float*)d_in[14], (const float*)d_in[17]};
    const float* al[3]   = {(const float*)d_in[12], (const float*)d_in[15], (const float*)d_in[18]};
    const float* ar[3]   = {(const float*)d_in[13], (const float*)d_in[16], (const float*)d_in[19]};
    const float* fcg_w = (const float*)d_in[20]; const float* fcg_b = (const float*)d_in[21];
    const float* c1w = (const float*)d_in[22];   const float* c1b = (const float*)d_in[23];
    const float* c2w = (const float*)d_in[24];   const float* c2b = (const float*)d_in[25];
    const float* c3w = (const float*)d_in[26];   const float* c3b = (const float*)d_in[27];
    const float* tf_w = (const float*)d_in[28];  const float* tf_b = (const float*)d_in[29];
    const float* w1 = (const float*)d_in[30];
    const float* fc1_w = (const float*)d_in[31]; const float* fc1_b = (const float*)d_in[32];
    const float* fc2_w = (const float*)d_in[33]; const float* fc2_b = (const float*)d_in[34];
    const float* outw = (const float*)d_in[35];  const float* outb = (const float*)d_in[36];
    float* out = (float*)d_out;

    const int N = in_sizes[0] / 64;   // 8000
    const int E = in_sizes[4];        // 160000
    const int B = 16, L = 1200;
    const size_t NS = (size_t)N * 576;

    char* wsb = (char*)d_ws;
    size_t off = 0;
    auto allocB = [&](size_t bytes) -> void* {
        void* p = wsb + off;
        off += (bytes + 255) & ~(size_t)255;
        return p;
    };
    auto alloc = [&](size_t elems) -> void* { return allocB(elems * 4); };

    unsigned short* h_bf = (unsigned short*)allocB(2 * NS * 2);   // h in bf16 only
    float* gA    = (float*)alloc(2 * NS);
    float* el    = (float*)alloc(2 * (size_t)N * 3);
    float* er    = (float*)alloc(2 * (size_t)N * 3);
    int* rs      = (int*)alloc(2 * (N + 1));
    int* cnt     = (int*)alloc(2 * N);
    int* eidx    = (int*)alloc(2 * E);
    int* gmax    = (int*)alloc(2 * (size_t)B * 576);
    float* gvec  = (float*)alloc(2 * (size_t)B * 128);
    float* sp    = (float*)alloc(2 * (size_t)B * 128);
    float* sf    = (float*)alloc(2 * (size_t)B * 128);
    float* cat   = (float*)alloc((size_t)B * 256);
    float* f1    = (float*)alloc((size_t)B * 512);
    float* f2    = (float*)alloc((size_t)B * 256);
    short* w2t1  = (short*)allocB((size_t)192 * 2 * 64 * 2);
    short* w2t2  = (short*)allocB((size_t)576 * 2 * 192 * 2);
    short* w2t3  = (short*)allocB((size_t)576 * 2 * 576 * 2);
    short* cw1   = (short*)allocB((size_t)128 * 2 * 192 * 2);
    short* cw2   = (short*)allocB((size_t)128 * 2 * 384 * 2);
    short* cw3   = (short*)allocB((size_t)128 * 2 * 384 * 2);
    size_t tcnn_elems = 2 * ((size_t)B * 64 * L + (size_t)B * 128 * (1198 + 399 + 397 + 132 + 130));
    size_t uni_elems = 2 * NS > tcnn_elems ? 2 * NS : tcnn_elems;
    float* uni = (float*)alloc(uni_elems);
    float* gB = uni;
    float* xT = uni;
    float* y1 = xT + 2 * (size_t)B * 64 * L;
    float* p1 = y1 + 2 * (size_t)B * 128 * 1198;
    float* y2 = p1 + 2 * (size_t)B * 128 * 399;
    float* p2 = y2 + 2 * (size_t)B * 128 * 397;
    float* y3 = p2 + 2 * (size_t)B * 128 * 132;
    (void)ws_size; (void)n_in; (void)out_size;

    // all 6 weight splits in one dispatch (577536 elements)
    prep_weights<<<2256, 256, 0, stream>>>(Wg[0], Wg[1], Wg[2], c1w, c2w, c3w,
                                           w2t1, w2t2, w2t3, cw1, cw2, cw3);
    short* w2t[3] = {w2t1, w2t2, w2t3};

    // --- CSR for both branches ---
    zero_i32<<<(2 * N + 255) / 256, 256, 0, stream>>>(cnt, 2 * N);
    count_edges2<<<(2 * E + 255) / 256, 256, 0, stream>>>(dst[0], dst[1], cnt, N, E);
    scan_block<<<2, 1024, 0, stream>>>(cnt, rs, N);
    zero_i32<<<(2 * N + 255) / 256, 256, 0, stream>>>(cnt, 2 * N);
    scatter_edges2<<<(2 * E + 255) / 256, 256, 0, stream>>>(dst[0], dst[1], rs, cnt, eidx, N, E);

    // --- 3 GAT layers, both branches per dispatch ---
    const int dims[3][3] = {{64, 3, 64}, {192, 3, 192}, {576, 1, 576}};  // K,H,D
    float* outs[3] = {gA, gB, gA};
    const float* inp0 = feat[0];
    const float* inp1 = feat[1];
    for (int ly = 0; ly < 3; ++ly) {
        int K = dims[ly][0], H = dims[ly][1], D = dims[ly][2];
        int HD = H * D;
        gemm_bf3_v4<<<dim3(HD / 192, N / 64, 2), 256, 0, stream>>>(inp0, inp1, w2t[ly], h_bf,
                                                                   N, K, HD, NS);
        int waves2 = 2 * N * H;
        gat_elr<<<((size_t)waves2 * 64 + 255) / 256, 256, 0, stream>>>(h_bf, al[ly], ar[ly], el, er,
                                                                       N, H, D, NS, (size_t)N * 3);
        int aggThreads = (((HD >> 2) + 63) / 64) * 64;   // 64 for HD=192, 192 for HD=576
        gat_softagg<<<dim3(N, 2), aggThreads, 0, stream>>>(
            h_bf, el, er, src[0], src[1], rs, eidx, (float4*)outs[ly],
            N, H, D, E, NS, (size_t)N * 3, NS / 4);
        inp0 = outs[ly];
        inp1 = outs[ly] + NS;
    }
    zero_i32<<<(2 * B * 576 + 255) / 256, 256, 0, stream>>>(gmax, 2 * B * 576);
    seg_max_atomic<<<dim3((N + 31) / 32, 2), 256, 0, stream>>>(gA, nid[0], gmax, N, 576,
                                                               NS, (size_t)B * 576);
    linear_wave<<<dim3(32, B, 2), 256, 0, stream>>>((const float*)gmax, fcg_w, fcg_b, gvec,
                                                    576, 128, 1, (size_t)B * 576, (size_t)B * 128);

    // --- TextCNN (MFMA convs), both branches per dispatch ---
    transpose_pad2<<<((2 * B * 64 * L) + 255) / 256, 256, 0, stream>>>(pad[0], pad[1], xT, B, L, 64);
    conv_mfma<<<dim3(19, B, 2), 256, 64 * 68 * 4 + 128 * 72 * 2, stream>>>(
        xT, cw1, c1b, y1, 64, 1200, 1198, (size_t)B * 64 * L, (size_t)B * 128 * 1198);
    maxpool<<<(2 * B * 128 * 399 + 255) / 256, 256, 0, stream>>>(y1, p1, 2 * B * 128, 1198, 3, 3, 399);
    conv_mfma<<<dim3(7, B, 2), 256, 128 * 68 * 4 + 128 * 72 * 2, stream>>>(
        p1, cw2, c2b, y2, 128, 399, 397, (size_t)B * 128 * 399, (size_t)B * 128 * 397);
    maxpool<<<(2 * B * 128 * 132 + 255) / 256, 256, 0, stream>>>(y2, p2, 2 * B * 128, 397, 3, 3, 132);
    conv_mfma<<<dim3(3, B, 2), 256, 128 * 68 * 4 + 128 * 72 * 2, stream>>>(
        p2, cw3, c3b, y3, 128, 132, 130, (size_t)B * 128 * 132, (size_t)B * 128 * 130);
    maxpool<<<(2 * B * 128 + 255) / 256, 256, 0, stream>>>(y3, sp, 2 * B * 128, 130, 130, 1, 1);
    linear_wave<<<dim3(32, B, 2), 256, 0, stream>>>(sp, tf_w, tf_b, sf, 128, 128, 1,
                                                    (size_t)B * 128, (size_t)B * 128);
    combine_branch2<<<(2 * B * 128 + 255) / 256, 256, 0, stream>>>(gvec, sf, w1, cat, B);

    // --- head MLP ---
    linear_wave<<<dim3(128, B, 1), 256, 0, stream>>>(cat, fc1_w, fc1_b, f1, 256, 512, 1, 0, 0);
    linear_wave<<<dim3(64, B, 1), 256, 0, stream>>>(f1, fc2_w, fc2_b, f2, 512, 256, 1, 0, 0);
    linear_wave<<<dim3(1, B, 1), 256, 0, stream>>>(f2, outw, outb, out, 256, 1, 2, 0, 0);
}

// Round 15
// 585.774 us; speedup vs baseline: 5.6339x; 1.0108x over previous
//
#include <hip/hip_runtime.h>
#include <hip/hip_bf16.h>
#include <math.h>

#define NEG_SLOPE 0.2f

// ---------------- utility ----------------
__global__ void zero_i32(int* __restrict__ p, int n) {
    int i = blockIdx.x * blockDim.x + threadIdx.x;
    if (i < n) p[i] = 0;
}

// ---------------- CSR build (both branches in one dispatch) ----------------
__global__ void count_edges2(const int* __restrict__ dst0, const int* __restrict__ dst1,
                             int* __restrict__ cnt, int N, int E) {
    int i = blockIdx.x * blockDim.x + threadIdx.x;
    if (i >= 2 * E) return;
    int br = i >= E;
    int j = i - br * E;
    const int* d = br ? dst1 : dst0;
    atomicAdd(&cnt[br * N + d[j]], 1);
}

// scan + zero cnt in place (cnt reused as fill[] by scatter afterwards)
__global__ void scan_block(int* __restrict__ cnt_all, int* __restrict__ rs_all, int N) {
    __shared__ int s[1024];
    int br = blockIdx.x;
    int* cnt = cnt_all + br * N;
    int* rs = rs_all + br * (N + 1);
    int tid = threadIdx.x;
    int running = 0;
    for (int base = 0; base < N; base += 1024) {
        int v = (base + tid < N) ? cnt[base + tid] : 0;
        if (base + tid < N) cnt[base + tid] = 0;
        __syncthreads();
        s[tid] = v;
        __syncthreads();
        for (int off = 1; off < 1024; off <<= 1) {
            int t = (tid >= off) ? s[tid - off] : 0;
            __syncthreads();
            if (tid >= off) s[tid] += t;
            __syncthreads();
        }
        if (base + tid < N) rs[base + tid] = running + s[tid] - v;
        running += s[1023];
    }
    if (tid == 0) rs[N] = running;
}

__global__ void scatter_edges2(const int* __restrict__ dst0, const int* __restrict__ dst1,
                               const int* __restrict__ rs_all, int* __restrict__ fill_all,
                               int* __restrict__ eidx_all, int N, int E) {
    int i = blockIdx.x * blockDim.x + threadIdx.x;
    if (i >= 2 * E) return;
    int br = i >= E;
    int j = i - br * E;
    const int* d = br ? dst1 : dst0;
    int dd = d[j];
    int pos = atomicAdd(&fill_all[br * N + dd], 1);
    eidx_all[br * E + rs_all[br * (N + 1) + dd] + pos] = j;
}

// ---------------- bf16 hi/lo helpers ----------------
__device__ __forceinline__ short f2bf(float x) {
    __hip_bfloat16 h = __float2bfloat16(x);
    return *reinterpret_cast<short*>(&h);
}
__device__ __forceinline__ float bf2f(short s) {
    unsigned int u = ((unsigned int)(unsigned short)s) << 16;
    return __uint_as_float(u);
}
__device__ __forceinline__ float us2f(unsigned short s) {
    return __uint_as_float((unsigned int)s << 16);
}

// ---------------- merged weight prep (all 6 splits, one dispatch) -----------
__device__ __forceinline__ void split_w_elem(const float* W, short* W2t, int K, int N, int idx) {
    int k = idx / N, n = idx - k * N;
    float x = W[idx];
    short hs = f2bf(x);
    short ls = f2bf(x - bf2f(hs));
    size_t base = (size_t)n * 2 * K;
    W2t[base + k] = hs;
    W2t[base + K + k] = ls;
}
__device__ __forceinline__ void split_cw_elem(const float* w, short* w2, int Kp, int idx) {
    int o = idx / Kp, k = idx - o * Kp;
    float x = w[idx];
    short hs = f2bf(x);
    short ls = f2bf(x - bf2f(hs));
    size_t base = (size_t)o * 2 * Kp;
    w2[base + k] = hs;
    w2[base + Kp + k] = ls;
}
__global__ void prep_weights(const float* __restrict__ Wg1, const float* __restrict__ Wg2,
                             const float* __restrict__ Wg3, const float* __restrict__ c1w,
                             const float* __restrict__ c2w, const float* __restrict__ c3w,
                             short* __restrict__ w2t1, short* __restrict__ w2t2,
                             short* __restrict__ w2t3, short* __restrict__ cw1,
                             short* __restrict__ cw2, short* __restrict__ cw3) {
    int idx = blockIdx.x * blockDim.x + threadIdx.x;
    if (idx < 12288)       split_w_elem(Wg1, w2t1, 64, 192, idx);
    else if (idx < 122880) split_w_elem(Wg2, w2t2, 192, 576, idx - 12288);
    else if (idx < 454656) split_w_elem(Wg3, w2t3, 576, 576, idx - 122880);
    else if (idx < 479232) split_cw_elem(c1w, cw1, 192, idx - 454656);
    else if (idx < 528384) split_cw_elem(c2w, cw2, 384, idx - 479232);
    else if (idx < 577536) split_cw_elem(c3w, cw3, 384, idx - 528384);
}

// ---------------- MFMA bf16-split GEMM v4 (bf16-only output) ----------------
typedef __attribute__((ext_vector_type(8))) short short8;
typedef __attribute__((ext_vector_type(4))) short short4v;
typedef __attribute__((ext_vector_type(4))) float floatx4;

__global__ __launch_bounds__(256) void gemm_bf3_v4(const float* __restrict__ A0,
                                                   const float* __restrict__ A1,
                                                   const short* __restrict__ Bt,
                                                   unsigned short* __restrict__ Cbf,
                                                   int M, int K, int N, size_t cBrStride) {
    __shared__ __align__(16) short sA[64 * 72];   // rows: [Ah(32) | Al(32) | pad8]
    __shared__ __align__(16) short sB[192 * 72];  // rows: [Wh(32) | Wl(32) | pad8]
    int tid = threadIdx.x;
    int wave = tid >> 6, lane = tid & 63;
    int m = lane & 15, q = lane >> 4;
    int row0 = blockIdx.y << 6;
    int col0 = blockIdx.x * 192;
    const float* A = blockIdx.z ? A1 : A0;
    unsigned short* Cbfb = Cbf + blockIdx.z * cBrStride;
    int K2 = K * 2;
    floatx4 acc[4][3];
#pragma unroll
    for (int rt = 0; rt < 4; ++rt)
#pragma unroll
        for (int ct = 0; ct < 3; ++ct) acc[rt][ct] = (floatx4){0.f, 0.f, 0.f, 0.f};

    for (int k0 = 0; k0 < K; k0 += 32) {
#pragma unroll
        for (int p = 0; p < 2; ++p) {
            int t = tid + (p << 8);
            int r = t >> 3, c = (t & 7) << 2;
            float4 av = *(const float4*)&A[(size_t)(row0 + r) * K + k0 + c];
            short4v hs, ls;
            hs[0] = f2bf(av.x); ls[0] = f2bf(av.x - bf2f(hs[0]));
            hs[1] = f2bf(av.y); ls[1] = f2bf(av.y - bf2f(hs[1]));
            hs[2] = f2bf(av.z); ls[2] = f2bf(av.z - bf2f(hs[2]));
            hs[3] = f2bf(av.w); ls[3] = f2bf(av.w - bf2f(hs[3]));
            *(short4v*)&sA[r * 72 + c] = hs;
            *(short4v*)&sA[r * 72 + 32 + c] = ls;
        }
#pragma unroll
        for (int p = 0; p < 6; ++p) {
            int t = tid + (p << 8);
            int n = t >> 3, sub = t & 7;
            int srcoff = k0 + (sub << 3) + ((sub >= 4) ? (K - 32) : 0);
            *(float4*)&sB[n * 72 + (sub << 3)] =
                *(const float4*)&Bt[(size_t)(col0 + n) * K2 + srcoff];
        }
        __syncthreads();
        short8 a_hi[4], a_lo[4];
#pragma unroll
        for (int rt = 0; rt < 4; ++rt) {
            a_hi[rt] = *(const short8*)&sA[(rt * 16 + m) * 72 + q * 8];
            a_lo[rt] = *(const short8*)&sA[(rt * 16 + m) * 72 + 32 + q * 8];
        }
#pragma unroll
        for (int ct = 0; ct < 3; ++ct) {
            short8 b_hi = *(const short8*)&sB[(wave * 48 + ct * 16 + m) * 72 + q * 8];
            short8 b_lo = *(const short8*)&sB[(wave * 48 + ct * 16 + m) * 72 + 32 + q * 8];
#pragma unroll
            for (int rt = 0; rt < 4; ++rt) {
                acc[rt][ct] = __builtin_amdgcn_mfma_f32_16x16x32_bf16(a_hi[rt], b_hi, acc[rt][ct], 0, 0, 0);
                acc[rt][ct] = __builtin_amdgcn_mfma_f32_16x16x32_bf16(a_lo[rt], b_hi, acc[rt][ct], 0, 0, 0);
                acc[rt][ct] = __builtin_amdgcn_mfma_f32_16x16x32_bf16(a_hi[rt], b_lo, acc[rt][ct], 0, 0, 0);
            }
        }
        __syncthreads();
    }
#pragma unroll
    for (int rt = 0; rt < 4; ++rt)
#pragma unroll
        for (int ct = 0; ct < 3; ++ct)
#pragma unroll
            for (int r = 0; r < 4; ++r) {
                size_t idx = (size_t)(row0 + rt * 16 + q * 4 + r) * N + col0 + wave * 48 + ct * 16 + m;
                Cbfb[idx] = (unsigned short)f2bf(acc[rt][ct][r]);
            }
}

// ---------------- GAT pieces (branch-fused; h in bf16) ----------------
__global__ void gat_elr(const unsigned short* __restrict__ h, const float* __restrict__ al,
                        const float* __restrict__ ar, float* __restrict__ el,
                        float* __restrict__ er, int N, int H, int D,
                        size_t hBr, size_t eBr) {
    int wid = (blockIdx.x * blockDim.x + threadIdx.x) >> 6;
    int lane = threadIdx.x & 63;
    if (wid >= 2 * N * H) return;
    int br = wid / (N * H);
    int loc = wid - br * N * H;
    int n = loc / H, hh = loc - n * H;
    const unsigned short* hp = h + br * hBr + ((size_t)n * H + hh) * D;
    const float* alp = al + (size_t)hh * D;
    const float* arp = ar + (size_t)hh * D;
    float sl = 0.f, sr = 0.f;
    for (int d = lane; d < D; d += 64) {
        float v = us2f(hp[d]);
        sl += v * alp[d];
        sr += v * arp[d];
    }
    for (int off = 32; off > 0; off >>= 1) {
        sl += __shfl_down(sl, off, 64);
        sr += __shfl_down(sr, off, 64);
    }
    if (lane == 0) { el[br * eBr + loc] = sl; er[br * eBr + loc] = sr; }
}

__device__ __forceinline__ float lrelu(float v) {
    return (v > 0.f) ? v : NEG_SLOPE * v;
}

// ---------------- fused softmax + aggregate (block per node) ----------------
// Wave 0 computes edge softmax into LDS; all waves aggregate bf16 h rows
// with DUAL accumulators (even/odd edges) to break the FMA dependency chain.
#define TILE_E 64
__global__ void gat_softagg(const unsigned short* __restrict__ hb_all,
                            const float* __restrict__ el_all, const float* __restrict__ er_all,
                            const int* __restrict__ src0, const int* __restrict__ src1,
                            const int* __restrict__ rs_all, const int* __restrict__ eidx_all,
                            float4* __restrict__ out4_all, int N, int H, int D, int E,
                            size_t hBr, size_t eBr, size_t o4Br) {
    __shared__ int s_src[TILE_E];
    __shared__ float s_alpha[TILE_E * 3];
    __shared__ float s_stat[6];
    int n = blockIdx.x;
    int br = blockIdx.y;
    const int* src = br ? src1 : src0;
    const int* rs = rs_all + br * (N + 1);
    const int* eidx = eidx_all + br * E;
    const unsigned short* hb = hb_all + br * hBr;
    const float* el = el_all + br * eBr;
    const float* er = er_all + br * eBr;
    float4* out4 = out4_all + br * o4Br;
    int HD = H * D;
    int HD4 = HD >> 2;
    int tid = threadIdx.x;
    int s0 = rs[n], s1 = rs[n + 1];
    int deg = s1 - s0;
    bool activeC = tid < HD4;
    int hh = activeC ? (tid << 2) / D : 0;
    float4 accA = {0.f, 0.f, 0.f, 0.f};
    float4 accB = {0.f, 0.f, 0.f, 0.f};

    if (deg > 0 && deg <= 64) {
        if (tid < 64) {
            int lane = tid;
            float ern0 = er[n * H + 0];
            float ern1 = (H > 1) ? er[n * H + 1] : 0.f;
            float ern2 = (H > 2) ? er[n * H + 2] : 0.f;
            int s = 0;
            float v0 = -INFINITY, v1 = -INFINITY, v2 = -INFINITY;
            if (lane < deg) {
                int e = eidx[s0 + lane];
                s = src[e];
                v0 = lrelu(el[s * H + 0] + ern0);
                if (H > 1) {
                    v1 = lrelu(el[s * H + 1] + ern1);
                    v2 = lrelu(el[s * H + 2] + ern2);
                }
            }
            float m0 = v0, m1 = v1, m2 = v2;
#pragma unroll
            for (int off = 32; off > 0; off >>= 1) {
                m0 = fmaxf(m0, __shfl_xor(m0, off, 64));
                m1 = fmaxf(m1, __shfl_xor(m1, off, 64));
                m2 = fmaxf(m2, __shfl_xor(m2, off, 64));
            }
            float ex0 = (lane < deg) ? expf(v0 - m0) : 0.f;
            float ex1 = (lane < deg && H > 1) ? expf(v1 - m1) : 0.f;
            float ex2 = (lane < deg && H > 2) ? expf(v2 - m2) : 0.f;
            float d0 = ex0, d1 = ex1, d2 = ex2;
#pragma unroll
            for (int off = 32; off > 0; off >>= 1) {
                d0 += __shfl_xor(d0, off, 64);
                d1 += __shfl_xor(d1, off, 64);
                d2 += __shfl_xor(d2, off, 64);
            }
            if (lane < deg) {
                s_src[lane] = s;
                s_alpha[lane * 3 + 0] = ex0 / d0;
                if (H > 1) {
                    s_alpha[lane * 3 + 1] = ex1 / d1;
                    s_alpha[lane * 3 + 2] = ex2 / d2;
                }
            }
        }
        __syncthreads();
        if (activeC) {
            int i = 0;
#pragma unroll 4
            for (; i + 1 < deg; i += 2) {
                float a0 = s_alpha[i * 3 + hh];
                float a1 = s_alpha[(i + 1) * 3 + hh];
                ushort4 h0 = *(const ushort4*)&hb[(size_t)s_src[i] * HD + (tid << 2)];
                ushort4 h1 = *(const ushort4*)&hb[(size_t)s_src[i + 1] * HD + (tid << 2)];
                accA.x += a0 * us2f(h0.x); accA.y += a0 * us2f(h0.y);
                accA.z += a0 * us2f(h0.z); accA.w += a0 * us2f(h0.w);
                accB.x += a1 * us2f(h1.x); accB.y += a1 * us2f(h1.y);
                accB.z += a1 * us2f(h1.z); accB.w += a1 * us2f(h1.w);
            }
            if (i < deg) {
                float a0 = s_alpha[i * 3 + hh];
                ushort4 h0 = *(const ushort4*)&hb[(size_t)s_src[i] * HD + (tid << 2)];
                accA.x += a0 * us2f(h0.x); accA.y += a0 * us2f(h0.y);
                accA.z += a0 * us2f(h0.z); accA.w += a0 * us2f(h0.w);
            }
        }
    } else if (deg > 64) {
        if (tid < 64) {
            int lane = tid;
            float ern0 = er[n * H + 0];
            float ern1 = (H > 1) ? er[n * H + 1] : 0.f;
            float ern2 = (H > 2) ? er[n * H + 2] : 0.f;
            float m0 = -INFINITY, m1 = -INFINITY, m2 = -INFINITY;
            for (int j = s0 + lane; j < s1; j += 64) {
                int e = eidx[j], s = src[e];
                m0 = fmaxf(m0, lrelu(el[s * H + 0] + ern0));
                if (H > 1) {
                    m1 = fmaxf(m1, lrelu(el[s * H + 1] + ern1));
                    m2 = fmaxf(m2, lrelu(el[s * H + 2] + ern2));
                }
            }
#pragma unroll
            for (int off = 32; off > 0; off >>= 1) {
                m0 = fmaxf(m0, __shfl_xor(m0, off, 64));
                m1 = fmaxf(m1, __shfl_xor(m1, off, 64));
                m2 = fmaxf(m2, __shfl_xor(m2, off, 64));
            }
            float d0 = 0.f, d1 = 0.f, d2 = 0.f;
            for (int j = s0 + lane; j < s1; j += 64) {
                int e = eidx[j], s = src[e];
                d0 += expf(lrelu(el[s * H + 0] + ern0) - m0);
                if (H > 1) {
                    d1 += expf(lrelu(el[s * H + 1] + ern1) - m1);
                    d2 += expf(lrelu(el[s * H + 2] + ern2) - m2);
                }
            }
#pragma unroll
            for (int off = 32; off > 0; off >>= 1) {
                d0 += __shfl_xor(d0, off, 64);
                d1 += __shfl_xor(d1, off, 64);
                d2 += __shfl_xor(d2, off, 64);
            }
            if (lane == 0) {
                s_stat[0] = m0; s_stat[1] = m1; s_stat[2] = m2;
                s_stat[3] = 1.f / d0;
                s_stat[4] = (H > 1) ? 1.f / d1 : 0.f;
                s_stat[5] = (H > 2) ? 1.f / d2 : 0.f;
            }
        }
        __syncthreads();
        float m0 = s_stat[0], m1 = s_stat[1], m2 = s_stat[2];
        float i0 = s_stat[3], i1 = s_stat[4], i2 = s_stat[5];
        for (int base = s0; base < s1; base += TILE_E) {
            int cnt = s1 - base; if (cnt > TILE_E) cnt = TILE_E;
            __syncthreads();
            if (tid < cnt) {
                int e = eidx[base + tid], s = src[e];
                s_src[tid] = s;
                s_alpha[tid * 3 + 0] = expf(lrelu(el[s * H + 0] + er[n * H + 0]) - m0) * i0;
                if (H > 1) {
                    s_alpha[tid * 3 + 1] = expf(lrelu(el[s * H + 1] + er[n * H + 1]) - m1) * i1;
                    s_alpha[tid * 3 + 2] = expf(lrelu(el[s * H + 2] + er[n * H + 2]) - m2) * i2;
                }
            }
            __syncthreads();
            if (activeC) {
                int i = 0;
#pragma unroll 2
                for (; i + 1 < cnt; i += 2) {
                    float a0 = s_alpha[i * 3 + hh];
                    float a1 = s_alpha[(i + 1) * 3 + hh];
                    ushort4 h0 = *(const ushort4*)&hb[(size_t)s_src[i] * HD + (tid << 2)];
                    ushort4 h1 = *(const ushort4*)&hb[(size_t)s_src[i + 1] * HD + (tid << 2)];
                    accA.x += a0 * us2f(h0.x); accA.y += a0 * us2f(h0.y);
                    accA.z += a0 * us2f(h0.z); accA.w += a0 * us2f(h0.w);
                    accB.x += a1 * us2f(h1.x); accB.y += a1 * us2f(h1.y);
                    accB.z += a1 * us2f(h1.z); accB.w += a1 * us2f(h1.w);
                }
                if (i < cnt) {
                    float a0 = s_alpha[i * 3 + hh];
                    ushort4 h0 = *(const ushort4*)&hb[(size_t)s_src[i] * HD + (tid << 2)];
                    accA.x += a0 * us2f(h0.x); accA.y += a0 * us2f(h0.y);
                    accA.z += a0 * us2f(h0.z); accA.w += a0 * us2f(h0.w);
                }
            }
        }
    }
    if (activeC) {
        float4 acc;
        acc.x = fmaxf(accA.x + accB.x, 0.f);
        acc.y = fmaxf(accA.y + accB.y, 0.f);
        acc.z = fmaxf(accA.z + accB.z, 0.f);
        acc.w = fmaxf(accA.w + accB.w, 0.f);
        out4[(size_t)n * HD4 + tid] = acc;
    }
}

// Graph max-readout (post-ReLU >=0) via int-bitcast atomicMax. grid.y = branch.
__global__ void seg_max_atomic(const float* __restrict__ g_all, const int* __restrict__ nid,
                               int* __restrict__ out_all, int N, int C,
                               size_t gBr, size_t oBr) {
    int br = blockIdx.y;
    const float* g = g_all + br * gBr;
    int* out = out_all + br * oBr;
    int n0 = blockIdx.x << 5;
    int n1 = n0 + 32; if (n1 > N) n1 = N;
    if (n0 >= N) return;
    for (int c = threadIdx.x; c < C; c += blockDim.x) {
        int cur = nid[n0];
        float m = 0.f;
        for (int n = n0; n < n1; ++n) {
            int gid = nid[n];
            if (gid != cur) {
                atomicMax(&out[cur * C + c], __float_as_int(m));
                cur = gid; m = 0.f;
            }
            m = fmaxf(m, g[(size_t)n * C + c]);
        }
        atomicMax(&out[cur * C + c], __float_as_int(m));
    }
}

// ---------------- small dense layers (grid.z = branch; strides may be 0) ----
__global__ void linear_wave(const float* __restrict__ in, const float* __restrict__ W,
                            const float* __restrict__ bias, float* __restrict__ out,
                            int K, int O, int act, size_t inBr, size_t outBr) {
    int o = blockIdx.x * 4 + (threadIdx.x >> 6);
    int b = blockIdx.y;
    int lane = threadIdx.x & 63;
    if (o >= O) return;
    const float* ip = in + blockIdx.z * inBr + (size_t)b * K;
    float acc = 0.f;
    for (int k = lane; k < K; k += 64)
        acc += ip[k] * W[(size_t)k * O + o];
    for (int off = 32; off > 0; off >>= 1)
        acc += __shfl_down(acc, off, 64);
    if (lane == 0) {
        acc += bias[o];
        if (act == 1) acc = fmaxf(acc, 0.f);
        else if (act == 2) acc = 1.f / (1.f + expf(-acc));
        out[blockIdx.z * outBr + (size_t)b * O + o] = acc;
    }
}

// fc1 fused with the branch gate: in_k = (1-w)*gvec[br][b,c] + w*sf[br][b,c],
// br = k>>7, c = k&127, w = sigmoid(w1). K = 256 fixed.
__global__ void linear_cat(const float* __restrict__ gvec, const float* __restrict__ sf,
                           const float* __restrict__ w1, const float* __restrict__ W,
                           const float* __restrict__ bias, float* __restrict__ out,
                           int O, int B128) {
    int o = blockIdx.x * 4 + (threadIdx.x >> 6);
    int b = blockIdx.y;
    int lane = threadIdx.x & 63;
    if (o >= 512) return;
    float w = 1.f / (1.f + expf(-w1[0]));
    float acc = 0.f;
    for (int k = lane; k < 256; k += 64) {
        int br = k >> 7, c = k & 127;
        float v = (1.f - w) * gvec[br * B128 + b * 128 + c] + w * sf[br * B128 + b * 128 + c];
        acc += v * W[(size_t)k * 512 + o];
    }
    for (int off = 32; off > 0; off >>= 1)
        acc += __shfl_down(acc, off, 64);
    if (lane == 0)
        out[(size_t)b * 512 + o] = fmaxf(acc + bias[o], 0.f);
    (void)O;
}

// ---------------- TextCNN (branch-fused) ----------------
__global__ void transpose_pad2(const float* __restrict__ pad0, const float* __restrict__ pad1,
                               float* __restrict__ xT, int B, int L, int C) {
    int idx = blockIdx.x * blockDim.x + threadIdx.x;
    int per = B * L * C;
    if (idx >= 2 * per) return;
    int br = idx >= per;
    int loc = idx - br * per;
    const float* pad = br ? pad1 : pad0;
    int l = loc % L;
    int c = (loc / L) % C;
    int b = loc / (L * C);
    xT[idx] = pad[((size_t)b * L + l) * C + c];
}

// ---------------- conv1d k=3 as MFMA (im2col on the fly) --------------------
__global__ __launch_bounds__(256) void conv_mfma(const float* __restrict__ x,
                                                 const short* __restrict__ w2,
                                                 const float* __restrict__ bias,
                                                 float* __restrict__ y,
                                                 int Cin, int Lin, int Lout,
                                                 size_t xBr, size_t yBr) {
    extern __shared__ __align__(16) char smem[];
    float* sx = (float*)smem;                          // Cin x 68 fp32
    short* sB = (short*)(smem + (size_t)Cin * 68 * 4); // 128 x 72 shorts
    int Kp = Cin * 3;
    int K2 = Kp * 2;
    int b = blockIdx.y;
    const float* xb = x + blockIdx.z * xBr + (size_t)b * Cin * Lin;
    float* yb = y + blockIdx.z * yBr + (size_t)b * 128 * Lout;
    int l0 = blockIdx.x << 6;
    int tid = threadIdx.x;
    int wave = tid >> 6, lane = tid & 63;
    int m = lane & 15, q = lane >> 4;
    int wrow = (wave & 1) << 5;
    int wcol = (wave >> 1) << 6;
    int loadL = Lin - l0; if (loadL > 66) loadL = 66;
    for (int idx = tid; idx < Cin * loadL; idx += 256) {
        int c = idx / loadL, i = idx - c * loadL;
        sx[c * 68 + i] = xb[(size_t)c * Lin + l0 + i];
    }
    floatx4 acc[2][4];
#pragma unroll
    for (int rt = 0; rt < 2; ++rt)
#pragma unroll
        for (int ct = 0; ct < 4; ++ct) acc[rt][ct] = (floatx4){0.f, 0.f, 0.f, 0.f};

    for (int k0 = 0; k0 < Kp; k0 += 32) {
#pragma unroll
        for (int p = 0; p < 4; ++p) {
            int t = tid + (p << 8);
            int o = t >> 3, slot = t & 7;
            int srcoff = k0 + ((slot & 3) << 3) + ((slot >= 4) ? Kp : 0);
            *(float4*)&sB[o * 72 + (slot << 3)] = *(const float4*)&w2[(size_t)o * K2 + srcoff];
        }
        __syncthreads();
        short8 a_hi[2], a_lo[2];
#pragma unroll
        for (int rt = 0; rt < 2; ++rt) {
            int pos = wrow + rt * 16 + m;
#pragma unroll
            for (int kk = 0; kk < 8; ++kk) {
                int k = k0 + q * 8 + kk;
                int c = k / 3, j = k - c * 3;
                float v = sx[c * 68 + pos + j];
                short hv = f2bf(v);
                a_hi[rt][kk] = hv;
                a_lo[rt][kk] = f2bf(v - bf2f(hv));
            }
        }
#pragma unroll
        for (int ct = 0; ct < 4; ++ct) {
            short8 b_hi = *(const short8*)&sB[(wcol + ct * 16 + m) * 72 + q * 8];
            short8 b_lo = *(const short8*)&sB[(wcol + ct * 16 + m) * 72 + 32 + q * 8];
#pragma unroll
            for (int rt = 0; rt < 2; ++rt) {
                acc[rt][ct] = __builtin_amdgcn_mfma_f32_16x16x32_bf16(a_hi[rt], b_hi, acc[rt][ct], 0, 0, 0);
                acc[rt][ct] = __builtin_amdgcn_mfma_f32_16x16x32_bf16(a_lo[rt], b_hi, acc[rt][ct], 0, 0, 0);
                acc[rt][ct] = __builtin_amdgcn_mfma_f32_16x16x32_bf16(a_hi[rt], b_lo, acc[rt][ct], 0, 0, 0);
            }
        }
        __syncthreads();
    }
#pragma unroll
    for (int ct = 0; ct < 4; ++ct) {
        int o = wcol + ct * 16 + m;
        float bv = bias[o];
#pragma unroll
        for (int rt = 0; rt < 2; ++rt)
#pragma unroll
            for (int r = 0; r < 4; ++r) {
                int pos = wrow + rt * 16 + q * 4 + r;
                if (l0 + pos < Lout)
                    yb[(size_t)o * Lout + l0 + pos] = acc[rt][ct][r] + bv;
            }
    }
}

__global__ void maxpool(const float* __restrict__ y, float* __restrict__ p,
                        int BC, int Lin, int k, int s, int Lout) {
    int idx = blockIdx.x * blockDim.x + threadIdx.x;
    if (idx >= BC * Lout) return;
    int lo = idx % Lout, bc = idx / Lout;
    const float* yp = y + (size_t)bc * Lin + lo * s;
    float m = -INFINITY;
    for (int i = 0; i < k; ++i) m = fmaxf(m, yp[i]);
    p[idx] = m;
}

// ---------------- host ----------------
extern "C" void kernel_launch(void* const* d_in, const int* in_sizes, int n_in,
                              void* d_out, int out_size, void* d_ws, size_t ws_size,
                              hipStream_t stream) {
    const float* feat[2] = {(const float*)d_in[0], (const float*)d_in[1]};
    const float* pad[2]  = {(const float*)d_in[2], (const float*)d_in[3]};
    const int* src[2]    = {(const int*)d_in[4], (const int*)d_in[6]};
    const int* dst[2]    = {(const int*)d_in[5], (const int*)d_in[7]};
    const int* nid[2]    = {(const int*)d_in[8], (const int*)d_in[9]};
    const float* Wg[3]   = {(const float*)d_in[11], (const float*)d_in[14], (const float*)d_in[17]};
    const float* al[3]   = {(const float*)d_in[12], (const float*)d_in[15], (const float*)d_in[18]};
    const float* ar[3]   = {(const float*)d_in[13], (const float*)d_in[16], (const float*)d_in[19]};
    const float* fcg_w = (const float*)d_in[20]; const float* fcg_b = (const float*)d_in[21];
    const float* c1w = (const float*)d_in[22];   const float* c1b = (const float*)d_in[23];
    const float* c2w = (const float*)d_in[24];   const float* c2b = (const float*)d_in[25];
    const float* c3w = (const float*)d_in[26];   const float* c3b = (const float*)d_in[27];
    const float* tf_w = (const float*)d_in[28];  const float* tf_b = (const float*)d_in[29];
    const float* w1 = (const float*)d_in[30];
    const float* fc1_w = (const float*)d_in[31]; const float* fc1_b = (const float*)d_in[32];
    const float* fc2_w = (const float*)d_in[33]; const float* fc2_b = (const float*)d_in[34];
    const float* outw = (const float*)d_in[35];  const float* outb = (const float*)d_in[36];
    float* out = (float*)d_out;

    const int N = in_sizes[0] / 64;   // 8000
    const int E = in_sizes[4];        // 160000
    const int B = 16, L = 1200;
    const size_t NS = (size_t)N * 576;

    char* wsb = (char*)d_ws;
    size_t off = 0;
    auto allocB = [&](size_t bytes) -> void* {
        void* p = wsb + off;
        off += (bytes + 255) & ~(size_t)255;
        return p;
    };
    auto alloc = [&](size_t elems) -> void* { return allocB(elems * 4); };

    unsigned short* h_bf = (unsigned short*)allocB(2 * NS * 2);   // h in bf16 only
    float* gA    = (float*)alloc(2 * NS);
    float* el    = (float*)alloc(2 * (size_t)N * 3);
    float* er    = (float*)alloc(2 * (size_t)N * 3);
    int* rs      = (int*)alloc(2 * (N + 1));
    int* cnt     = (int*)alloc(2 * N);
    int* eidx    = (int*)alloc(2 * E);
    int* gmax    = (int*)alloc(2 * (size_t)B * 576);
    float* gvec  = (float*)alloc(2 * (size_t)B * 128);
    float* sp    = (float*)alloc(2 * (size_t)B * 128);
    float* sf    = (float*)alloc(2 * (size_t)B * 128);
    float* f1    = (float*)alloc((size_t)B * 512);
    float* f2    = (float*)alloc((size_t)B * 256);
    short* w2t1  = (short*)allocB((size_t)192 * 2 * 64 * 2);
    short* w2t2  = (short*)allocB((size_t)576 * 2 * 192 * 2);
    short* w2t3  = (short*)allocB((size_t)576 * 2 * 576 * 2);
    short* cw1   = (short*)allocB((size_t)128 * 2 * 192 * 2);
    short* cw2   = (short*)allocB((size_t)128 * 2 * 384 * 2);
    short* cw3   = (short*)allocB((size_t)128 * 2 * 384 * 2);
    size_t tcnn_elems = 2 * ((size_t)B * 64 * L + (size_t)B * 128 * (1198 + 399 + 397 + 132 + 130));
    size_t uni_elems = 2 * NS > tcnn_elems ? 2 * NS : tcnn_elems;
    float* uni = (float*)alloc(uni_elems);
    float* gB = uni;
    float* xT = uni;
    float* y1 = xT + 2 * (size_t)B * 64 * L;
    float* p1 = y1 + 2 * (size_t)B * 128 * 1198;
    float* y2 = p1 + 2 * (size_t)B * 128 * 399;
    float* p2 = y2 + 2 * (size_t)B * 128 * 397;
    float* y3 = p2 + 2 * (size_t)B * 128 * 132;
    (void)ws_size; (void)n_in; (void)out_size;

    prep_weights<<<2256, 256, 0, stream>>>(Wg[0], Wg[1], Wg[2], c1w, c2w, c3w,
                                           w2t1, w2t2, w2t3, cw1, cw2, cw3);
    short* w2t[3] = {w2t1, w2t2, w2t3};

    // --- CSR for both branches (scan zeroes cnt for reuse as fill) ---
    zero_i32<<<(2 * N + 255) / 256, 256, 0, stream>>>(cnt, 2 * N);
    count_edges2<<<(2 * E + 255) / 256, 256, 0, stream>>>(dst[0], dst[1], cnt, N, E);
    scan_block<<<2, 1024, 0, stream>>>(cnt, rs, N);
    scatter_edges2<<<(2 * E + 255) / 256, 256, 0, stream>>>(dst[0], dst[1], rs, cnt, eidx, N, E);

    // --- 3 GAT layers, both branches per dispatch ---
    const int dims[3][3] = {{64, 3, 64}, {192, 3, 192}, {576, 1, 576}};  // K,H,D
    float* outs[3] = {gA, gB, gA};
    const float* inp0 = feat[0];
    const float* inp1 = feat[1];
    for (int ly = 0; ly < 3; ++ly) {
        int K = dims[ly][0], H = dims[ly][1], D = dims[ly][2];
        int HD = H * D;
        gemm_bf3_v4<<<dim3(HD / 192, N / 64, 2), 256, 0, stream>>>(inp0, inp1, w2t[ly], h_bf,
                                                                   N, K, HD, NS);
        int waves2 = 2 * N * H;
        gat_elr<<<((size_t)waves2 * 64 + 255) / 256, 256, 0, stream>>>(h_bf, al[ly], ar[ly], el, er,
                                                                       N, H, D, NS, (size_t)N * 3);
        int aggThreads = (((HD >> 2) + 63) / 64) * 64;   // 64 for HD=192, 192 for HD=576
        gat_softagg<<<dim3(N, 2), aggThreads, 0, stream>>>(
            h_bf, el, er, src[0], src[1], rs, eidx, (float4*)outs[ly],
            N, H, D, E, NS, (size_t)N * 3, NS / 4);
        inp0 = outs[ly];
        inp1 = outs[ly] + NS;
    }
    zero_i32<<<(2 * B * 576 + 255) / 256, 256, 0, stream>>>(gmax, 2 * B * 576);
    seg_max_atomic<<<dim3((N + 31) / 32, 2), 256, 0, stream>>>(gA, nid[0], gmax, N, 576,
                                                               NS, (size_t)B * 576);
    linear_wave<<<dim3(32, B, 2), 256, 0, stream>>>((const float*)gmax, fcg_w, fcg_b, gvec,
                                                    576, 128, 1, (size_t)B * 576, (size_t)B * 128);

    // --- TextCNN (MFMA convs), both branches per dispatch ---
    transpose_pad2<<<((2 * B * 64 * L) + 255) / 256, 256, 0, stream>>>(pad[0], pad[1], xT, B, L, 64);
    conv_mfma<<<dim3(19, B, 2), 256, 64 * 68 * 4 + 128 * 72 * 2, stream>>>(
        xT, cw1, c1b, y1, 64, 1200, 1198, (size_t)B * 64 * L, (size_t)B * 128 * 1198);
    maxpool<<<(2 * B * 128 * 399 + 255) / 256, 256, 0, stream>>>(y1, p1, 2 * B * 128, 1198, 3, 3, 399);
    conv_mfma<<<dim3(7, B, 2), 256, 128 * 68 * 4 + 128 * 72 * 2, stream>>>(
        p1, cw2, c2b, y2, 128, 399, 397, (size_t)B * 128 * 399, (size_t)B * 128 * 397);
    maxpool<<<(2 * B * 128 * 132 + 255) / 256, 256, 0, stream>>>(y2, p2, 2 * B * 128, 397, 3, 3, 132);
    conv_mfma<<<dim3(3, B, 2), 256, 128 * 68 * 4 + 128 * 72 * 2, stream>>>(
        p2, cw3, c3b, y3, 128, 132, 130, (size_t)B * 128 * 132, (size_t)B * 128 * 130);
    maxpool<<<(2 * B * 128 + 255) / 256, 256, 0, stream>>>(y3, sp, 2 * B * 128, 130, 130, 1, 1);
    linear_wave<<<dim3(32, B, 2), 256, 0, stream>>>(sp, tf_w, tf_b, sf, 128, 128, 1,
                                                    (size_t)B * 128, (size_t)B * 128);

    // --- head MLP (fc1 fused with branch gate) ---
    linear_cat<<<dim3(128, B, 1), 256, 0, stream>>>(gvec, sf, w1, fc1_w, fc1_b, f1, 512, B * 128);
    linear_wave<<<dim3(64, B, 1), 256, 0, stream>>>(f1, fc2_w, fc2_b, f2, 512, 256, 1, 0, 0);
    linear_wave<<<dim3(1, B, 1), 256, 0, stream>>>(f2, outw, outb, out, 256, 1, 2, 0, 0);
}